// Round 1
// baseline (3027.630 us; speedup 1.0000x reference)
//
#include <hip/hip_runtime.h>
#include <hip/hip_bf16.h>
#include <math.h>

#define DINL __device__ __forceinline__

namespace {
constexpr int Bn = 8, Cn = 3, Hn = 512, Wn = 512;
constexpr int HW  = Hn * Wn;        // 262144
constexpr int CHW = Cn * HW;        // 786432
constexpr float GEPS = 1e-5f;
constexpr float PIf  = 3.14159265358979323846f;

// workspace layout (bytes)
constexpr size_t OFF_RED = 0;                                   // 128 floats
constexpr size_t OFF_PHI = 512;                                 // 6291456 f32
constexpr size_t OFF_U   = OFF_PHI + (size_t)Bn * CHW * 4;      // 6291456 float2
constexpr size_t OFF_J   = OFF_U   + (size_t)Bn * CHW * 8;      // 6291456 f32
constexpr size_t OFF_D   = OFF_J   + (size_t)Bn * CHW * 4;      // 6291456 f32
constexpr size_t OFF_Y2  = OFF_D   + (size_t)Bn * CHW * 4;      // 8*32*HW bf16
// red float indices:
// 0..7 xsum, 8..15 xss, 16..39 zsum, 40..47 g1sum, 48..55 g1ss,
// 56..63 g2sum, 64..71 g2ss, 72..95 dsum, 96..119 aw
}

DINL float sigm(float a) { return 1.f / (1.f + __expf(-a)); }
DINL float siluf(float a) { return a / (1.f + __expf(-a)); }

DINL float blockReduceSum(float v) {   // blockDim.x == 256
    __shared__ float sm[4];
    int lane = threadIdx.x & 63, wid = threadIdx.x >> 6;
    #pragma unroll
    for (int o = 32; o > 0; o >>= 1) v += __shfl_down(v, o, 64);
    __syncthreads();
    if (lane == 0) sm[wid] = v;
    __syncthreads();
    if (wid == 0) {
        float r = (lane < 4) ? sm[lane] : 0.f;
        r += __shfl_down(r, 2, 64);
        r += __shfl_down(r, 1, 64);
        return r;                       // valid on thread 0
    }
    return 0.f;
}

__global__ void k_zero(float* __restrict__ red) { red[threadIdx.x] = 0.f; }

__global__ __launch_bounds__(256) void k_reduce_x(const float* __restrict__ x,
                                                  float* __restrict__ red) {
    int b = blockIdx.x >> 5, blk = blockIdx.x & 31;
    const float4* xv = (const float4*)(x + (size_t)b * CHW + (size_t)blk * (CHW / 32));
    float s = 0.f, ss = 0.f;
    for (int i = threadIdx.x; i < (CHW / 32) / 4; i += 256) {
        float4 v = xv[i];
        s  += v.x + v.y + v.z + v.w;
        ss += v.x * v.x + v.y * v.y + v.z * v.z + v.w * v.w;
    }
    float rs = blockReduceSum(s);
    float rss = blockReduceSum(ss);
    if (threadIdx.x == 0) { atomicAdd(&red[b], rs); atomicAdd(&red[8 + b], rss); }
}

// ---------------- phase head: xn -> 16ch silu -> phi ----------------
__global__ __launch_bounds__(256) void k_conv_ph(
    const float* __restrict__ x, const float* __restrict__ red,
    const float* __restrict__ ng, const float* __restrict__ nb,
    const float* __restrict__ w1, const float* __restrict__ b1,
    const float* __restrict__ w2, const float* __restrict__ b2,
    float* __restrict__ phi)
{
    const int tx0 = blockIdx.x * 16, ty0 = blockIdx.y * 16, b = blockIdx.z;
    __shared__ float xt[3][20][20];
    __shared__ float ht[16][18][18];
    const int t = threadIdx.x;
    const float mu = red[b] * (1.f / CHW);
    const float rs = rsqrtf(red[8 + b] * (1.f / CHW) - mu * mu + GEPS);
    float sc[3], sh[3];
    #pragma unroll
    for (int c = 0; c < 3; ++c) { sc[c] = rs * ng[c]; sh[c] = nb[c] - mu * rs * ng[c]; }
    for (int i = t; i < 1200; i += 256) {
        int c = i / 400, r = i - c * 400;
        int yy = r / 20, xx = r - yy * 20;
        int gy = ty0 - 2 + yy, gx = tx0 - 2 + xx;
        float v = 0.f;
        if ((unsigned)gy < (unsigned)Hn && (unsigned)gx < (unsigned)Wn)
            v = x[(size_t)b * CHW + (size_t)c * HW + (size_t)gy * Wn + gx] * sc[c] + sh[c];
        xt[c][yy][xx] = v;
    }
    __syncthreads();
    for (int i = t; i < 324; i += 256) {
        int hy = i / 18, hx = i - hy * 18;
        int gy = ty0 - 1 + hy, gx = tx0 - 1 + hx;
        bool inimg = (unsigned)gy < (unsigned)Hn && (unsigned)gx < (unsigned)Wn;
        float acc[16];
        #pragma unroll
        for (int o = 0; o < 16; ++o) acc[o] = b1[o];
        #pragma unroll
        for (int ci = 0; ci < 3; ++ci)
            #pragma unroll
            for (int ky = 0; ky < 3; ++ky)
                #pragma unroll
                for (int kx = 0; kx < 3; ++kx) {
                    float v = xt[ci][hy + ky][hx + kx];
                    #pragma unroll
                    for (int o = 0; o < 16; ++o)
                        acc[o] += v * w1[o * 27 + ci * 9 + ky * 3 + kx];
                }
        #pragma unroll
        for (int o = 0; o < 16; ++o) ht[o][hy][hx] = inimg ? siluf(acc[o]) : 0.f;
    }
    __syncthreads();
    int oy = t >> 4, ox = t & 15;
    float a0 = b2[0], a1 = b2[1], a2 = b2[2];
    #pragma unroll
    for (int ci = 0; ci < 16; ++ci)
        #pragma unroll
        for (int ky = 0; ky < 3; ++ky)
            #pragma unroll
            for (int kx = 0; kx < 3; ++kx) {
                float v = ht[ci][oy + ky][ox + kx];
                a0 += v * w2[0 * 144 + ci * 9 + ky * 3 + kx];
                a1 += v * w2[1 * 144 + ci * 9 + ky * 3 + kx];
                a2 += v * w2[2 * 144 + ci * 9 + ky * 3 + kx];
            }
    size_t p = (size_t)b * CHW + (size_t)(ty0 + oy) * Wn + tx0 + ox;
    phi[p]            = tanhf(a0) * PIf;
    phi[p + HW]       = tanhf(a1) * PIf;
    phi[p + 2 * HW]   = tanhf(a2) * PIf;
}

// ---------------- z head: xn -> 32ch silu -> z, reduced to z_sum ----------------
__global__ __launch_bounds__(256) void k_conv_z(
    const float* __restrict__ x, float* __restrict__ red,
    const float* __restrict__ ng, const float* __restrict__ nb,
    const float* __restrict__ w1, const float* __restrict__ b1,
    const float* __restrict__ w2, const float* __restrict__ b2)
{
    const int tx0 = blockIdx.x * 16, ty0 = blockIdx.y * 16, b = blockIdx.z;
    __shared__ float xt[3][20][20];
    __shared__ float ht[32][18][18];
    const int t = threadIdx.x;
    const float mu = red[b] * (1.f / CHW);
    const float rs = rsqrtf(red[8 + b] * (1.f / CHW) - mu * mu + GEPS);
    float sc[3], sh[3];
    #pragma unroll
    for (int c = 0; c < 3; ++c) { sc[c] = rs * ng[c]; sh[c] = nb[c] - mu * rs * ng[c]; }
    for (int i = t; i < 1200; i += 256) {
        int c = i / 400, r = i - c * 400;
        int yy = r / 20, xx = r - yy * 20;
        int gy = ty0 - 2 + yy, gx = tx0 - 2 + xx;
        float v = 0.f;
        if ((unsigned)gy < (unsigned)Hn && (unsigned)gx < (unsigned)Wn)
            v = x[(size_t)b * CHW + (size_t)c * HW + (size_t)gy * Wn + gx] * sc[c] + sh[c];
        xt[c][yy][xx] = v;
    }
    __syncthreads();
    for (int i = t; i < 324; i += 256) {
        int hy = i / 18, hx = i - hy * 18;
        int gy = ty0 - 1 + hy, gx = tx0 - 1 + hx;
        bool inimg = (unsigned)gy < (unsigned)Hn && (unsigned)gx < (unsigned)Wn;
        float acc[32];
        #pragma unroll
        for (int o = 0; o < 32; ++o) acc[o] = b1[o];
        #pragma unroll
        for (int ci = 0; ci < 3; ++ci)
            #pragma unroll
            for (int ky = 0; ky < 3; ++ky)
                #pragma unroll
                for (int kx = 0; kx < 3; ++kx) {
                    float v = xt[ci][hy + ky][hx + kx];
                    #pragma unroll
                    for (int o = 0; o < 32; ++o)
                        acc[o] += v * w1[o * 27 + ci * 9 + ky * 3 + kx];
                }
        #pragma unroll
        for (int o = 0; o < 32; ++o) ht[o][hy][hx] = inimg ? siluf(acc[o]) : 0.f;
    }
    __syncthreads();
    float z0, z1, z2;
    {
        int oy = t >> 4, ox = t & 15;
        float a0 = b2[0], a1 = b2[1], a2 = b2[2];
        #pragma unroll
        for (int ci = 0; ci < 32; ++ci)
            #pragma unroll
            for (int ky = 0; ky < 3; ++ky)
                #pragma unroll
                for (int kx = 0; kx < 3; ++kx) {
                    float v = ht[ci][oy + ky][ox + kx];
                    a0 += v * w2[0 * 288 + ci * 9 + ky * 3 + kx];
                    a1 += v * w2[1 * 288 + ci * 9 + ky * 3 + kx];
                    a2 += v * w2[2 * 288 + ci * 9 + ky * 3 + kx];
                }
        z0 = sigm(a0) * 0.3f; z1 = sigm(a1) * 0.3f; z2 = sigm(a2) * 0.3f;
    }
    float r0 = blockReduceSum(z0);
    float r1 = blockReduceSum(z1);
    float r2 = blockReduceSum(z2);
    if (t == 0) {
        atomicAdd(&red[16 + b * 3 + 0], r0);
        atomicAdd(&red[16 + b * 3 + 1], r1);
        atomicAdd(&red[16 + b * 3 + 2], r2);
    }
}

// ---------------- FFT: 512-pt radix-2 Stockham (self-sorting) ----------------
template<bool INV>
DINL float2* fft512_stages(float2* a, float2* b, const float2* tw, int t)
{
    float2* src = a; float2* dst = b;
    int s = 1;
    #pragma unroll
    for (int st = 0; st < 9; ++st) {
        int q = t & (s - 1);
        float2 u = src[t], v = src[t + 256];
        float2 w = tw[t - q];
        float wy = INV ? -w.y : w.y;
        float dx = u.x - v.x, dy = u.y - v.y;
        dst[2 * t - q]     = make_float2(u.x + v.x, u.y + v.y);
        dst[2 * t - q + s] = make_float2(dx * w.x - dy * wy, dx * wy + dy * w.x);
        float2* tmp = src; src = dst; dst = tmp;
        s <<= 1;
        __syncthreads();
    }
    return src;
}

__global__ __launch_bounds__(256) void k_fftA(
    const float* __restrict__ x, const float* __restrict__ phi, float2* __restrict__ U)
{
    __shared__ float2 bufA[512], bufB[512], tw[256];
    const int t = threadIdx.x;
    const size_t line = blockIdx.x;                // (b*3+c)*512 + h
    { float s, c; __sincosf(-2.f * PIf * (float)t * (1.f / 512.f), &s, &c); tw[t] = make_float2(c, s); }
    const float* xr = x + line * 512;
    const float* pr = phi + line * 512;
    #pragma unroll
    for (int i = t; i < 512; i += 256) {
        float s, c; __sincosf(pr[i], &s, &c);
        float xv = xr[i];
        bufA[i] = make_float2(xv * c, xv * s);
    }
    __syncthreads();
    float2* res = fft512_stages<false>(bufA, bufB, tw, t);
    float2* Ur = U + line * 512;
    #pragma unroll
    for (int i = t; i < 512; i += 256) Ur[i] = res[i];
}

__global__ __launch_bounds__(256) void k_transpose(float2* __restrict__ U)
{
    const int img = blockIdx.y;
    int rem = blockIdx.x, ti = 0;
    while (rem >= 16 - ti) { rem -= 16 - ti; ++ti; }
    const int tj = ti + rem;
    float2* Ub = U + (size_t)img * HW;
    __shared__ float2 ta[32][33];
    __shared__ float2 tb[32][33];
    const int t = threadIdx.x;
    const int cc = t & 31, r0 = t >> 5;
    const int ar = ti * 32, ac = tj * 32;
    #pragma unroll
    for (int k = 0; k < 4; ++k) {
        int r = r0 + k * 8;
        ta[r][cc] = Ub[(size_t)(ar + r) * 512 + ac + cc];
    }
    if (ti != tj) {
        #pragma unroll
        for (int k = 0; k < 4; ++k) {
            int r = r0 + k * 8;
            tb[r][cc] = Ub[(size_t)(ac + r) * 512 + ar + cc];
        }
    }
    __syncthreads();
    #pragma unroll
    for (int k = 0; k < 4; ++k) {
        int r = r0 + k * 8;
        Ub[(size_t)(ac + r) * 512 + ar + cc] = ta[cc][r];
    }
    if (ti != tj) {
        #pragma unroll
        for (int k = 0; k < 4; ++k) {
            int r = r0 + k * 8;
            Ub[(size_t)(ar + r) * 512 + ac + cc] = tb[cc][r];
        }
    }
}

// fused: fwd FFT along H + (1+g)*exp(i*kz*z_mean) + inv FFT along H (in transposed layout)
__global__ __launch_bounds__(256) void k_fftB(
    float2* __restrict__ U, const float* __restrict__ red, const float* __restrict__ fgain)
{
    __shared__ float2 bufA[512], bufB[512], tw[256];
    const int t = threadIdx.x;
    const int line = blockIdx.x;                   // (b*3+c)*512 + fw
    const int bc = line >> 9;
    const int fw = line & 511;
    const int c = bc % 3;
    { float s, cc2; __sincosf(-2.f * PIf * (float)t * (1.f / 512.f), &s, &cc2); tw[t] = make_float2(cc2, s); }
    float2* Ur = U + (size_t)line * 512;
    #pragma unroll
    for (int i = t; i < 512; i += 256) bufA[i] = Ur[i];
    __syncthreads();
    float2* res = fft512_stages<false>(bufA, bufB, tw, t);
    const float zm   = red[16 + bc] * (1.f / HW);
    const float gain = 1.f + fgain[c];
    const float lam  = (c == 0) ? 0.65f : (c == 1) ? 0.53f : 0.47f;
    const float il2  = 1.f / (lam * lam);
    const float fwv  = (float)(fw < 256 ? fw : fw - 512) * (1.f / 512.f);
    const float f2w  = fwv * fwv;
    #pragma unroll
    for (int i = t; i < 512; i += 256) {
        float fh = (float)(i < 256 ? i : i - 512) * (1.f / 512.f);
        float kz = 2.f * PIf * sqrtf(fmaxf(il2 - f2w - fh * fh, 0.f));
        float sn, cs; __sincosf(kz * zm, &sn, &cs);
        float2 v = res[i];
        res[i] = make_float2(gain * (v.x * cs - v.y * sn), gain * (v.x * sn + v.y * cs));
    }
    __syncthreads();
    float2* other = (res == (float2*)bufA) ? (float2*)bufB : (float2*)bufA;
    float2* res2 = fft512_stages<true>(res, other, tw, t);
    #pragma unroll
    for (int i = t; i < 512; i += 256) {
        float2 v = res2[i];
        Ur[i] = make_float2(v.x * (1.f / 512.f), v.y * (1.f / 512.f));
    }
}

// inverse FFT along W + |.| epilogue (phase factor exp(i*cp) drops out of |Uz|)
__global__ __launch_bounds__(256) void k_fftC(
    const float2* __restrict__ U, float* __restrict__ J)
{
    __shared__ float2 bufA[512], bufB[512], tw[256];
    const int t = threadIdx.x;
    const size_t line = blockIdx.x;
    { float s, c; __sincosf(-2.f * PIf * (float)t * (1.f / 512.f), &s, &c); tw[t] = make_float2(c, s); }
    const float2* Ur = U + line * 512;
    #pragma unroll
    for (int i = t; i < 512; i += 256) bufA[i] = Ur[i];
    __syncthreads();
    float2* res = fft512_stages<true>(bufA, bufB, tw, t);
    float* Jr = J + line * 512;
    #pragma unroll
    for (int i = t; i < 512; i += 256) {
        float2 v = res[i];
        float re = v.x * (1.f / 512.f), im = v.y * (1.f / 512.f);
        Jr[i] = sqrtf(fmaxf(re * re + im * im, 1e-12f));
    }
}

// ---------------- mix path ----------------
__global__ __launch_bounds__(256) void k_m1(
    const float* __restrict__ x, const float* __restrict__ Jb,
    const float* __restrict__ w1, const float* __restrict__ b1,
    float* __restrict__ red)
{
    const int tx0 = blockIdx.x * 16, ty0 = blockIdx.y * 16, b = blockIdx.z;
    __shared__ float mt[5][18][18];
    const int t = threadIdx.x;
    for (int i = t; i < 324; i += 256) {
        int yy = i / 18, xx = i - yy * 18;
        int gy = ty0 - 1 + yy, gx = tx0 - 1 + xx;
        float v0 = 0, v1 = 0, v2 = 0, jl = 0, d5 = 0;
        if ((unsigned)gy < (unsigned)Hn && (unsigned)gx < (unsigned)Wn) {
            size_t p = (size_t)b * CHW + (size_t)gy * Wn + gx;
            v0 = x[p]; v1 = x[p + HW]; v2 = x[p + 2 * HW];
            float j0 = Jb[p], j1 = Jb[p + HW], j2 = Jb[p + 2 * HW];
            float xl = 0.299f * v0 + 0.587f * v1 + 0.114f * v2;
            jl = 0.299f * j0 + 0.587f * j1 + 0.114f * j2;
            d5 = jl - xl;
        }
        mt[0][yy][xx] = v0; mt[1][yy][xx] = v1; mt[2][yy][xx] = v2;
        mt[3][yy][xx] = jl; mt[4][yy][xx] = d5;
    }
    __syncthreads();
    int oy = t >> 4, ox = t & 15;
    float acc[32];
    #pragma unroll
    for (int o = 0; o < 32; ++o) acc[o] = b1[o];
    #pragma unroll
    for (int ci = 0; ci < 5; ++ci)
        #pragma unroll
        for (int ky = 0; ky < 3; ++ky)
            #pragma unroll
            for (int kx = 0; kx < 3; ++kx) {
                float v = mt[ci][oy + ky][ox + kx];
                #pragma unroll
                for (int o = 0; o < 32; ++o)
                    acc[o] += v * w1[o * 45 + ci * 9 + ky * 3 + kx];
            }
    float s = 0.f, ss = 0.f;
    #pragma unroll
    for (int o = 0; o < 32; ++o) { s += acc[o]; ss += acc[o] * acc[o]; }
    float rs = blockReduceSum(s);
    float rss = blockReduceSum(ss);
    if (t == 0) { atomicAdd(&red[40 + b], rs); atomicAdd(&red[48 + b], rss); }
}

__global__ __launch_bounds__(256) void k_m2(
    const float* __restrict__ x, const float* __restrict__ Jb,
    const float* __restrict__ w1, const float* __restrict__ b1,
    const float* __restrict__ g1g, const float* __restrict__ g1b,
    const float* __restrict__ w2, const float* __restrict__ b2,
    float* __restrict__ red, __hip_bfloat16* __restrict__ y2)
{
    const int tx0 = blockIdx.x * 16, ty0 = blockIdx.y * 16, b = blockIdx.z;
    __shared__ float mt[5][20][20];
    __shared__ float dt[32][18][18];
    const int t = threadIdx.x;
    const float mu1 = red[40 + b] * (1.f / (32.f * HW));
    const float rs1 = rsqrtf(red[48 + b] * (1.f / (32.f * HW)) - mu1 * mu1 + GEPS);
    for (int i = t; i < 400; i += 256) {
        int yy = i / 20, xx = i - yy * 20;
        int gy = ty0 - 2 + yy, gx = tx0 - 2 + xx;
        float v0 = 0, v1 = 0, v2 = 0, jl = 0, d5 = 0;
        if ((unsigned)gy < (unsigned)Hn && (unsigned)gx < (unsigned)Wn) {
            size_t p = (size_t)b * CHW + (size_t)gy * Wn + gx;
            v0 = x[p]; v1 = x[p + HW]; v2 = x[p + 2 * HW];
            float j0 = Jb[p], j1 = Jb[p + HW], j2 = Jb[p + 2 * HW];
            float xl = 0.299f * v0 + 0.587f * v1 + 0.114f * v2;
            jl = 0.299f * j0 + 0.587f * j1 + 0.114f * j2;
            d5 = jl - xl;
        }
        mt[0][yy][xx] = v0; mt[1][yy][xx] = v1; mt[2][yy][xx] = v2;
        mt[3][yy][xx] = jl; mt[4][yy][xx] = d5;
    }
    __syncthreads();
    for (int i = t; i < 324; i += 256) {
        int hy = i / 18, hx = i - hy * 18;
        int gy = ty0 - 1 + hy, gx = tx0 - 1 + hx;
        bool inimg = (unsigned)gy < (unsigned)Hn && (unsigned)gx < (unsigned)Wn;
        float acc[32];
        #pragma unroll
        for (int o = 0; o < 32; ++o) acc[o] = b1[o];
        #pragma unroll
        for (int ci = 0; ci < 5; ++ci)
            #pragma unroll
            for (int ky = 0; ky < 3; ++ky)
                #pragma unroll
                for (int kx = 0; kx < 3; ++kx) {
                    float v = mt[ci][hy + ky][hx + kx];
                    #pragma unroll
                    for (int o = 0; o < 32; ++o)
                        acc[o] += v * w1[o * 45 + ci * 9 + ky * 3 + kx];
                }
        #pragma unroll
        for (int o = 0; o < 32; ++o) {
            float dn = (acc[o] - mu1) * rs1 * g1g[o] + g1b[o];
            dt[o][hy][hx] = inimg ? siluf(dn) : 0.f;
        }
    }
    __syncthreads();
    int oy = t >> 4, ox = t & 15;
    float acc2[32];
    #pragma unroll
    for (int o = 0; o < 32; ++o) acc2[o] = b2[o];
    for (int ci = 0; ci < 32; ++ci) {
        float v0 = dt[ci][oy][ox],     v1 = dt[ci][oy][ox + 1],     v2 = dt[ci][oy][ox + 2];
        float v3 = dt[ci][oy + 1][ox], v4 = dt[ci][oy + 1][ox + 1], v5 = dt[ci][oy + 1][ox + 2];
        float v6 = dt[ci][oy + 2][ox], v7 = dt[ci][oy + 2][ox + 1], v8 = dt[ci][oy + 2][ox + 2];
        const float* wp = w2 + ci * 9;
        #pragma unroll
        for (int o = 0; o < 32; ++o) {
            const float* wo = wp + o * 288;
            acc2[o] += v0 * wo[0] + v1 * wo[1] + v2 * wo[2] + v3 * wo[3] + v4 * wo[4]
                     + v5 * wo[5] + v6 * wo[6] + v7 * wo[7] + v8 * wo[8];
        }
    }
    size_t base = ((size_t)b * 32) * HW + (size_t)(ty0 + oy) * Wn + tx0 + ox;
    float s = 0.f, ss = 0.f;
    #pragma unroll
    for (int o = 0; o < 32; ++o) {
        float a = acc2[o];
        s += a; ss += a * a;
        y2[base + (size_t)o * HW] = __float2bfloat16(a);
    }
    float rsum = blockReduceSum(s);
    float rss = blockReduceSum(ss);
    if (t == 0) { atomicAdd(&red[56 + b], rsum); atomicAdd(&red[64 + b], rss); }
}

__global__ __launch_bounds__(256) void k_m3(
    const __hip_bfloat16* __restrict__ y2, float* __restrict__ red,
    const float* __restrict__ g2g, const float* __restrict__ g2b,
    const float* __restrict__ w3, const float* __restrict__ b3,
    float* __restrict__ dl)
{
    int idx = blockIdx.x * 256 + threadIdx.x;
    int b = idx >> 18;
    int pix = idx & (HW - 1);
    float mu = red[56 + b] * (1.f / (32.f * HW));
    float rs = rsqrtf(red[64 + b] * (1.f / (32.f * HW)) - mu * mu + GEPS);
    const __hip_bfloat16* yp = y2 + (size_t)b * 32 * HW + pix;
    float a0 = b3[0], a1 = b3[1], a2 = b3[2];
    #pragma unroll
    for (int ci = 0; ci < 32; ++ci) {
        float v = __bfloat162float(yp[(size_t)ci * HW]);
        float dn = (v - mu) * rs * g2g[ci] + g2b[ci];
        float sv = siluf(dn);
        a0 += sv * w3[ci]; a1 += sv * w3[32 + ci]; a2 += sv * w3[64 + ci];
    }
    size_t p = (size_t)b * CHW + pix;
    dl[p] = a0; dl[p + HW] = a1; dl[p + 2 * HW] = a2;
    float r0 = blockReduceSum(a0);
    float r1 = blockReduceSum(a1);
    float r2 = blockReduceSum(a2);
    if (threadIdx.x == 0) {
        atomicAdd(&red[72 + b * 3 + 0], r0);
        atomicAdd(&red[72 + b * 3 + 1], r1);
        atomicAdd(&red[72 + b * 3 + 2], r2);
    }
}

__global__ void k_se(float* __restrict__ red,
    const float* __restrict__ w1, const float* __restrict__ b1,
    const float* __restrict__ w2, const float* __restrict__ b2,
    const float* __restrict__ alpha)
{
    int b = threadIdx.x;
    if (b < 8) {
        float p0 = red[72 + b * 3 + 0] * (1.f / HW);
        float p1 = red[72 + b * 3 + 1] * (1.f / HW);
        float p2 = red[72 + b * 3 + 2] * (1.f / HW);
        float h[4];
        #pragma unroll
        for (int j = 0; j < 4; ++j) {
            float a = b1[j] + p0 * w1[j * 3] + p1 * w1[j * 3 + 1] + p2 * w1[j * 3 + 2];
            h[j] = siluf(a);
        }
        float al = alpha[0];
        #pragma unroll
        for (int c = 0; c < 3; ++c) {
            float a = b2[c] + h[0] * w2[c * 4] + h[1] * w2[c * 4 + 1]
                            + h[2] * w2[c * 4 + 2] + h[3] * w2[c * 4 + 3];
            red[96 + b * 3 + c] = al * sigm(a);
        }
    }
}

__global__ __launch_bounds__(256) void k_out(
    const float* __restrict__ x, const float* __restrict__ dl,
    const float* __restrict__ red, float* __restrict__ out)
{
    int i = blockIdx.x * 256 + threadIdx.x;     // float4 index
    float aw = red[96 + (i >> 16)];             // HW/4 = 65536 vec4 per (b,c)
    float4 xv = ((const float4*)x)[i];
    float4 dv = ((const float4*)dl)[i];
    float4 o;
    o.x = xv.x + aw * dv.x; o.y = xv.y + aw * dv.y;
    o.z = xv.z + aw * dv.z; o.w = xv.w + aw * dv.w;
    ((float4*)out)[i] = o;
}

extern "C" void kernel_launch(void* const* d_in, const int* in_sizes, int n_in,
                              void* d_out, int out_size, void* d_ws, size_t ws_size,
                              hipStream_t stream)
{
    const float* x     = (const float*)d_in[0];
    const float* ng    = (const float*)d_in[1];
    const float* nb    = (const float*)d_in[2];
    const float* ph_w1 = (const float*)d_in[3];
    const float* ph_b1 = (const float*)d_in[4];
    const float* ph_w2 = (const float*)d_in[5];
    const float* ph_b2 = (const float*)d_in[6];
    const float* z_w1  = (const float*)d_in[7];
    const float* z_b1  = (const float*)d_in[8];
    const float* z_w2  = (const float*)d_in[9];
    const float* z_b2  = (const float*)d_in[10];
    const float* fgain = (const float*)d_in[11];
    const float* mw1   = (const float*)d_in[12];
    const float* mb1   = (const float*)d_in[13];
    const float* g1g   = (const float*)d_in[14];
    const float* g1b   = (const float*)d_in[15];
    const float* mw2   = (const float*)d_in[16];
    const float* mb2   = (const float*)d_in[17];
    const float* g2g   = (const float*)d_in[18];
    const float* g2b   = (const float*)d_in[19];
    const float* mw3   = (const float*)d_in[20];
    const float* mb3   = (const float*)d_in[21];
    const float* sw1   = (const float*)d_in[22];
    const float* sb1   = (const float*)d_in[23];
    const float* sw2   = (const float*)d_in[24];
    const float* sb2   = (const float*)d_in[25];
    const float* alpha = (const float*)d_in[26];

    char* ws = (char*)d_ws;
    float*  red = (float*)(ws + OFF_RED);
    float*  phi = (float*)(ws + OFF_PHI);
    float2* U   = (float2*)(ws + OFF_U);
    float*  Jb  = (float*)(ws + OFF_J);
    float*  dl  = (float*)(ws + OFF_D);
    __hip_bfloat16* y2 = (__hip_bfloat16*)(ws + OFF_Y2);
    float* out = (float*)d_out;

    hipLaunchKernelGGL(k_zero, dim3(1), dim3(128), 0, stream, red);
    hipLaunchKernelGGL(k_reduce_x, dim3(256), dim3(256), 0, stream, x, red);
    hipLaunchKernelGGL(k_conv_ph, dim3(32, 32, 8), dim3(256), 0, stream,
                       x, red, ng, nb, ph_w1, ph_b1, ph_w2, ph_b2, phi);
    hipLaunchKernelGGL(k_conv_z, dim3(32, 32, 8), dim3(256), 0, stream,
                       x, red, ng, nb, z_w1, z_b1, z_w2, z_b2);
    hipLaunchKernelGGL(k_fftA, dim3(12288), dim3(256), 0, stream, x, phi, U);
    hipLaunchKernelGGL(k_transpose, dim3(136, 24), dim3(256), 0, stream, U);
    hipLaunchKernelGGL(k_fftB, dim3(12288), dim3(256), 0, stream, U, red, fgain);
    hipLaunchKernelGGL(k_transpose, dim3(136, 24), dim3(256), 0, stream, U);
    hipLaunchKernelGGL(k_fftC, dim3(12288), dim3(256), 0, stream, U, Jb);
    hipLaunchKernelGGL(k_m1, dim3(32, 32, 8), dim3(256), 0, stream, x, Jb, mw1, mb1, red);
    hipLaunchKernelGGL(k_m2, dim3(32, 32, 8), dim3(256), 0, stream,
                       x, Jb, mw1, mb1, g1g, g1b, mw2, mb2, red, y2);
    hipLaunchKernelGGL(k_m3, dim3(8192), dim3(256), 0, stream, y2, red, g2g, g2b, mw3, mb3, dl);
    hipLaunchKernelGGL(k_se, dim3(1), dim3(64), 0, stream, red, sw1, sb1, sw2, sb2, alpha);
    hipLaunchKernelGGL(k_out, dim3(6144), dim3(256), 0, stream, x, dl, red, out);
}

// Round 4
// 1611.855 us; speedup vs baseline: 1.8784x; 1.8784x over previous
//
#include <hip/hip_runtime.h>
#include <hip/hip_bf16.h>
#include <math.h>

#define DINL __device__ __forceinline__

namespace {
constexpr int Bn = 8, Cn = 3, Hn = 512, Wn = 512;
constexpr int HW  = Hn * Wn;        // 262144
constexpr int CHW = Cn * HW;        // 786432
constexpr float GEPS = 1e-5f;
constexpr float PIf  = 3.14159265358979323846f;

// workspace layout (bytes)
constexpr size_t OFF_RED = 0;                                   // 128 floats
constexpr size_t OFF_PHI = 512;                                 // 6291456 f32
constexpr size_t OFF_U   = OFF_PHI + (size_t)Bn * CHW * 4;      // 6291456 float2
constexpr size_t OFF_J   = OFF_U   + (size_t)Bn * CHW * 8;      // 6291456 f32
constexpr size_t OFF_D   = OFF_J   + (size_t)Bn * CHW * 4;      // 6291456 f32
constexpr size_t OFF_Y2  = OFF_D   + (size_t)Bn * CHW * 4;      // 8*32*HW bf16
constexpr size_t OFF_W1B = OFF_Y2  + (size_t)Bn * 32 * HW * 2;  // 32*96 bf16
constexpr size_t OFF_W2B = OFF_W1B + 32 * 96 * 2;               // 9*32*32 bf16
// red float indices:
// 0..7 xsum, 8..15 xss, 16..39 zsum, 40..47 g1sum, 48..55 g1ss,
// 56..63 g2sum, 64..71 g2ss, 72..95 dsum, 96..119 aw
}

typedef __bf16 bfx8 __attribute__((ext_vector_type(8)));
typedef float  fx4  __attribute__((ext_vector_type(4)));

DINL float sigm(float a) { return 1.f / (1.f + __expf(-a)); }
DINL float siluf(float a) { return a / (1.f + __expf(-a)); }
DINL unsigned short f2bf(float f) {           // RNE float->bf16 bits
    unsigned u = __float_as_uint(f);
    return (unsigned short)((u + 0x7FFFu + ((u >> 16) & 1u)) >> 16);
}
DINL float bf2f(unsigned short h) {
    return __uint_as_float(((unsigned)h) << 16);
}

DINL float blockReduceSum(float v) {   // blockDim.x == 256
    __shared__ float sm[4];
    int lane = threadIdx.x & 63, wid = threadIdx.x >> 6;
    #pragma unroll
    for (int o = 32; o > 0; o >>= 1) v += __shfl_down(v, o, 64);
    __syncthreads();
    if (lane == 0) sm[wid] = v;
    __syncthreads();
    if (wid == 0) {
        float r = (lane < 4) ? sm[lane] : 0.f;
        r += __shfl_down(r, 2, 64);
        r += __shfl_down(r, 1, 64);
        return r;                       // valid on thread 0
    }
    return 0.f;
}

__global__ void k_zero(float* __restrict__ red) { red[threadIdx.x] = 0.f; }

// bf16 weight repack: w1bf[o][ky*32 + kx*8 + c] (zero-pad kx=3, c=5..7),
// w2bf[tap][o][ci]
__global__ __launch_bounds__(256) void k_prep(
    const float* __restrict__ w1, const float* __restrict__ w2,
    unsigned short* __restrict__ w1bf, unsigned short* __restrict__ w2bf)
{
    int i = blockIdx.x * 256 + threadIdx.x;     // 0..9215
    if (i < 3072) {
        int o = i / 96, k = i - o * 96;
        int ky = k >> 5, r = k & 31, kx = r >> 3, c = r & 7;
        float v = (kx < 3 && c < 5) ? w1[o * 45 + c * 9 + ky * 3 + kx] : 0.f;
        w1bf[i] = f2bf(v);
    }
    if (i < 9216) {
        int tap = i >> 10, rr = i & 1023, o = rr >> 5, ci = rr & 31;
        w2bf[i] = f2bf(w2[o * 288 + ci * 9 + tap]);
    }
}

__global__ __launch_bounds__(256) void k_reduce_x(const float* __restrict__ x,
                                                  float* __restrict__ red) {
    int b = blockIdx.x >> 5, blk = blockIdx.x & 31;
    const float4* xv = (const float4*)(x + (size_t)b * CHW + (size_t)blk * (CHW / 32));
    float s = 0.f, ss = 0.f;
    for (int i = threadIdx.x; i < (CHW / 32) / 4; i += 256) {
        float4 v = xv[i];
        s  += v.x + v.y + v.z + v.w;
        ss += v.x * v.x + v.y * v.y + v.z * v.z + v.w * v.w;
    }
    float rs = blockReduceSum(s);
    float rss = blockReduceSum(ss);
    if (threadIdx.x == 0) { atomicAdd(&red[b], rs); atomicAdd(&red[8 + b], rss); }
}

// ---------------- phase head: xn -> 16ch silu -> phi ----------------
__global__ __launch_bounds__(256) void k_conv_ph(
    const float* __restrict__ x, const float* __restrict__ red,
    const float* __restrict__ ng, const float* __restrict__ nb,
    const float* __restrict__ w1, const float* __restrict__ b1,
    const float* __restrict__ w2, const float* __restrict__ b2,
    float* __restrict__ phi)
{
    const int tx0 = blockIdx.x * 16, ty0 = blockIdx.y * 16, b = blockIdx.z;
    __shared__ float xt[3][20][20];
    __shared__ float ht[16][18][18];
    const int t = threadIdx.x;
    const float mu = red[b] * (1.f / CHW);
    const float rs = rsqrtf(red[8 + b] * (1.f / CHW) - mu * mu + GEPS);
    float sc[3], sh[3];
    #pragma unroll
    for (int c = 0; c < 3; ++c) { sc[c] = rs * ng[c]; sh[c] = nb[c] - mu * rs * ng[c]; }
    for (int i = t; i < 1200; i += 256) {
        int c = i / 400, r = i - c * 400;
        int yy = r / 20, xx = r - yy * 20;
        int gy = ty0 - 2 + yy, gx = tx0 - 2 + xx;
        float v = 0.f;
        if ((unsigned)gy < (unsigned)Hn && (unsigned)gx < (unsigned)Wn)
            v = x[(size_t)b * CHW + (size_t)c * HW + (size_t)gy * Wn + gx] * sc[c] + sh[c];
        xt[c][yy][xx] = v;
    }
    __syncthreads();
    for (int i = t; i < 324; i += 256) {
        int hy = i / 18, hx = i - hy * 18;
        int gy = ty0 - 1 + hy, gx = tx0 - 1 + hx;
        bool inimg = (unsigned)gy < (unsigned)Hn && (unsigned)gx < (unsigned)Wn;
        float acc[16];
        #pragma unroll
        for (int o = 0; o < 16; ++o) acc[o] = b1[o];
        #pragma unroll
        for (int ci = 0; ci < 3; ++ci)
            #pragma unroll
            for (int ky = 0; ky < 3; ++ky)
                #pragma unroll
                for (int kx = 0; kx < 3; ++kx) {
                    float v = xt[ci][hy + ky][hx + kx];
                    #pragma unroll
                    for (int o = 0; o < 16; ++o)
                        acc[o] += v * w1[o * 27 + ci * 9 + ky * 3 + kx];
                }
        #pragma unroll
        for (int o = 0; o < 16; ++o) ht[o][hy][hx] = inimg ? siluf(acc[o]) : 0.f;
    }
    __syncthreads();
    int oy = t >> 4, ox = t & 15;
    float a0 = b2[0], a1 = b2[1], a2 = b2[2];
    #pragma unroll
    for (int ci = 0; ci < 16; ++ci)
        #pragma unroll
        for (int ky = 0; ky < 3; ++ky)
            #pragma unroll
            for (int kx = 0; kx < 3; ++kx) {
                float v = ht[ci][oy + ky][ox + kx];
                a0 += v * w2[0 * 144 + ci * 9 + ky * 3 + kx];
                a1 += v * w2[1 * 144 + ci * 9 + ky * 3 + kx];
                a2 += v * w2[2 * 144 + ci * 9 + ky * 3 + kx];
            }
    size_t p = (size_t)b * CHW + (size_t)(ty0 + oy) * Wn + tx0 + ox;
    phi[p]            = tanhf(a0) * PIf;
    phi[p + HW]       = tanhf(a1) * PIf;
    phi[p + 2 * HW]   = tanhf(a2) * PIf;
}

// ---------------- z head: xn -> 32ch silu -> z, reduced to z_sum ----------------
__global__ __launch_bounds__(256) void k_conv_z(
    const float* __restrict__ x, float* __restrict__ red,
    const float* __restrict__ ng, const float* __restrict__ nb,
    const float* __restrict__ w1, const float* __restrict__ b1,
    const float* __restrict__ w2, const float* __restrict__ b2)
{
    const int tx0 = blockIdx.x * 16, ty0 = blockIdx.y * 16, b = blockIdx.z;
    __shared__ float xt[3][20][20];
    __shared__ float ht[32][18][18];
    const int t = threadIdx.x;
    const float mu = red[b] * (1.f / CHW);
    const float rs = rsqrtf(red[8 + b] * (1.f / CHW) - mu * mu + GEPS);
    float sc[3], sh[3];
    #pragma unroll
    for (int c = 0; c < 3; ++c) { sc[c] = rs * ng[c]; sh[c] = nb[c] - mu * rs * ng[c]; }
    for (int i = t; i < 1200; i += 256) {
        int c = i / 400, r = i - c * 400;
        int yy = r / 20, xx = r - yy * 20;
        int gy = ty0 - 2 + yy, gx = tx0 - 2 + xx;
        float v = 0.f;
        if ((unsigned)gy < (unsigned)Hn && (unsigned)gx < (unsigned)Wn)
            v = x[(size_t)b * CHW + (size_t)c * HW + (size_t)gy * Wn + gx] * sc[c] + sh[c];
        xt[c][yy][xx] = v;
    }
    __syncthreads();
    for (int i = t; i < 324; i += 256) {
        int hy = i / 18, hx = i - hy * 18;
        int gy = ty0 - 1 + hy, gx = tx0 - 1 + hx;
        bool inimg = (unsigned)gy < (unsigned)Hn && (unsigned)gx < (unsigned)Wn;
        float acc[32];
        #pragma unroll
        for (int o = 0; o < 32; ++o) acc[o] = b1[o];
        #pragma unroll
        for (int ci = 0; ci < 3; ++ci)
            #pragma unroll
            for (int ky = 0; ky < 3; ++ky)
                #pragma unroll
                for (int kx = 0; kx < 3; ++kx) {
                    float v = xt[ci][hy + ky][hx + kx];
                    #pragma unroll
                    for (int o = 0; o < 32; ++o)
                        acc[o] += v * w1[o * 27 + ci * 9 + ky * 3 + kx];
                }
        #pragma unroll
        for (int o = 0; o < 32; ++o) ht[o][hy][hx] = inimg ? siluf(acc[o]) : 0.f;
    }
    __syncthreads();
    float z0, z1, z2;
    {
        int oy = t >> 4, ox = t & 15;
        float a0 = b2[0], a1 = b2[1], a2 = b2[2];
        #pragma unroll
        for (int ci = 0; ci < 32; ++ci)
            #pragma unroll
            for (int ky = 0; ky < 3; ++ky)
                #pragma unroll
                for (int kx = 0; kx < 3; ++kx) {
                    float v = ht[ci][oy + ky][ox + kx];
                    a0 += v * w2[0 * 288 + ci * 9 + ky * 3 + kx];
                    a1 += v * w2[1 * 288 + ci * 9 + ky * 3 + kx];
                    a2 += v * w2[2 * 288 + ci * 9 + ky * 3 + kx];
                }
        z0 = sigm(a0) * 0.3f; z1 = sigm(a1) * 0.3f; z2 = sigm(a2) * 0.3f;
    }
    float r0 = blockReduceSum(z0);
    float r1 = blockReduceSum(z1);
    float r2 = blockReduceSum(z2);
    if (t == 0) {
        atomicAdd(&red[16 + b * 3 + 0], r0);
        atomicAdd(&red[16 + b * 3 + 1], r1);
        atomicAdd(&red[16 + b * 3 + 2], r2);
    }
}

// ---------------- FFT: 512-pt radix-2 Stockham (self-sorting) ----------------
template<bool INV>
DINL float2* fft512_stages(float2* a, float2* b, const float2* tw, int t)
{
    float2* src = a; float2* dst = b;
    int s = 1;
    #pragma unroll
    for (int st = 0; st < 9; ++st) {
        int q = t & (s - 1);
        float2 u = src[t], v = src[t + 256];
        float2 w = tw[t - q];
        float wy = INV ? -w.y : w.y;
        float dx = u.x - v.x, dy = u.y - v.y;
        dst[2 * t - q]     = make_float2(u.x + v.x, u.y + v.y);
        dst[2 * t - q + s] = make_float2(dx * w.x - dy * wy, dx * wy + dy * w.x);
        float2* tmp = src; src = dst; dst = tmp;
        s <<= 1;
        __syncthreads();
    }
    return src;
}

__global__ __launch_bounds__(256) void k_fftA(
    const float* __restrict__ x, const float* __restrict__ phi, float2* __restrict__ U)
{
    __shared__ float2 bufA[512], bufB[512], tw[256];
    const int t = threadIdx.x;
    const size_t line = blockIdx.x;                // (b*3+c)*512 + h
    { float s, c; __sincosf(-2.f * PIf * (float)t * (1.f / 512.f), &s, &c); tw[t] = make_float2(c, s); }
    const float* xr = x + line * 512;
    const float* pr = phi + line * 512;
    #pragma unroll
    for (int i = t; i < 512; i += 256) {
        float s, c; __sincosf(pr[i], &s, &c);
        float xv = xr[i];
        bufA[i] = make_float2(xv * c, xv * s);
    }
    __syncthreads();
    float2* res = fft512_stages<false>(bufA, bufB, tw, t);
    float2* Ur = U + line * 512;
    #pragma unroll
    for (int i = t; i < 512; i += 256) Ur[i] = res[i];
}

__global__ __launch_bounds__(256) void k_transpose(float2* __restrict__ U)
{
    const int img = blockIdx.y;
    int rem = blockIdx.x, ti = 0;
    while (rem >= 16 - ti) { rem -= 16 - ti; ++ti; }
    const int tj = ti + rem;
    float2* Ub = U + (size_t)img * HW;
    __shared__ float2 ta[32][33];
    __shared__ float2 tb[32][33];
    const int t = threadIdx.x;
    const int cc = t & 31, r0 = t >> 5;
    const int ar = ti * 32, ac = tj * 32;
    #pragma unroll
    for (int k = 0; k < 4; ++k) {
        int r = r0 + k * 8;
        ta[r][cc] = Ub[(size_t)(ar + r) * 512 + ac + cc];
    }
    if (ti != tj) {
        #pragma unroll
        for (int k = 0; k < 4; ++k) {
            int r = r0 + k * 8;
            tb[r][cc] = Ub[(size_t)(ac + r) * 512 + ar + cc];
        }
    }
    __syncthreads();
    #pragma unroll
    for (int k = 0; k < 4; ++k) {
        int r = r0 + k * 8;
        Ub[(size_t)(ac + r) * 512 + ar + cc] = ta[cc][r];
    }
    if (ti != tj) {
        #pragma unroll
        for (int k = 0; k < 4; ++k) {
            int r = r0 + k * 8;
            Ub[(size_t)(ar + r) * 512 + ac + cc] = tb[cc][r];
        }
    }
}

// fused: fwd FFT along H + (1+g)*exp(i*kz*z_mean) + inv FFT along H (in transposed layout)
__global__ __launch_bounds__(256) void k_fftB(
    float2* __restrict__ U, const float* __restrict__ red, const float* __restrict__ fgain)
{
    __shared__ float2 bufA[512], bufB[512], tw[256];
    const int t = threadIdx.x;
    const int line = blockIdx.x;                   // (b*3+c)*512 + fw
    const int bc = line >> 9;
    const int fw = line & 511;
    const int c = bc % 3;
    { float s, cc2; __sincosf(-2.f * PIf * (float)t * (1.f / 512.f), &s, &cc2); tw[t] = make_float2(cc2, s); }
    float2* Ur = U + (size_t)line * 512;
    #pragma unroll
    for (int i = t; i < 512; i += 256) bufA[i] = Ur[i];
    __syncthreads();
    float2* res = fft512_stages<false>(bufA, bufB, tw, t);
    const float zm   = red[16 + bc] * (1.f / HW);
    const float gain = 1.f + fgain[c];
    const float lam  = (c == 0) ? 0.65f : (c == 1) ? 0.53f : 0.47f;
    const float il2  = 1.f / (lam * lam);
    const float fwv  = (float)(fw < 256 ? fw : fw - 512) * (1.f / 512.f);
    const float f2w  = fwv * fwv;
    #pragma unroll
    for (int i = t; i < 512; i += 256) {
        float fh = (float)(i < 256 ? i : i - 512) * (1.f / 512.f);
        float kz = 2.f * PIf * sqrtf(fmaxf(il2 - f2w - fh * fh, 0.f));
        float sn, cs; __sincosf(kz * zm, &sn, &cs);
        float2 v = res[i];
        res[i] = make_float2(gain * (v.x * cs - v.y * sn), gain * (v.x * sn + v.y * cs));
    }
    __syncthreads();
    float2* other = (res == (float2*)bufA) ? (float2*)bufB : (float2*)bufA;
    float2* res2 = fft512_stages<true>(res, other, tw, t);
    #pragma unroll
    for (int i = t; i < 512; i += 256) {
        float2 v = res2[i];
        Ur[i] = make_float2(v.x * (1.f / 512.f), v.y * (1.f / 512.f));
    }
}

// inverse FFT along W + |.| epilogue (phase factor exp(i*cp) drops out of |Uz|)
__global__ __launch_bounds__(256) void k_fftC(
    const float2* __restrict__ U, float* __restrict__ J)
{
    __shared__ float2 bufA[512], bufB[512], tw[256];
    const int t = threadIdx.x;
    const size_t line = blockIdx.x;
    { float s, c; __sincosf(-2.f * PIf * (float)t * (1.f / 512.f), &s, &c); tw[t] = make_float2(c, s); }
    const float2* Ur = U + line * 512;
    #pragma unroll
    for (int i = t; i < 512; i += 256) bufA[i] = Ur[i];
    __syncthreads();
    float2* res = fft512_stages<true>(bufA, bufB, tw, t);
    float* Jr = J + line * 512;
    #pragma unroll
    for (int i = t; i < 512; i += 256) {
        float2 v = res[i];
        float re = v.x * (1.f / 512.f), im = v.y * (1.f / 512.f);
        Jr[i] = sqrtf(fmaxf(re * re + im * im, 1e-12f));
    }
}

// ---------------- mix path (MFMA) ----------------
// gn1 stats: conv1 (5ch->32ch, 3x3) via mfma_f32_16x16x32_bf16, tap-row K-packing.
__global__ __launch_bounds__(256) void k_m1(
    const float* __restrict__ x, const float* __restrict__ Jb,
    const unsigned short* __restrict__ w1bf, const float* __restrict__ b1,
    float* __restrict__ red)
{
    const int tx0 = blockIdx.x * 16, ty0 = blockIdx.y * 16, b = blockIdx.z;
    __shared__ unsigned short mt8[18 * 19 * 8];   // [y][x][8ch] bf16, col 18 = zero pad
    const int t = threadIdx.x;
    for (int e = t; e < 18 * 19; e += 256) {
        int yy = e / 19, xx = e - yy * 19;
        int gy = ty0 - 1 + yy, gx = tx0 - 1 + xx;
        float v0 = 0, v1 = 0, v2 = 0, jl = 0, d5 = 0;
        if (xx < 18 && (unsigned)gy < (unsigned)Hn && (unsigned)gx < (unsigned)Wn) {
            size_t p = (size_t)b * CHW + (size_t)gy * Wn + gx;
            v0 = x[p]; v1 = x[p + HW]; v2 = x[p + 2 * HW];
            float j0 = Jb[p], j1 = Jb[p + HW], j2 = Jb[p + 2 * HW];
            float xl = 0.299f * v0 + 0.587f * v1 + 0.114f * v2;
            jl = 0.299f * j0 + 0.587f * j1 + 0.114f * j2;
            d5 = jl - xl;
        }
        unsigned short* d = mt8 + e * 8;
        d[0] = f2bf(v0); d[1] = f2bf(v1); d[2] = f2bf(v2);
        d[3] = f2bf(jl); d[4] = f2bf(d5); d[5] = 0; d[6] = 0; d[7] = 0;
    }
    __syncthreads();
    const int wv = t >> 6, lane = t & 63, ln = lane & 15, q = lane >> 4;
    bfx8 Bf[3][2];
    #pragma unroll
    for (int ks = 0; ks < 3; ++ks)
        #pragma unroll
        for (int nt = 0; nt < 2; ++nt)
            Bf[ks][nt] = *(const bfx8*)(w1bf + (nt * 16 + ln) * 96 + ks * 32 + q * 8);
    const float b1v0 = b1[ln], b1v1 = b1[16 + ln];
    float s = 0.f, ss = 0.f;
    #pragma unroll
    for (int i = 0; i < 4; ++i) {
        const int oy = wv * 4 + i;
        fx4 a0 = {0.f, 0.f, 0.f, 0.f}, a1 = {0.f, 0.f, 0.f, 0.f};
        #pragma unroll
        for (int ks = 0; ks < 3; ++ks) {
            bfx8 A = *(const bfx8*)(mt8 + ((oy + ks) * 19 + ln + q) * 8);
            a0 = __builtin_amdgcn_mfma_f32_16x16x32_bf16(A, Bf[ks][0], a0, 0, 0, 0);
            a1 = __builtin_amdgcn_mfma_f32_16x16x32_bf16(A, Bf[ks][1], a1, 0, 0, 0);
        }
        #pragma unroll
        for (int r = 0; r < 4; ++r) {
            float u0 = a0[r] + b1v0, u1 = a1[r] + b1v1;
            s += u0 + u1; ss += u0 * u0 + u1 * u1;
        }
    }
    float rs = blockReduceSum(s);
    float rss = blockReduceSum(ss);
    if (t == 0) { atomicAdd(&red[40 + b], rs); atomicAdd(&red[48 + b], rss); }
}

// conv1 -> gn1 -> silu -> conv2 (both via MFMA), y2 store + gn2 stats
__global__ __launch_bounds__(256) void k_m2(
    const float* __restrict__ x, const float* __restrict__ Jb,
    const unsigned short* __restrict__ w1bf, const float* __restrict__ b1,
    const float* __restrict__ g1g, const float* __restrict__ g1b,
    const unsigned short* __restrict__ w2bf, const float* __restrict__ b2,
    float* __restrict__ red, unsigned short* __restrict__ y2)
{
    const int tx0 = blockIdx.x * 16, ty0 = blockIdx.y * 16, b = blockIdx.z;
    __shared__ unsigned short mt8[20 * 21 * 8];   // [y][x][8ch] bf16, col 20 = zero pad
    __shared__ unsigned short dt2[324 * 32];      // hidden 18x18, channel-last bf16
    const int t = threadIdx.x;
    const float mu1 = red[40 + b] * (1.f / (32.f * HW));
    const float rs1 = rsqrtf(red[48 + b] * (1.f / (32.f * HW)) - mu1 * mu1 + GEPS);
    for (int e = t; e < 20 * 21; e += 256) {
        int yy = e / 21, xx = e - yy * 21;
        int gy = ty0 - 2 + yy, gx = tx0 - 2 + xx;
        float v0 = 0, v1 = 0, v2 = 0, jl = 0, d5 = 0;
        if (xx < 20 && (unsigned)gy < (unsigned)Hn && (unsigned)gx < (unsigned)Wn) {
            size_t p = (size_t)b * CHW + (size_t)gy * Wn + gx;
            v0 = x[p]; v1 = x[p + HW]; v2 = x[p + 2 * HW];
            float j0 = Jb[p], j1 = Jb[p + HW], j2 = Jb[p + 2 * HW];
            float xl = 0.299f * v0 + 0.587f * v1 + 0.114f * v2;
            jl = 0.299f * j0 + 0.587f * j1 + 0.114f * j2;
            d5 = jl - xl;
        }
        unsigned short* d = mt8 + e * 8;
        d[0] = f2bf(v0); d[1] = f2bf(v1); d[2] = f2bf(v2);
        d[3] = f2bf(jl); d[4] = f2bf(d5); d[5] = 0; d[6] = 0; d[7] = 0;
    }
    const int wv = t >> 6, lane = t & 63, ln = lane & 15, q = lane >> 4;
    // per-lane gn1 constants for channels o = ln, 16+ln
    const float sc0 = rs1 * g1g[ln],       sc1 = rs1 * g1g[16 + ln];
    const float of0 = (b1[ln] - mu1) * sc0 + g1b[ln];
    const float of1 = (b1[16 + ln] - mu1) * sc1 + g1b[16 + ln];
    bfx8 Bf[3][2];
    #pragma unroll
    for (int ks = 0; ks < 3; ++ks)
        #pragma unroll
        for (int nt = 0; nt < 2; ++nt)
            Bf[ks][nt] = *(const bfx8*)(w1bf + (nt * 16 + ln) * 96 + ks * 32 + q * 8);
    __syncthreads();
    // ---- conv1 + gn1 + silu -> dt2 (hidden 18x18, 21 m-tiles) ----
    // out-of-image hidden pixels MUST be zero (SAME-padding for conv2).
    for (int mt = wv; mt < 21; mt += 4) {
        int p = mt * 16 + ln; if (p > 323) p = 323;
        const int hy = p / 18, hx = p - hy * 18;
        fx4 a0 = {0.f, 0.f, 0.f, 0.f}, a1 = {0.f, 0.f, 0.f, 0.f};
        #pragma unroll
        for (int ks = 0; ks < 3; ++ks) {
            bfx8 A = *(const bfx8*)(mt8 + ((hy + ks) * 21 + hx + q) * 8);
            a0 = __builtin_amdgcn_mfma_f32_16x16x32_bf16(A, Bf[ks][0], a0, 0, 0, 0);
            a1 = __builtin_amdgcn_mfma_f32_16x16x32_bf16(A, Bf[ks][1], a1, 0, 0, 0);
        }
        const int prb = mt * 16 + q * 4;
        #pragma unroll
        for (int r = 0; r < 4; ++r) {
            const int pr = prb + r;
            if (pr < 324) {
                const int py = pr / 18, px = pr - py * 18;
                const int gy = ty0 - 1 + py, gx = tx0 - 1 + px;
                const bool inimg = (unsigned)gy < (unsigned)Hn && (unsigned)gx < (unsigned)Wn;
                dt2[pr * 32 + ln]      = inimg ? f2bf(siluf(a0[r] * sc0 + of0)) : (unsigned short)0;
                dt2[pr * 32 + 16 + ln] = inimg ? f2bf(siluf(a1[r] * sc1 + of1)) : (unsigned short)0;
            }
        }
    }
    __syncthreads();
    // ---- conv2: 9 tap-GEMMs, K=32 ----
    fx4 c2[4][2];
    #pragma unroll
    for (int i = 0; i < 4; ++i)
        #pragma unroll
        for (int nt = 0; nt < 2; ++nt)
            c2[i][nt] = fx4{0.f, 0.f, 0.f, 0.f};
    #pragma unroll
    for (int tap = 0; tap < 9; ++tap) {
        const int ky = tap / 3, kx = tap - ky * 3;
        bfx8 B0 = *(const bfx8*)(w2bf + tap * 1024 + ln * 32 + q * 8);
        bfx8 B1 = *(const bfx8*)(w2bf + tap * 1024 + (16 + ln) * 32 + q * 8);
        #pragma unroll
        for (int i = 0; i < 4; ++i) {
            const int oy = wv * 4 + i;
            bfx8 A = *(const bfx8*)(dt2 + ((oy + ky) * 18 + ln + kx) * 32 + q * 8);
            c2[i][0] = __builtin_amdgcn_mfma_f32_16x16x32_bf16(A, B0, c2[i][0], 0, 0, 0);
            c2[i][1] = __builtin_amdgcn_mfma_f32_16x16x32_bf16(A, B1, c2[i][1], 0, 0, 0);
        }
    }
    // ---- epilogue: bias, stats, packed bf16 store ----
    float s = 0.f, ss = 0.f;
    const float b2v0 = b2[ln], b2v1 = b2[16 + ln];
    #pragma unroll
    for (int i = 0; i < 4; ++i) {
        const int gy = ty0 + wv * 4 + i;
        #pragma unroll
        for (int nt = 0; nt < 2; ++nt) {
            const float bb = nt ? b2v1 : b2v0;
            union { unsigned int u[2]; unsigned short h[4]; } pk;
            #pragma unroll
            for (int r = 0; r < 4; ++r) {
                float a = c2[i][nt][r] + bb;
                s += a; ss += a * a;
                pk.h[r] = f2bf(a);
            }
            size_t off = ((size_t)b * 32 + nt * 16 + ln) * HW + (size_t)gy * 512 + tx0 + q * 4;
            *(uint2*)(y2 + off) = make_uint2(pk.u[0], pk.u[1]);
        }
    }
    float rsum = blockReduceSum(s);
    float rss = blockReduceSum(ss);
    if (t == 0) { atomicAdd(&red[56 + b], rsum); atomicAdd(&red[64 + b], rss); }
}

__global__ __launch_bounds__(256) void k_m3(
    const unsigned short* __restrict__ y2, float* __restrict__ red,
    const float* __restrict__ g2g, const float* __restrict__ g2b,
    const float* __restrict__ w3, const float* __restrict__ b3,
    float* __restrict__ dl)
{
    int idx = blockIdx.x * 256 + threadIdx.x;
    int b = idx >> 18;
    int pix = idx & (HW - 1);
    float mu = red[56 + b] * (1.f / (32.f * HW));
    float rs = rsqrtf(red[64 + b] * (1.f / (32.f * HW)) - mu * mu + GEPS);
    const unsigned short* yp = y2 + (size_t)b * 32 * HW + pix;
    float a0 = b3[0], a1 = b3[1], a2 = b3[2];
    #pragma unroll
    for (int ci = 0; ci < 32; ++ci) {
        float v = bf2f(yp[(size_t)ci * HW]);
        float dn = (v - mu) * rs * g2g[ci] + g2b[ci];
        float sv = siluf(dn);
        a0 += sv * w3[ci]; a1 += sv * w3[32 + ci]; a2 += sv * w3[64 + ci];
    }
    size_t p = (size_t)b * CHW + pix;
    dl[p] = a0; dl[p + HW] = a1; dl[p + 2 * HW] = a2;
    float r0 = blockReduceSum(a0);
    float r1 = blockReduceSum(a1);
    float r2 = blockReduceSum(a2);
    if (threadIdx.x == 0) {
        atomicAdd(&red[72 + b * 3 + 0], r0);
        atomicAdd(&red[72 + b * 3 + 1], r1);
        atomicAdd(&red[72 + b * 3 + 2], r2);
    }
}

__global__ void k_se(float* __restrict__ red,
    const float* __restrict__ w1, const float* __restrict__ b1,
    const float* __restrict__ w2, const float* __restrict__ b2,
    const float* __restrict__ alpha)
{
    int b = threadIdx.x;
    if (b < 8) {
        float p0 = red[72 + b * 3 + 0] * (1.f / HW);
        float p1 = red[72 + b * 3 + 1] * (1.f / HW);
        float p2 = red[72 + b * 3 + 2] * (1.f / HW);
        float h[4];
        #pragma unroll
        for (int j = 0; j < 4; ++j) {
            float a = b1[j] + p0 * w1[j * 3] + p1 * w1[j * 3 + 1] + p2 * w1[j * 3 + 2];
            h[j] = siluf(a);
        }
        float al = alpha[0];
        #pragma unroll
        for (int c = 0; c < 3; ++c) {
            float a = b2[c] + h[0] * w2[c * 4] + h[1] * w2[c * 4 + 1]
                            + h[2] * w2[c * 4 + 2] + h[3] * w2[c * 4 + 3];
            red[96 + b * 3 + c] = al * sigm(a);
        }
    }
}

__global__ __launch_bounds__(256) void k_out(
    const float* __restrict__ x, const float* __restrict__ dl,
    const float* __restrict__ red, float* __restrict__ out)
{
    int i = blockIdx.x * 256 + threadIdx.x;     // float4 index
    float aw = red[96 + (i >> 16)];             // HW/4 = 65536 vec4 per (b,c)
    float4 xv = ((const float4*)x)[i];
    float4 dv = ((const float4*)dl)[i];
    float4 o;
    o.x = xv.x + aw * dv.x; o.y = xv.y + aw * dv.y;
    o.z = xv.z + aw * dv.z; o.w = xv.w + aw * dv.w;
    ((float4*)out)[i] = o;
}

extern "C" void kernel_launch(void* const* d_in, const int* in_sizes, int n_in,
                              void* d_out, int out_size, void* d_ws, size_t ws_size,
                              hipStream_t stream)
{
    const float* x     = (const float*)d_in[0];
    const float* ng    = (const float*)d_in[1];
    const float* nb    = (const float*)d_in[2];
    const float* ph_w1 = (const float*)d_in[3];
    const float* ph_b1 = (const float*)d_in[4];
    const float* ph_w2 = (const float*)d_in[5];
    const float* ph_b2 = (const float*)d_in[6];
    const float* z_w1  = (const float*)d_in[7];
    const float* z_b1  = (const float*)d_in[8];
    const float* z_w2  = (const float*)d_in[9];
    const float* z_b2  = (const float*)d_in[10];
    const float* fgain = (const float*)d_in[11];
    const float* mw1   = (const float*)d_in[12];
    const float* mb1   = (const float*)d_in[13];
    const float* g1g   = (const float*)d_in[14];
    const float* g1b   = (const float*)d_in[15];
    const float* mw2   = (const float*)d_in[16];
    const float* mb2   = (const float*)d_in[17];
    const float* g2g   = (const float*)d_in[18];
    const float* g2b   = (const float*)d_in[19];
    const float* mw3   = (const float*)d_in[20];
    const float* mb3   = (const float*)d_in[21];
    const float* sw1   = (const float*)d_in[22];
    const float* sb1   = (const float*)d_in[23];
    const float* sw2   = (const float*)d_in[24];
    const float* sb2   = (const float*)d_in[25];
    const float* alpha = (const float*)d_in[26];

    char* ws = (char*)d_ws;
    float*  red = (float*)(ws + OFF_RED);
    float*  phi = (float*)(ws + OFF_PHI);
    float2* U   = (float2*)(ws + OFF_U);
    float*  Jb  = (float*)(ws + OFF_J);
    float*  dl  = (float*)(ws + OFF_D);
    unsigned short* y2   = (unsigned short*)(ws + OFF_Y2);
    unsigned short* w1bf = (unsigned short*)(ws + OFF_W1B);
    unsigned short* w2bf = (unsigned short*)(ws + OFF_W2B);
    float* out = (float*)d_out;

    hipLaunchKernelGGL(k_zero, dim3(1), dim3(128), 0, stream, red);
    hipLaunchKernelGGL(k_prep, dim3(36), dim3(256), 0, stream, mw1, mw2, w1bf, w2bf);
    hipLaunchKernelGGL(k_reduce_x, dim3(256), dim3(256), 0, stream, x, red);
    hipLaunchKernelGGL(k_conv_ph, dim3(32, 32, 8), dim3(256), 0, stream,
                       x, red, ng, nb, ph_w1, ph_b1, ph_w2, ph_b2, phi);
    hipLaunchKernelGGL(k_conv_z, dim3(32, 32, 8), dim3(256), 0, stream,
                       x, red, ng, nb, z_w1, z_b1, z_w2, z_b2);
    hipLaunchKernelGGL(k_fftA, dim3(12288), dim3(256), 0, stream, x, phi, U);
    hipLaunchKernelGGL(k_transpose, dim3(136, 24), dim3(256), 0, stream, U);
    hipLaunchKernelGGL(k_fftB, dim3(12288), dim3(256), 0, stream, U, red, fgain);
    hipLaunchKernelGGL(k_transpose, dim3(136, 24), dim3(256), 0, stream, U);
    hipLaunchKernelGGL(k_fftC, dim3(12288), dim3(256), 0, stream, U, Jb);
    hipLaunchKernelGGL(k_m1, dim3(32, 32, 8), dim3(256), 0, stream, x, Jb, w1bf, mb1, red);
    hipLaunchKernelGGL(k_m2, dim3(32, 32, 8), dim3(256), 0, stream,
                       x, Jb, w1bf, mb1, g1g, g1b, w2bf, mb2, red, y2);
    hipLaunchKernelGGL(k_m3, dim3(8192), dim3(256), 0, stream, y2, red, g2g, g2b, mw3, mb3, dl);
    hipLaunchKernelGGL(k_se, dim3(1), dim3(64), 0, stream, red, sw1, sb1, sw2, sb2, alpha);
    hipLaunchKernelGGL(k_out, dim3(6144), dim3(256), 0, stream, x, dl, red, out);
}

// Round 6
// 1438.559 us; speedup vs baseline: 2.1046x; 1.1205x over previous
//
#include <hip/hip_runtime.h>
#include <hip/hip_bf16.h>
#include <math.h>

#define DINL __device__ __forceinline__

namespace {
constexpr int Bn = 8, Cn = 3, Hn = 512, Wn = 512;
constexpr int HW  = Hn * Wn;        // 262144
constexpr int CHW = Cn * HW;        // 786432
constexpr float GEPS = 1e-5f;
constexpr float PIf  = 3.14159265358979323846f;

// workspace layout (bytes)
constexpr size_t OFF_RED = 0;                                   // 128 floats
constexpr size_t OFF_PHI = 512;
constexpr size_t OFF_U   = OFF_PHI + (size_t)Bn * CHW * 4;
constexpr size_t OFF_J   = OFF_U   + (size_t)Bn * CHW * 8;
constexpr size_t OFF_D   = OFF_J   + (size_t)Bn * CHW * 4;
constexpr size_t OFF_Y2  = OFF_D   + (size_t)Bn * CHW * 4;      // 8*32*HW bf16 (channel-last)
constexpr size_t OFF_W1B = OFF_Y2  + (size_t)Bn * 32 * HW * 2;  // 3072 bf16
constexpr size_t OFF_W2B = OFF_W1B + 3072 * 2;                  // 9216 bf16
constexpr size_t OFF_WH1 = OFF_W2B + 9216 * 2;                  // 4608 bf16 (48x96 head conv1)
constexpr size_t OFF_WP2 = OFF_WH1 + 4608 * 2;                  // 4608 bf16 (9x16x32 ph conv2, k>=16 zero)
constexpr size_t OFF_WZ2 = OFF_WP2 + 4608 * 2;                  // 4608 bf16 (9x16x32 z conv2)
constexpr size_t OFF_PRM = OFF_WZ2 + 4608 * 2;                  // 160 f32 (permuted g2g,g2b,w3)
// red float indices:
// 0..7 xsum, 8..15 xss, 16..39 zsum, 40..47 g1sum, 48..55 g1ss,
// 56..63 g2sum, 64..71 g2ss, 72..95 dsum, 96..119 aw
}

typedef __bf16 bfx8 __attribute__((ext_vector_type(8)));
typedef float  fx4  __attribute__((ext_vector_type(4)));

DINL float sigm(float a) { return 1.f / (1.f + __expf(-a)); }
DINL float siluf(float a) { return a / (1.f + __expf(-a)); }
DINL unsigned short f2bf(float f) {           // RNE float->bf16 bits
    unsigned u = __float_as_uint(f);
    return (unsigned short)((u + 0x7FFFu + ((u >> 16) & 1u)) >> 16);
}
DINL float bf2f(unsigned short h) {
    return __uint_as_float(((unsigned)h) << 16);
}

DINL float blockReduceSum(float v) {   // blockDim.x == 256
    __shared__ float sm[4];
    int lane = threadIdx.x & 63, wid = threadIdx.x >> 6;
    #pragma unroll
    for (int o = 32; o > 0; o >>= 1) v += __shfl_down(v, o, 64);
    __syncthreads();
    if (lane == 0) sm[wid] = v;
    __syncthreads();
    if (wid == 0) {
        float r = (lane < 4) ? sm[lane] : 0.f;
        r += __shfl_down(r, 2, 64);
        r += __shfl_down(r, 1, 64);
        return r;                       // valid on thread 0
    }
    return 0.f;
}

__global__ void k_zero(float* __restrict__ red) { red[threadIdx.x] = 0.f; }

// weight repack (all bf16 fragment-order):
//  w1bf[o][ky*32+kx*8+c]  (mix conv1, pad kx=3,c>=5)
//  w2bf[tap][o][ci]       (mix conv2)
//  wh1[o48][ky*32+kx*8+c] (heads conv1: o<16 ph, o>=16 z; pad c>=3)
//  wp2[tap][n16][k32]     (ph conv2: n<3,k<16 else 0)
//  wz2[tap][n16][k32]     (z conv2: n<3 else 0)
//  prm: g2g,g2b,w3 permuted to slot order slot=ln*2+nt <-> ch=nt*16+ln
__global__ __launch_bounds__(256) void k_prep(
    const float* __restrict__ w1, const float* __restrict__ w2,
    const float* __restrict__ phw1, const float* __restrict__ zw1,
    const float* __restrict__ phw2, const float* __restrict__ zw2,
    const float* __restrict__ g2g, const float* __restrict__ g2b,
    const float* __restrict__ w3,
    unsigned short* __restrict__ w1bf, unsigned short* __restrict__ w2bf,
    unsigned short* __restrict__ wh1, unsigned short* __restrict__ wp2,
    unsigned short* __restrict__ wz2, float* __restrict__ prm)
{
    int i = blockIdx.x * 256 + threadIdx.x;     // 0..9215
    if (i < 3072) {
        int o = i / 96, k = i - o * 96;
        int ky = k >> 5, r = k & 31, kx = r >> 3, c = r & 7;
        float v = (kx < 3 && c < 5) ? w1[o * 45 + c * 9 + ky * 3 + kx] : 0.f;
        w1bf[i] = f2bf(v);
    }
    if (i < 9216) {
        int tap = i >> 10, rr = i & 1023, o = rr >> 5, ci = rr & 31;
        w2bf[i] = f2bf(w2[o * 288 + ci * 9 + tap]);
    }
    if (i < 4608) {
        int o = i / 96, k = i - o * 96;
        int ky = k >> 5, r = k & 31, kx = r >> 3, c = r & 7;
        float v = 0.f;
        if (kx < 3 && c < 3)
            v = (o < 16) ? phw1[o * 27 + c * 9 + ky * 3 + kx]
                         : zw1[(o - 16) * 27 + c * 9 + ky * 3 + kx];
        wh1[i] = f2bf(v);
    }
    if (i < 4608) {
        int tap = i / 512, rr = i - tap * 512, n = rr >> 5, k = rr & 31;
        float vp = (n < 3 && k < 16) ? phw2[n * 144 + k * 9 + tap] : 0.f;
        float vz = (n < 3) ? zw2[n * 288 + k * 9 + tap] : 0.f;
        wp2[i] = f2bf(vp);
        wz2[i] = f2bf(vz);
    }
    if (i < 160) {
        if (i < 32) {
            int ch = (i & 1) * 16 + (i >> 1);
            prm[i] = g2g[ch];
        } else if (i < 64) {
            int j = i - 32, ch = (j & 1) * 16 + (j >> 1);
            prm[i] = g2b[ch];
        } else {
            int j = (i - 64) & 31, c = (i - 64) >> 5;
            int ch = (j & 1) * 16 + (j >> 1);
            prm[i] = w3[c * 32 + ch];
        }
    }
}

__global__ __launch_bounds__(256) void k_reduce_x(const float* __restrict__ x,
                                                  float* __restrict__ red) {
    int b = blockIdx.x >> 5, blk = blockIdx.x & 31;
    const float4* xv = (const float4*)(x + (size_t)b * CHW + (size_t)blk * (CHW / 32));
    float s = 0.f, ss = 0.f;
    for (int i = threadIdx.x; i < (CHW / 32) / 4; i += 256) {
        float4 v = xv[i];
        s  += v.x + v.y + v.z + v.w;
        ss += v.x * v.x + v.y * v.y + v.z * v.z + v.w * v.w;
    }
    float rs = blockReduceSum(s);
    float rss = blockReduceSum(ss);
    if (threadIdx.x == 0) { atomicAdd(&red[b], rs); atomicAdd(&red[8 + b], rss); }
}

// ---------------- fused heads (MFMA): xn -> [ph16 | z32] hidden -> phi + z_sum ----------------
__global__ __launch_bounds__(256) void k_heads(
    const float* __restrict__ x, float* __restrict__ red,
    const float* __restrict__ ng, const float* __restrict__ nb,
    const unsigned short* __restrict__ wh1,
    const float* __restrict__ phb1, const float* __restrict__ zb1,
    const unsigned short* __restrict__ wp2, const unsigned short* __restrict__ wz2,
    const float* __restrict__ phb2, const float* __restrict__ zb2,
    float* __restrict__ phi)
{
    const int tx0 = blockIdx.x * 16, ty0 = blockIdx.y * 16, b = blockIdx.z;
    __shared__ unsigned short mt8[20 * 21 * 8];   // xn tile [y][x][8ch], col 20 zero pad
    __shared__ unsigned short ht8[324 * 48];      // hidden 18x18, channel-last (0..15 ph, 16..47 z)
    const int t = threadIdx.x;
    const float mu = red[b] * (1.f / CHW);
    const float rsv = rsqrtf(red[8 + b] * (1.f / CHW) - mu * mu + GEPS);
    float sc[3], sh[3];
    #pragma unroll
    for (int c = 0; c < 3; ++c) { sc[c] = rsv * ng[c]; sh[c] = nb[c] - mu * rsv * ng[c]; }
    for (int e = t; e < 20 * 21; e += 256) {
        int yy = e / 21, xx = e - yy * 21;
        int gy = ty0 - 2 + yy, gx = tx0 - 2 + xx;
        float v0 = 0, v1 = 0, v2 = 0;
        if (xx < 20 && (unsigned)gy < (unsigned)Hn && (unsigned)gx < (unsigned)Wn) {
            size_t p = (size_t)b * CHW + (size_t)gy * Wn + gx;
            v0 = x[p] * sc[0] + sh[0];
            v1 = x[p + HW] * sc[1] + sh[1];
            v2 = x[p + 2 * HW] * sc[2] + sh[2];
        }
        unsigned short* d = mt8 + e * 8;
        d[0] = f2bf(v0); d[1] = f2bf(v1); d[2] = f2bf(v2);
        d[3] = 0; d[4] = 0; d[5] = 0; d[6] = 0; d[7] = 0;
    }
    const int wv = t >> 6, lane = t & 63, ln = lane & 15, q = lane >> 4;
    bfx8 Bf[3][3];
    #pragma unroll
    for (int ks = 0; ks < 3; ++ks)
        #pragma unroll
        for (int nt = 0; nt < 3; ++nt)
            Bf[ks][nt] = *(const bfx8*)(wh1 + (nt * 16 + ln) * 96 + ks * 32 + q * 8);
    const float bb0 = phb1[ln], bb1 = zb1[ln], bb2 = zb1[16 + ln];
    __syncthreads();
    // conv1 -> silu -> ht8 (zero outside image: SAME padding for conv2)
    for (int mt = wv; mt < 21; mt += 4) {
        int p = mt * 16 + ln; if (p > 323) p = 323;
        const int hy = p / 18, hx = p - hy * 18;
        fx4 a0 = {0,0,0,0}, a1 = {0,0,0,0}, a2 = {0,0,0,0};
        #pragma unroll
        for (int ks = 0; ks < 3; ++ks) {
            bfx8 A = *(const bfx8*)(mt8 + ((hy + ks) * 21 + hx + q) * 8);
            a0 = __builtin_amdgcn_mfma_f32_16x16x32_bf16(A, Bf[ks][0], a0, 0, 0, 0);
            a1 = __builtin_amdgcn_mfma_f32_16x16x32_bf16(A, Bf[ks][1], a1, 0, 0, 0);
            a2 = __builtin_amdgcn_mfma_f32_16x16x32_bf16(A, Bf[ks][2], a2, 0, 0, 0);
        }
        const int prb = mt * 16 + q * 4;
        #pragma unroll
        for (int r = 0; r < 4; ++r) {
            const int pr = prb + r;
            if (pr < 324) {
                const int py = pr / 18, px = pr - py * 18;
                const int gy = ty0 - 1 + py, gx = tx0 - 1 + px;
                const bool inimg = (unsigned)gy < (unsigned)Hn && (unsigned)gx < (unsigned)Wn;
                unsigned short* hp = ht8 + pr * 48;
                hp[ln]      = inimg ? f2bf(siluf(a0[r] + bb0)) : (unsigned short)0;
                hp[16 + ln] = inimg ? f2bf(siluf(a1[r] + bb1)) : (unsigned short)0;
                hp[32 + ln] = inimg ? f2bf(siluf(a2[r] + bb2)) : (unsigned short)0;
            }
        }
    }
    __syncthreads();
    // conv2: 9 tap-GEMMs. ph reads ch 0..31 (k>=16 weights zero), z reads ch 16..47.
    fx4 accp[4], accz[4];
    #pragma unroll
    for (int i = 0; i < 4; ++i) { accp[i] = fx4{0,0,0,0}; accz[i] = fx4{0,0,0,0}; }
    #pragma unroll
    for (int tap = 0; tap < 9; ++tap) {
        const int ky = tap / 3, kx = tap - ky * 3;
        bfx8 Bp = *(const bfx8*)(wp2 + tap * 512 + ln * 32 + q * 8);
        bfx8 Bz = *(const bfx8*)(wz2 + tap * 512 + ln * 32 + q * 8);
        #pragma unroll
        for (int i = 0; i < 4; ++i) {
            const int oy = wv * 4 + i;
            const unsigned short* ap = ht8 + ((oy + ky) * 18 + ln + kx) * 48;
            bfx8 Ap = *(const bfx8*)(ap + q * 8);
            bfx8 Az = *(const bfx8*)(ap + 16 + q * 8);
            accp[i] = __builtin_amdgcn_mfma_f32_16x16x32_bf16(Ap, Bp, accp[i], 0, 0, 0);
            accz[i] = __builtin_amdgcn_mfma_f32_16x16x32_bf16(Az, Bz, accz[i], 0, 0, 0);
        }
    }
    // epilogue: phi store (lanes ln<3), z accumulate
    float zacc = 0.f;
    const float pb = (ln < 3) ? phb2[ln] : 0.f;
    const float zb = (ln < 3) ? zb2[ln] : 0.f;
    #pragma unroll
    for (int i = 0; i < 4; ++i) {
        const int gy = ty0 + wv * 4 + i;
        #pragma unroll
        for (int r = 0; r < 4; ++r) {
            const int gx = tx0 + q * 4 + r;
            if (ln < 3) {
                phi[(size_t)b * CHW + (size_t)ln * HW + (size_t)gy * Wn + gx]
                    = tanhf(accp[i][r] + pb) * PIf;
                zacc += sigm(accz[i][r] + zb) * 0.3f;
            }
        }
    }
    #pragma unroll
    for (int c = 0; c < 3; ++c) {
        float rc = blockReduceSum((ln == c) ? zacc : 0.f);
        if (t == 0) atomicAdd(&red[16 + b * 3 + c], rc);
    }
}

// ---------------- FFT: 512-pt radix-2 Stockham (self-sorting) ----------------
template<bool INV>
DINL float2* fft512_stages(float2* a, float2* b, const float2* tw, int t)
{
    float2* src = a; float2* dst = b;
    int s = 1;
    #pragma unroll
    for (int st = 0; st < 9; ++st) {
        int q = t & (s - 1);
        float2 u = src[t], v = src[t + 256];
        float2 w = tw[t - q];
        float wy = INV ? -w.y : w.y;
        float dx = u.x - v.x, dy = u.y - v.y;
        dst[2 * t - q]     = make_float2(u.x + v.x, u.y + v.y);
        dst[2 * t - q + s] = make_float2(dx * w.x - dy * wy, dx * wy + dy * w.x);
        float2* tmp = src; src = dst; dst = tmp;
        s <<= 1;
        __syncthreads();
    }
    return src;
}

__global__ __launch_bounds__(256) void k_fftA(
    const float* __restrict__ x, const float* __restrict__ phi, float2* __restrict__ U)
{
    __shared__ float2 bufA[512], bufB[512], tw[256];
    const int t = threadIdx.x;
    const size_t line = blockIdx.x;                // (b*3+c)*512 + h
    { float s, c; __sincosf(-2.f * PIf * (float)t * (1.f / 512.f), &s, &c); tw[t] = make_float2(c, s); }
    const float* xr = x + line * 512;
    const float* pr = phi + line * 512;
    #pragma unroll
    for (int i = t; i < 512; i += 256) {
        float s, c; __sincosf(pr[i], &s, &c);
        float xv = xr[i];
        bufA[i] = make_float2(xv * c, xv * s);
    }
    __syncthreads();
    float2* res = fft512_stages<false>(bufA, bufB, tw, t);
    float2* Ur = U + line * 512;
    #pragma unroll
    for (int i = t; i < 512; i += 256) Ur[i] = res[i];
}

__global__ __launch_bounds__(256) void k_transpose(float2* __restrict__ U)
{
    const int img = blockIdx.y;
    int rem = blockIdx.x, ti = 0;
    while (rem >= 16 - ti) { rem -= 16 - ti; ++ti; }
    const int tj = ti + rem;
    float2* Ub = U + (size_t)img * HW;
    __shared__ float2 ta[32][33];
    __shared__ float2 tb[32][33];
    const int t = threadIdx.x;
    const int cc = t & 31, r0 = t >> 5;
    const int ar = ti * 32, ac = tj * 32;
    #pragma unroll
    for (int k = 0; k < 4; ++k) {
        int r = r0 + k * 8;
        ta[r][cc] = Ub[(size_t)(ar + r) * 512 + ac + cc];
    }
    if (ti != tj) {
        #pragma unroll
        for (int k = 0; k < 4; ++k) {
            int r = r0 + k * 8;
            tb[r][cc] = Ub[(size_t)(ac + r) * 512 + ar + cc];
        }
    }
    __syncthreads();
    #pragma unroll
    for (int k = 0; k < 4; ++k) {
        int r = r0 + k * 8;
        Ub[(size_t)(ac + r) * 512 + ar + cc] = ta[cc][r];
    }
    if (ti != tj) {
        #pragma unroll
        for (int k = 0; k < 4; ++k) {
            int r = r0 + k * 8;
            Ub[(size_t)(ar + r) * 512 + ac + cc] = tb[cc][r];
        }
    }
}

__global__ __launch_bounds__(256) void k_fftB(
    float2* __restrict__ U, const float* __restrict__ red, const float* __restrict__ fgain)
{
    __shared__ float2 bufA[512], bufB[512], tw[256];
    const int t = threadIdx.x;
    const int line = blockIdx.x;                   // (b*3+c)*512 + fw
    const int bc = line >> 9;
    const int fw = line & 511;
    const int c = bc % 3;
    { float s, cc2; __sincosf(-2.f * PIf * (float)t * (1.f / 512.f), &s, &cc2); tw[t] = make_float2(cc2, s); }
    float2* Ur = U + (size_t)line * 512;
    #pragma unroll
    for (int i = t; i < 512; i += 256) bufA[i] = Ur[i];
    __syncthreads();
    float2* res = fft512_stages<false>(bufA, bufB, tw, t);
    const float zm   = red[16 + bc] * (1.f / HW);
    const float gain = 1.f + fgain[c];
    const float lam  = (c == 0) ? 0.65f : (c == 1) ? 0.53f : 0.47f;
    const float il2  = 1.f / (lam * lam);
    const float fwv  = (float)(fw < 256 ? fw : fw - 512) * (1.f / 512.f);
    const float f2w  = fwv * fwv;
    #pragma unroll
    for (int i = t; i < 512; i += 256) {
        float fh = (float)(i < 256 ? i : i - 512) * (1.f / 512.f);
        float kz = 2.f * PIf * sqrtf(fmaxf(il2 - f2w - fh * fh, 0.f));
        float sn, cs; __sincosf(kz * zm, &sn, &cs);
        float2 v = res[i];
        res[i] = make_float2(gain * (v.x * cs - v.y * sn), gain * (v.x * sn + v.y * cs));
    }
    __syncthreads();
    float2* other = (res == (float2*)bufA) ? (float2*)bufB : (float2*)bufA;
    float2* res2 = fft512_stages<true>(res, other, tw, t);
    #pragma unroll
    for (int i = t; i < 512; i += 256) {
        float2 v = res2[i];
        Ur[i] = make_float2(v.x * (1.f / 512.f), v.y * (1.f / 512.f));
    }
}

__global__ __launch_bounds__(256) void k_fftC(
    const float2* __restrict__ U, float* __restrict__ J)
{
    __shared__ float2 bufA[512], bufB[512], tw[256];
    const int t = threadIdx.x;
    const size_t line = blockIdx.x;
    { float s, c; __sincosf(-2.f * PIf * (float)t * (1.f / 512.f), &s, &c); tw[t] = make_float2(c, s); }
    const float2* Ur = U + line * 512;
    #pragma unroll
    for (int i = t; i < 512; i += 256) bufA[i] = Ur[i];
    __syncthreads();
    float2* res = fft512_stages<true>(bufA, bufB, tw, t);
    float* Jr = J + line * 512;
    #pragma unroll
    for (int i = t; i < 512; i += 256) {
        float2 v = res[i];
        float re = v.x * (1.f / 512.f), im = v.y * (1.f / 512.f);
        Jr[i] = sqrtf(fmaxf(re * re + im * im, 1e-12f));
    }
}

// ---------------- mix path (MFMA) ----------------
__global__ __launch_bounds__(256) void k_m1(
    const float* __restrict__ x, const float* __restrict__ Jb,
    const unsigned short* __restrict__ w1bf, const float* __restrict__ b1,
    float* __restrict__ red)
{
    const int tx0 = blockIdx.x * 16, ty0 = blockIdx.y * 16, b = blockIdx.z;
    __shared__ unsigned short mt8[18 * 19 * 8];
    const int t = threadIdx.x;
    for (int e = t; e < 18 * 19; e += 256) {
        int yy = e / 19, xx = e - yy * 19;
        int gy = ty0 - 1 + yy, gx = tx0 - 1 + xx;
        float v0 = 0, v1 = 0, v2 = 0, jl = 0, d5 = 0;
        if (xx < 18 && (unsigned)gy < (unsigned)Hn && (unsigned)gx < (unsigned)Wn) {
            size_t p = (size_t)b * CHW + (size_t)gy * Wn + gx;
            v0 = x[p]; v1 = x[p + HW]; v2 = x[p + 2 * HW];
            float j0 = Jb[p], j1 = Jb[p + HW], j2 = Jb[p + 2 * HW];
            float xl = 0.299f * v0 + 0.587f * v1 + 0.114f * v2;
            jl = 0.299f * j0 + 0.587f * j1 + 0.114f * j2;
            d5 = jl - xl;
        }
        unsigned short* d = mt8 + e * 8;
        d[0] = f2bf(v0); d[1] = f2bf(v1); d[2] = f2bf(v2);
        d[3] = f2bf(jl); d[4] = f2bf(d5); d[5] = 0; d[6] = 0; d[7] = 0;
    }
    __syncthreads();
    const int wv = t >> 6, lane = t & 63, ln = lane & 15, q = lane >> 4;
    bfx8 Bf[3][2];
    #pragma unroll
    for (int ks = 0; ks < 3; ++ks)
        #pragma unroll
        for (int nt = 0; nt < 2; ++nt)
            Bf[ks][nt] = *(const bfx8*)(w1bf + (nt * 16 + ln) * 96 + ks * 32 + q * 8);
    const float b1v0 = b1[ln], b1v1 = b1[16 + ln];
    float s = 0.f, ss = 0.f;
    #pragma unroll
    for (int i = 0; i < 4; ++i) {
        const int oy = wv * 4 + i;
        fx4 a0 = {0.f, 0.f, 0.f, 0.f}, a1 = {0.f, 0.f, 0.f, 0.f};
        #pragma unroll
        for (int ks = 0; ks < 3; ++ks) {
            bfx8 A = *(const bfx8*)(mt8 + ((oy + ks) * 19 + ln + q) * 8);
            a0 = __builtin_amdgcn_mfma_f32_16x16x32_bf16(A, Bf[ks][0], a0, 0, 0, 0);
            a1 = __builtin_amdgcn_mfma_f32_16x16x32_bf16(A, Bf[ks][1], a1, 0, 0, 0);
        }
        #pragma unroll
        for (int r = 0; r < 4; ++r) {
            float u0 = a0[r] + b1v0, u1 = a1[r] + b1v1;
            s += u0 + u1; ss += u0 * u0 + u1 * u1;
        }
    }
    float rs = blockReduceSum(s);
    float rss = blockReduceSum(ss);
    if (t == 0) { atomicAdd(&red[40 + b], rs); atomicAdd(&red[48 + b], rss); }
}

// conv1 -> gn1 -> silu -> conv2 (MFMA); y2 stored CHANNEL-LAST (slot=ln*2+nt) + gn2 stats
__global__ __launch_bounds__(256) void k_m2(
    const float* __restrict__ x, const float* __restrict__ Jb,
    const unsigned short* __restrict__ w1bf, const float* __restrict__ b1,
    const float* __restrict__ g1g, const float* __restrict__ g1b,
    const unsigned short* __restrict__ w2bf, const float* __restrict__ b2,
    float* __restrict__ red, unsigned short* __restrict__ y2)
{
    const int tx0 = blockIdx.x * 16, ty0 = blockIdx.y * 16, b = blockIdx.z;
    __shared__ unsigned short mt8[20 * 21 * 8];
    __shared__ unsigned short dt2[324 * 32];
    const int t = threadIdx.x;
    const float mu1 = red[40 + b] * (1.f / (32.f * HW));
    const float rs1 = rsqrtf(red[48 + b] * (1.f / (32.f * HW)) - mu1 * mu1 + GEPS);
    for (int e = t; e < 20 * 21; e += 256) {
        int yy = e / 21, xx = e - yy * 21;
        int gy = ty0 - 2 + yy, gx = tx0 - 2 + xx;
        float v0 = 0, v1 = 0, v2 = 0, jl = 0, d5 = 0;
        if (xx < 20 && (unsigned)gy < (unsigned)Hn && (unsigned)gx < (unsigned)Wn) {
            size_t p = (size_t)b * CHW + (size_t)gy * Wn + gx;
            v0 = x[p]; v1 = x[p + HW]; v2 = x[p + 2 * HW];
            float j0 = Jb[p], j1 = Jb[p + HW], j2 = Jb[p + 2 * HW];
            float xl = 0.299f * v0 + 0.587f * v1 + 0.114f * v2;
            jl = 0.299f * j0 + 0.587f * j1 + 0.114f * j2;
            d5 = jl - xl;
        }
        unsigned short* d = mt8 + e * 8;
        d[0] = f2bf(v0); d[1] = f2bf(v1); d[2] = f2bf(v2);
        d[3] = f2bf(jl); d[4] = f2bf(d5); d[5] = 0; d[6] = 0; d[7] = 0;
    }
    const int wv = t >> 6, lane = t & 63, ln = lane & 15, q = lane >> 4;
    const float sc0 = rs1 * g1g[ln],       sc1 = rs1 * g1g[16 + ln];
    const float of0 = (b1[ln] - mu1) * sc0 + g1b[ln];
    const float of1 = (b1[16 + ln] - mu1) * sc1 + g1b[16 + ln];
    bfx8 Bf[3][2];
    #pragma unroll
    for (int ks = 0; ks < 3; ++ks)
        #pragma unroll
        for (int nt = 0; nt < 2; ++nt)
            Bf[ks][nt] = *(const bfx8*)(w1bf + (nt * 16 + ln) * 96 + ks * 32 + q * 8);
    __syncthreads();
    // conv1 + gn1 + silu -> dt2 (out-of-image hidden pixels zeroed: SAME padding)
    for (int mt = wv; mt < 21; mt += 4) {
        int p = mt * 16 + ln; if (p > 323) p = 323;
        const int hy = p / 18, hx = p - hy * 18;
        fx4 a0 = {0.f, 0.f, 0.f, 0.f}, a1 = {0.f, 0.f, 0.f, 0.f};
        #pragma unroll
        for (int ks = 0; ks < 3; ++ks) {
            bfx8 A = *(const bfx8*)(mt8 + ((hy + ks) * 21 + hx + q) * 8);
            a0 = __builtin_amdgcn_mfma_f32_16x16x32_bf16(A, Bf[ks][0], a0, 0, 0, 0);
            a1 = __builtin_amdgcn_mfma_f32_16x16x32_bf16(A, Bf[ks][1], a1, 0, 0, 0);
        }
        const int prb = mt * 16 + q * 4;
        #pragma unroll
        for (int r = 0; r < 4; ++r) {
            const int pr = prb + r;
            if (pr < 324) {
                const int py = pr / 18, px = pr - py * 18;
                const int gy = ty0 - 1 + py, gx = tx0 - 1 + px;
                const bool inimg = (unsigned)gy < (unsigned)Hn && (unsigned)gx < (unsigned)Wn;
                dt2[pr * 32 + ln]      = inimg ? f2bf(siluf(a0[r] * sc0 + of0)) : (unsigned short)0;
                dt2[pr * 32 + 16 + ln] = inimg ? f2bf(siluf(a1[r] * sc1 + of1)) : (unsigned short)0;
            }
        }
    }
    __syncthreads();
    // conv2: 9 tap-GEMMs, K=32
    fx4 c2[4][2];
    #pragma unroll
    for (int i = 0; i < 4; ++i)
        #pragma unroll
        for (int nt = 0; nt < 2; ++nt)
            c2[i][nt] = fx4{0.f, 0.f, 0.f, 0.f};
    #pragma unroll
    for (int tap = 0; tap < 9; ++tap) {
        const int ky = tap / 3, kx = tap - ky * 3;
        bfx8 B0 = *(const bfx8*)(w2bf + tap * 1024 + ln * 32 + q * 8);
        bfx8 B1 = *(const bfx8*)(w2bf + tap * 1024 + (16 + ln) * 32 + q * 8);
        #pragma unroll
        for (int i = 0; i < 4; ++i) {
            const int oy = wv * 4 + i;
            bfx8 A = *(const bfx8*)(dt2 + ((oy + ky) * 18 + ln + kx) * 32 + q * 8);
            c2[i][0] = __builtin_amdgcn_mfma_f32_16x16x32_bf16(A, B0, c2[i][0], 0, 0, 0);
            c2[i][1] = __builtin_amdgcn_mfma_f32_16x16x32_bf16(A, B1, c2[i][1], 0, 0, 0);
        }
    }
    // epilogue: bias, stats, channel-last packed store (slot pair 2*ln, 2*ln+1)
    float s = 0.f, ss = 0.f;
    const float b2v0 = b2[ln], b2v1 = b2[16 + ln];
    #pragma unroll
    for (int i = 0; i < 4; ++i) {
        const int gy = ty0 + wv * 4 + i;
        #pragma unroll
        for (int r = 0; r < 4; ++r) {
            const int gx = tx0 + q * 4 + r;
            float a0 = c2[i][0][r] + b2v0;
            float a1 = c2[i][1][r] + b2v1;
            s += a0 + a1; ss += a0 * a0 + a1 * a1;
            unsigned pk = (unsigned)f2bf(a0) | ((unsigned)f2bf(a1) << 16);
            size_t off = ((size_t)b * HW + (size_t)gy * Wn + gx) * 32 + ln * 2;
            *(unsigned*)(y2 + off) = pk;
        }
    }
    float rsum = blockReduceSum(s);
    float rss = blockReduceSum(ss);
    if (t == 0) { atomicAdd(&red[56 + b], rsum); atomicAdd(&red[64 + b], rss); }
}

// gn2 -> silu -> 1x1 conv; y2 is channel-last (permuted slots), weights pre-permuted in prm
__global__ __launch_bounds__(256) void k_m3(
    const unsigned short* __restrict__ y2, float* __restrict__ red,
    const float* __restrict__ prm, const float* __restrict__ b3,
    float* __restrict__ dl)
{
    int idx = blockIdx.x * 256 + threadIdx.x;     // global pixel (b*HW+pix)
    int b = idx >> 18;
    int pix = idx & (HW - 1);
    float mu = red[56 + b] * (1.f / (32.f * HW));
    float rs = rsqrtf(red[64 + b] * (1.f / (32.f * HW)) - mu * mu + GEPS);
    const uint4* yp = (const uint4*)(y2 + (size_t)idx * 32);
    uint4 L[4];
    #pragma unroll
    for (int c = 0; c < 4; ++c) L[c] = yp[c];
    float a0 = b3[0], a1 = b3[1], a2 = b3[2];
    const unsigned* Lw = (const unsigned*)L;
    #pragma unroll
    for (int w = 0; w < 16; ++w) {     // 16 dwords = all 32 channels
        unsigned u = Lw[w];
        #pragma unroll
        for (int h = 0; h < 2; ++h) {
            int j = w * 2 + h;
            float v = bf2f((unsigned short)(h ? (u >> 16) : (u & 0xFFFFu)));
            float dn = (v - mu) * rs * prm[j] + prm[32 + j];
            float sv = siluf(dn);
            a0 += sv * prm[64 + j]; a1 += sv * prm[96 + j]; a2 += sv * prm[128 + j];
        }
    }
    size_t p = (size_t)b * CHW + pix;
    dl[p] = a0; dl[p + HW] = a1; dl[p + 2 * HW] = a2;
    float r0 = blockReduceSum(a0);
    float r1 = blockReduceSum(a1);
    float r2 = blockReduceSum(a2);
    if (threadIdx.x == 0) {
        atomicAdd(&red[72 + b * 3 + 0], r0);
        atomicAdd(&red[72 + b * 3 + 1], r1);
        atomicAdd(&red[72 + b * 3 + 2], r2);
    }
}

__global__ void k_se(float* __restrict__ red,
    const float* __restrict__ w1, const float* __restrict__ b1,
    const float* __restrict__ w2, const float* __restrict__ b2,
    const float* __restrict__ alpha)
{
    int b = threadIdx.x;
    if (b < 8) {
        float p0 = red[72 + b * 3 + 0] * (1.f / HW);
        float p1 = red[72 + b * 3 + 1] * (1.f / HW);
        float p2 = red[72 + b * 3 + 2] * (1.f / HW);
        float h[4];
        #pragma unroll
        for (int j = 0; j < 4; ++j) {
            float a = b1[j] + p0 * w1[j * 3] + p1 * w1[j * 3 + 1] + p2 * w1[j * 3 + 2];
            h[j] = siluf(a);
        }
        float al = alpha[0];
        #pragma unroll
        for (int c = 0; c < 3; ++c) {
            float a = b2[c] + h[0] * w2[c * 4] + h[1] * w2[c * 4 + 1]
                            + h[2] * w2[c * 4 + 2] + h[3] * w2[c * 4 + 3];
            red[96 + b * 3 + c] = al * sigm(a);
        }
    }
}

__global__ __launch_bounds__(256) void k_out(
    const float* __restrict__ x, const float* __restrict__ dl,
    const float* __restrict__ red, float* __restrict__ out)
{
    int i = blockIdx.x * 256 + threadIdx.x;     // float4 index
    float aw = red[96 + (i >> 16)];
    float4 xv = ((const float4*)x)[i];
    float4 dv = ((const float4*)dl)[i];
    float4 o;
    o.x = xv.x + aw * dv.x; o.y = xv.y + aw * dv.y;
    o.z = xv.z + aw * dv.z; o.w = xv.w + aw * dv.w;
    ((float4*)out)[i] = o;
}

extern "C" void kernel_launch(void* const* d_in, const int* in_sizes, int n_in,
                              void* d_out, int out_size, void* d_ws, size_t ws_size,
                              hipStream_t stream)
{
    const float* x     = (const float*)d_in[0];
    const float* ng    = (const float*)d_in[1];
    const float* nb    = (const float*)d_in[2];
    const float* ph_w1 = (const float*)d_in[3];
    const float* ph_b1 = (const float*)d_in[4];
    const float* ph_w2 = (const float*)d_in[5];
    const float* ph_b2 = (const float*)d_in[6];
    const float* z_w1  = (const float*)d_in[7];
    const float* z_b1  = (const float*)d_in[8];
    const float* z_w2  = (const float*)d_in[9];
    const float* z_b2  = (const float*)d_in[10];
    const float* fgain = (const float*)d_in[11];
    const float* mw1   = (const float*)d_in[12];
    const float* mb1   = (const float*)d_in[13];
    const float* g1g   = (const float*)d_in[14];
    const float* g1b   = (const float*)d_in[15];
    const float* mw2   = (const float*)d_in[16];
    const float* mb2   = (const float*)d_in[17];
    const float* g2g   = (const float*)d_in[18];
    const float* g2b   = (const float*)d_in[19];
    const float* mw3   = (const float*)d_in[20];
    const float* mb3   = (const float*)d_in[21];
    const float* sw1   = (const float*)d_in[22];
    const float* sb1   = (const float*)d_in[23];
    const float* sw2   = (const float*)d_in[24];
    const float* sb2   = (const float*)d_in[25];
    const float* alpha = (const float*)d_in[26];

    char* ws = (char*)d_ws;
    float*  red = (float*)(ws + OFF_RED);
    float*  phi = (float*)(ws + OFF_PHI);
    float2* U   = (float2*)(ws + OFF_U);
    float*  Jb  = (float*)(ws + OFF_J);
    float*  dl  = (float*)(ws + OFF_D);
    unsigned short* y2   = (unsigned short*)(ws + OFF_Y2);
    unsigned short* w1bf = (unsigned short*)(ws + OFF_W1B);
    unsigned short* w2bf = (unsigned short*)(ws + OFF_W2B);
    unsigned short* wh1  = (unsigned short*)(ws + OFF_WH1);
    unsigned short* wp2  = (unsigned short*)(ws + OFF_WP2);
    unsigned short* wz2  = (unsigned short*)(ws + OFF_WZ2);
    float* prm = (float*)(ws + OFF_PRM);
    float* out = (float*)d_out;

    hipLaunchKernelGGL(k_zero, dim3(1), dim3(128), 0, stream, red);
    hipLaunchKernelGGL(k_prep, dim3(36), dim3(256), 0, stream,
                       mw1, mw2, ph_w1, z_w1, ph_w2, z_w2, g2g, g2b, mw3,
                       w1bf, w2bf, wh1, wp2, wz2, prm);
    hipLaunchKernelGGL(k_reduce_x, dim3(256), dim3(256), 0, stream, x, red);
    hipLaunchKernelGGL(k_heads, dim3(32, 32, 8), dim3(256), 0, stream,
                       x, red, ng, nb, wh1, ph_b1, z_b1, wp2, wz2, ph_b2, z_b2, phi);
    hipLaunchKernelGGL(k_fftA, dim3(12288), dim3(256), 0, stream, x, phi, U);
    hipLaunchKernelGGL(k_transpose, dim3(136, 24), dim3(256), 0, stream, U);
    hipLaunchKernelGGL(k_fftB, dim3(12288), dim3(256), 0, stream, U, red, fgain);
    hipLaunchKernelGGL(k_transpose, dim3(136, 24), dim3(256), 0, stream, U);
    hipLaunchKernelGGL(k_fftC, dim3(12288), dim3(256), 0, stream, U, Jb);
    hipLaunchKernelGGL(k_m1, dim3(32, 32, 8), dim3(256), 0, stream, x, Jb, w1bf, mb1, red);
    hipLaunchKernelGGL(k_m2, dim3(32, 32, 8), dim3(256), 0, stream,
                       x, Jb, w1bf, mb1, g1g, g1b, w2bf, mb2, red, y2);
    hipLaunchKernelGGL(k_m3, dim3(8192), dim3(256), 0, stream, y2, red, prm, mb3, dl);
    hipLaunchKernelGGL(k_se, dim3(1), dim3(64), 0, stream, red, sw1, sb1, sw2, sb2, alpha);
    hipLaunchKernelGGL(k_out, dim3(6144), dim3(256), 0, stream, x, dl, red, out);
}

// Round 7
// 661.755 us; speedup vs baseline: 4.5751x; 2.1739x over previous
//
#include <hip/hip_runtime.h>
#include <hip/hip_bf16.h>
#include <math.h>

#define DINL __device__ __forceinline__

namespace {
constexpr int Bn = 8, Cn = 3, Hn = 512, Wn = 512;
constexpr int HW  = Hn * Wn;        // 262144
constexpr int CHW = Cn * HW;        // 786432
constexpr float GEPS = 1e-5f;
constexpr float PIf  = 3.14159265358979323846f;

// workspace layout (bytes)
constexpr size_t OFF_RED = 0;                                   // 128 floats
constexpr size_t OFF_PHI = 512;
constexpr size_t OFF_U   = OFF_PHI + (size_t)Bn * CHW * 4;
constexpr size_t OFF_J   = OFF_U   + (size_t)Bn * CHW * 8;
constexpr size_t OFF_D   = OFF_J   + (size_t)Bn * CHW * 4;
constexpr size_t OFF_Y2  = OFF_D   + (size_t)Bn * CHW * 4;      // 8*32*HW bf16 (channel-last)
constexpr size_t OFF_W1B = OFF_Y2  + (size_t)Bn * 32 * HW * 2;  // 3072 bf16
constexpr size_t OFF_W2B = OFF_W1B + 3072 * 2;                  // 9216 bf16
constexpr size_t OFF_WH1 = OFF_W2B + 9216 * 2;                  // 4608 bf16
constexpr size_t OFF_WP2 = OFF_WH1 + 4608 * 2;                  // 4608 bf16
constexpr size_t OFF_WZ2 = OFF_WP2 + 4608 * 2;                  // 4608 bf16
constexpr size_t OFF_PRM = OFF_WZ2 + 4608 * 2;                  // 160 f32
constexpr size_t OFF_PART= OFF_PRM + 160 * 4;                   // 81920 f32 partials
// part float sub-offsets (in floats)
constexpr int PZ = 0;          // 24 groups (b*3+c) x 1024
constexpr int PG1 = 24576;     // 16 groups (b:sum, 8+b:ss) x 1024
constexpr int PG2 = 40960;     // 16 groups x 1024
constexpr int PD  = 57344;     // 24 groups (b*3+c) x 1024
// red float indices:
// 0..7 xsum, 8..15 xss, 16..39 zsum, 40..47 g1sum, 48..55 g1ss,
// 56..63 g2sum, 64..71 g2ss, 72..95 dsum, 96..119 aw
}

typedef __bf16 bfx8 __attribute__((ext_vector_type(8)));
typedef float  fx4  __attribute__((ext_vector_type(4)));

DINL float sigm(float a) { return __frcp_rn(1.f + __expf(-a)); }
DINL float siluf(float a) { return a * __frcp_rn(1.f + __expf(-a)); }
DINL unsigned short f2bf(float f) {           // RNE float->bf16 bits
    unsigned u = __float_as_uint(f);
    return (unsigned short)((u + 0x7FFFu + ((u >> 16) & 1u)) >> 16);
}
DINL float bf2f(unsigned short h) {
    return __uint_as_float(((unsigned)h) << 16);
}

DINL float blockReduceSum(float v) {   // blockDim.x == 256
    __shared__ float sm[4];
    int lane = threadIdx.x & 63, wid = threadIdx.x >> 6;
    #pragma unroll
    for (int o = 32; o > 0; o >>= 1) v += __shfl_down(v, o, 64);
    __syncthreads();
    if (lane == 0) sm[wid] = v;
    __syncthreads();
    if (wid == 0) {
        float r = (lane < 4) ? sm[lane] : 0.f;
        r += __shfl_down(r, 2, 64);
        r += __shfl_down(r, 1, 64);
        return r;                       // valid on thread 0
    }
    return 0.f;
}

__global__ void k_zero(float* __restrict__ red) { red[threadIdx.x] = 0.f; }

// generic 1024-wide partial reduce: dst[g] = sum(src[g*1024 .. +1024))
__global__ __launch_bounds__(256) void k_red(const float* __restrict__ src,
                                             float* __restrict__ dst)
{
    const float4* s4 = (const float4*)(src + (size_t)blockIdx.x * 1024);
    float4 q = s4[threadIdx.x];
    float r = blockReduceSum(q.x + q.y + q.z + q.w);
    if (threadIdx.x == 0) dst[blockIdx.x] = r;
}

// weight repack (all bf16 fragment-order)
__global__ __launch_bounds__(256) void k_prep(
    const float* __restrict__ w1, const float* __restrict__ w2,
    const float* __restrict__ phw1, const float* __restrict__ zw1,
    const float* __restrict__ phw2, const float* __restrict__ zw2,
    const float* __restrict__ g2g, const float* __restrict__ g2b,
    const float* __restrict__ w3,
    unsigned short* __restrict__ w1bf, unsigned short* __restrict__ w2bf,
    unsigned short* __restrict__ wh1, unsigned short* __restrict__ wp2,
    unsigned short* __restrict__ wz2, float* __restrict__ prm)
{
    int i = blockIdx.x * 256 + threadIdx.x;     // 0..9215
    if (i < 3072) {
        int o = i / 96, k = i - o * 96;
        int ky = k >> 5, r = k & 31, kx = r >> 3, c = r & 7;
        float v = (kx < 3 && c < 5) ? w1[o * 45 + c * 9 + ky * 3 + kx] : 0.f;
        w1bf[i] = f2bf(v);
    }
    if (i < 9216) {
        int tap = i >> 10, rr = i & 1023, o = rr >> 5, ci = rr & 31;
        w2bf[i] = f2bf(w2[o * 288 + ci * 9 + tap]);
    }
    if (i < 4608) {
        int o = i / 96, k = i - o * 96;
        int ky = k >> 5, r = k & 31, kx = r >> 3, c = r & 7;
        float v = 0.f;
        if (kx < 3 && c < 3)
            v = (o < 16) ? phw1[o * 27 + c * 9 + ky * 3 + kx]
                         : zw1[(o - 16) * 27 + c * 9 + ky * 3 + kx];
        wh1[i] = f2bf(v);
    }
    if (i < 4608) {
        int tap = i / 512, rr = i - tap * 512, n = rr >> 5, k = rr & 31;
        float vp = (n < 3 && k < 16) ? phw2[n * 144 + k * 9 + tap] : 0.f;
        float vz = (n < 3) ? zw2[n * 288 + k * 9 + tap] : 0.f;
        wp2[i] = f2bf(vp);
        wz2[i] = f2bf(vz);
    }
    if (i < 160) {
        if (i < 32) {
            int ch = (i & 1) * 16 + (i >> 1);
            prm[i] = g2g[ch];
        } else if (i < 64) {
            int j = i - 32, ch = (j & 1) * 16 + (j >> 1);
            prm[i] = g2b[ch];
        } else {
            int j = (i - 64) & 31, c = (i - 64) >> 5;
            int ch = (j & 1) * 16 + (j >> 1);
            prm[i] = w3[c * 32 + ch];
        }
    }
}

__global__ __launch_bounds__(256) void k_reduce_x(const float* __restrict__ x,
                                                  float* __restrict__ red) {
    int b = blockIdx.x >> 5, blk = blockIdx.x & 31;
    const float4* xv = (const float4*)(x + (size_t)b * CHW + (size_t)blk * (CHW / 32));
    float s = 0.f, ss = 0.f;
    for (int i = threadIdx.x; i < (CHW / 32) / 4; i += 256) {
        float4 v = xv[i];
        s  += v.x + v.y + v.z + v.w;
        ss += v.x * v.x + v.y * v.y + v.z * v.z + v.w * v.w;
    }
    float rs = blockReduceSum(s);
    float rss = blockReduceSum(ss);
    if (threadIdx.x == 0) { atomicAdd(&red[b], rs); atomicAdd(&red[8 + b], rss); }
}

// ---------------- fused heads (MFMA): xn -> [ph16 | z32] hidden -> phi + z partials ----------------
__global__ __launch_bounds__(256) void k_heads(
    const float* __restrict__ x, const float* __restrict__ red,
    const float* __restrict__ ng, const float* __restrict__ nb,
    const unsigned short* __restrict__ wh1,
    const float* __restrict__ phb1, const float* __restrict__ zb1,
    const unsigned short* __restrict__ wp2, const unsigned short* __restrict__ wz2,
    const float* __restrict__ phb2, const float* __restrict__ zb2,
    float* __restrict__ phi, float* __restrict__ part)
{
    const int tx0 = blockIdx.x * 16, ty0 = blockIdx.y * 16, b = blockIdx.z;
    const int local = blockIdx.y * 32 + blockIdx.x;
    __shared__ unsigned short mt8[20 * 21 * 8];
    __shared__ unsigned short ht8[324 * 48];
    const int t = threadIdx.x;
    const float mu = red[b] * (1.f / CHW);
    const float rsv = rsqrtf(red[8 + b] * (1.f / CHW) - mu * mu + GEPS);
    float sc[3], sh[3];
    #pragma unroll
    for (int c = 0; c < 3; ++c) { sc[c] = rsv * ng[c]; sh[c] = nb[c] - mu * rsv * ng[c]; }
    for (int e = t; e < 20 * 21; e += 256) {
        int yy = e / 21, xx = e - yy * 21;
        int gy = ty0 - 2 + yy, gx = tx0 - 2 + xx;
        float v0 = 0, v1 = 0, v2 = 0;
        if (xx < 20 && (unsigned)gy < (unsigned)Hn && (unsigned)gx < (unsigned)Wn) {
            size_t p = (size_t)b * CHW + (size_t)gy * Wn + gx;
            v0 = x[p] * sc[0] + sh[0];
            v1 = x[p + HW] * sc[1] + sh[1];
            v2 = x[p + 2 * HW] * sc[2] + sh[2];
        }
        unsigned short* d = mt8 + e * 8;
        d[0] = f2bf(v0); d[1] = f2bf(v1); d[2] = f2bf(v2);
        d[3] = 0; d[4] = 0; d[5] = 0; d[6] = 0; d[7] = 0;
    }
    const int wv = t >> 6, lane = t & 63, ln = lane & 15, q = lane >> 4;
    bfx8 Bf[3][3];
    #pragma unroll
    for (int ks = 0; ks < 3; ++ks)
        #pragma unroll
        for (int nt = 0; nt < 3; ++nt)
            Bf[ks][nt] = *(const bfx8*)(wh1 + (nt * 16 + ln) * 96 + ks * 32 + q * 8);
    const float bb0 = phb1[ln], bb1 = zb1[ln], bb2 = zb1[16 + ln];
    __syncthreads();
    for (int mt = wv; mt < 21; mt += 4) {
        int p = mt * 16 + ln; if (p > 323) p = 323;
        const int hy = p / 18, hx = p - hy * 18;
        fx4 a0 = {0,0,0,0}, a1 = {0,0,0,0}, a2 = {0,0,0,0};
        #pragma unroll
        for (int ks = 0; ks < 3; ++ks) {
            bfx8 A = *(const bfx8*)(mt8 + ((hy + ks) * 21 + hx + q) * 8);
            a0 = __builtin_amdgcn_mfma_f32_16x16x32_bf16(A, Bf[ks][0], a0, 0, 0, 0);
            a1 = __builtin_amdgcn_mfma_f32_16x16x32_bf16(A, Bf[ks][1], a1, 0, 0, 0);
            a2 = __builtin_amdgcn_mfma_f32_16x16x32_bf16(A, Bf[ks][2], a2, 0, 0, 0);
        }
        const int prb = mt * 16 + q * 4;
        #pragma unroll
        for (int r = 0; r < 4; ++r) {
            const int pr = prb + r;
            if (pr < 324) {
                const int py = pr / 18, px = pr - py * 18;
                const int gy = ty0 - 1 + py, gx = tx0 - 1 + px;
                const bool inimg = (unsigned)gy < (unsigned)Hn && (unsigned)gx < (unsigned)Wn;
                unsigned short* hp = ht8 + pr * 48;
                hp[ln]      = inimg ? f2bf(siluf(a0[r] + bb0)) : (unsigned short)0;
                hp[16 + ln] = inimg ? f2bf(siluf(a1[r] + bb1)) : (unsigned short)0;
                hp[32 + ln] = inimg ? f2bf(siluf(a2[r] + bb2)) : (unsigned short)0;
            }
        }
    }
    __syncthreads();
    fx4 accp[4], accz[4];
    #pragma unroll
    for (int i = 0; i < 4; ++i) { accp[i] = fx4{0,0,0,0}; accz[i] = fx4{0,0,0,0}; }
    #pragma unroll
    for (int tap = 0; tap < 9; ++tap) {
        const int ky = tap / 3, kx = tap - ky * 3;
        bfx8 Bp = *(const bfx8*)(wp2 + tap * 512 + ln * 32 + q * 8);
        bfx8 Bz = *(const bfx8*)(wz2 + tap * 512 + ln * 32 + q * 8);
        #pragma unroll
        for (int i = 0; i < 4; ++i) {
            const int oy = wv * 4 + i;
            const unsigned short* ap = ht8 + ((oy + ky) * 18 + ln + kx) * 48;
            bfx8 Ap = *(const bfx8*)(ap + q * 8);
            bfx8 Az = *(const bfx8*)(ap + 16 + q * 8);
            accp[i] = __builtin_amdgcn_mfma_f32_16x16x32_bf16(Ap, Bp, accp[i], 0, 0, 0);
            accz[i] = __builtin_amdgcn_mfma_f32_16x16x32_bf16(Az, Bz, accz[i], 0, 0, 0);
        }
    }
    float zacc = 0.f;
    const float pb = (ln < 3) ? phb2[ln] : 0.f;
    const float zb = (ln < 3) ? zb2[ln] : 0.f;
    #pragma unroll
    for (int i = 0; i < 4; ++i) {
        const int gy = ty0 + wv * 4 + i;
        #pragma unroll
        for (int r = 0; r < 4; ++r) {
            const int gx = tx0 + q * 4 + r;
            if (ln < 3) {
                phi[(size_t)b * CHW + (size_t)ln * HW + (size_t)gy * Wn + gx]
                    = tanhf(accp[i][r] + pb) * PIf;
                zacc += sigm(accz[i][r] + zb) * 0.3f;
            }
        }
    }
    #pragma unroll
    for (int c = 0; c < 3; ++c) {
        float rc = blockReduceSum((ln == c) ? zacc : 0.f);
        if (t == 0) part[PZ + (size_t)(b * 3 + c) * 1024 + local] = rc;
    }
}

// ---------------- FFT: 512-pt radix-2 Stockham (self-sorting) ----------------
template<bool INV>
DINL float2* fft512_stages(float2* a, float2* b, const float2* tw, int t)
{
    float2* src = a; float2* dst = b;
    int s = 1;
    #pragma unroll
    for (int st = 0; st < 9; ++st) {
        int q = t & (s - 1);
        float2 u = src[t], v = src[t + 256];
        float2 w = tw[t - q];
        float wy = INV ? -w.y : w.y;
        float dx = u.x - v.x, dy = u.y - v.y;
        dst[2 * t - q]     = make_float2(u.x + v.x, u.y + v.y);
        dst[2 * t - q + s] = make_float2(dx * w.x - dy * wy, dx * wy + dy * w.x);
        float2* tmp = src; src = dst; dst = tmp;
        s <<= 1;
        __syncthreads();
    }
    return src;
}

__global__ __launch_bounds__(256) void k_fftA(
    const float* __restrict__ x, const float* __restrict__ phi, float2* __restrict__ U)
{
    __shared__ float2 bufA[512], bufB[512], tw[256];
    const int t = threadIdx.x;
    const size_t line = blockIdx.x;                // (b*3+c)*512 + h
    { float s, c; __sincosf(-2.f * PIf * (float)t * (1.f / 512.f), &s, &c); tw[t] = make_float2(c, s); }
    const float* xr = x + line * 512;
    const float* pr = phi + line * 512;
    #pragma unroll
    for (int i = t; i < 512; i += 256) {
        float s, c; __sincosf(pr[i], &s, &c);
        float xv = xr[i];
        bufA[i] = make_float2(xv * c, xv * s);
    }
    __syncthreads();
    float2* res = fft512_stages<false>(bufA, bufB, tw, t);
    float2* Ur = U + line * 512;
    #pragma unroll
    for (int i = t; i < 512; i += 256) Ur[i] = res[i];
}

__global__ __launch_bounds__(256) void k_transpose(float2* __restrict__ U)
{
    const int img = blockIdx.y;
    int rem = blockIdx.x, ti = 0;
    while (rem >= 16 - ti) { rem -= 16 - ti; ++ti; }
    const int tj = ti + rem;
    float2* Ub = U + (size_t)img * HW;
    __shared__ float2 ta[32][33];
    __shared__ float2 tb[32][33];
    const int t = threadIdx.x;
    const int cc = t & 31, r0 = t >> 5;
    const int ar = ti * 32, ac = tj * 32;
    #pragma unroll
    for (int k = 0; k < 4; ++k) {
        int r = r0 + k * 8;
        ta[r][cc] = Ub[(size_t)(ar + r) * 512 + ac + cc];
    }
    if (ti != tj) {
        #pragma unroll
        for (int k = 0; k < 4; ++k) {
            int r = r0 + k * 8;
            tb[r][cc] = Ub[(size_t)(ac + r) * 512 + ar + cc];
        }
    }
    __syncthreads();
    #pragma unroll
    for (int k = 0; k < 4; ++k) {
        int r = r0 + k * 8;
        Ub[(size_t)(ac + r) * 512 + ar + cc] = ta[cc][r];
    }
    if (ti != tj) {
        #pragma unroll
        for (int k = 0; k < 4; ++k) {
            int r = r0 + k * 8;
            Ub[(size_t)(ar + r) * 512 + ac + cc] = tb[cc][r];
        }
    }
}

__global__ __launch_bounds__(256) void k_fftB(
    float2* __restrict__ U, const float* __restrict__ red, const float* __restrict__ fgain)
{
    __shared__ float2 bufA[512], bufB[512], tw[256];
    const int t = threadIdx.x;
    const int line = blockIdx.x;                   // (b*3+c)*512 + fw
    const int bc = line >> 9;
    const int fw = line & 511;
    const int c = bc % 3;
    { float s, cc2; __sincosf(-2.f * PIf * (float)t * (1.f / 512.f), &s, &cc2); tw[t] = make_float2(cc2, s); }
    float2* Ur = U + (size_t)line * 512;
    #pragma unroll
    for (int i = t; i < 512; i += 256) bufA[i] = Ur[i];
    __syncthreads();
    float2* res = fft512_stages<false>(bufA, bufB, tw, t);
    const float zm   = red[16 + bc] * (1.f / HW);
    const float gain = 1.f + fgain[c];
    const float lam  = (c == 0) ? 0.65f : (c == 1) ? 0.53f : 0.47f;
    const float il2  = 1.f / (lam * lam);
    const float fwv  = (float)(fw < 256 ? fw : fw - 512) * (1.f / 512.f);
    const float f2w  = fwv * fwv;
    #pragma unroll
    for (int i = t; i < 512; i += 256) {
        float fh = (float)(i < 256 ? i : i - 512) * (1.f / 512.f);
        float kz = 2.f * PIf * sqrtf(fmaxf(il2 - f2w - fh * fh, 0.f));
        float sn, cs; __sincosf(kz * zm, &sn, &cs);
        float2 v = res[i];
        res[i] = make_float2(gain * (v.x * cs - v.y * sn), gain * (v.x * sn + v.y * cs));
    }
    __syncthreads();
    float2* other = (res == (float2*)bufA) ? (float2*)bufB : (float2*)bufA;
    float2* res2 = fft512_stages<true>(res, other, tw, t);
    #pragma unroll
    for (int i = t; i < 512; i += 256) {
        float2 v = res2[i];
        Ur[i] = make_float2(v.x * (1.f / 512.f), v.y * (1.f / 512.f));
    }
}

__global__ __launch_bounds__(256) void k_fftC(
    const float2* __restrict__ U, float* __restrict__ J)
{
    __shared__ float2 bufA[512], bufB[512], tw[256];
    const int t = threadIdx.x;
    const size_t line = blockIdx.x;
    { float s, c; __sincosf(-2.f * PIf * (float)t * (1.f / 512.f), &s, &c); tw[t] = make_float2(c, s); }
    const float2* Ur = U + line * 512;
    #pragma unroll
    for (int i = t; i < 512; i += 256) bufA[i] = Ur[i];
    __syncthreads();
    float2* res = fft512_stages<true>(bufA, bufB, tw, t);
    float* Jr = J + line * 512;
    #pragma unroll
    for (int i = t; i < 512; i += 256) {
        float2 v = res[i];
        float re = v.x * (1.f / 512.f), im = v.y * (1.f / 512.f);
        Jr[i] = sqrtf(fmaxf(re * re + im * im, 1e-12f));
    }
}

// ---------------- mix path (MFMA) ----------------
__global__ __launch_bounds__(256) void k_m1(
    const float* __restrict__ x, const float* __restrict__ Jb,
    const unsigned short* __restrict__ w1bf, const float* __restrict__ b1,
    float* __restrict__ part)
{
    const int tx0 = blockIdx.x * 16, ty0 = blockIdx.y * 16, b = blockIdx.z;
    const int local = blockIdx.y * 32 + blockIdx.x;
    __shared__ unsigned short mt8[18 * 19 * 8];
    const int t = threadIdx.x;
    for (int e = t; e < 18 * 19; e += 256) {
        int yy = e / 19, xx = e - yy * 19;
        int gy = ty0 - 1 + yy, gx = tx0 - 1 + xx;
        float v0 = 0, v1 = 0, v2 = 0, jl = 0, d5 = 0;
        if (xx < 18 && (unsigned)gy < (unsigned)Hn && (unsigned)gx < (unsigned)Wn) {
            size_t p = (size_t)b * CHW + (size_t)gy * Wn + gx;
            v0 = x[p]; v1 = x[p + HW]; v2 = x[p + 2 * HW];
            float j0 = Jb[p], j1 = Jb[p + HW], j2 = Jb[p + 2 * HW];
            float xl = 0.299f * v0 + 0.587f * v1 + 0.114f * v2;
            jl = 0.299f * j0 + 0.587f * j1 + 0.114f * j2;
            d5 = jl - xl;
        }
        unsigned short* d = mt8 + e * 8;
        d[0] = f2bf(v0); d[1] = f2bf(v1); d[2] = f2bf(v2);
        d[3] = f2bf(jl); d[4] = f2bf(d5); d[5] = 0; d[6] = 0; d[7] = 0;
    }
    __syncthreads();
    const int wv = t >> 6, lane = t & 63, ln = lane & 15, q = lane >> 4;
    bfx8 Bf[3][2];
    #pragma unroll
    for (int ks = 0; ks < 3; ++ks)
        #pragma unroll
        for (int nt = 0; nt < 2; ++nt)
            Bf[ks][nt] = *(const bfx8*)(w1bf + (nt * 16 + ln) * 96 + ks * 32 + q * 8);
    const float b1v0 = b1[ln], b1v1 = b1[16 + ln];
    float s = 0.f, ss = 0.f;
    #pragma unroll
    for (int i = 0; i < 4; ++i) {
        const int oy = wv * 4 + i;
        fx4 a0 = {0.f, 0.f, 0.f, 0.f}, a1 = {0.f, 0.f, 0.f, 0.f};
        #pragma unroll
        for (int ks = 0; ks < 3; ++ks) {
            bfx8 A = *(const bfx8*)(mt8 + ((oy + ks) * 19 + ln + q) * 8);
            a0 = __builtin_amdgcn_mfma_f32_16x16x32_bf16(A, Bf[ks][0], a0, 0, 0, 0);
            a1 = __builtin_amdgcn_mfma_f32_16x16x32_bf16(A, Bf[ks][1], a1, 0, 0, 0);
        }
        #pragma unroll
        for (int r = 0; r < 4; ++r) {
            float u0 = a0[r] + b1v0, u1 = a1[r] + b1v1;
            s += u0 + u1; ss += u0 * u0 + u1 * u1;
        }
    }
    float rs = blockReduceSum(s);
    float rss = blockReduceSum(ss);
    if (t == 0) {
        part[PG1 + (size_t)b * 1024 + local] = rs;
        part[PG1 + (size_t)(8 + b) * 1024 + local] = rss;
    }
}

// conv1 -> gn1 -> silu -> conv2 (MFMA); y2 channel-last + gn2 partials
__global__ __launch_bounds__(256) void k_m2(
    const float* __restrict__ x, const float* __restrict__ Jb,
    const unsigned short* __restrict__ w1bf, const float* __restrict__ b1,
    const float* __restrict__ g1g, const float* __restrict__ g1b,
    const unsigned short* __restrict__ w2bf, const float* __restrict__ b2,
    const float* __restrict__ red, float* __restrict__ part,
    unsigned short* __restrict__ y2)
{
    const int tx0 = blockIdx.x * 16, ty0 = blockIdx.y * 16, b = blockIdx.z;
    const int local = blockIdx.y * 32 + blockIdx.x;
    __shared__ unsigned short mt8[20 * 21 * 8];
    __shared__ unsigned short dt2[324 * 32];
    const int t = threadIdx.x;
    const float mu1 = red[40 + b] * (1.f / (32.f * HW));
    const float rs1 = rsqrtf(red[48 + b] * (1.f / (32.f * HW)) - mu1 * mu1 + GEPS);
    for (int e = t; e < 20 * 21; e += 256) {
        int yy = e / 21, xx = e - yy * 21;
        int gy = ty0 - 2 + yy, gx = tx0 - 2 + xx;
        float v0 = 0, v1 = 0, v2 = 0, jl = 0, d5 = 0;
        if (xx < 20 && (unsigned)gy < (unsigned)Hn && (unsigned)gx < (unsigned)Wn) {
            size_t p = (size_t)b * CHW + (size_t)gy * Wn + gx;
            v0 = x[p]; v1 = x[p + HW]; v2 = x[p + 2 * HW];
            float j0 = Jb[p], j1 = Jb[p + HW], j2 = Jb[p + 2 * HW];
            float xl = 0.299f * v0 + 0.587f * v1 + 0.114f * v2;
            jl = 0.299f * j0 + 0.587f * j1 + 0.114f * j2;
            d5 = jl - xl;
        }
        unsigned short* d = mt8 + e * 8;
        d[0] = f2bf(v0); d[1] = f2bf(v1); d[2] = f2bf(v2);
        d[3] = f2bf(jl); d[4] = f2bf(d5); d[5] = 0; d[6] = 0; d[7] = 0;
    }
    const int wv = t >> 6, lane = t & 63, ln = lane & 15, q = lane >> 4;
    const float sc0 = rs1 * g1g[ln],       sc1 = rs1 * g1g[16 + ln];
    const float of0 = (b1[ln] - mu1) * sc0 + g1b[ln];
    const float of1 = (b1[16 + ln] - mu1) * sc1 + g1b[16 + ln];
    bfx8 Bf[3][2];
    #pragma unroll
    for (int ks = 0; ks < 3; ++ks)
        #pragma unroll
        for (int nt = 0; nt < 2; ++nt)
            Bf[ks][nt] = *(const bfx8*)(w1bf + (nt * 16 + ln) * 96 + ks * 32 + q * 8);
    __syncthreads();
    for (int mt = wv; mt < 21; mt += 4) {
        int p = mt * 16 + ln; if (p > 323) p = 323;
        const int hy = p / 18, hx = p - hy * 18;
        fx4 a0 = {0.f, 0.f, 0.f, 0.f}, a1 = {0.f, 0.f, 0.f, 0.f};
        #pragma unroll
        for (int ks = 0; ks < 3; ++ks) {
            bfx8 A = *(const bfx8*)(mt8 + ((hy + ks) * 21 + hx + q) * 8);
            a0 = __builtin_amdgcn_mfma_f32_16x16x32_bf16(A, Bf[ks][0], a0, 0, 0, 0);
            a1 = __builtin_amdgcn_mfma_f32_16x16x32_bf16(A, Bf[ks][1], a1, 0, 0, 0);
        }
        const int prb = mt * 16 + q * 4;
        #pragma unroll
        for (int r = 0; r < 4; ++r) {
            const int pr = prb + r;
            if (pr < 324) {
                const int py = pr / 18, px = pr - py * 18;
                const int gy = ty0 - 1 + py, gx = tx0 - 1 + px;
                const bool inimg = (unsigned)gy < (unsigned)Hn && (unsigned)gx < (unsigned)Wn;
                dt2[pr * 32 + ln]      = inimg ? f2bf(siluf(a0[r] * sc0 + of0)) : (unsigned short)0;
                dt2[pr * 32 + 16 + ln] = inimg ? f2bf(siluf(a1[r] * sc1 + of1)) : (unsigned short)0;
            }
        }
    }
    __syncthreads();
    fx4 c2[4][2];
    #pragma unroll
    for (int i = 0; i < 4; ++i)
        #pragma unroll
        for (int nt = 0; nt < 2; ++nt)
            c2[i][nt] = fx4{0.f, 0.f, 0.f, 0.f};
    #pragma unroll
    for (int tap = 0; tap < 9; ++tap) {
        const int ky = tap / 3, kx = tap - ky * 3;
        bfx8 B0 = *(const bfx8*)(w2bf + tap * 1024 + ln * 32 + q * 8);
        bfx8 B1 = *(const bfx8*)(w2bf + tap * 1024 + (16 + ln) * 32 + q * 8);
        #pragma unroll
        for (int i = 0; i < 4; ++i) {
            const int oy = wv * 4 + i;
            bfx8 A = *(const bfx8*)(dt2 + ((oy + ky) * 18 + ln + kx) * 32 + q * 8);
            c2[i][0] = __builtin_amdgcn_mfma_f32_16x16x32_bf16(A, B0, c2[i][0], 0, 0, 0);
            c2[i][1] = __builtin_amdgcn_mfma_f32_16x16x32_bf16(A, B1, c2[i][1], 0, 0, 0);
        }
    }
    float s = 0.f, ss = 0.f;
    const float b2v0 = b2[ln], b2v1 = b2[16 + ln];
    #pragma unroll
    for (int i = 0; i < 4; ++i) {
        const int gy = ty0 + wv * 4 + i;
        #pragma unroll
        for (int r = 0; r < 4; ++r) {
            const int gx = tx0 + q * 4 + r;
            float a0 = c2[i][0][r] + b2v0;
            float a1 = c2[i][1][r] + b2v1;
            s += a0 + a1; ss += a0 * a0 + a1 * a1;
            unsigned pk = (unsigned)f2bf(a0) | ((unsigned)f2bf(a1) << 16);
            size_t off = ((size_t)b * HW + (size_t)gy * Wn + gx) * 32 + ln * 2;
            *(unsigned*)(y2 + off) = pk;
        }
    }
    float rsum = blockReduceSum(s);
    float rss = blockReduceSum(ss);
    if (t == 0) {
        part[PG2 + (size_t)b * 1024 + local] = rsum;
        part[PG2 + (size_t)(8 + b) * 1024 + local] = rss;
    }
}

// gn2 -> silu -> 1x1 conv; channel-last y2; dsum partials (no atomics)
__global__ __launch_bounds__(256) void k_m3(
    const unsigned short* __restrict__ y2, const float* __restrict__ red,
    const float* __restrict__ prm, const float* __restrict__ b3,
    float* __restrict__ dl, float* __restrict__ part)
{
    int idx = blockIdx.x * 256 + threadIdx.x;     // global pixel (b*HW+pix)
    int b = idx >> 18;
    int pix = idx & (HW - 1);
    const int local = blockIdx.x & 1023;
    float mu = red[56 + b] * (1.f / (32.f * HW));
    float rs = rsqrtf(red[64 + b] * (1.f / (32.f * HW)) - mu * mu + GEPS);
    const uint4* yp = (const uint4*)(y2 + (size_t)idx * 32);
    uint4 L[4];
    #pragma unroll
    for (int c = 0; c < 4; ++c) L[c] = yp[c];
    float a0 = b3[0], a1 = b3[1], a2 = b3[2];
    const unsigned* Lw = (const unsigned*)L;
    #pragma unroll
    for (int w = 0; w < 16; ++w) {     // 16 dwords = all 32 channels
        unsigned u = Lw[w];
        #pragma unroll
        for (int h = 0; h < 2; ++h) {
            int j = w * 2 + h;
            float v = bf2f((unsigned short)(h ? (u >> 16) : (u & 0xFFFFu)));
            float dn = (v - mu) * rs * prm[j] + prm[32 + j];
            float sv = siluf(dn);
            a0 += sv * prm[64 + j]; a1 += sv * prm[96 + j]; a2 += sv * prm[128 + j];
        }
    }
    size_t p = (size_t)b * CHW + pix;
    dl[p] = a0; dl[p + HW] = a1; dl[p + 2 * HW] = a2;
    float r0 = blockReduceSum(a0);
    float r1 = blockReduceSum(a1);
    float r2 = blockReduceSum(a2);
    if (threadIdx.x == 0) {
        part[PD + (size_t)(b * 3 + 0) * 1024 + local] = r0;
        part[PD + (size_t)(b * 3 + 1) * 1024 + local] = r1;
        part[PD + (size_t)(b * 3 + 2) * 1024 + local] = r2;
    }
}

__global__ void k_se(float* __restrict__ red,
    const float* __restrict__ w1, const float* __restrict__ b1,
    const float* __restrict__ w2, const float* __restrict__ b2,
    const float* __restrict__ alpha)
{
    int b = threadIdx.x;
    if (b < 8) {
        float p0 = red[72 + b * 3 + 0] * (1.f / HW);
        float p1 = red[72 + b * 3 + 1] * (1.f / HW);
        float p2 = red[72 + b * 3 + 2] * (1.f / HW);
        float h[4];
        #pragma unroll
        for (int j = 0; j < 4; ++j) {
            float a = b1[j] + p0 * w1[j * 3] + p1 * w1[j * 3 + 1] + p2 * w1[j * 3 + 2];
            h[j] = siluf(a);
        }
        float al = alpha[0];
        #pragma unroll
        for (int c = 0; c < 3; ++c) {
            float a = b2[c] + h[0] * w2[c * 4] + h[1] * w2[c * 4 + 1]
                            + h[2] * w2[c * 4 + 2] + h[3] * w2[c * 4 + 3];
            red[96 + b * 3 + c] = al * sigm(a);
        }
    }
}

__global__ __launch_bounds__(256) void k_out(
    const float* __restrict__ x, const float* __restrict__ dl,
    const float* __restrict__ red, float* __restrict__ out)
{
    int i = blockIdx.x * 256 + threadIdx.x;     // float4 index
    float aw = red[96 + (i >> 16)];
    float4 xv = ((const float4*)x)[i];
    float4 dv = ((const float4*)dl)[i];
    float4 o;
    o.x = xv.x + aw * dv.x; o.y = xv.y + aw * dv.y;
    o.z = xv.z + aw * dv.z; o.w = xv.w + aw * dv.w;
    ((float4*)out)[i] = o;
}

extern "C" void kernel_launch(void* const* d_in, const int* in_sizes, int n_in,
                              void* d_out, int out_size, void* d_ws, size_t ws_size,
                              hipStream_t stream)
{
    const float* x     = (const float*)d_in[0];
    const float* ng    = (const float*)d_in[1];
    const float* nb    = (const float*)d_in[2];
    const float* ph_w1 = (const float*)d_in[3];
    const float* ph_b1 = (const float*)d_in[4];
    const float* ph_w2 = (const float*)d_in[5];
    const float* ph_b2 = (const float*)d_in[6];
    const float* z_w1  = (const float*)d_in[7];
    const float* z_b1  = (const float*)d_in[8];
    const float* z_w2  = (const float*)d_in[9];
    const float* z_b2  = (const float*)d_in[10];
    const float* fgain = (const float*)d_in[11];
    const float* mw1   = (const float*)d_in[12];
    const float* mb1   = (const float*)d_in[13];
    const float* g1g   = (const float*)d_in[14];
    const float* g1b   = (const float*)d_in[15];
    const float* mw2   = (const float*)d_in[16];
    const float* mb2   = (const float*)d_in[17];
    const float* g2g   = (const float*)d_in[18];
    const float* g2b   = (const float*)d_in[19];
    const float* mw3   = (const float*)d_in[20];
    const float* mb3   = (const float*)d_in[21];
    const float* sw1   = (const float*)d_in[22];
    const float* sb1   = (const float*)d_in[23];
    const float* sw2   = (const float*)d_in[24];
    const float* sb2   = (const float*)d_in[25];
    const float* alpha = (const float*)d_in[26];

    char* ws = (char*)d_ws;
    float*  red = (float*)(ws + OFF_RED);
    float*  phi = (float*)(ws + OFF_PHI);
    float2* U   = (float2*)(ws + OFF_U);
    float*  Jb  = (float*)(ws + OFF_J);
    float*  dl  = (float*)(ws + OFF_D);
    unsigned short* y2   = (unsigned short*)(ws + OFF_Y2);
    unsigned short* w1bf = (unsigned short*)(ws + OFF_W1B);
    unsigned short* w2bf = (unsigned short*)(ws + OFF_W2B);
    unsigned short* wh1  = (unsigned short*)(ws + OFF_WH1);
    unsigned short* wp2  = (unsigned short*)(ws + OFF_WP2);
    unsigned short* wz2  = (unsigned short*)(ws + OFF_WZ2);
    float* prm  = (float*)(ws + OFF_PRM);
    float* part = (float*)(ws + OFF_PART);
    float* out = (float*)d_out;

    hipLaunchKernelGGL(k_zero, dim3(1), dim3(128), 0, stream, red);
    hipLaunchKernelGGL(k_prep, dim3(36), dim3(256), 0, stream,
                       mw1, mw2, ph_w1, z_w1, ph_w2, z_w2, g2g, g2b, mw3,
                       w1bf, w2bf, wh1, wp2, wz2, prm);
    hipLaunchKernelGGL(k_reduce_x, dim3(256), dim3(256), 0, stream, x, red);
    hipLaunchKernelGGL(k_heads, dim3(32, 32, 8), dim3(256), 0, stream,
                       x, red, ng, nb, wh1, ph_b1, z_b1, wp2, wz2, ph_b2, z_b2, phi, part);
    hipLaunchKernelGGL(k_red, dim3(24), dim3(256), 0, stream, part + PZ, red + 16);
    hipLaunchKernelGGL(k_fftA, dim3(12288), dim3(256), 0, stream, x, phi, U);
    hipLaunchKernelGGL(k_transpose, dim3(136, 24), dim3(256), 0, stream, U);
    hipLaunchKernelGGL(k_fftB, dim3(12288), dim3(256), 0, stream, U, red, fgain);
    hipLaunchKernelGGL(k_transpose, dim3(136, 24), dim3(256), 0, stream, U);
    hipLaunchKernelGGL(k_fftC, dim3(12288), dim3(256), 0, stream, U, Jb);
    hipLaunchKernelGGL(k_m1, dim3(32, 32, 8), dim3(256), 0, stream, x, Jb, w1bf, mb1, part);
    hipLaunchKernelGGL(k_red, dim3(16), dim3(256), 0, stream, part + PG1, red + 40);
    hipLaunchKernelGGL(k_m2, dim3(32, 32, 8), dim3(256), 0, stream,
                       x, Jb, w1bf, mb1, g1g, g1b, w2bf, mb2, red, part, y2);
    hipLaunchKernelGGL(k_red, dim3(16), dim3(256), 0, stream, part + PG2, red + 56);
    hipLaunchKernelGGL(k_m3, dim3(8192), dim3(256), 0, stream, y2, red, prm, mb3, dl, part);
    hipLaunchKernelGGL(k_red, dim3(24), dim3(256), 0, stream, part + PD, red + 72);
    hipLaunchKernelGGL(k_se, dim3(1), dim3(64), 0, stream, red, sw1, sb1, sw2, sb2, alpha);
    hipLaunchKernelGGL(k_out, dim3(6144), dim3(256), 0, stream, x, dl, red, out);
}

// Round 8
// 622.639 us; speedup vs baseline: 4.8626x; 1.0628x over previous
//
#include <hip/hip_runtime.h>
#include <hip/hip_bf16.h>
#include <math.h>

#define DINL __device__ __forceinline__

namespace {
constexpr int Bn = 8, Cn = 3, Hn = 512, Wn = 512;
constexpr int HW  = Hn * Wn;        // 262144
constexpr int CHW = Cn * HW;        // 786432
constexpr float GEPS = 1e-5f;
constexpr float PIf  = 3.14159265358979323846f;

// workspace layout (bytes)
constexpr size_t OFF_RED = 0;                                   // 128 floats
constexpr size_t OFF_PHI = 512;
constexpr size_t OFF_U   = OFF_PHI + (size_t)Bn * CHW * 4;
constexpr size_t OFF_J   = OFF_U   + (size_t)Bn * CHW * 8;
constexpr size_t OFF_D   = OFF_J   + (size_t)Bn * CHW * 4;
constexpr size_t OFF_Y2  = OFF_D   + (size_t)Bn * CHW * 4;      // 8*32*HW bf16 (channel-last)
constexpr size_t OFF_W1B = OFF_Y2  + (size_t)Bn * 32 * HW * 2;  // 3072 bf16
constexpr size_t OFF_W2B = OFF_W1B + 3072 * 2;                  // 9216 bf16
constexpr size_t OFF_WH1 = OFF_W2B + 9216 * 2;                  // 4608 bf16
constexpr size_t OFF_WP2 = OFF_WH1 + 4608 * 2;                  // 4608 bf16
constexpr size_t OFF_WZ2 = OFF_WP2 + 4608 * 2;                  // 4608 bf16
constexpr size_t OFF_PRM = OFF_WZ2 + 4608 * 2;                  // 160 f32
constexpr size_t OFF_PART= OFF_PRM + 160 * 4;                   // 81920 f32 partials
// part float sub-offsets (in floats)
constexpr int PZ = 0;          // 24 groups (b*3+c) x 1024
constexpr int PG1 = 24576;     // 16 groups (b:sum, 8+b:ss) x 1024
constexpr int PG2 = 40960;     // 16 groups x 1024
constexpr int PD  = 57344;     // 24 groups (b*3+c) x 1024
}

typedef __bf16 bfx8 __attribute__((ext_vector_type(8)));
typedef float  fx4  __attribute__((ext_vector_type(4)));

DINL float sigm(float a) { return __frcp_rn(1.f + __expf(-a)); }
DINL float siluf(float a) { return a * __frcp_rn(1.f + __expf(-a)); }
DINL float ftanh(float a) { return 1.f - 2.f * __frcp_rn(1.f + __expf(2.f * a)); }
DINL unsigned short f2bf(float f) {           // RNE float->bf16 bits
    unsigned u = __float_as_uint(f);
    return (unsigned short)((u + 0x7FFFu + ((u >> 16) & 1u)) >> 16);
}
DINL float bf2f(unsigned short h) {
    return __uint_as_float(((unsigned)h) << 16);
}
DINL unsigned pk2(float a, float b) {
    return (unsigned)f2bf(a) | ((unsigned)f2bf(b) << 16);
}

DINL float blockReduceSum(float v) {   // blockDim.x == 256
    __shared__ float sm[4];
    int lane = threadIdx.x & 63, wid = threadIdx.x >> 6;
    #pragma unroll
    for (int o = 32; o > 0; o >>= 1) v += __shfl_down(v, o, 64);
    __syncthreads();
    if (lane == 0) sm[wid] = v;
    __syncthreads();
    if (wid == 0) {
        float r = (lane < 4) ? sm[lane] : 0.f;
        r += __shfl_down(r, 2, 64);
        r += __shfl_down(r, 1, 64);
        return r;                       // valid on thread 0
    }
    return 0.f;
}

__global__ void k_zero(float* __restrict__ red) { red[threadIdx.x] = 0.f; }

__global__ __launch_bounds__(256) void k_red(const float* __restrict__ src,
                                             float* __restrict__ dst)
{
    const float4* s4 = (const float4*)(src + (size_t)blockIdx.x * 1024);
    float4 q = s4[threadIdx.x];
    float r = blockReduceSum(q.x + q.y + q.z + q.w);
    if (threadIdx.x == 0) dst[blockIdx.x] = r;
}

// weight repack (all bf16 fragment-order)
__global__ __launch_bounds__(256) void k_prep(
    const float* __restrict__ w1, const float* __restrict__ w2,
    const float* __restrict__ phw1, const float* __restrict__ zw1,
    const float* __restrict__ phw2, const float* __restrict__ zw2,
    const float* __restrict__ g2g, const float* __restrict__ g2b,
    const float* __restrict__ w3,
    unsigned short* __restrict__ w1bf, unsigned short* __restrict__ w2bf,
    unsigned short* __restrict__ wh1, unsigned short* __restrict__ wp2,
    unsigned short* __restrict__ wz2, float* __restrict__ prm)
{
    int i = blockIdx.x * 256 + threadIdx.x;     // 0..9215
    if (i < 3072) {
        int o = i / 96, k = i - o * 96;
        int ky = k >> 5, r = k & 31, kx = r >> 3, c = r & 7;
        float v = (kx < 3 && c < 5) ? w1[o * 45 + c * 9 + ky * 3 + kx] : 0.f;
        w1bf[i] = f2bf(v);
    }
    if (i < 9216) {
        int tap = i >> 10, rr = i & 1023, o = rr >> 5, ci = rr & 31;
        w2bf[i] = f2bf(w2[o * 288 + ci * 9 + tap]);
    }
    if (i < 4608) {
        int o = i / 96, k = i - o * 96;
        int ky = k >> 5, r = k & 31, kx = r >> 3, c = r & 7;
        float v = 0.f;
        if (kx < 3 && c < 3)
            v = (o < 16) ? phw1[o * 27 + c * 9 + ky * 3 + kx]
                         : zw1[(o - 16) * 27 + c * 9 + ky * 3 + kx];
        wh1[i] = f2bf(v);
    }
    if (i < 4608) {
        int tap = i / 512, rr = i - tap * 512, n = rr >> 5, k = rr & 31;
        float vp = (n < 3 && k < 16) ? phw2[n * 144 + k * 9 + tap] : 0.f;
        float vz = (n < 3) ? zw2[n * 288 + k * 9 + tap] : 0.f;
        wp2[i] = f2bf(vp);
        wz2[i] = f2bf(vz);
    }
    if (i < 160) {
        if (i < 32) {
            int ch = (i & 1) * 16 + (i >> 1);
            prm[i] = g2g[ch];
        } else if (i < 64) {
            int j = i - 32, ch = (j & 1) * 16 + (j >> 1);
            prm[i] = g2b[ch];
        } else {
            int j = (i - 64) & 31, c = (i - 64) >> 5;
            int ch = (j & 1) * 16 + (j >> 1);
            prm[i] = w3[c * 32 + ch];
        }
    }
}

__global__ __launch_bounds__(256) void k_reduce_x(const float* __restrict__ x,
                                                  float* __restrict__ red) {
    int b = blockIdx.x >> 5, blk = blockIdx.x & 31;
    const float4* xv = (const float4*)(x + (size_t)b * CHW + (size_t)blk * (CHW / 32));
    float s = 0.f, ss = 0.f;
    for (int i = threadIdx.x; i < (CHW / 32) / 4; i += 256) {
        float4 v = xv[i];
        s  += v.x + v.y + v.z + v.w;
        ss += v.x * v.x + v.y * v.y + v.z * v.z + v.w * v.w;
    }
    float rs = blockReduceSum(s);
    float rss = blockReduceSum(ss);
    if (threadIdx.x == 0) { atomicAdd(&red[b], rs); atomicAdd(&red[8 + b], rss); }
}

// ---------------- fused heads (MFMA): xn -> [ph16 | z32] hidden -> phi + z partials ----------------
__global__ __launch_bounds__(256) void k_heads(
    const float* __restrict__ x, const float* __restrict__ red,
    const float* __restrict__ ng, const float* __restrict__ nb,
    const unsigned short* __restrict__ wh1,
    const float* __restrict__ phb1, const float* __restrict__ zb1,
    const unsigned short* __restrict__ wp2, const unsigned short* __restrict__ wz2,
    const float* __restrict__ phb2, const float* __restrict__ zb2,
    float* __restrict__ phi, float* __restrict__ part)
{
    const int tx0 = blockIdx.x * 16, ty0 = blockIdx.y * 16, b = blockIdx.z;
    const int local = blockIdx.y * 32 + blockIdx.x;
    __shared__ unsigned short mt8[20 * 21 * 8];
    __shared__ unsigned short ht8[324 * 48];      // reused as phs/zs in epilogue
    const int t = threadIdx.x;
    const float mu = red[b] * (1.f / CHW);
    const float rsv = rsqrtf(red[8 + b] * (1.f / CHW) - mu * mu + GEPS);
    float sc[3], sh[3];
    #pragma unroll
    for (int c = 0; c < 3; ++c) { sc[c] = rsv * ng[c]; sh[c] = nb[c] - mu * rsv * ng[c]; }
    for (int e = t; e < 20 * 21; e += 256) {
        int yy = e / 21, xx = e - yy * 21;
        int gy = ty0 - 2 + yy, gx = tx0 - 2 + xx;
        float v0 = 0, v1 = 0, v2 = 0;
        if (xx < 20 && (unsigned)gy < (unsigned)Hn && (unsigned)gx < (unsigned)Wn) {
            size_t p = (size_t)b * CHW + (size_t)gy * Wn + gx;
            v0 = x[p] * sc[0] + sh[0];
            v1 = x[p + HW] * sc[1] + sh[1];
            v2 = x[p + 2 * HW] * sc[2] + sh[2];
        }
        uint4 pk = make_uint4(pk2(v0, v1), (unsigned)f2bf(v2), 0u, 0u);
        *(uint4*)(mt8 + e * 8) = pk;
    }
    const int wv = t >> 6, lane = t & 63, ln = lane & 15, q = lane >> 4;
    bfx8 Bf[3][3];
    #pragma unroll
    for (int ks = 0; ks < 3; ++ks)
        #pragma unroll
        for (int nt = 0; nt < 3; ++nt)
            Bf[ks][nt] = *(const bfx8*)(wh1 + (nt * 16 + ln) * 96 + ks * 32 + q * 8);
    const float bb0 = phb1[ln], bb1 = zb1[ln], bb2 = zb1[16 + ln];
    __syncthreads();
    for (int mt = wv; mt < 21; mt += 4) {
        int p = mt * 16 + ln; if (p > 323) p = 323;
        const int hy = p / 18, hx = p - hy * 18;
        fx4 a0 = {0,0,0,0}, a1 = {0,0,0,0}, a2 = {0,0,0,0};
        #pragma unroll
        for (int ks = 0; ks < 3; ++ks) {
            bfx8 A = *(const bfx8*)(mt8 + ((hy + ks) * 21 + hx + q) * 8);
            a0 = __builtin_amdgcn_mfma_f32_16x16x32_bf16(A, Bf[ks][0], a0, 0, 0, 0);
            a1 = __builtin_amdgcn_mfma_f32_16x16x32_bf16(A, Bf[ks][1], a1, 0, 0, 0);
            a2 = __builtin_amdgcn_mfma_f32_16x16x32_bf16(A, Bf[ks][2], a2, 0, 0, 0);
        }
        const int prb = mt * 16 + q * 4;
        #pragma unroll
        for (int r = 0; r < 4; ++r) {
            const int pr = prb + r;
            if (pr < 324) {
                const int py = pr / 18, px = pr - py * 18;
                const int gy = ty0 - 1 + py, gx = tx0 - 1 + px;
                const bool inimg = (unsigned)gy < (unsigned)Hn && (unsigned)gx < (unsigned)Wn;
                unsigned short* hp = ht8 + pr * 48;
                hp[ln]      = inimg ? f2bf(siluf(a0[r] + bb0)) : (unsigned short)0;
                hp[16 + ln] = inimg ? f2bf(siluf(a1[r] + bb1)) : (unsigned short)0;
                hp[32 + ln] = inimg ? f2bf(siluf(a2[r] + bb2)) : (unsigned short)0;
            }
        }
    }
    __syncthreads();
    fx4 accp[4], accz[4];
    #pragma unroll
    for (int i = 0; i < 4; ++i) { accp[i] = fx4{0,0,0,0}; accz[i] = fx4{0,0,0,0}; }
    #pragma unroll
    for (int tap = 0; tap < 9; ++tap) {
        const int ky = tap / 3, kx = tap - ky * 3;
        bfx8 Bp = *(const bfx8*)(wp2 + tap * 512 + ln * 32 + q * 8);
        bfx8 Bz = *(const bfx8*)(wz2 + tap * 512 + ln * 32 + q * 8);
        #pragma unroll
        for (int i = 0; i < 4; ++i) {
            const int oy = wv * 4 + i;
            const unsigned short* ap = ht8 + ((oy + ky) * 18 + ln + kx) * 48;
            bfx8 Ap = *(const bfx8*)(ap + q * 8);
            bfx8 Az = *(const bfx8*)(ap + 16 + q * 8);
            accp[i] = __builtin_amdgcn_mfma_f32_16x16x32_bf16(Ap, Bp, accp[i], 0, 0, 0);
            accz[i] = __builtin_amdgcn_mfma_f32_16x16x32_bf16(Az, Bz, accz[i], 0, 0, 0);
        }
    }
    // epilogue via LDS: full-lane tanh/sigm, coalesced stores
    __syncthreads();                       // ht8 reads done; reuse as float staging
    float* phs = (float*)ht8;              // [256][4]
    float* zs  = phs + 1024;               // [256][4]
    if (ln < 3) {
        #pragma unroll
        for (int i = 0; i < 4; ++i)
            #pragma unroll
            for (int r = 0; r < 4; ++r) {
                int pl = (wv * 4 + i) * 16 + q * 4 + r;
                phs[pl * 4 + ln] = accp[i][r];
                zs [pl * 4 + ln] = accz[i][r];
            }
    }
    __syncthreads();
    float4 pv = ((const float4*)phs)[t];
    float4 zv = ((const float4*)zs)[t];
    const int gy = ty0 + (t >> 4), gx = tx0 + (t & 15);
    size_t pp = (size_t)b * CHW + (size_t)gy * Wn + gx;
    phi[pp]          = ftanh(pv.x + phb2[0]) * PIf;
    phi[pp + HW]     = ftanh(pv.y + phb2[1]) * PIf;
    phi[pp + 2 * HW] = ftanh(pv.z + phb2[2]) * PIf;
    float z0 = sigm(zv.x + zb2[0]) * 0.3f;
    float z1 = sigm(zv.y + zb2[1]) * 0.3f;
    float z2 = sigm(zv.z + zb2[2]) * 0.3f;
    float r0 = blockReduceSum(z0);
    float r1 = blockReduceSum(z1);
    float r2 = blockReduceSum(z2);
    if (t == 0) {
        part[PZ + (size_t)(b * 3 + 0) * 1024 + local] = r0;
        part[PZ + (size_t)(b * 3 + 1) * 1024 + local] = r1;
        part[PZ + (size_t)(b * 3 + 2) * 1024 + local] = r2;
    }
}

// ---------------- FFT: 512-pt radix-2 Stockham, wave-per-line (no block barriers) ----------------
template<bool INV>
DINL float2* fft512_wave(float2* a, float2* b, const float2* tw, int l)
{
    float2* src = a; float2* dst = b;
    int s = 1;
    #pragma unroll
    for (int st = 0; st < 9; ++st) {
        #pragma unroll
        for (int k = 0; k < 4; ++k) {
            int j = l + k * 64;
            int q = j & (s - 1);
            float2 u = src[j], v = src[j + 256];
            float2 w = tw[j - q];
            float wy = INV ? -w.y : w.y;
            float dx = u.x - v.x, dy = u.y - v.y;
            dst[2 * j - q]     = make_float2(u.x + v.x, u.y + v.y);
            dst[2 * j - q + s] = make_float2(dx * w.x - dy * wy, dx * wy + dy * w.x);
        }
        float2* tmp = src; src = dst; dst = tmp;
        s <<= 1;
        asm volatile("" ::: "memory");   // keep stages ordered; wave-sync LDS needs no barrier
    }
    return src;
}

__global__ __launch_bounds__(256) void k_fftA(
    const float* __restrict__ x, const float* __restrict__ phi, float2* __restrict__ U)
{
    __shared__ float2 buf[4][2][512];
    __shared__ float2 tw[256];
    const int t = threadIdx.x, wv = t >> 6, l = t & 63;
    { float s, c; __sincosf(-2.f * PIf * (float)t * (1.f / 512.f), &s, &c); tw[t] = make_float2(c, s); }
    __syncthreads();
    const size_t line = (size_t)blockIdx.x * 4 + wv;
    const float* xr = x + line * 512;
    const float* pr = phi + line * 512;
    float2* A = buf[wv][0];
    float2* B = buf[wv][1];
    #pragma unroll
    for (int i = l; i < 512; i += 64) {
        float s, c; __sincosf(pr[i], &s, &c);
        float xv = xr[i];
        A[i] = make_float2(xv * c, xv * s);
    }
    asm volatile("" ::: "memory");
    float2* res = fft512_wave<false>(A, B, tw, l);
    float2* Ur = U + line * 512;
    #pragma unroll
    for (int i = l; i < 512; i += 64) Ur[i] = res[i];
}

__global__ __launch_bounds__(256) void k_transpose(float2* __restrict__ U)
{
    const int img = blockIdx.y;
    int rem = blockIdx.x, ti = 0;
    while (rem >= 16 - ti) { rem -= 16 - ti; ++ti; }
    const int tj = ti + rem;
    float2* Ub = U + (size_t)img * HW;
    __shared__ float2 ta[32][33];
    __shared__ float2 tb[32][33];
    const int t = threadIdx.x;
    const int cc = t & 31, r0 = t >> 5;
    const int ar = ti * 32, ac = tj * 32;
    #pragma unroll
    for (int k = 0; k < 4; ++k) {
        int r = r0 + k * 8;
        ta[r][cc] = Ub[(size_t)(ar + r) * 512 + ac + cc];
    }
    if (ti != tj) {
        #pragma unroll
        for (int k = 0; k < 4; ++k) {
            int r = r0 + k * 8;
            tb[r][cc] = Ub[(size_t)(ac + r) * 512 + ar + cc];
        }
    }
    __syncthreads();
    #pragma unroll
    for (int k = 0; k < 4; ++k) {
        int r = r0 + k * 8;
        Ub[(size_t)(ac + r) * 512 + ar + cc] = ta[cc][r];
    }
    if (ti != tj) {
        #pragma unroll
        for (int k = 0; k < 4; ++k) {
            int r = r0 + k * 8;
            Ub[(size_t)(ar + r) * 512 + ac + cc] = tb[cc][r];
        }
    }
}

__global__ __launch_bounds__(256) void k_fftB(
    float2* __restrict__ U, const float* __restrict__ red, const float* __restrict__ fgain)
{
    __shared__ float2 buf[4][2][512];
    __shared__ float2 tw[256];
    const int t = threadIdx.x, wv = t >> 6, l = t & 63;
    { float s, c; __sincosf(-2.f * PIf * (float)t * (1.f / 512.f), &s, &c); tw[t] = make_float2(c, s); }
    __syncthreads();
    const int line = blockIdx.x * 4 + wv;          // (b*3+c)*512 + fw
    const int bc = line >> 9;
    const int fw = line & 511;
    const int c = bc % 3;
    float2* Ur = U + (size_t)line * 512;
    float2* A = buf[wv][0];
    float2* B = buf[wv][1];
    #pragma unroll
    for (int i = l; i < 512; i += 64) A[i] = Ur[i];
    asm volatile("" ::: "memory");
    float2* res = fft512_wave<false>(A, B, tw, l);
    const float zm   = red[16 + bc] * (1.f / HW);
    const float gain = 1.f + fgain[c];
    const float lam  = (c == 0) ? 0.65f : (c == 1) ? 0.53f : 0.47f;
    const float il2  = 1.f / (lam * lam);
    const float fwv  = (float)(fw < 256 ? fw : fw - 512) * (1.f / 512.f);
    const float f2w  = fwv * fwv;
    #pragma unroll
    for (int i = l; i < 512; i += 64) {
        float fh = (float)(i < 256 ? i : i - 512) * (1.f / 512.f);
        float kz = 2.f * PIf * sqrtf(fmaxf(il2 - f2w - fh * fh, 0.f));
        float sn, cs; __sincosf(kz * zm, &sn, &cs);
        float2 v = res[i];
        res[i] = make_float2(gain * (v.x * cs - v.y * sn), gain * (v.x * sn + v.y * cs));
    }
    asm volatile("" ::: "memory");
    float2* other = (res == A) ? B : A;
    float2* res2 = fft512_wave<true>(res, other, tw, l);
    #pragma unroll
    for (int i = l; i < 512; i += 64) {
        float2 v = res2[i];
        Ur[i] = make_float2(v.x * (1.f / 512.f), v.y * (1.f / 512.f));
    }
}

__global__ __launch_bounds__(256) void k_fftC(
    const float2* __restrict__ U, float* __restrict__ J)
{
    __shared__ float2 buf[4][2][512];
    __shared__ float2 tw[256];
    const int t = threadIdx.x, wv = t >> 6, l = t & 63;
    { float s, c; __sincosf(-2.f * PIf * (float)t * (1.f / 512.f), &s, &c); tw[t] = make_float2(c, s); }
    __syncthreads();
    const size_t line = (size_t)blockIdx.x * 4 + wv;
    const float2* Ur = U + line * 512;
    float2* A = buf[wv][0];
    float2* B = buf[wv][1];
    #pragma unroll
    for (int i = l; i < 512; i += 64) A[i] = Ur[i];
    asm volatile("" ::: "memory");
    float2* res = fft512_wave<true>(A, B, tw, l);
    float* Jr = J + line * 512;
    #pragma unroll
    for (int i = l; i < 512; i += 64) {
        float2 v = res[i];
        float re = v.x * (1.f / 512.f), im = v.y * (1.f / 512.f);
        Jr[i] = sqrtf(fmaxf(re * re + im * im, 1e-12f));
    }
}

// ---------------- mix path (MFMA) ----------------
__global__ __launch_bounds__(256) void k_m1(
    const float* __restrict__ x, const float* __restrict__ Jb,
    const unsigned short* __restrict__ w1bf, const float* __restrict__ b1,
    float* __restrict__ part)
{
    const int tx0 = blockIdx.x * 16, ty0 = blockIdx.y * 16, b = blockIdx.z;
    const int local = blockIdx.y * 32 + blockIdx.x;
    __shared__ unsigned short mt8[18 * 19 * 8];
    const int t = threadIdx.x;
    for (int e = t; e < 18 * 19; e += 256) {
        int yy = e / 19, xx = e - yy * 19;
        int gy = ty0 - 1 + yy, gx = tx0 - 1 + xx;
        float v0 = 0, v1 = 0, v2 = 0, jl = 0, d5 = 0;
        if (xx < 18 && (unsigned)gy < (unsigned)Hn && (unsigned)gx < (unsigned)Wn) {
            size_t p = (size_t)b * CHW + (size_t)gy * Wn + gx;
            v0 = x[p]; v1 = x[p + HW]; v2 = x[p + 2 * HW];
            float j0 = Jb[p], j1 = Jb[p + HW], j2 = Jb[p + 2 * HW];
            float xl = 0.299f * v0 + 0.587f * v1 + 0.114f * v2;
            jl = 0.299f * j0 + 0.587f * j1 + 0.114f * j2;
            d5 = jl - xl;
        }
        uint4 pk = make_uint4(pk2(v0, v1), pk2(v2, jl), (unsigned)f2bf(d5), 0u);
        *(uint4*)(mt8 + e * 8) = pk;
    }
    __syncthreads();
    const int wv = t >> 6, lane = t & 63, ln = lane & 15, q = lane >> 4;
    bfx8 Bf[3][2];
    #pragma unroll
    for (int ks = 0; ks < 3; ++ks)
        #pragma unroll
        for (int nt = 0; nt < 2; ++nt)
            Bf[ks][nt] = *(const bfx8*)(w1bf + (nt * 16 + ln) * 96 + ks * 32 + q * 8);
    const float b1v0 = b1[ln], b1v1 = b1[16 + ln];
    float s = 0.f, ss = 0.f;
    #pragma unroll
    for (int i = 0; i < 4; ++i) {
        const int oy = wv * 4 + i;
        fx4 a0 = {0.f, 0.f, 0.f, 0.f}, a1 = {0.f, 0.f, 0.f, 0.f};
        #pragma unroll
        for (int ks = 0; ks < 3; ++ks) {
            bfx8 A = *(const bfx8*)(mt8 + ((oy + ks) * 19 + ln + q) * 8);
            a0 = __builtin_amdgcn_mfma_f32_16x16x32_bf16(A, Bf[ks][0], a0, 0, 0, 0);
            a1 = __builtin_amdgcn_mfma_f32_16x16x32_bf16(A, Bf[ks][1], a1, 0, 0, 0);
        }
        #pragma unroll
        for (int r = 0; r < 4; ++r) {
            float u0 = a0[r] + b1v0, u1 = a1[r] + b1v1;
            s += u0 + u1; ss += u0 * u0 + u1 * u1;
        }
    }
    float rs = blockReduceSum(s);
    float rss = blockReduceSum(ss);
    if (t == 0) {
        part[PG1 + (size_t)b * 1024 + local] = rs;
        part[PG1 + (size_t)(8 + b) * 1024 + local] = rss;
    }
}

// conv1 -> gn1 -> silu -> conv2 (MFMA); y2 channel-last + gn2 partials
// dt2 stride 40 shorts (80 B): conflict-free, 16B-aligned
__global__ __launch_bounds__(256) void k_m2(
    const float* __restrict__ x, const float* __restrict__ Jb,
    const unsigned short* __restrict__ w1bf, const float* __restrict__ b1,
    const float* __restrict__ g1g, const float* __restrict__ g1b,
    const unsigned short* __restrict__ w2bf, const float* __restrict__ b2,
    const float* __restrict__ red, float* __restrict__ part,
    unsigned short* __restrict__ y2)
{
    const int tx0 = blockIdx.x * 16, ty0 = blockIdx.y * 16, b = blockIdx.z;
    const int local = blockIdx.y * 32 + blockIdx.x;
    __shared__ unsigned short mt8[20 * 21 * 8];
    __shared__ unsigned short dt2[324 * 40];
    const int t = threadIdx.x;
    const float mu1 = red[40 + b] * (1.f / (32.f * HW));
    const float rs1 = rsqrtf(red[48 + b] * (1.f / (32.f * HW)) - mu1 * mu1 + GEPS);
    for (int e = t; e < 20 * 21; e += 256) {
        int yy = e / 21, xx = e - yy * 21;
        int gy = ty0 - 2 + yy, gx = tx0 - 2 + xx;
        float v0 = 0, v1 = 0, v2 = 0, jl = 0, d5 = 0;
        if (xx < 20 && (unsigned)gy < (unsigned)Hn && (unsigned)gx < (unsigned)Wn) {
            size_t p = (size_t)b * CHW + (size_t)gy * Wn + gx;
            v0 = x[p]; v1 = x[p + HW]; v2 = x[p + 2 * HW];
            float j0 = Jb[p], j1 = Jb[p + HW], j2 = Jb[p + 2 * HW];
            float xl = 0.299f * v0 + 0.587f * v1 + 0.114f * v2;
            jl = 0.299f * j0 + 0.587f * j1 + 0.114f * j2;
            d5 = jl - xl;
        }
        uint4 pk = make_uint4(pk2(v0, v1), pk2(v2, jl), (unsigned)f2bf(d5), 0u);
        *(uint4*)(mt8 + e * 8) = pk;
    }
    const int wv = t >> 6, lane = t & 63, ln = lane & 15, q = lane >> 4;
    const float sc0 = rs1 * g1g[ln],       sc1 = rs1 * g1g[16 + ln];
    const float of0 = (b1[ln] - mu1) * sc0 + g1b[ln];
    const float of1 = (b1[16 + ln] - mu1) * sc1 + g1b[16 + ln];
    bfx8 Bf[3][2];
    #pragma unroll
    for (int ks = 0; ks < 3; ++ks)
        #pragma unroll
        for (int nt = 0; nt < 2; ++nt)
            Bf[ks][nt] = *(const bfx8*)(w1bf + (nt * 16 + ln) * 96 + ks * 32 + q * 8);
    __syncthreads();
    for (int mt = wv; mt < 21; mt += 4) {
        int p = mt * 16 + ln; if (p > 323) p = 323;
        const int hy = p / 18, hx = p - hy * 18;
        fx4 a0 = {0.f, 0.f, 0.f, 0.f}, a1 = {0.f, 0.f, 0.f, 0.f};
        #pragma unroll
        for (int ks = 0; ks < 3; ++ks) {
            bfx8 A = *(const bfx8*)(mt8 + ((hy + ks) * 21 + hx + q) * 8);
            a0 = __builtin_amdgcn_mfma_f32_16x16x32_bf16(A, Bf[ks][0], a0, 0, 0, 0);
            a1 = __builtin_amdgcn_mfma_f32_16x16x32_bf16(A, Bf[ks][1], a1, 0, 0, 0);
        }
        const int prb = mt * 16 + q * 4;
        #pragma unroll
        for (int r = 0; r < 4; ++r) {
            const int pr = prb + r;
            if (pr < 324) {
                const int py = pr / 18, px = pr - py * 18;
                const int gy = ty0 - 1 + py, gx = tx0 - 1 + px;
                const bool inimg = (unsigned)gy < (unsigned)Hn && (unsigned)gx < (unsigned)Wn;
                dt2[pr * 40 + ln]      = inimg ? f2bf(siluf(a0[r] * sc0 + of0)) : (unsigned short)0;
                dt2[pr * 40 + 16 + ln] = inimg ? f2bf(siluf(a1[r] * sc1 + of1)) : (unsigned short)0;
            }
        }
    }
    __syncthreads();
    fx4 c2[4][2];
    #pragma unroll
    for (int i = 0; i < 4; ++i)
        #pragma unroll
        for (int nt = 0; nt < 2; ++nt)
            c2[i][nt] = fx4{0.f, 0.f, 0.f, 0.f};
    #pragma unroll
    for (int tap = 0; tap < 9; ++tap) {
        const int ky = tap / 3, kx = tap - ky * 3;
        bfx8 B0 = *(const bfx8*)(w2bf + tap * 1024 + ln * 32 + q * 8);
        bfx8 B1 = *(const bfx8*)(w2bf + tap * 1024 + (16 + ln) * 32 + q * 8);
        #pragma unroll
        for (int i = 0; i < 4; ++i) {
            const int oy = wv * 4 + i;
            bfx8 A = *(const bfx8*)(dt2 + ((oy + ky) * 18 + ln + kx) * 40 + q * 8);
            c2[i][0] = __builtin_amdgcn_mfma_f32_16x16x32_bf16(A, B0, c2[i][0], 0, 0, 0);
            c2[i][1] = __builtin_amdgcn_mfma_f32_16x16x32_bf16(A, B1, c2[i][1], 0, 0, 0);
        }
    }
    float s = 0.f, ss = 0.f;
    const float b2v0 = b2[ln], b2v1 = b2[16 + ln];
    #pragma unroll
    for (int i = 0; i < 4; ++i) {
        const int gy = ty0 + wv * 4 + i;
        #pragma unroll
        for (int r = 0; r < 4; ++r) {
            const int gx = tx0 + q * 4 + r;
            float a0 = c2[i][0][r] + b2v0;
            float a1 = c2[i][1][r] + b2v1;
            s += a0 + a1; ss += a0 * a0 + a1 * a1;
            unsigned pk = pk2(a0, a1);
            size_t off = ((size_t)b * HW + (size_t)gy * Wn + gx) * 32 + ln * 2;
            *(unsigned*)(y2 + off) = pk;
        }
    }
    float rsum = blockReduceSum(s);
    float rss = blockReduceSum(ss);
    if (t == 0) {
        part[PG2 + (size_t)b * 1024 + local] = rsum;
        part[PG2 + (size_t)(8 + b) * 1024 + local] = rss;
    }
}

// gn2 -> silu -> 1x1 conv; channel-last y2; dsum partials (no atomics)
__global__ __launch_bounds__(256) void k_m3(
    const unsigned short* __restrict__ y2, const float* __restrict__ red,
    const float* __restrict__ prm, const float* __restrict__ b3,
    float* __restrict__ dl, float* __restrict__ part)
{
    int idx = blockIdx.x * 256 + threadIdx.x;     // global pixel (b*HW+pix)
    int b = idx >> 18;
    int pix = idx & (HW - 1);
    const int local = blockIdx.x & 1023;
    float mu = red[56 + b] * (1.f / (32.f * HW));
    float rs = rsqrtf(red[64 + b] * (1.f / (32.f * HW)) - mu * mu + GEPS);
    const uint4* yp = (const uint4*)(y2 + (size_t)idx * 32);
    uint4 L[4];
    #pragma unroll
    for (int c = 0; c < 4; ++c) L[c] = yp[c];
    float a0 = b3[0], a1 = b3[1], a2 = b3[2];
    const unsigned* Lw = (const unsigned*)L;
    #pragma unroll
    for (int w = 0; w < 16; ++w) {     // 16 dwords = all 32 channels
        unsigned u = Lw[w];
        #pragma unroll
        for (int h = 0; h < 2; ++h) {
            int j = w * 2 + h;
            float v = bf2f((unsigned short)(h ? (u >> 16) : (u & 0xFFFFu)));
            float dn = (v - mu) * rs * prm[j] + prm[32 + j];
            float sv = siluf(dn);
            a0 += sv * prm[64 + j]; a1 += sv * prm[96 + j]; a2 += sv * prm[128 + j];
        }
    }
    size_t p = (size_t)b * CHW + pix;
    dl[p] = a0; dl[p + HW] = a1; dl[p + 2 * HW] = a2;
    float r0 = blockReduceSum(a0);
    float r1 = blockReduceSum(a1);
    float r2 = blockReduceSum(a2);
    if (threadIdx.x == 0) {
        part[PD + (size_t)(b * 3 + 0) * 1024 + local] = r0;
        part[PD + (size_t)(b * 3 + 1) * 1024 + local] = r1;
        part[PD + (size_t)(b * 3 + 2) * 1024 + local] = r2;
    }
}

__global__ void k_se(float* __restrict__ red,
    const float* __restrict__ w1, const float* __restrict__ b1,
    const float* __restrict__ w2, const float* __restrict__ b2,
    const float* __restrict__ alpha)
{
    int b = threadIdx.x;
    if (b < 8) {
        float p0 = red[72 + b * 3 + 0] * (1.f / HW);
        float p1 = red[72 + b * 3 + 1] * (1.f / HW);
        float p2 = red[72 + b * 3 + 2] * (1.f / HW);
        float h[4];
        #pragma unroll
        for (int j = 0; j < 4; ++j) {
            float a = b1[j] + p0 * w1[j * 3] + p1 * w1[j * 3 + 1] + p2 * w1[j * 3 + 2];
            h[j] = siluf(a);
        }
        float al = alpha[0];
        #pragma unroll
        for (int c = 0; c < 3; ++c) {
            float a = b2[c] + h[0] * w2[c * 4] + h[1] * w2[c * 4 + 1]
                            + h[2] * w2[c * 4 + 2] + h[3] * w2[c * 4 + 3];
            red[96 + b * 3 + c] = al * sigm(a);
        }
    }
}

__global__ __launch_bounds__(256) void k_out(
    const float* __restrict__ x, const float* __restrict__ dl,
    const float* __restrict__ red, float* __restrict__ out)
{
    int i = blockIdx.x * 256 + threadIdx.x;     // float4 index
    float aw = red[96 + (i >> 16)];
    float4 xv = ((const float4*)x)[i];
    float4 dv = ((const float4*)dl)[i];
    float4 o;
    o.x = xv.x + aw * dv.x; o.y = xv.y + aw * dv.y;
    o.z = xv.z + aw * dv.z; o.w = xv.w + aw * dv.w;
    ((float4*)out)[i] = o;
}

extern "C" void kernel_launch(void* const* d_in, const int* in_sizes, int n_in,
                              void* d_out, int out_size, void* d_ws, size_t ws_size,
                              hipStream_t stream)
{
    const float* x     = (const float*)d_in[0];
    const float* ng    = (const float*)d_in[1];
    const float* nb    = (const float*)d_in[2];
    const float* ph_w1 = (const float*)d_in[3];
    const float* ph_b1 = (const float*)d_in[4];
    const float* ph_w2 = (const float*)d_in[5];
    const float* ph_b2 = (const float*)d_in[6];
    const float* z_w1  = (const float*)d_in[7];
    const float* z_b1  = (const float*)d_in[8];
    const float* z_w2  = (const float*)d_in[9];
    const float* z_b2  = (const float*)d_in[10];
    const float* fgain = (const float*)d_in[11];
    const float* mw1   = (const float*)d_in[12];
    const float* mb1   = (const float*)d_in[13];
    const float* g1g   = (const float*)d_in[14];
    const float* g1b   = (const float*)d_in[15];
    const float* mw2   = (const float*)d_in[16];
    const float* mb2   = (const float*)d_in[17];
    const float* g2g   = (const float*)d_in[18];
    const float* g2b   = (const float*)d_in[19];
    const float* mw3   = (const float*)d_in[20];
    const float* mb3   = (const float*)d_in[21];
    const float* sw1   = (const float*)d_in[22];
    const float* sb1   = (const float*)d_in[23];
    const float* sw2   = (const float*)d_in[24];
    const float* sb2   = (const float*)d_in[25];
    const float* alpha = (const float*)d_in[26];

    char* ws = (char*)d_ws;
    float*  red = (float*)(ws + OFF_RED);
    float*  phi = (float*)(ws + OFF_PHI);
    float2* U   = (float2*)(ws + OFF_U);
    float*  Jb  = (float*)(ws + OFF_J);
    float*  dl  = (float*)(ws + OFF_D);
    unsigned short* y2   = (unsigned short*)(ws + OFF_Y2);
    unsigned short* w1bf = (unsigned short*)(ws + OFF_W1B);
    unsigned short* w2bf = (unsigned short*)(ws + OFF_W2B);
    unsigned short* wh1  = (unsigned short*)(ws + OFF_WH1);
    unsigned short* wp2  = (unsigned short*)(ws + OFF_WP2);
    unsigned short* wz2  = (unsigned short*)(ws + OFF_WZ2);
    float* prm  = (float*)(ws + OFF_PRM);
    float* part = (float*)(ws + OFF_PART);
    float* out = (float*)d_out;

    hipLaunchKernelGGL(k_zero, dim3(1), dim3(128), 0, stream, red);
    hipLaunchKernelGGL(k_prep, dim3(36), dim3(256), 0, stream,
                       mw1, mw2, ph_w1, z_w1, ph_w2, z_w2, g2g, g2b, mw3,
                       w1bf, w2bf, wh1, wp2, wz2, prm);
    hipLaunchKernelGGL(k_reduce_x, dim3(256), dim3(256), 0, stream, x, red);
    hipLaunchKernelGGL(k_heads, dim3(32, 32, 8), dim3(256), 0, stream,
                       x, red, ng, nb, wh1, ph_b1, z_b1, wp2, wz2, ph_b2, z_b2, phi, part);
    hipLaunchKernelGGL(k_red, dim3(24), dim3(256), 0, stream, part + PZ, red + 16);
    hipLaunchKernelGGL(k_fftA, dim3(3072), dim3(256), 0, stream, x, phi, U);
    hipLaunchKernelGGL(k_transpose, dim3(136, 24), dim3(256), 0, stream, U);
    hipLaunchKernelGGL(k_fftB, dim3(3072), dim3(256), 0, stream, U, red, fgain);
    hipLaunchKernelGGL(k_transpose, dim3(136, 24), dim3(256), 0, stream, U);
    hipLaunchKernelGGL(k_fftC, dim3(3072), dim3(256), 0, stream, U, Jb);
    hipLaunchKernelGGL(k_m1, dim3(32, 32, 8), dim3(256), 0, stream, x, Jb, w1bf, mb1, part);
    hipLaunchKernelGGL(k_red, dim3(16), dim3(256), 0, stream, part + PG1, red + 40);
    hipLaunchKernelGGL(k_m2, dim3(32, 32, 8), dim3(256), 0, stream,
                       x, Jb, w1bf, mb1, g1g, g1b, w2bf, mb2, red, part, y2);
    hipLaunchKernelGGL(k_red, dim3(16), dim3(256), 0, stream, part + PG2, red + 56);
    hipLaunchKernelGGL(k_m3, dim3(8192), dim3(256), 0, stream, y2, red, prm, mb3, dl, part);
    hipLaunchKernelGGL(k_red, dim3(24), dim3(256), 0, stream, part + PD, red + 72);
    hipLaunchKernelGGL(k_se, dim3(1), dim3(64), 0, stream, red, sw1, sb1, sw2, sb2, alpha);
    hipLaunchKernelGGL(k_out, dim3(6144), dim3(256), 0, stream, x, dl, red, out);
}

// Round 9
// 604.606 us; speedup vs baseline: 5.0076x; 1.0298x over previous
//
#include <hip/hip_runtime.h>
#include <hip/hip_bf16.h>
#include <math.h>

#define DINL __device__ __forceinline__

namespace {
constexpr int Bn = 8, Cn = 3, Hn = 512, Wn = 512;
constexpr int HW  = Hn * Wn;        // 262144
constexpr int CHW = Cn * HW;        // 786432
constexpr float GEPS = 1e-5f;
constexpr float PIf  = 3.14159265358979323846f;

// workspace layout (bytes)
constexpr size_t OFF_RED = 0;                                   // 128 floats
constexpr size_t OFF_PHI = 512;
constexpr size_t OFF_U   = OFF_PHI + (size_t)Bn * CHW * 4;
constexpr size_t OFF_J   = OFF_U   + (size_t)Bn * CHW * 8;
constexpr size_t OFF_D   = OFF_J   + (size_t)Bn * CHW * 4;
constexpr size_t OFF_Y2  = OFF_D   + (size_t)Bn * CHW * 4;      // 8*32*HW bf16 (channel-last)
constexpr size_t OFF_W1B = OFF_Y2  + (size_t)Bn * 32 * HW * 2;  // 3072 bf16
constexpr size_t OFF_W2B = OFF_W1B + 3072 * 2;                  // 9216 bf16
constexpr size_t OFF_WH1 = OFF_W2B + 9216 * 2;                  // 4608 bf16
constexpr size_t OFF_WP2 = OFF_WH1 + 4608 * 2;                  // 4608 bf16
constexpr size_t OFF_WZ2 = OFF_WP2 + 4608 * 2;                  // 4608 bf16
constexpr size_t OFF_PRM = OFF_WZ2 + 4608 * 2;                  // 160 f32
constexpr size_t OFF_PART= OFF_PRM + 160 * 4;                   // 81920 f32 partials
// part float sub-offsets (in floats)
constexpr int PZ = 0;          // 24 groups (b*3+c) x 1024
constexpr int PG1 = 24576;     // 16 groups (b:sum, 8+b:ss) x 1024
constexpr int PG2 = 40960;     // 16 groups x 1024
constexpr int PD  = 57344;     // 24 groups (b*3+c) x 1024
}

typedef __bf16 bfx8 __attribute__((ext_vector_type(8)));
typedef float  fx4  __attribute__((ext_vector_type(4)));

DINL float sigm(float a) { return __frcp_rn(1.f + __expf(-a)); }
DINL float siluf(float a) { return a * __frcp_rn(1.f + __expf(-a)); }
DINL float ftanh(float a) { return 1.f - 2.f * __frcp_rn(1.f + __expf(2.f * a)); }
DINL unsigned short f2bf(float f) {           // RNE float->bf16 bits
    unsigned u = __float_as_uint(f);
    return (unsigned short)((u + 0x7FFFu + ((u >> 16) & 1u)) >> 16);
}
DINL float bf2f(unsigned short h) {
    return __uint_as_float(((unsigned)h) << 16);
}
DINL unsigned pk2(float a, float b) {
    return (unsigned)f2bf(a) | ((unsigned)f2bf(b) << 16);
}

DINL float blockReduceSum(float v) {   // blockDim.x == 256
    __shared__ float sm[4];
    int lane = threadIdx.x & 63, wid = threadIdx.x >> 6;
    #pragma unroll
    for (int o = 32; o > 0; o >>= 1) v += __shfl_down(v, o, 64);
    __syncthreads();
    if (lane == 0) sm[wid] = v;
    __syncthreads();
    if (wid == 0) {
        float r = (lane < 4) ? sm[lane] : 0.f;
        r += __shfl_down(r, 2, 64);
        r += __shfl_down(r, 1, 64);
        return r;                       // valid on thread 0
    }
    return 0.f;
}

__global__ void k_zero(float* __restrict__ red) { red[threadIdx.x] = 0.f; }

__global__ __launch_bounds__(256) void k_red(const float* __restrict__ src,
                                             float* __restrict__ dst)
{
    const float4* s4 = (const float4*)(src + (size_t)blockIdx.x * 1024);
    float4 q = s4[threadIdx.x];
    float r = blockReduceSum(q.x + q.y + q.z + q.w);
    if (threadIdx.x == 0) dst[blockIdx.x] = r;
}

// weight repack (all bf16 fragment-order)
__global__ __launch_bounds__(256) void k_prep(
    const float* __restrict__ w1, const float* __restrict__ w2,
    const float* __restrict__ phw1, const float* __restrict__ zw1,
    const float* __restrict__ phw2, const float* __restrict__ zw2,
    const float* __restrict__ g2g, const float* __restrict__ g2b,
    const float* __restrict__ w3,
    unsigned short* __restrict__ w1bf, unsigned short* __restrict__ w2bf,
    unsigned short* __restrict__ wh1, unsigned short* __restrict__ wp2,
    unsigned short* __restrict__ wz2, float* __restrict__ prm)
{
    int i = blockIdx.x * 256 + threadIdx.x;     // 0..9215
    if (i < 3072) {
        int o = i / 96, k = i - o * 96;
        int ky = k >> 5, r = k & 31, kx = r >> 3, c = r & 7;
        float v = (kx < 3 && c < 5) ? w1[o * 45 + c * 9 + ky * 3 + kx] : 0.f;
        w1bf[i] = f2bf(v);
    }
    if (i < 9216) {
        int tap = i >> 10, rr = i & 1023, o = rr >> 5, ci = rr & 31;
        w2bf[i] = f2bf(w2[o * 288 + ci * 9 + tap]);
    }
    if (i < 4608) {
        int o = i / 96, k = i - o * 96;
        int ky = k >> 5, r = k & 31, kx = r >> 3, c = r & 7;
        float v = 0.f;
        if (kx < 3 && c < 3)
            v = (o < 16) ? phw1[o * 27 + c * 9 + ky * 3 + kx]
                         : zw1[(o - 16) * 27 + c * 9 + ky * 3 + kx];
        wh1[i] = f2bf(v);
    }
    if (i < 4608) {
        int tap = i / 512, rr = i - tap * 512, n = rr >> 5, k = rr & 31;
        float vp = (n < 3 && k < 16) ? phw2[n * 144 + k * 9 + tap] : 0.f;
        float vz = (n < 3) ? zw2[n * 288 + k * 9 + tap] : 0.f;
        wp2[i] = f2bf(vp);
        wz2[i] = f2bf(vz);
    }
    if (i < 160) {
        if (i < 32) {
            int ch = (i & 1) * 16 + (i >> 1);
            prm[i] = g2g[ch];
        } else if (i < 64) {
            int j = i - 32, ch = (j & 1) * 16 + (j >> 1);
            prm[i] = g2b[ch];
        } else {
            int j = (i - 64) & 31, c = (i - 64) >> 5;
            int ch = (j & 1) * 16 + (j >> 1);
            prm[i] = w3[c * 32 + ch];
        }
    }
}

__global__ __launch_bounds__(256) void k_reduce_x(const float* __restrict__ x,
                                                  float* __restrict__ red) {
    int b = blockIdx.x >> 5, blk = blockIdx.x & 31;
    const float4* xv = (const float4*)(x + (size_t)b * CHW + (size_t)blk * (CHW / 32));
    float s = 0.f, ss = 0.f;
    for (int i = threadIdx.x; i < (CHW / 32) / 4; i += 256) {
        float4 v = xv[i];
        s  += v.x + v.y + v.z + v.w;
        ss += v.x * v.x + v.y * v.y + v.z * v.z + v.w * v.w;
    }
    float rs = blockReduceSum(s);
    float rss = blockReduceSum(ss);
    if (threadIdx.x == 0) { atomicAdd(&red[b], rs); atomicAdd(&red[8 + b], rss); }
}

// ---------------- fused heads (MFMA): xn -> [ph16 | z32] hidden -> phi + z partials ----------------
__global__ __launch_bounds__(256) void k_heads(
    const float* __restrict__ x, const float* __restrict__ red,
    const float* __restrict__ ng, const float* __restrict__ nb,
    const unsigned short* __restrict__ wh1,
    const float* __restrict__ phb1, const float* __restrict__ zb1,
    const unsigned short* __restrict__ wp2, const unsigned short* __restrict__ wz2,
    const float* __restrict__ phb2, const float* __restrict__ zb2,
    float* __restrict__ phi, float* __restrict__ part)
{
    const int tx0 = blockIdx.x * 16, ty0 = blockIdx.y * 16, b = blockIdx.z;
    const int local = blockIdx.y * 32 + blockIdx.x;
    const bool edge = (blockIdx.x == 0) || (blockIdx.x == 31) ||
                      (blockIdx.y == 0) || (blockIdx.y == 31);
    __shared__ unsigned short mt8[20 * 21 * 8];
    __shared__ unsigned short ht8[324 * 48];      // reused as phs/zs in epilogue
    const int t = threadIdx.x;
    const float mu = red[b] * (1.f / CHW);
    const float rsv = rsqrtf(red[8 + b] * (1.f / CHW) - mu * mu + GEPS);
    float sc[3], sh[3];
    #pragma unroll
    for (int c = 0; c < 3; ++c) { sc[c] = rsv * ng[c]; sh[c] = nb[c] - mu * rsv * ng[c]; }
    if (edge) {
        for (int e = t; e < 20 * 21; e += 256) {
            int yy = e / 21, xx = e - yy * 21;
            int gy = ty0 - 2 + yy, gx = tx0 - 2 + xx;
            float v0 = 0, v1 = 0, v2 = 0;
            if (xx < 20 && (unsigned)gy < (unsigned)Hn && (unsigned)gx < (unsigned)Wn) {
                size_t p = (size_t)b * CHW + (size_t)gy * Wn + gx;
                v0 = x[p] * sc[0] + sh[0];
                v1 = x[p + HW] * sc[1] + sh[1];
                v2 = x[p + 2 * HW] * sc[2] + sh[2];
            }
            *(uint4*)(mt8 + e * 8) = make_uint4(pk2(v0, v1), (unsigned)f2bf(v2), 0u, 0u);
        }
    } else {
        for (int e = t; e < 20 * 21; e += 256) {
            int yy = e / 21, xx = e - yy * 21;
            float v0 = 0, v1 = 0, v2 = 0;
            if (xx < 20) {
                size_t p = (size_t)b * CHW + (size_t)(ty0 - 2 + yy) * Wn + (tx0 - 2 + xx);
                v0 = x[p] * sc[0] + sh[0];
                v1 = x[p + HW] * sc[1] + sh[1];
                v2 = x[p + 2 * HW] * sc[2] + sh[2];
            }
            *(uint4*)(mt8 + e * 8) = make_uint4(pk2(v0, v1), (unsigned)f2bf(v2), 0u, 0u);
        }
    }
    const int wv = t >> 6, lane = t & 63, ln = lane & 15, q = lane >> 4;
    bfx8 Bf[3][3];
    #pragma unroll
    for (int ks = 0; ks < 3; ++ks)
        #pragma unroll
        for (int nt = 0; nt < 3; ++nt)
            Bf[ks][nt] = *(const bfx8*)(wh1 + (nt * 16 + ln) * 96 + ks * 32 + q * 8);
    const float bb0 = phb1[ln], bb1 = zb1[ln], bb2 = zb1[16 + ln];
    __syncthreads();
    for (int mt = wv; mt < 21; mt += 4) {
        int p = mt * 16 + ln; if (p > 323) p = 323;
        const int hy = p / 18, hx = p - hy * 18;
        fx4 a0 = {0,0,0,0}, a1 = {0,0,0,0}, a2 = {0,0,0,0};
        #pragma unroll
        for (int ks = 0; ks < 3; ++ks) {
            bfx8 A = *(const bfx8*)(mt8 + ((hy + ks) * 21 + hx + q) * 8);
            a0 = __builtin_amdgcn_mfma_f32_16x16x32_bf16(A, Bf[ks][0], a0, 0, 0, 0);
            a1 = __builtin_amdgcn_mfma_f32_16x16x32_bf16(A, Bf[ks][1], a1, 0, 0, 0);
            a2 = __builtin_amdgcn_mfma_f32_16x16x32_bf16(A, Bf[ks][2], a2, 0, 0, 0);
        }
        const int prb = mt * 16 + q * 4;
        if (edge) {
            #pragma unroll
            for (int r = 0; r < 4; ++r) {
                const int pr = prb + r;
                if (pr < 324) {
                    const int py = pr / 18, px = pr - py * 18;
                    const int gy = ty0 - 1 + py, gx = tx0 - 1 + px;
                    const bool inimg = (unsigned)gy < (unsigned)Hn && (unsigned)gx < (unsigned)Wn;
                    unsigned short* hp = ht8 + pr * 48;
                    hp[ln]      = inimg ? f2bf(siluf(a0[r] + bb0)) : (unsigned short)0;
                    hp[16 + ln] = inimg ? f2bf(siluf(a1[r] + bb1)) : (unsigned short)0;
                    hp[32 + ln] = inimg ? f2bf(siluf(a2[r] + bb2)) : (unsigned short)0;
                }
            }
        } else {
            #pragma unroll
            for (int r = 0; r < 4; ++r) {
                const int pr = prb + r;
                if (pr < 324) {
                    unsigned short* hp = ht8 + pr * 48;
                    hp[ln]      = f2bf(siluf(a0[r] + bb0));
                    hp[16 + ln] = f2bf(siluf(a1[r] + bb1));
                    hp[32 + ln] = f2bf(siluf(a2[r] + bb2));
                }
            }
        }
    }
    __syncthreads();
    fx4 accp[4], accz[4];
    #pragma unroll
    for (int i = 0; i < 4; ++i) { accp[i] = fx4{0,0,0,0}; accz[i] = fx4{0,0,0,0}; }
    #pragma unroll
    for (int tap = 0; tap < 9; ++tap) {
        const int ky = tap / 3, kx = tap - ky * 3;
        bfx8 Bp = *(const bfx8*)(wp2 + tap * 512 + ln * 32 + q * 8);
        bfx8 Bz = *(const bfx8*)(wz2 + tap * 512 + ln * 32 + q * 8);
        #pragma unroll
        for (int i = 0; i < 4; ++i) {
            const int oy = wv * 4 + i;
            const unsigned short* ap = ht8 + ((oy + ky) * 18 + ln + kx) * 48;
            bfx8 Ap = *(const bfx8*)(ap + q * 8);
            bfx8 Az = *(const bfx8*)(ap + 16 + q * 8);
            accp[i] = __builtin_amdgcn_mfma_f32_16x16x32_bf16(Ap, Bp, accp[i], 0, 0, 0);
            accz[i] = __builtin_amdgcn_mfma_f32_16x16x32_bf16(Az, Bz, accz[i], 0, 0, 0);
        }
    }
    // epilogue via LDS: full-lane tanh/sigm, coalesced stores
    __syncthreads();                       // ht8 reads done; reuse as float staging
    float* phs = (float*)ht8;              // [256][4]
    float* zs  = phs + 1024;               // [256][4]
    if (ln < 3) {
        #pragma unroll
        for (int i = 0; i < 4; ++i)
            #pragma unroll
            for (int r = 0; r < 4; ++r) {
                int pl = (wv * 4 + i) * 16 + q * 4 + r;
                phs[pl * 4 + ln] = accp[i][r];
                zs [pl * 4 + ln] = accz[i][r];
            }
    }
    __syncthreads();
    float4 pv = ((const float4*)phs)[t];
    float4 zv = ((const float4*)zs)[t];
    const int gy = ty0 + (t >> 4), gx = tx0 + (t & 15);
    size_t pp = (size_t)b * CHW + (size_t)gy * Wn + gx;
    phi[pp]          = ftanh(pv.x + phb2[0]) * PIf;
    phi[pp + HW]     = ftanh(pv.y + phb2[1]) * PIf;
    phi[pp + 2 * HW] = ftanh(pv.z + phb2[2]) * PIf;
    float z0 = sigm(zv.x + zb2[0]) * 0.3f;
    float z1 = sigm(zv.y + zb2[1]) * 0.3f;
    float z2 = sigm(zv.z + zb2[2]) * 0.3f;
    float r0 = blockReduceSum(z0);
    float r1 = blockReduceSum(z1);
    float r2 = blockReduceSum(z2);
    if (t == 0) {
        part[PZ + (size_t)(b * 3 + 0) * 1024 + local] = r0;
        part[PZ + (size_t)(b * 3 + 1) * 1024 + local] = r1;
        part[PZ + (size_t)(b * 3 + 2) * 1024 + local] = r2;
    }
}

// ---------------- FFT: 512-pt Stockham radix-4 (x4) + radix-2, wave-per-line ----------------
// recurrence: dst[q + s(4m+k)] = butterfly_k(a,b,c,d) * W512^{s*m*k}; tw has 512 entries.
template<bool INV>
DINL float2* fft512_wave4(float2* a, float2* b, const float2* tw, int l)
{
    float2* src = a; float2* dst = b;
    int s = 1;
    #pragma unroll
    for (int st = 0; st < 4; ++st) {
        #pragma unroll
        for (int h = 0; h < 2; ++h) {
            const int i = l + h * 64;          // butterfly index in [0,128)
            const int q = i & (s - 1);
            const int sm = i - q;              // s*m
            float2 A = src[i], B = src[i + 128], C = src[i + 256], D = src[i + 384];
            float t0x = A.x + C.x, t0y = A.y + C.y;
            float t1x = A.x - C.x, t1y = A.y - C.y;
            float t2x = B.x + D.x, t2y = B.y + D.y;
            float t3x = B.x - D.x, t3y = B.y - D.y;
            // sigma*i*t3: fwd(-i): (t3y,-t3x); inv(+i): (-t3y,t3x)
            float i3x = INV ? -t3y : t3y;
            float i3y = INV ? t3x : -t3x;
            float u0x = t0x + t2x, u0y = t0y + t2y;
            float u2x = t0x - t2x, u2y = t0y - t2y;
            float u1x = t1x + i3x, u1y = t1y + i3y;
            float u3x = t1x - i3x, u3y = t1y - i3y;
            float2 w1 = tw[sm], w2 = tw[2 * sm], w3 = tw[3 * sm];
            float w1y = INV ? -w1.y : w1.y;
            float w2y = INV ? -w2.y : w2.y;
            float w3y = INV ? -w3.y : w3.y;
            const int base = q + 4 * sm;
            dst[base]         = make_float2(u0x, u0y);
            dst[base + s]     = make_float2(u1x * w1.x - u1y * w1y, u1x * w1y + u1y * w1.x);
            dst[base + 2 * s] = make_float2(u2x * w2.x - u2y * w2y, u2x * w2y + u2y * w2.x);
            dst[base + 3 * s] = make_float2(u3x * w3.x - u3y * w3y, u3x * w3y + u3y * w3.x);
        }
        float2* tmp = src; src = dst; dst = tmp;
        s <<= 2;
        asm volatile("" ::: "memory");   // wave-synchronous LDS: fence compiler only
    }
    // final radix-2, s=256 (m=0 -> no twiddle)
    #pragma unroll
    for (int h = 0; h < 4; ++h) {
        const int j = l + h * 64;
        float2 u = src[j], v = src[j + 256];
        dst[j]       = make_float2(u.x + v.x, u.y + v.y);
        dst[j + 256] = make_float2(u.x - v.x, u.y - v.y);
    }
    float2* tmp = src; src = dst; dst = tmp;
    asm volatile("" ::: "memory");
    return src;
}

__global__ __launch_bounds__(256) void k_fftA(
    const float* __restrict__ x, const float* __restrict__ phi, float2* __restrict__ U)
{
    __shared__ float2 buf[4][2][512];
    __shared__ float2 tw[512];
    const int t = threadIdx.x, wv = t >> 6, l = t & 63;
    #pragma unroll
    for (int i = t; i < 512; i += 256) {
        float s, c; __sincosf(-2.f * PIf * (float)i * (1.f / 512.f), &s, &c);
        tw[i] = make_float2(c, s);
    }
    __syncthreads();
    const size_t line = (size_t)blockIdx.x * 4 + wv;
    const float* xr = x + line * 512;
    const float* pr = phi + line * 512;
    float2* A = buf[wv][0];
    float2* B = buf[wv][1];
    #pragma unroll
    for (int i = l; i < 512; i += 64) {
        float s, c; __sincosf(pr[i], &s, &c);
        float xv = xr[i];
        A[i] = make_float2(xv * c, xv * s);
    }
    asm volatile("" ::: "memory");
    float2* res = fft512_wave4<false>(A, B, tw, l);
    float2* Ur = U + line * 512;
    #pragma unroll
    for (int i = l; i < 512; i += 64) Ur[i] = res[i];
}

__global__ __launch_bounds__(256) void k_transpose(float2* __restrict__ U)
{
    const int img = blockIdx.y;
    int rem = blockIdx.x, ti = 0;
    while (rem >= 16 - ti) { rem -= 16 - ti; ++ti; }
    const int tj = ti + rem;
    float2* Ub = U + (size_t)img * HW;
    __shared__ float2 ta[32][33];
    __shared__ float2 tb[32][33];
    const int t = threadIdx.x;
    const int cc = t & 31, r0 = t >> 5;
    const int ar = ti * 32, ac = tj * 32;
    #pragma unroll
    for (int k = 0; k < 4; ++k) {
        int r = r0 + k * 8;
        ta[r][cc] = Ub[(size_t)(ar + r) * 512 + ac + cc];
    }
    if (ti != tj) {
        #pragma unroll
        for (int k = 0; k < 4; ++k) {
            int r = r0 + k * 8;
            tb[r][cc] = Ub[(size_t)(ac + r) * 512 + ar + cc];
        }
    }
    __syncthreads();
    #pragma unroll
    for (int k = 0; k < 4; ++k) {
        int r = r0 + k * 8;
        Ub[(size_t)(ac + r) * 512 + ar + cc] = ta[cc][r];
    }
    if (ti != tj) {
        #pragma unroll
        for (int k = 0; k < 4; ++k) {
            int r = r0 + k * 8;
            Ub[(size_t)(ar + r) * 512 + ac + cc] = tb[cc][r];
        }
    }
}

__global__ __launch_bounds__(256) void k_fftB(
    float2* __restrict__ U, const float* __restrict__ red, const float* __restrict__ fgain)
{
    __shared__ float2 buf[4][2][512];
    __shared__ float2 tw[512];
    const int t = threadIdx.x, wv = t >> 6, l = t & 63;
    #pragma unroll
    for (int i = t; i < 512; i += 256) {
        float s, c; __sincosf(-2.f * PIf * (float)i * (1.f / 512.f), &s, &c);
        tw[i] = make_float2(c, s);
    }
    __syncthreads();
    const int line = blockIdx.x * 4 + wv;          // (b*3+c)*512 + fw
    const int bc = line >> 9;
    const int fw = line & 511;
    const int c = bc % 3;
    float2* Ur = U + (size_t)line * 512;
    float2* A = buf[wv][0];
    float2* B = buf[wv][1];
    #pragma unroll
    for (int i = l; i < 512; i += 64) A[i] = Ur[i];
    asm volatile("" ::: "memory");
    float2* res = fft512_wave4<false>(A, B, tw, l);
    const float zm   = red[16 + bc] * (1.f / HW);
    const float gain = 1.f + fgain[c];
    const float lam  = (c == 0) ? 0.65f : (c == 1) ? 0.53f : 0.47f;
    const float il2  = 1.f / (lam * lam);
    const float fwv  = (float)(fw < 256 ? fw : fw - 512) * (1.f / 512.f);
    const float f2w  = fwv * fwv;
    #pragma unroll
    for (int i = l; i < 512; i += 64) {
        float fh = (float)(i < 256 ? i : i - 512) * (1.f / 512.f);
        float kz = 2.f * PIf * sqrtf(fmaxf(il2 - f2w - fh * fh, 0.f));
        float sn, cs; __sincosf(kz * zm, &sn, &cs);
        float2 v = res[i];
        res[i] = make_float2(gain * (v.x * cs - v.y * sn), gain * (v.x * sn + v.y * cs));
    }
    asm volatile("" ::: "memory");
    float2* other = (res == A) ? B : A;
    float2* res2 = fft512_wave4<true>(res, other, tw, l);
    #pragma unroll
    for (int i = l; i < 512; i += 64) {
        float2 v = res2[i];
        Ur[i] = make_float2(v.x * (1.f / 512.f), v.y * (1.f / 512.f));
    }
}

__global__ __launch_bounds__(256) void k_fftC(
    const float2* __restrict__ U, float* __restrict__ J)
{
    __shared__ float2 buf[4][2][512];
    __shared__ float2 tw[512];
    const int t = threadIdx.x, wv = t >> 6, l = t & 63;
    #pragma unroll
    for (int i = t; i < 512; i += 256) {
        float s, c; __sincosf(-2.f * PIf * (float)i * (1.f / 512.f), &s, &c);
        tw[i] = make_float2(c, s);
    }
    __syncthreads();
    const size_t line = (size_t)blockIdx.x * 4 + wv;
    const float2* Ur = U + line * 512;
    float2* A = buf[wv][0];
    float2* B = buf[wv][1];
    #pragma unroll
    for (int i = l; i < 512; i += 64) A[i] = Ur[i];
    asm volatile("" ::: "memory");
    float2* res = fft512_wave4<true>(A, B, tw, l);
    float* Jr = J + line * 512;
    #pragma unroll
    for (int i = l; i < 512; i += 64) {
        float2 v = res[i];
        float re = v.x * (1.f / 512.f), im = v.y * (1.f / 512.f);
        Jr[i] = sqrtf(fmaxf(re * re + im * im, 1e-12f));
    }
}

// ---------------- mix path (MFMA) ----------------
__global__ __launch_bounds__(256) void k_m1(
    const float* __restrict__ x, const float* __restrict__ Jb,
    const unsigned short* __restrict__ w1bf, const float* __restrict__ b1,
    float* __restrict__ part)
{
    const int tx0 = blockIdx.x * 16, ty0 = blockIdx.y * 16, b = blockIdx.z;
    const int local = blockIdx.y * 32 + blockIdx.x;
    const bool edge = (blockIdx.x == 0) || (blockIdx.x == 31) ||
                      (blockIdx.y == 0) || (blockIdx.y == 31);
    __shared__ unsigned short mt8[18 * 19 * 8];
    const int t = threadIdx.x;
    for (int e = t; e < 18 * 19; e += 256) {
        int yy = e / 19, xx = e - yy * 19;
        int gy = ty0 - 1 + yy, gx = tx0 - 1 + xx;
        float v0 = 0, v1 = 0, v2 = 0, jl = 0, d5 = 0;
        bool ok = edge ? (xx < 18 && (unsigned)gy < (unsigned)Hn && (unsigned)gx < (unsigned)Wn)
                       : (xx < 18);
        if (ok) {
            size_t p = (size_t)b * CHW + (size_t)gy * Wn + gx;
            v0 = x[p]; v1 = x[p + HW]; v2 = x[p + 2 * HW];
            float j0 = Jb[p], j1 = Jb[p + HW], j2 = Jb[p + 2 * HW];
            float xl = 0.299f * v0 + 0.587f * v1 + 0.114f * v2;
            jl = 0.299f * j0 + 0.587f * j1 + 0.114f * j2;
            d5 = jl - xl;
        }
        *(uint4*)(mt8 + e * 8) = make_uint4(pk2(v0, v1), pk2(v2, jl), (unsigned)f2bf(d5), 0u);
    }
    __syncthreads();
    const int wv = t >> 6, lane = t & 63, ln = lane & 15, q = lane >> 4;
    bfx8 Bf[3][2];
    #pragma unroll
    for (int ks = 0; ks < 3; ++ks)
        #pragma unroll
        for (int nt = 0; nt < 2; ++nt)
            Bf[ks][nt] = *(const bfx8*)(w1bf + (nt * 16 + ln) * 96 + ks * 32 + q * 8);
    const float b1v0 = b1[ln], b1v1 = b1[16 + ln];
    float s = 0.f, ss = 0.f;
    #pragma unroll
    for (int i = 0; i < 4; ++i) {
        const int oy = wv * 4 + i;
        fx4 a0 = {0.f, 0.f, 0.f, 0.f}, a1 = {0.f, 0.f, 0.f, 0.f};
        #pragma unroll
        for (int ks = 0; ks < 3; ++ks) {
            bfx8 A = *(const bfx8*)(mt8 + ((oy + ks) * 19 + ln + q) * 8);
            a0 = __builtin_amdgcn_mfma_f32_16x16x32_bf16(A, Bf[ks][0], a0, 0, 0, 0);
            a1 = __builtin_amdgcn_mfma_f32_16x16x32_bf16(A, Bf[ks][1], a1, 0, 0, 0);
        }
        #pragma unroll
        for (int r = 0; r < 4; ++r) {
            float u0 = a0[r] + b1v0, u1 = a1[r] + b1v1;
            s += u0 + u1; ss += u0 * u0 + u1 * u1;
        }
    }
    float rs = blockReduceSum(s);
    float rss = blockReduceSum(ss);
    if (t == 0) {
        part[PG1 + (size_t)b * 1024 + local] = rs;
        part[PG1 + (size_t)(8 + b) * 1024 + local] = rss;
    }
}

// conv1 -> gn1 -> silu -> conv2 (MFMA); y2 channel-last + gn2 partials
__global__ __launch_bounds__(256) void k_m2(
    const float* __restrict__ x, const float* __restrict__ Jb,
    const unsigned short* __restrict__ w1bf, const float* __restrict__ b1,
    const float* __restrict__ g1g, const float* __restrict__ g1b,
    const unsigned short* __restrict__ w2bf, const float* __restrict__ b2,
    const float* __restrict__ red, float* __restrict__ part,
    unsigned short* __restrict__ y2)
{
    const int tx0 = blockIdx.x * 16, ty0 = blockIdx.y * 16, b = blockIdx.z;
    const int local = blockIdx.y * 32 + blockIdx.x;
    const bool edge = (blockIdx.x == 0) || (blockIdx.x == 31) ||
                      (blockIdx.y == 0) || (blockIdx.y == 31);
    __shared__ unsigned short mt8[20 * 21 * 8];
    __shared__ unsigned short dt2[324 * 40];
    const int t = threadIdx.x;
    const float mu1 = red[40 + b] * (1.f / (32.f * HW));
    const float rs1 = rsqrtf(red[48 + b] * (1.f / (32.f * HW)) - mu1 * mu1 + GEPS);
    for (int e = t; e < 20 * 21; e += 256) {
        int yy = e / 21, xx = e - yy * 21;
        int gy = ty0 - 2 + yy, gx = tx0 - 2 + xx;
        float v0 = 0, v1 = 0, v2 = 0, jl = 0, d5 = 0;
        bool ok = edge ? (xx < 20 && (unsigned)gy < (unsigned)Hn && (unsigned)gx < (unsigned)Wn)
                       : (xx < 20);
        if (ok) {
            size_t p = (size_t)b * CHW + (size_t)gy * Wn + gx;
            v0 = x[p]; v1 = x[p + HW]; v2 = x[p + 2 * HW];
            float j0 = Jb[p], j1 = Jb[p + HW], j2 = Jb[p + 2 * HW];
            float xl = 0.299f * v0 + 0.587f * v1 + 0.114f * v2;
            jl = 0.299f * j0 + 0.587f * j1 + 0.114f * j2;
            d5 = jl - xl;
        }
        *(uint4*)(mt8 + e * 8) = make_uint4(pk2(v0, v1), pk2(v2, jl), (unsigned)f2bf(d5), 0u);
    }
    const int wv = t >> 6, lane = t & 63, ln = lane & 15, q = lane >> 4;
    const float sc0 = rs1 * g1g[ln],       sc1 = rs1 * g1g[16 + ln];
    const float of0 = (b1[ln] - mu1) * sc0 + g1b[ln];
    const float of1 = (b1[16 + ln] - mu1) * sc1 + g1b[16 + ln];
    bfx8 Bf[3][2];
    #pragma unroll
    for (int ks = 0; ks < 3; ++ks)
        #pragma unroll
        for (int nt = 0; nt < 2; ++nt)
            Bf[ks][nt] = *(const bfx8*)(w1bf + (nt * 16 + ln) * 96 + ks * 32 + q * 8);
    __syncthreads();
    for (int mt = wv; mt < 21; mt += 4) {
        int p = mt * 16 + ln; if (p > 323) p = 323;
        const int hy = p / 18, hx = p - hy * 18;
        fx4 a0 = {0.f, 0.f, 0.f, 0.f}, a1 = {0.f, 0.f, 0.f, 0.f};
        #pragma unroll
        for (int ks = 0; ks < 3; ++ks) {
            bfx8 A = *(const bfx8*)(mt8 + ((hy + ks) * 21 + hx + q) * 8);
            a0 = __builtin_amdgcn_mfma_f32_16x16x32_bf16(A, Bf[ks][0], a0, 0, 0, 0);
            a1 = __builtin_amdgcn_mfma_f32_16x16x32_bf16(A, Bf[ks][1], a1, 0, 0, 0);
        }
        const int prb = mt * 16 + q * 4;
        if (edge) {
            #pragma unroll
            for (int r = 0; r < 4; ++r) {
                const int pr = prb + r;
                if (pr < 324) {
                    const int py = pr / 18, px = pr - py * 18;
                    const int gy = ty0 - 1 + py, gx = tx0 - 1 + px;
                    const bool inimg = (unsigned)gy < (unsigned)Hn && (unsigned)gx < (unsigned)Wn;
                    dt2[pr * 40 + ln]      = inimg ? f2bf(siluf(a0[r] * sc0 + of0)) : (unsigned short)0;
                    dt2[pr * 40 + 16 + ln] = inimg ? f2bf(siluf(a1[r] * sc1 + of1)) : (unsigned short)0;
                }
            }
        } else {
            #pragma unroll
            for (int r = 0; r < 4; ++r) {
                const int pr = prb + r;
                if (pr < 324) {
                    dt2[pr * 40 + ln]      = f2bf(siluf(a0[r] * sc0 + of0));
                    dt2[pr * 40 + 16 + ln] = f2bf(siluf(a1[r] * sc1 + of1));
                }
            }
        }
    }
    __syncthreads();
    fx4 c2[4][2];
    #pragma unroll
    for (int i = 0; i < 4; ++i)
        #pragma unroll
        for (int nt = 0; nt < 2; ++nt)
            c2[i][nt] = fx4{0.f, 0.f, 0.f, 0.f};
    #pragma unroll
    for (int tap = 0; tap < 9; ++tap) {
        const int ky = tap / 3, kx = tap - ky * 3;
        bfx8 B0 = *(const bfx8*)(w2bf + tap * 1024 + ln * 32 + q * 8);
        bfx8 B1 = *(const bfx8*)(w2bf + tap * 1024 + (16 + ln) * 32 + q * 8);
        #pragma unroll
        for (int i = 0; i < 4; ++i) {
            const int oy = wv * 4 + i;
            bfx8 A = *(const bfx8*)(dt2 + ((oy + ky) * 18 + ln + kx) * 40 + q * 8);
            c2[i][0] = __builtin_amdgcn_mfma_f32_16x16x32_bf16(A, B0, c2[i][0], 0, 0, 0);
            c2[i][1] = __builtin_amdgcn_mfma_f32_16x16x32_bf16(A, B1, c2[i][1], 0, 0, 0);
        }
    }
    float s = 0.f, ss = 0.f;
    const float b2v0 = b2[ln], b2v1 = b2[16 + ln];
    #pragma unroll
    for (int i = 0; i < 4; ++i) {
        const int gy = ty0 + wv * 4 + i;
        #pragma unroll
        for (int r = 0; r < 4; ++r) {
            const int gx = tx0 + q * 4 + r;
            float a0 = c2[i][0][r] + b2v0;
            float a1 = c2[i][1][r] + b2v1;
            s += a0 + a1; ss += a0 * a0 + a1 * a1;
            unsigned pk = pk2(a0, a1);
            size_t off = ((size_t)b * HW + (size_t)gy * Wn + gx) * 32 + ln * 2;
            *(unsigned*)(y2 + off) = pk;
        }
    }
    float rsum = blockReduceSum(s);
    float rss = blockReduceSum(ss);
    if (t == 0) {
        part[PG2 + (size_t)b * 1024 + local] = rsum;
        part[PG2 + (size_t)(8 + b) * 1024 + local] = rss;
    }
}

// gn2 -> silu -> 1x1 conv; channel-last y2; dsum partials (no atomics)
__global__ __launch_bounds__(256) void k_m3(
    const unsigned short* __restrict__ y2, const float* __restrict__ red,
    const float* __restrict__ prm, const float* __restrict__ b3,
    float* __restrict__ dl, float* __restrict__ part)
{
    int idx = blockIdx.x * 256 + threadIdx.x;     // global pixel (b*HW+pix)
    int b = idx >> 18;
    int pix = idx & (HW - 1);
    const int local = blockIdx.x & 1023;
    float mu = red[56 + b] * (1.f / (32.f * HW));
    float rs = rsqrtf(red[64 + b] * (1.f / (32.f * HW)) - mu * mu + GEPS);
    const uint4* yp = (const uint4*)(y2 + (size_t)idx * 32);
    uint4 L[4];
    #pragma unroll
    for (int c = 0; c < 4; ++c) L[c] = yp[c];
    float a0 = b3[0], a1 = b3[1], a2 = b3[2];
    const unsigned* Lw = (const unsigned*)L;
    #pragma unroll
    for (int w = 0; w < 16; ++w) {     // 16 dwords = all 32 channels
        unsigned u = Lw[w];
        #pragma unroll
        for (int h = 0; h < 2; ++h) {
            int j = w * 2 + h;
            float v = bf2f((unsigned short)(h ? (u >> 16) : (u & 0xFFFFu)));
            float dn = (v - mu) * rs * prm[j] + prm[32 + j];
            float sv = siluf(dn);
            a0 += sv * prm[64 + j]; a1 += sv * prm[96 + j]; a2 += sv * prm[128 + j];
        }
    }
    size_t p = (size_t)b * CHW + pix;
    dl[p] = a0; dl[p + HW] = a1; dl[p + 2 * HW] = a2;
    float r0 = blockReduceSum(a0);
    float r1 = blockReduceSum(a1);
    float r2 = blockReduceSum(a2);
    if (threadIdx.x == 0) {
        part[PD + (size_t)(b * 3 + 0) * 1024 + local] = r0;
        part[PD + (size_t)(b * 3 + 1) * 1024 + local] = r1;
        part[PD + (size_t)(b * 3 + 2) * 1024 + local] = r2;
    }
}

__global__ void k_se(float* __restrict__ red,
    const float* __restrict__ w1, const float* __restrict__ b1,
    const float* __restrict__ w2, const float* __restrict__ b2,
    const float* __restrict__ alpha)
{
    int b = threadIdx.x;
    if (b < 8) {
        float p0 = red[72 + b * 3 + 0] * (1.f / HW);
        float p1 = red[72 + b * 3 + 1] * (1.f / HW);
        float p2 = red[72 + b * 3 + 2] * (1.f / HW);
        float h[4];
        #pragma unroll
        for (int j = 0; j < 4; ++j) {
            float a = b1[j] + p0 * w1[j * 3] + p1 * w1[j * 3 + 1] + p2 * w1[j * 3 + 2];
            h[j] = siluf(a);
        }
        float al = alpha[0];
        #pragma unroll
        for (int c = 0; c < 3; ++c) {
            float a = b2[c] + h[0] * w2[c * 4] + h[1] * w2[c * 4 + 1]
                            + h[2] * w2[c * 4 + 2] + h[3] * w2[c * 4 + 3];
            red[96 + b * 3 + c] = al * sigm(a);
        }
    }
}

__global__ __launch_bounds__(256) void k_out(
    const float* __restrict__ x, const float* __restrict__ dl,
    const float* __restrict__ red, float* __restrict__ out)
{
    int i = blockIdx.x * 256 + threadIdx.x;     // float4 index
    float aw = red[96 + (i >> 16)];
    float4 xv = ((const float4*)x)[i];
    float4 dv = ((const float4*)dl)[i];
    float4 o;
    o.x = xv.x + aw * dv.x; o.y = xv.y + aw * dv.y;
    o.z = xv.z + aw * dv.z; o.w = xv.w + aw * dv.w;
    ((float4*)out)[i] = o;
}

extern "C" void kernel_launch(void* const* d_in, const int* in_sizes, int n_in,
                              void* d_out, int out_size, void* d_ws, size_t ws_size,
                              hipStream_t stream)
{
    const float* x     = (const float*)d_in[0];
    const float* ng    = (const float*)d_in[1];
    const float* nb    = (const float*)d_in[2];
    const float* ph_w1 = (const float*)d_in[3];
    const float* ph_b1 = (const float*)d_in[4];
    const float* ph_w2 = (const float*)d_in[5];
    const float* ph_b2 = (const float*)d_in[6];
    const float* z_w1  = (const float*)d_in[7];
    const float* z_b1  = (const float*)d_in[8];
    const float* z_w2  = (const float*)d_in[9];
    const float* z_b2  = (const float*)d_in[10];
    const float* fgain = (const float*)d_in[11];
    const float* mw1   = (const float*)d_in[12];
    const float* mb1   = (const float*)d_in[13];
    const float* g1g   = (const float*)d_in[14];
    const float* g1b   = (const float*)d_in[15];
    const float* mw2   = (const float*)d_in[16];
    const float* mb2   = (const float*)d_in[17];
    const float* g2g   = (const float*)d_in[18];
    const float* g2b   = (const float*)d_in[19];
    const float* mw3   = (const float*)d_in[20];
    const float* mb3   = (const float*)d_in[21];
    const float* sw1   = (const float*)d_in[22];
    const float* sb1   = (const float*)d_in[23];
    const float* sw2   = (const float*)d_in[24];
    const float* sb2   = (const float*)d_in[25];
    const float* alpha = (const float*)d_in[26];

    char* ws = (char*)d_ws;
    float*  red = (float*)(ws + OFF_RED);
    float*  phi = (float*)(ws + OFF_PHI);
    float2* U   = (float2*)(ws + OFF_U);
    float*  Jb  = (float*)(ws + OFF_J);
    float*  dl  = (float*)(ws + OFF_D);
    unsigned short* y2   = (unsigned short*)(ws + OFF_Y2);
    unsigned short* w1bf = (unsigned short*)(ws + OFF_W1B);
    unsigned short* w2bf = (unsigned short*)(ws + OFF_W2B);
    unsigned short* wh1  = (unsigned short*)(ws + OFF_WH1);
    unsigned short* wp2  = (unsigned short*)(ws + OFF_WP2);
    unsigned short* wz2  = (unsigned short*)(ws + OFF_WZ2);
    float* prm  = (float*)(ws + OFF_PRM);
    float* part = (float*)(ws + OFF_PART);
    float* out = (float*)d_out;

    hipLaunchKernelGGL(k_zero, dim3(1), dim3(128), 0, stream, red);
    hipLaunchKernelGGL(k_prep, dim3(36), dim3(256), 0, stream,
                       mw1, mw2, ph_w1, z_w1, ph_w2, z_w2, g2g, g2b, mw3,
                       w1bf, w2bf, wh1, wp2, wz2, prm);
    hipLaunchKernelGGL(k_reduce_x, dim3(256), dim3(256), 0, stream, x, red);
    hipLaunchKernelGGL(k_heads, dim3(32, 32, 8), dim3(256), 0, stream,
                       x, red, ng, nb, wh1, ph_b1, z_b1, wp2, wz2, ph_b2, z_b2, phi, part);
    hipLaunchKernelGGL(k_red, dim3(24), dim3(256), 0, stream, part + PZ, red + 16);
    hipLaunchKernelGGL(k_fftA, dim3(3072), dim3(256), 0, stream, x, phi, U);
    hipLaunchKernelGGL(k_transpose, dim3(136, 24), dim3(256), 0, stream, U);
    hipLaunchKernelGGL(k_fftB, dim3(3072), dim3(256), 0, stream, U, red, fgain);
    hipLaunchKernelGGL(k_transpose, dim3(136, 24), dim3(256), 0, stream, U);
    hipLaunchKernelGGL(k_fftC, dim3(3072), dim3(256), 0, stream, U, Jb);
    hipLaunchKernelGGL(k_m1, dim3(32, 32, 8), dim3(256), 0, stream, x, Jb, w1bf, mb1, part);
    hipLaunchKernelGGL(k_red, dim3(16), dim3(256), 0, stream, part + PG1, red + 40);
    hipLaunchKernelGGL(k_m2, dim3(32, 32, 8), dim3(256), 0, stream,
                       x, Jb, w1bf, mb1, g1g, g1b, w2bf, mb2, red, part, y2);
    hipLaunchKernelGGL(k_red, dim3(16), dim3(256), 0, stream, part + PG2, red + 56);
    hipLaunchKernelGGL(k_m3, dim3(8192), dim3(256), 0, stream, y2, red, prm, mb3, dl, part);
    hipLaunchKernelGGL(k_red, dim3(24), dim3(256), 0, stream, part + PD, red + 72);
    hipLaunchKernelGGL(k_se, dim3(1), dim3(64), 0, stream, red, sw1, sb1, sw2, sb2, alpha);
    hipLaunchKernelGGL(k_out, dim3(6144), dim3(256), 0, stream, x, dl, red, out);
}

// Round 11
// 589.444 us; speedup vs baseline: 5.1364x; 1.0257x over previous
//
#include <hip/hip_runtime.h>
#include <hip/hip_bf16.h>
#include <math.h>

#define DINL __device__ __forceinline__

namespace {
constexpr int Bn = 8, Cn = 3, Hn = 512, Wn = 512;
constexpr int HW  = Hn * Wn;        // 262144
constexpr int CHW = Cn * HW;        // 786432
constexpr float GEPS = 1e-5f;
constexpr float PIf  = 3.14159265358979323846f;

// workspace layout (bytes) — U packed half2, J/phi/dl fp16
constexpr size_t OFF_RED = 0;                                   // 128 floats
constexpr size_t OFF_PHI = 512;                                 // Bn*CHW ushort
constexpr size_t OFF_U   = OFF_PHI + (size_t)Bn * CHW * 2;      // Bn*CHW uint (half2)
constexpr size_t OFF_J   = OFF_U   + (size_t)Bn * CHW * 4;      // Bn*CHW ushort
constexpr size_t OFF_D   = OFF_J   + (size_t)Bn * CHW * 2;      // Bn*CHW ushort
constexpr size_t OFF_Y2  = OFF_D   + (size_t)Bn * CHW * 2;      // 8*32*HW bf16 (channel-last)
constexpr size_t OFF_W1B = OFF_Y2  + (size_t)Bn * 32 * HW * 2;  // 3072 bf16
constexpr size_t OFF_W2B = OFF_W1B + 3072 * 2;                  // 9216 bf16
constexpr size_t OFF_WH1 = OFF_W2B + 9216 * 2;                  // 4608 bf16
constexpr size_t OFF_WP2 = OFF_WH1 + 4608 * 2;                  // 4608 bf16
constexpr size_t OFF_WZ2 = OFF_WP2 + 4608 * 2;                  // 4608 bf16
constexpr size_t OFF_PRM = OFF_WZ2 + 4608 * 2;                  // 160 f32
constexpr size_t OFF_PART= OFF_PRM + 160 * 4;                   // 81920 f32 partials
// part float sub-offsets (in floats)
constexpr int PZ = 0;          // 24 groups (b*3+c) x 1024
constexpr int PG1 = 24576;     // 16 groups (b:sum, 8+b:ss) x 1024
constexpr int PG2 = 40960;     // 16 groups x 1024
constexpr int PD  = 57344;     // 24 groups (b*3+c) x 1024
}

typedef __bf16 bfx8 __attribute__((ext_vector_type(8)));
typedef float  fx4  __attribute__((ext_vector_type(4)));

DINL float sigm(float a) { return __frcp_rn(1.f + __expf(-a)); }
DINL float siluf(float a) { return a * __frcp_rn(1.f + __expf(-a)); }
DINL float ftanh(float a) { return 1.f - 2.f * __frcp_rn(1.f + __expf(2.f * a)); }
DINL unsigned short f2bf(float f) {           // RNE float->bf16 bits
    unsigned u = __float_as_uint(f);
    return (unsigned short)((u + 0x7FFFu + ((u >> 16) & 1u)) >> 16);
}
DINL float bf2f(unsigned short h) {
    return __uint_as_float(((unsigned)h) << 16);
}
DINL unsigned pk2(float a, float b) {
    return (unsigned)f2bf(a) | ((unsigned)f2bf(b) << 16);
}
// fp16 helpers (v_cvt_pkrtz_f16_f32 / v_cvt_f16_f32 / v_cvt_f32_f16)
DINL unsigned pkh(float a, float b) {
    auto h = __builtin_amdgcn_cvt_pkrtz(a, b);   // __fp16 ext_vector(2)
    unsigned u; __builtin_memcpy(&u, &h, 4); return u;
}
DINL float2 uph(unsigned u) {
    _Float16 h[2]; __builtin_memcpy(h, &u, 4);
    return make_float2((float)h[0], (float)h[1]);
}
DINL unsigned short f2h(float a) {
    _Float16 h = (_Float16)a; unsigned short s; __builtin_memcpy(&s, &h, 2); return s;
}
DINL float h2f(unsigned short s) {
    _Float16 h; __builtin_memcpy(&h, &s, 2); return (float)h;
}

DINL float blockReduceSum(float v) {   // blockDim.x == 256
    __shared__ float sm[4];
    int lane = threadIdx.x & 63, wid = threadIdx.x >> 6;
    #pragma unroll
    for (int o = 32; o > 0; o >>= 1) v += __shfl_down(v, o, 64);
    __syncthreads();
    if (lane == 0) sm[wid] = v;
    __syncthreads();
    if (wid == 0) {
        float r = (lane < 4) ? sm[lane] : 0.f;
        r += __shfl_down(r, 2, 64);
        r += __shfl_down(r, 1, 64);
        return r;                       // valid on thread 0
    }
    return 0.f;
}

__global__ void k_zero(float* __restrict__ red) { red[threadIdx.x] = 0.f; }

__global__ __launch_bounds__(256) void k_red(const float* __restrict__ src,
                                             float* __restrict__ dst)
{
    const float4* s4 = (const float4*)(src + (size_t)blockIdx.x * 1024);
    float4 q = s4[threadIdx.x];
    float r = blockReduceSum(q.x + q.y + q.z + q.w);
    if (threadIdx.x == 0) dst[blockIdx.x] = r;
}

// weight repack (all bf16 fragment-order)
__global__ __launch_bounds__(256) void k_prep(
    const float* __restrict__ w1, const float* __restrict__ w2,
    const float* __restrict__ phw1, const float* __restrict__ zw1,
    const float* __restrict__ phw2, const float* __restrict__ zw2,
    const float* __restrict__ g2g, const float* __restrict__ g2b,
    const float* __restrict__ w3,
    unsigned short* __restrict__ w1bf, unsigned short* __restrict__ w2bf,
    unsigned short* __restrict__ wh1, unsigned short* __restrict__ wp2,
    unsigned short* __restrict__ wz2, float* __restrict__ prm)
{
    int i = blockIdx.x * 256 + threadIdx.x;     // 0..9215
    if (i < 3072) {
        int o = i / 96, k = i - o * 96;
        int ky = k >> 5, r = k & 31, kx = r >> 3, c = r & 7;
        float v = (kx < 3 && c < 5) ? w1[o * 45 + c * 9 + ky * 3 + kx] : 0.f;
        w1bf[i] = f2bf(v);
    }
    if (i < 9216) {
        int tap = i >> 10, rr = i & 1023, o = rr >> 5, ci = rr & 31;
        w2bf[i] = f2bf(w2[o * 288 + ci * 9 + tap]);
    }
    if (i < 4608) {
        int o = i / 96, k = i - o * 96;
        int ky = k >> 5, r = k & 31, kx = r >> 3, c = r & 7;
        float v = 0.f;
        if (kx < 3 && c < 3)
            v = (o < 16) ? phw1[o * 27 + c * 9 + ky * 3 + kx]
                         : zw1[(o - 16) * 27 + c * 9 + ky * 3 + kx];
        wh1[i] = f2bf(v);
    }
    if (i < 4608) {
        int tap = i / 512, rr = i - tap * 512, n = rr >> 5, k = rr & 31;
        float vp = (n < 3 && k < 16) ? phw2[n * 144 + k * 9 + tap] : 0.f;
        float vz = (n < 3) ? zw2[n * 288 + k * 9 + tap] : 0.f;
        wp2[i] = f2bf(vp);
        wz2[i] = f2bf(vz);
    }
    if (i < 160) {
        if (i < 32) {
            int ch = (i & 1) * 16 + (i >> 1);
            prm[i] = g2g[ch];
        } else if (i < 64) {
            int j = i - 32, ch = (j & 1) * 16 + (j >> 1);
            prm[i] = g2b[ch];
        } else {
            int j = (i - 64) & 31, c = (i - 64) >> 5;
            int ch = (j & 1) * 16 + (j >> 1);
            prm[i] = w3[c * 32 + ch];
        }
    }
}

__global__ __launch_bounds__(256) void k_reduce_x(const float* __restrict__ x,
                                                  float* __restrict__ red) {
    int b = blockIdx.x >> 5, blk = blockIdx.x & 31;
    const float4* xv = (const float4*)(x + (size_t)b * CHW + (size_t)blk * (CHW / 32));
    float s = 0.f, ss = 0.f;
    for (int i = threadIdx.x; i < (CHW / 32) / 4; i += 256) {
        float4 v = xv[i];
        s  += v.x + v.y + v.z + v.w;
        ss += v.x * v.x + v.y * v.y + v.z * v.z + v.w * v.w;
    }
    float rs = blockReduceSum(s);
    float rss = blockReduceSum(ss);
    if (threadIdx.x == 0) { atomicAdd(&red[b], rs); atomicAdd(&red[8 + b], rss); }
}

// ---------------- fused heads (MFMA): xn -> [ph16 | z32] hidden -> phi + z partials ----------------
__global__ __launch_bounds__(256) void k_heads(
    const float* __restrict__ x, const float* __restrict__ red,
    const float* __restrict__ ng, const float* __restrict__ nb,
    const unsigned short* __restrict__ wh1,
    const float* __restrict__ phb1, const float* __restrict__ zb1,
    const unsigned short* __restrict__ wp2, const unsigned short* __restrict__ wz2,
    const float* __restrict__ phb2, const float* __restrict__ zb2,
    unsigned short* __restrict__ phi, float* __restrict__ part)
{
    const int tx0 = blockIdx.x * 16, ty0 = blockIdx.y * 16, b = blockIdx.z;
    const int local = blockIdx.y * 32 + blockIdx.x;
    const bool edge = (blockIdx.x == 0) || (blockIdx.x == 31) ||
                      (blockIdx.y == 0) || (blockIdx.y == 31);
    __shared__ unsigned short mt8[20 * 21 * 8];
    __shared__ unsigned short ht8[324 * 48];      // reused as phs/zs in epilogue
    const int t = threadIdx.x;
    const float mu = red[b] * (1.f / CHW);
    const float rsv = rsqrtf(red[8 + b] * (1.f / CHW) - mu * mu + GEPS);
    float sc[3], sh[3];
    #pragma unroll
    for (int c = 0; c < 3; ++c) { sc[c] = rsv * ng[c]; sh[c] = nb[c] - mu * rsv * ng[c]; }
    if (edge) {
        for (int e = t; e < 20 * 21; e += 256) {
            int yy = e / 21, xx = e - yy * 21;
            int gy = ty0 - 2 + yy, gx = tx0 - 2 + xx;
            float v0 = 0, v1 = 0, v2 = 0;
            if (xx < 20 && (unsigned)gy < (unsigned)Hn && (unsigned)gx < (unsigned)Wn) {
                size_t p = (size_t)b * CHW + (size_t)gy * Wn + gx;
                v0 = x[p] * sc[0] + sh[0];
                v1 = x[p + HW] * sc[1] + sh[1];
                v2 = x[p + 2 * HW] * sc[2] + sh[2];
            }
            *(uint4*)(mt8 + e * 8) = make_uint4(pk2(v0, v1), (unsigned)f2bf(v2), 0u, 0u);
        }
    } else {
        for (int e = t; e < 20 * 21; e += 256) {
            int yy = e / 21, xx = e - yy * 21;
            float v0 = 0, v1 = 0, v2 = 0;
            if (xx < 20) {
                size_t p = (size_t)b * CHW + (size_t)(ty0 - 2 + yy) * Wn + (tx0 - 2 + xx);
                v0 = x[p] * sc[0] + sh[0];
                v1 = x[p + HW] * sc[1] + sh[1];
                v2 = x[p + 2 * HW] * sc[2] + sh[2];
            }
            *(uint4*)(mt8 + e * 8) = make_uint4(pk2(v0, v1), (unsigned)f2bf(v2), 0u, 0u);
        }
    }
    const int wv = t >> 6, lane = t & 63, ln = lane & 15, q = lane >> 4;
    bfx8 Bf[3][3];
    #pragma unroll
    for (int ks = 0; ks < 3; ++ks)
        #pragma unroll
        for (int nt = 0; nt < 3; ++nt)
            Bf[ks][nt] = *(const bfx8*)(wh1 + (nt * 16 + ln) * 96 + ks * 32 + q * 8);
    const float bb0 = phb1[ln], bb1 = zb1[ln], bb2 = zb1[16 + ln];
    __syncthreads();
    for (int mt = wv; mt < 21; mt += 4) {
        int p = mt * 16 + ln; if (p > 323) p = 323;
        const int hy = p / 18, hx = p - hy * 18;
        fx4 a0 = {0,0,0,0}, a1 = {0,0,0,0}, a2 = {0,0,0,0};
        #pragma unroll
        for (int ks = 0; ks < 3; ++ks) {
            bfx8 A = *(const bfx8*)(mt8 + ((hy + ks) * 21 + hx + q) * 8);
            a0 = __builtin_amdgcn_mfma_f32_16x16x32_bf16(A, Bf[ks][0], a0, 0, 0, 0);
            a1 = __builtin_amdgcn_mfma_f32_16x16x32_bf16(A, Bf[ks][1], a1, 0, 0, 0);
            a2 = __builtin_amdgcn_mfma_f32_16x16x32_bf16(A, Bf[ks][2], a2, 0, 0, 0);
        }
        const int prb = mt * 16 + q * 4;
        if (edge) {
            #pragma unroll
            for (int r = 0; r < 4; ++r) {
                const int pr = prb + r;
                if (pr < 324) {
                    const int py = pr / 18, px = pr - py * 18;
                    const int gy = ty0 - 1 + py, gx = tx0 - 1 + px;
                    const bool inimg = (unsigned)gy < (unsigned)Hn && (unsigned)gx < (unsigned)Wn;
                    unsigned short* hp = ht8 + pr * 48;
                    hp[ln]      = inimg ? f2bf(siluf(a0[r] + bb0)) : (unsigned short)0;
                    hp[16 + ln] = inimg ? f2bf(siluf(a1[r] + bb1)) : (unsigned short)0;
                    hp[32 + ln] = inimg ? f2bf(siluf(a2[r] + bb2)) : (unsigned short)0;
                }
            }
        } else {
            #pragma unroll
            for (int r = 0; r < 4; ++r) {
                const int pr = prb + r;
                if (pr < 324) {
                    unsigned short* hp = ht8 + pr * 48;
                    hp[ln]      = f2bf(siluf(a0[r] + bb0));
                    hp[16 + ln] = f2bf(siluf(a1[r] + bb1));
                    hp[32 + ln] = f2bf(siluf(a2[r] + bb2));
                }
            }
        }
    }
    __syncthreads();
    fx4 accp[4], accz[4];
    #pragma unroll
    for (int i = 0; i < 4; ++i) { accp[i] = fx4{0,0,0,0}; accz[i] = fx4{0,0,0,0}; }
    #pragma unroll
    for (int tap = 0; tap < 9; ++tap) {
        const int ky = tap / 3, kx = tap - ky * 3;
        bfx8 Bp = *(const bfx8*)(wp2 + tap * 512 + ln * 32 + q * 8);
        bfx8 Bz = *(const bfx8*)(wz2 + tap * 512 + ln * 32 + q * 8);
        #pragma unroll
        for (int i = 0; i < 4; ++i) {
            const int oy = wv * 4 + i;
            const unsigned short* ap = ht8 + ((oy + ky) * 18 + ln + kx) * 48;
            bfx8 Ap = *(const bfx8*)(ap + q * 8);
            bfx8 Az = *(const bfx8*)(ap + 16 + q * 8);
            accp[i] = __builtin_amdgcn_mfma_f32_16x16x32_bf16(Ap, Bp, accp[i], 0, 0, 0);
            accz[i] = __builtin_amdgcn_mfma_f32_16x16x32_bf16(Az, Bz, accz[i], 0, 0, 0);
        }
    }
    // epilogue via LDS: full-lane tanh/sigm, coalesced fp16 stores
    __syncthreads();                       // ht8 reads done; reuse as float staging
    float* phs = (float*)ht8;              // [256][4]
    float* zs  = phs + 1024;               // [256][4]
    if (ln < 3) {
        #pragma unroll
        for (int i = 0; i < 4; ++i)
            #pragma unroll
            for (int r = 0; r < 4; ++r) {
                int pl = (wv * 4 + i) * 16 + q * 4 + r;
                phs[pl * 4 + ln] = accp[i][r];
                zs [pl * 4 + ln] = accz[i][r];
            }
    }
    __syncthreads();
    float4 pv = ((const float4*)phs)[t];
    float4 zv = ((const float4*)zs)[t];
    const int gy = ty0 + (t >> 4), gx = tx0 + (t & 15);
    size_t pp = (size_t)b * CHW + (size_t)gy * Wn + gx;
    phi[pp]          = f2h(ftanh(pv.x + phb2[0]) * PIf);
    phi[pp + HW]     = f2h(ftanh(pv.y + phb2[1]) * PIf);
    phi[pp + 2 * HW] = f2h(ftanh(pv.z + phb2[2]) * PIf);
    float z0 = sigm(zv.x + zb2[0]) * 0.3f;
    float z1 = sigm(zv.y + zb2[1]) * 0.3f;
    float z2 = sigm(zv.z + zb2[2]) * 0.3f;
    float r0 = blockReduceSum(z0);
    float r1 = blockReduceSum(z1);
    float r2 = blockReduceSum(z2);
    if (t == 0) {
        part[PZ + (size_t)(b * 3 + 0) * 1024 + local] = r0;
        part[PZ + (size_t)(b * 3 + 1) * 1024 + local] = r1;
        part[PZ + (size_t)(b * 3 + 2) * 1024 + local] = r2;
    }
}

// ---------------- FFT: 512-pt Stockham radix-4 (x4) + radix-2, wave-per-line ----------------
template<bool INV>
DINL float2* fft512_wave4(float2* a, float2* b, const float2* tw, int l)
{
    float2* src = a; float2* dst = b;
    int s = 1;
    #pragma unroll
    for (int st = 0; st < 4; ++st) {
        #pragma unroll
        for (int h = 0; h < 2; ++h) {
            const int i = l + h * 64;          // butterfly index in [0,128)
            const int q = i & (s - 1);
            const int sm = i - q;              // s*m
            float2 A = src[i], B = src[i + 128], C = src[i + 256], D = src[i + 384];
            float t0x = A.x + C.x, t0y = A.y + C.y;
            float t1x = A.x - C.x, t1y = A.y - C.y;
            float t2x = B.x + D.x, t2y = B.y + D.y;
            float t3x = B.x - D.x, t3y = B.y - D.y;
            float i3x = INV ? -t3y : t3y;
            float i3y = INV ? t3x : -t3x;
            float u0x = t0x + t2x, u0y = t0y + t2y;
            float u2x = t0x - t2x, u2y = t0y - t2y;
            float u1x = t1x + i3x, u1y = t1y + i3y;
            float u3x = t1x - i3x, u3y = t1y - i3y;
            float2 w1 = tw[sm], w2 = tw[2 * sm], w3 = tw[3 * sm];
            float w1y = INV ? -w1.y : w1.y;
            float w2y = INV ? -w2.y : w2.y;
            float w3y = INV ? -w3.y : w3.y;
            const int base = q + 4 * sm;
            dst[base]         = make_float2(u0x, u0y);
            dst[base + s]     = make_float2(u1x * w1.x - u1y * w1y, u1x * w1y + u1y * w1.x);
            dst[base + 2 * s] = make_float2(u2x * w2.x - u2y * w2y, u2x * w2y + u2y * w2.x);
            dst[base + 3 * s] = make_float2(u3x * w3.x - u3y * w3y, u3x * w3y + u3y * w3.x);
        }
        float2* tmp = src; src = dst; dst = tmp;
        s <<= 2;
        asm volatile("" ::: "memory");   // wave-synchronous LDS: fence compiler only
    }
    // final radix-2, s=256 (m=0 -> no twiddle)
    #pragma unroll
    for (int h = 0; h < 4; ++h) {
        const int j = l + h * 64;
        float2 u = src[j], v = src[j + 256];
        dst[j]       = make_float2(u.x + v.x, u.y + v.y);
        dst[j + 256] = make_float2(u.x - v.x, u.y - v.y);
    }
    float2* tmp = src; src = dst; dst = tmp;
    asm volatile("" ::: "memory");
    return src;
}

__global__ __launch_bounds__(256) void k_fftA(
    const float* __restrict__ x, const unsigned short* __restrict__ phi,
    unsigned* __restrict__ U)
{
    __shared__ float2 buf[4][2][512];
    __shared__ float2 tw[512];
    const int t = threadIdx.x, wv = t >> 6, l = t & 63;
    #pragma unroll
    for (int i = t; i < 512; i += 256) {
        float s, c; __sincosf(-2.f * PIf * (float)i * (1.f / 512.f), &s, &c);
        tw[i] = make_float2(c, s);
    }
    __syncthreads();
    const size_t line = (size_t)blockIdx.x * 4 + wv;
    const float* xr = x + line * 512;
    const unsigned short* pr = phi + line * 512;
    float2* A = buf[wv][0];
    float2* B = buf[wv][1];
    #pragma unroll
    for (int i = l; i < 512; i += 64) {
        float s, c; __sincosf(h2f(pr[i]), &s, &c);
        float xv = xr[i];
        A[i] = make_float2(xv * c, xv * s);
    }
    asm volatile("" ::: "memory");
    float2* res = fft512_wave4<false>(A, B, tw, l);
    unsigned* Ur = U + line * 512;
    #pragma unroll
    for (int i = l; i < 512; i += 64) Ur[i] = pkh(res[i].x, res[i].y);
}

__global__ __launch_bounds__(256) void k_transpose(unsigned* __restrict__ U)
{
    const int img = blockIdx.y;
    int rem = blockIdx.x, ti = 0;
    while (rem >= 16 - ti) { rem -= 16 - ti; ++ti; }
    const int tj = ti + rem;
    unsigned* Ub = U + (size_t)img * HW;
    __shared__ unsigned ta[32][33];
    __shared__ unsigned tb[32][33];
    const int t = threadIdx.x;
    const int cc = t & 31, r0 = t >> 5;
    const int ar = ti * 32, ac = tj * 32;
    #pragma unroll
    for (int k = 0; k < 4; ++k) {
        int r = r0 + k * 8;
        ta[r][cc] = Ub[(size_t)(ar + r) * 512 + ac + cc];
    }
    if (ti != tj) {
        #pragma unroll
        for (int k = 0; k < 4; ++k) {
            int r = r0 + k * 8;
            tb[r][cc] = Ub[(size_t)(ac + r) * 512 + ar + cc];
        }
    }
    __syncthreads();
    #pragma unroll
    for (int k = 0; k < 4; ++k) {
        int r = r0 + k * 8;
        Ub[(size_t)(ac + r) * 512 + ar + cc] = ta[cc][r];
    }
    if (ti != tj) {
        #pragma unroll
        for (int k = 0; k < 4; ++k) {
            int r = r0 + k * 8;
            Ub[(size_t)(ar + r) * 512 + ac + cc] = tb[cc][r];
        }
    }
}

__global__ __launch_bounds__(256) void k_fftB(
    unsigned* __restrict__ U, const float* __restrict__ red, const float* __restrict__ fgain)
{
    __shared__ float2 buf[4][2][512];
    __shared__ float2 tw[512];
    const int t = threadIdx.x, wv = t >> 6, l = t & 63;
    #pragma unroll
    for (int i = t; i < 512; i += 256) {
        float s, c; __sincosf(-2.f * PIf * (float)i * (1.f / 512.f), &s, &c);
        tw[i] = make_float2(c, s);
    }
    __syncthreads();
    const int line = blockIdx.x * 4 + wv;          // (b*3+c)*512 + fw
    const int bc = line >> 9;
    const int fw = line & 511;
    const int c = bc % 3;
    unsigned* Ur = U + (size_t)line * 512;
    float2* A = buf[wv][0];
    float2* B = buf[wv][1];
    #pragma unroll
    for (int i = l; i < 512; i += 64) A[i] = uph(Ur[i]);
    asm volatile("" ::: "memory");
    float2* res = fft512_wave4<false>(A, B, tw, l);
    const float zm   = red[16 + bc] * (1.f / HW);
    const float gain = 1.f + fgain[c];
    const float lam  = (c == 0) ? 0.65f : (c == 1) ? 0.53f : 0.47f;
    const float il2  = 1.f / (lam * lam);
    const float fwv  = (float)(fw < 256 ? fw : fw - 512) * (1.f / 512.f);
    const float f2w  = fwv * fwv;
    #pragma unroll
    for (int i = l; i < 512; i += 64) {
        float fh = (float)(i < 256 ? i : i - 512) * (1.f / 512.f);
        float kz = 2.f * PIf * sqrtf(fmaxf(il2 - f2w - fh * fh, 0.f));
        float sn, cs; __sincosf(kz * zm, &sn, &cs);
        float2 v = res[i];
        res[i] = make_float2(gain * (v.x * cs - v.y * sn), gain * (v.x * sn + v.y * cs));
    }
    asm volatile("" ::: "memory");
    float2* other = (res == A) ? B : A;
    float2* res2 = fft512_wave4<true>(res, other, tw, l);
    #pragma unroll
    for (int i = l; i < 512; i += 64) {
        float2 v = res2[i];
        Ur[i] = pkh(v.x * (1.f / 512.f), v.y * (1.f / 512.f));
    }
}

__global__ __launch_bounds__(256) void k_fftC(
    const unsigned* __restrict__ U, unsigned short* __restrict__ J)
{
    __shared__ float2 buf[4][2][512];
    __shared__ float2 tw[512];
    const int t = threadIdx.x, wv = t >> 6, l = t & 63;
    #pragma unroll
    for (int i = t; i < 512; i += 256) {
        float s, c; __sincosf(-2.f * PIf * (float)i * (1.f / 512.f), &s, &c);
        tw[i] = make_float2(c, s);
    }
    __syncthreads();
    const size_t line = (size_t)blockIdx.x * 4 + wv;
    const unsigned* Ur = U + line * 512;
    float2* A = buf[wv][0];
    float2* B = buf[wv][1];
    #pragma unroll
    for (int i = l; i < 512; i += 64) A[i] = uph(Ur[i]);
    asm volatile("" ::: "memory");
    float2* res = fft512_wave4<true>(A, B, tw, l);
    unsigned short* Jr = J + line * 512;
    #pragma unroll
    for (int i = l; i < 512; i += 64) {
        float2 v = res[i];
        float re = v.x * (1.f / 512.f), im = v.y * (1.f / 512.f);
        Jr[i] = f2h(sqrtf(fmaxf(re * re + im * im, 1e-12f)));
    }
}

// ---------------- mix path (MFMA) ----------------
__global__ __launch_bounds__(256) void k_m1(
    const float* __restrict__ x, const unsigned short* __restrict__ Jb,
    const unsigned short* __restrict__ w1bf, const float* __restrict__ b1,
    float* __restrict__ part)
{
    const int tx0 = blockIdx.x * 16, ty0 = blockIdx.y * 16, b = blockIdx.z;
    const int local = blockIdx.y * 32 + blockIdx.x;
    const bool edge = (blockIdx.x == 0) || (blockIdx.x == 31) ||
                      (blockIdx.y == 0) || (blockIdx.y == 31);
    __shared__ unsigned short mt8[18 * 19 * 8];
    const int t = threadIdx.x;
    for (int e = t; e < 18 * 19; e += 256) {
        int yy = e / 19, xx = e - yy * 19;
        int gy = ty0 - 1 + yy, gx = tx0 - 1 + xx;
        float v0 = 0, v1 = 0, v2 = 0, jl = 0, d5 = 0;
        bool ok = edge ? (xx < 18 && (unsigned)gy < (unsigned)Hn && (unsigned)gx < (unsigned)Wn)
                       : (xx < 18);
        if (ok) {
            size_t p = (size_t)b * CHW + (size_t)gy * Wn + gx;
            v0 = x[p]; v1 = x[p + HW]; v2 = x[p + 2 * HW];
            float j0 = h2f(Jb[p]), j1 = h2f(Jb[p + HW]), j2 = h2f(Jb[p + 2 * HW]);
            float xl = 0.299f * v0 + 0.587f * v1 + 0.114f * v2;
            jl = 0.299f * j0 + 0.587f * j1 + 0.114f * j2;
            d5 = jl - xl;
        }
        *(uint4*)(mt8 + e * 8) = make_uint4(pk2(v0, v1), pk2(v2, jl), (unsigned)f2bf(d5), 0u);
    }
    __syncthreads();
    const int wv = t >> 6, lane = t & 63, ln = lane & 15, q = lane >> 4;
    bfx8 Bf[3][2];
    #pragma unroll
    for (int ks = 0; ks < 3; ++ks)
        #pragma unroll
        for (int nt = 0; nt < 2; ++nt)
            Bf[ks][nt] = *(const bfx8*)(w1bf + (nt * 16 + ln) * 96 + ks * 32 + q * 8);
    const float b1v0 = b1[ln], b1v1 = b1[16 + ln];
    float s = 0.f, ss = 0.f;
    #pragma unroll
    for (int i = 0; i < 4; ++i) {
        const int oy = wv * 4 + i;
        fx4 a0 = {0.f, 0.f, 0.f, 0.f}, a1 = {0.f, 0.f, 0.f, 0.f};
        #pragma unroll
        for (int ks = 0; ks < 3; ++ks) {
            bfx8 A = *(const bfx8*)(mt8 + ((oy + ks) * 19 + ln + q) * 8);
            a0 = __builtin_amdgcn_mfma_f32_16x16x32_bf16(A, Bf[ks][0], a0, 0, 0, 0);
            a1 = __builtin_amdgcn_mfma_f32_16x16x32_bf16(A, Bf[ks][1], a1, 0, 0, 0);
        }
        #pragma unroll
        for (int r = 0; r < 4; ++r) {
            float u0 = a0[r] + b1v0, u1 = a1[r] + b1v1;
            s += u0 + u1; ss += u0 * u0 + u1 * u1;
        }
    }
    float rs = blockReduceSum(s);
    float rss = blockReduceSum(ss);
    if (t == 0) {
        part[PG1 + (size_t)b * 1024 + local] = rs;
        part[PG1 + (size_t)(8 + b) * 1024 + local] = rss;
    }
}

// conv1 -> gn1 -> silu -> conv2 (MFMA); y2 channel-last + gn2 partials
__global__ __launch_bounds__(256) void k_m2(
    const float* __restrict__ x, const unsigned short* __restrict__ Jb,
    const unsigned short* __restrict__ w1bf, const float* __restrict__ b1,
    const float* __restrict__ g1g, const float* __restrict__ g1b,
    const unsigned short* __restrict__ w2bf, const float* __restrict__ b2,
    const float* __restrict__ red, float* __restrict__ part,
    unsigned short* __restrict__ y2)
{
    const int tx0 = blockIdx.x * 16, ty0 = blockIdx.y * 16, b = blockIdx.z;
    const int local = blockIdx.y * 32 + blockIdx.x;
    const bool edge = (blockIdx.x == 0) || (blockIdx.x == 31) ||
                      (blockIdx.y == 0) || (blockIdx.y == 31);
    __shared__ unsigned short mt8[20 * 21 * 8];
    __shared__ unsigned short dt2[324 * 40];
    const int t = threadIdx.x;
    const float mu1 = red[40 + b] * (1.f / (32.f * HW));
    const float rs1 = rsqrtf(red[48 + b] * (1.f / (32.f * HW)) - mu1 * mu1 + GEPS);
    for (int e = t; e < 20 * 21; e += 256) {
        int yy = e / 21, xx = e - yy * 21;
        int gy = ty0 - 2 + yy, gx = tx0 - 2 + xx;
        float v0 = 0, v1 = 0, v2 = 0, jl = 0, d5 = 0;
        bool ok = edge ? (xx < 20 && (unsigned)gy < (unsigned)Hn && (unsigned)gx < (unsigned)Wn)
                       : (xx < 20);
        if (ok) {
            size_t p = (size_t)b * CHW + (size_t)gy * Wn + gx;
            v0 = x[p]; v1 = x[p + HW]; v2 = x[p + 2 * HW];
            float j0 = h2f(Jb[p]), j1 = h2f(Jb[p + HW]), j2 = h2f(Jb[p + 2 * HW]);
            float xl = 0.299f * v0 + 0.587f * v1 + 0.114f * v2;
            jl = 0.299f * j0 + 0.587f * j1 + 0.114f * j2;
            d5 = jl - xl;
        }
        *(uint4*)(mt8 + e * 8) = make_uint4(pk2(v0, v1), pk2(v2, jl), (unsigned)f2bf(d5), 0u);
    }
    const int wv = t >> 6, lane = t & 63, ln = lane & 15, q = lane >> 4;
    const float sc0 = rs1 * g1g[ln],       sc1 = rs1 * g1g[16 + ln];
    const float of0 = (b1[ln] - mu1) * sc0 + g1b[ln];
    const float of1 = (b1[16 + ln] - mu1) * sc1 + g1b[16 + ln];
    bfx8 Bf[3][2];
    #pragma unroll
    for (int ks = 0; ks < 3; ++ks)
        #pragma unroll
        for (int nt = 0; nt < 2; ++nt)
            Bf[ks][nt] = *(const bfx8*)(w1bf + (nt * 16 + ln) * 96 + ks * 32 + q * 8);
    __syncthreads();
    for (int mt = wv; mt < 21; mt += 4) {
        int p = mt * 16 + ln; if (p > 323) p = 323;
        const int hy = p / 18, hx = p - hy * 18;
        fx4 a0 = {0.f, 0.f, 0.f, 0.f}, a1 = {0.f, 0.f, 0.f, 0.f};
        #pragma unroll
        for (int ks = 0; ks < 3; ++ks) {
            bfx8 A = *(const bfx8*)(mt8 + ((hy + ks) * 21 + hx + q) * 8);
            a0 = __builtin_amdgcn_mfma_f32_16x16x32_bf16(A, Bf[ks][0], a0, 0, 0, 0);
            a1 = __builtin_amdgcn_mfma_f32_16x16x32_bf16(A, Bf[ks][1], a1, 0, 0, 0);
        }
        const int prb = mt * 16 + q * 4;
        if (edge) {
            #pragma unroll
            for (int r = 0; r < 4; ++r) {
                const int pr = prb + r;
                if (pr < 324) {
                    const int py = pr / 18, px = pr - py * 18;
                    const int gy = ty0 - 1 + py, gx = tx0 - 1 + px;
                    const bool inimg = (unsigned)gy < (unsigned)Hn && (unsigned)gx < (unsigned)Wn;
                    dt2[pr * 40 + ln]      = inimg ? f2bf(siluf(a0[r] * sc0 + of0)) : (unsigned short)0;
                    dt2[pr * 40 + 16 + ln] = inimg ? f2bf(siluf(a1[r] * sc1 + of1)) : (unsigned short)0;
                }
            }
        } else {
            #pragma unroll
            for (int r = 0; r < 4; ++r) {
                const int pr = prb + r;
                if (pr < 324) {
                    dt2[pr * 40 + ln]      = f2bf(siluf(a0[r] * sc0 + of0));
                    dt2[pr * 40 + 16 + ln] = f2bf(siluf(a1[r] * sc1 + of1));
                }
            }
        }
    }
    __syncthreads();
    fx4 c2[4][2];
    #pragma unroll
    for (int i = 0; i < 4; ++i)
        #pragma unroll
        for (int nt = 0; nt < 2; ++nt)
            c2[i][nt] = fx4{0.f, 0.f, 0.f, 0.f};
    #pragma unroll
    for (int tap = 0; tap < 9; ++tap) {
        const int ky = tap / 3, kx = tap - ky * 3;
        bfx8 B0 = *(const bfx8*)(w2bf + tap * 1024 + ln * 32 + q * 8);
        bfx8 B1 = *(const bfx8*)(w2bf + tap * 1024 + (16 + ln) * 32 + q * 8);
        #pragma unroll
        for (int i = 0; i < 4; ++i) {
            const int oy = wv * 4 + i;
            bfx8 A = *(const bfx8*)(dt2 + ((oy + ky) * 18 + ln + kx) * 40 + q * 8);
            c2[i][0] = __builtin_amdgcn_mfma_f32_16x16x32_bf16(A, B0, c2[i][0], 0, 0, 0);
            c2[i][1] = __builtin_amdgcn_mfma_f32_16x16x32_bf16(A, B1, c2[i][1], 0, 0, 0);
        }
    }
    float s = 0.f, ss = 0.f;
    const float b2v0 = b2[ln], b2v1 = b2[16 + ln];
    #pragma unroll
    for (int i = 0; i < 4; ++i) {
        const int gy = ty0 + wv * 4 + i;
        #pragma unroll
        for (int r = 0; r < 4; ++r) {
            const int gx = tx0 + q * 4 + r;
            float a0 = c2[i][0][r] + b2v0;
            float a1 = c2[i][1][r] + b2v1;
            s += a0 + a1; ss += a0 * a0 + a1 * a1;
            unsigned pk = pk2(a0, a1);
            size_t off = ((size_t)b * HW + (size_t)gy * Wn + gx) * 32 + ln * 2;
            *(unsigned*)(y2 + off) = pk;
        }
    }
    float rsum = blockReduceSum(s);
    float rss = blockReduceSum(ss);
    if (t == 0) {
        part[PG2 + (size_t)b * 1024 + local] = rsum;
        part[PG2 + (size_t)(8 + b) * 1024 + local] = rss;
    }
}

// gn2 -> silu -> 1x1 conv; channel-last y2; dl fp16; dsum partials (no atomics)
__global__ __launch_bounds__(256) void k_m3(
    const unsigned short* __restrict__ y2, const float* __restrict__ red,
    const float* __restrict__ prm, const float* __restrict__ b3,
    unsigned short* __restrict__ dl, float* __restrict__ part)
{
    int idx = blockIdx.x * 256 + threadIdx.x;     // global pixel (b*HW+pix)
    int b = idx >> 18;
    int pix = idx & (HW - 1);
    const int local = blockIdx.x & 1023;
    float mu = red[56 + b] * (1.f / (32.f * HW));
    float rs = rsqrtf(red[64 + b] * (1.f / (32.f * HW)) - mu * mu + GEPS);
    const uint4* yp = (const uint4*)(y2 + (size_t)idx * 32);
    uint4 L[4];
    #pragma unroll
    for (int c = 0; c < 4; ++c) L[c] = yp[c];
    float a0 = b3[0], a1 = b3[1], a2 = b3[2];
    const unsigned* Lw = (const unsigned*)L;
    #pragma unroll
    for (int w = 0; w < 16; ++w) {     // 16 dwords = all 32 channels
        unsigned u = Lw[w];
        #pragma unroll
        for (int h = 0; h < 2; ++h) {
            int j = w * 2 + h;
            float v = bf2f((unsigned short)(h ? (u >> 16) : (u & 0xFFFFu)));
            float dn = (v - mu) * rs * prm[j] + prm[32 + j];
            float sv = siluf(dn);
            a0 += sv * prm[64 + j]; a1 += sv * prm[96 + j]; a2 += sv * prm[128 + j];
        }
    }
    size_t p = (size_t)b * CHW + pix;
    dl[p] = f2h(a0); dl[p + HW] = f2h(a1); dl[p + 2 * HW] = f2h(a2);
    float r0 = blockReduceSum(a0);
    float r1 = blockReduceSum(a1);
    float r2 = blockReduceSum(a2);
    if (threadIdx.x == 0) {
        part[PD + (size_t)(b * 3 + 0) * 1024 + local] = r0;
        part[PD + (size_t)(b * 3 + 1) * 1024 + local] = r1;
        part[PD + (size_t)(b * 3 + 2) * 1024 + local] = r2;
    }
}

__global__ void k_se(float* __restrict__ red,
    const float* __restrict__ w1, const float* __restrict__ b1,
    const float* __restrict__ w2, const float* __restrict__ b2,
    const float* __restrict__ alpha)
{
    int b = threadIdx.x;
    if (b < 8) {
        float p0 = red[72 + b * 3 + 0] * (1.f / HW);
        float p1 = red[72 + b * 3 + 1] * (1.f / HW);
        float p2 = red[72 + b * 3 + 2] * (1.f / HW);
        float h[4];
        #pragma unroll
        for (int j = 0; j < 4; ++j) {
            float a = b1[j] + p0 * w1[j * 3] + p1 * w1[j * 3 + 1] + p2 * w1[j * 3 + 2];
            h[j] = siluf(a);
        }
        float al = alpha[0];
        #pragma unroll
        for (int c = 0; c < 3; ++c) {
            float a = b2[c] + h[0] * w2[c * 4] + h[1] * w2[c * 4 + 1]
                            + h[2] * w2[c * 4 + 2] + h[3] * w2[c * 4 + 3];
            red[96 + b * 3 + c] = al * sigm(a);
        }
    }
}

__global__ __launch_bounds__(256) void k_out(
    const float* __restrict__ x, const unsigned short* __restrict__ dl,
    const float* __restrict__ red, float* __restrict__ out)
{
    int i = blockIdx.x * 256 + threadIdx.x;     // float4 index
    float aw = red[96 + (i >> 16)];
    float4 xv = ((const float4*)x)[i];
    uint2 dv2 = ((const uint2*)dl)[i];          // 4 fp16
    float2 d01 = uph(dv2.x);
    float2 d23 = uph(dv2.y);
    float4 o;
    o.x = xv.x + aw * d01.x; o.y = xv.y + aw * d01.y;
    o.z = xv.z + aw * d23.x; o.w = xv.w + aw * d23.y;
    ((float4*)out)[i] = o;
}

extern "C" void kernel_launch(void* const* d_in, const int* in_sizes, int n_in,
                              void* d_out, int out_size, void* d_ws, size_t ws_size,
                              hipStream_t stream)
{
    const float* x     = (const float*)d_in[0];
    const float* ng    = (const float*)d_in[1];
    const float* nb    = (const float*)d_in[2];
    const float* ph_w1 = (const float*)d_in[3];
    const float* ph_b1 = (const float*)d_in[4];
    const float* ph_w2 = (const float*)d_in[5];
    const float* ph_b2 = (const float*)d_in[6];
    const float* z_w1  = (const float*)d_in[7];
    const float* z_b1  = (const float*)d_in[8];
    const float* z_w2  = (const float*)d_in[9];
    const float* z_b2  = (const float*)d_in[10];
    const float* fgain = (const float*)d_in[11];
    const float* mw1   = (const float*)d_in[12];
    const float* mb1   = (const float*)d_in[13];
    const float* g1g   = (const float*)d_in[14];
    const float* g1b   = (const float*)d_in[15];
    const float* mw2   = (const float*)d_in[16];
    const float* mb2   = (const float*)d_in[17];
    const float* g2g   = (const float*)d_in[18];
    const float* g2b   = (const float*)d_in[19];
    const float* mw3   = (const float*)d_in[20];
    const float* mb3   = (const float*)d_in[21];
    const float* sw1   = (const float*)d_in[22];
    const float* sb1   = (const float*)d_in[23];
    const float* sw2   = (const float*)d_in[24];
    const float* sb2   = (const float*)d_in[25];
    const float* alpha = (const float*)d_in[26];

    char* ws = (char*)d_ws;
    float*  red = (float*)(ws + OFF_RED);
    unsigned short* phi = (unsigned short*)(ws + OFF_PHI);
    unsigned* U = (unsigned*)(ws + OFF_U);
    unsigned short* Jb = (unsigned short*)(ws + OFF_J);
    unsigned short* dl = (unsigned short*)(ws + OFF_D);
    unsigned short* y2   = (unsigned short*)(ws + OFF_Y2);
    unsigned short* w1bf = (unsigned short*)(ws + OFF_W1B);
    unsigned short* w2bf = (unsigned short*)(ws + OFF_W2B);
    unsigned short* wh1  = (unsigned short*)(ws + OFF_WH1);
    unsigned short* wp2  = (unsigned short*)(ws + OFF_WP2);
    unsigned short* wz2  = (unsigned short*)(ws + OFF_WZ2);
    float* prm  = (float*)(ws + OFF_PRM);
    float* part = (float*)(ws + OFF_PART);
    float* out = (float*)d_out;

    hipLaunchKernelGGL(k_zero, dim3(1), dim3(128), 0, stream, red);
    hipLaunchKernelGGL(k_prep, dim3(36), dim3(256), 0, stream,
                       mw1, mw2, ph_w1, z_w1, ph_w2, z_w2, g2g, g2b, mw3,
                       w1bf, w2bf, wh1, wp2, wz2, prm);
    hipLaunchKernelGGL(k_reduce_x, dim3(256), dim3(256), 0, stream, x, red);
    hipLaunchKernelGGL(k_heads, dim3(32, 32, 8), dim3(256), 0, stream,
                       x, red, ng, nb, wh1, ph_b1, z_b1, wp2, wz2, ph_b2, z_b2, phi, part);
    hipLaunchKernelGGL(k_red, dim3(24), dim3(256), 0, stream, part + PZ, red + 16);
    hipLaunchKernelGGL(k_fftA, dim3(3072), dim3(256), 0, stream, x, phi, U);
    hipLaunchKernelGGL(k_transpose, dim3(136, 24), dim3(256), 0, stream, U);
    hipLaunchKernelGGL(k_fftB, dim3(3072), dim3(256), 0, stream, U, red, fgain);
    hipLaunchKernelGGL(k_transpose, dim3(136, 24), dim3(256), 0, stream, U);
    hipLaunchKernelGGL(k_fftC, dim3(3072), dim3(256), 0, stream, U, Jb);
    hipLaunchKernelGGL(k_m1, dim3(32, 32, 8), dim3(256), 0, stream, x, Jb, w1bf, mb1, part);
    hipLaunchKernelGGL(k_red, dim3(16), dim3(256), 0, stream, part + PG1, red + 40);
    hipLaunchKernelGGL(k_m2, dim3(32, 32, 8), dim3(256), 0, stream,
                       x, Jb, w1bf, mb1, g1g, g1b, w2bf, mb2, red, part, y2);
    hipLaunchKernelGGL(k_red, dim3(16), dim3(256), 0, stream, part + PG2, red + 56);
    hipLaunchKernelGGL(k_m3, dim3(8192), dim3(256), 0, stream, y2, red, prm, mb3, dl, part);
    hipLaunchKernelGGL(k_red, dim3(24), dim3(256), 0, stream, part + PD, red + 72);
    hipLaunchKernelGGL(k_se, dim3(1), dim3(64), 0, stream, red, sw1, sb1, sw2, sb2, alpha);
    hipLaunchKernelGGL(k_out, dim3(6144), dim3(256), 0, stream, x, dl, red, out);
}

// Round 12
// 530.833 us; speedup vs baseline: 5.7035x; 1.1104x over previous
//
#include <hip/hip_runtime.h>
#include <hip/hip_bf16.h>
#include <math.h>

#define DINL __device__ __forceinline__

namespace {
constexpr int Bn = 8, Cn = 3, Hn = 512, Wn = 512;
constexpr int HW  = Hn * Wn;        // 262144
constexpr int CHW = Cn * HW;        // 786432
constexpr float GEPS = 1e-5f;
constexpr float PIf  = 3.14159265358979323846f;

// workspace layout (bytes) — U packed half2, J/phi/dl fp16
constexpr size_t OFF_RED = 0;                                   // 128 floats
constexpr size_t OFF_PHI = 512;                                 // Bn*CHW ushort
constexpr size_t OFF_U   = OFF_PHI + (size_t)Bn * CHW * 2;      // Bn*CHW uint (half2)
constexpr size_t OFF_J   = OFF_U   + (size_t)Bn * CHW * 4;      // Bn*CHW ushort
constexpr size_t OFF_D   = OFF_J   + (size_t)Bn * CHW * 2;      // Bn*CHW ushort
constexpr size_t OFF_Y2  = OFF_D   + (size_t)Bn * CHW * 2;      // 8*32*HW bf16 (channel-last)
constexpr size_t OFF_W1B = OFF_Y2  + (size_t)Bn * 32 * HW * 2;  // 3072 bf16
constexpr size_t OFF_W2B = OFF_W1B + 3072 * 2;                  // 9216 bf16
constexpr size_t OFF_WH1 = OFF_W2B + 9216 * 2;                  // 4608 bf16
constexpr size_t OFF_WP2 = OFF_WH1 + 4608 * 2;                  // 4608 bf16
constexpr size_t OFF_WZ2 = OFF_WP2 + 4608 * 2;                  // 4608 bf16
constexpr size_t OFF_PRM = OFF_WZ2 + 4608 * 2;                  // 160 f32
constexpr size_t OFF_PART= OFF_PRM + 160 * 4;                   // 81920 f32 partials
// part float sub-offsets (in floats)
constexpr int PZ = 0;          // 24 groups (b*3+c) x 1024
constexpr int PG1 = 24576;     // 16 groups (b:sum, 8+b:ss) x 1024
constexpr int PG2 = 40960;     // 16 groups x 1024
constexpr int PD  = 57344;     // 24 groups (b*3+c) x 1024
}

typedef __bf16 bfx8 __attribute__((ext_vector_type(8)));
typedef float  fx4  __attribute__((ext_vector_type(4)));

DINL float frcp(float a) { return __builtin_amdgcn_rcpf(a); }   // v_rcp_f32, 1 ULP
DINL float sigm(float a) { return frcp(1.f + __expf(-a)); }
DINL float siluf(float a) { return a * frcp(1.f + __expf(-a)); }
DINL float ftanh(float a) { return 1.f - 2.f * frcp(1.f + __expf(2.f * a)); }
DINL unsigned short f2bf(float f) {           // RNE float->bf16 bits
    unsigned u = __float_as_uint(f);
    return (unsigned short)((u + 0x7FFFu + ((u >> 16) & 1u)) >> 16);
}
DINL float bf2f(unsigned short h) {
    return __uint_as_float(((unsigned)h) << 16);
}
DINL unsigned pk2(float a, float b) {         // RNE pack (for global y2)
    return (unsigned)f2bf(a) | ((unsigned)f2bf(b) << 16);
}
// truncating bf16 (LDS-internal MFMA operands only; 1 inst each)
DINL unsigned short t1(float a) { return (unsigned short)(__float_as_uint(a) >> 16); }
DINL unsigned t2(float a, float b) {
    return (__float_as_uint(a) >> 16) | (__float_as_uint(b) & 0xFFFF0000u);
}
// fp16 helpers
DINL unsigned pkh(float a, float b) {
    auto h = __builtin_amdgcn_cvt_pkrtz(a, b);   // __fp16 ext_vector(2)
    unsigned u; __builtin_memcpy(&u, &h, 4); return u;
}
DINL float2 uph(unsigned u) {
    _Float16 h[2]; __builtin_memcpy(h, &u, 4);
    return make_float2((float)h[0], (float)h[1]);
}
DINL unsigned short f2h(float a) {
    _Float16 h = (_Float16)a; unsigned short s; __builtin_memcpy(&s, &h, 2); return s;
}
DINL float h2f(unsigned short s) {
    _Float16 h; __builtin_memcpy(&h, &s, 2); return (float)h;
}

DINL float blockReduceSum(float v) {   // blockDim.x == 256
    __shared__ float sm[4];
    int lane = threadIdx.x & 63, wid = threadIdx.x >> 6;
    #pragma unroll
    for (int o = 32; o > 0; o >>= 1) v += __shfl_down(v, o, 64);
    __syncthreads();
    if (lane == 0) sm[wid] = v;
    __syncthreads();
    if (wid == 0) {
        float r = (lane < 4) ? sm[lane] : 0.f;
        r += __shfl_down(r, 2, 64);
        r += __shfl_down(r, 1, 64);
        return r;                       // valid on thread 0
    }
    return 0.f;
}

__global__ void k_zero(float* __restrict__ red) { red[threadIdx.x] = 0.f; }

__global__ __launch_bounds__(256) void k_red(const float* __restrict__ src,
                                             float* __restrict__ dst)
{
    const float4* s4 = (const float4*)(src + (size_t)blockIdx.x * 1024);
    float4 q = s4[threadIdx.x];
    float r = blockReduceSum(q.x + q.y + q.z + q.w);
    if (threadIdx.x == 0) dst[blockIdx.x] = r;
}

// weight repack (all bf16 fragment-order, RNE)
__global__ __launch_bounds__(256) void k_prep(
    const float* __restrict__ w1, const float* __restrict__ w2,
    const float* __restrict__ phw1, const float* __restrict__ zw1,
    const float* __restrict__ phw2, const float* __restrict__ zw2,
    const float* __restrict__ g2g, const float* __restrict__ g2b,
    const float* __restrict__ w3,
    unsigned short* __restrict__ w1bf, unsigned short* __restrict__ w2bf,
    unsigned short* __restrict__ wh1, unsigned short* __restrict__ wp2,
    unsigned short* __restrict__ wz2, float* __restrict__ prm)
{
    int i = blockIdx.x * 256 + threadIdx.x;     // 0..9215
    if (i < 3072) {
        int o = i / 96, k = i - o * 96;
        int ky = k >> 5, r = k & 31, kx = r >> 3, c = r & 7;
        float v = (kx < 3 && c < 5) ? w1[o * 45 + c * 9 + ky * 3 + kx] : 0.f;
        w1bf[i] = f2bf(v);
    }
    if (i < 9216) {
        int tap = i >> 10, rr = i & 1023, o = rr >> 5, ci = rr & 31;
        w2bf[i] = f2bf(w2[o * 288 + ci * 9 + tap]);
    }
    if (i < 4608) {
        int o = i / 96, k = i - o * 96;
        int ky = k >> 5, r = k & 31, kx = r >> 3, c = r & 7;
        float v = 0.f;
        if (kx < 3 && c < 3)
            v = (o < 16) ? phw1[o * 27 + c * 9 + ky * 3 + kx]
                         : zw1[(o - 16) * 27 + c * 9 + ky * 3 + kx];
        wh1[i] = f2bf(v);
    }
    if (i < 4608) {
        int tap = i / 512, rr = i - tap * 512, n = rr >> 5, k = rr & 31;
        float vp = (n < 3 && k < 16) ? phw2[n * 144 + k * 9 + tap] : 0.f;
        float vz = (n < 3) ? zw2[n * 288 + k * 9 + tap] : 0.f;
        wp2[i] = f2bf(vp);
        wz2[i] = f2bf(vz);
    }
    if (i < 160) {
        if (i < 32) {
            int ch = (i & 1) * 16 + (i >> 1);
            prm[i] = g2g[ch];
        } else if (i < 64) {
            int j = i - 32, ch = (j & 1) * 16 + (j >> 1);
            prm[i] = g2b[ch];
        } else {
            int j = (i - 64) & 31, c = (i - 64) >> 5;
            int ch = (j & 1) * 16 + (j >> 1);
            prm[i] = w3[c * 32 + ch];
        }
    }
}

__global__ __launch_bounds__(256) void k_reduce_x(const float* __restrict__ x,
                                                  float* __restrict__ red) {
    int b = blockIdx.x >> 5, blk = blockIdx.x & 31;
    const float4* xv = (const float4*)(x + (size_t)b * CHW + (size_t)blk * (CHW / 32));
    float s = 0.f, ss = 0.f;
    for (int i = threadIdx.x; i < (CHW / 32) / 4; i += 256) {
        float4 v = xv[i];
        s  += v.x + v.y + v.z + v.w;
        ss += v.x * v.x + v.y * v.y + v.z * v.z + v.w * v.w;
    }
    float rs = blockReduceSum(s);
    float rss = blockReduceSum(ss);
    if (threadIdx.x == 0) { atomicAdd(&red[b], rs); atomicAdd(&red[8 + b], rss); }
}

// ---------------- fused heads (MFMA): xn -> [ph16 | z32] hidden -> phi + z partials ----------------
__global__ __launch_bounds__(256) void k_heads(
    const float* __restrict__ x, const float* __restrict__ red,
    const float* __restrict__ ng, const float* __restrict__ nb,
    const unsigned short* __restrict__ wh1,
    const float* __restrict__ phb1, const float* __restrict__ zb1,
    const unsigned short* __restrict__ wp2, const unsigned short* __restrict__ wz2,
    const float* __restrict__ phb2, const float* __restrict__ zb2,
    unsigned short* __restrict__ phi, float* __restrict__ part)
{
    const int tx0 = blockIdx.x * 16, ty0 = blockIdx.y * 16, b = blockIdx.z;
    const int local = blockIdx.y * 32 + blockIdx.x;
    const bool edge = (blockIdx.x == 0) || (blockIdx.x == 31) ||
                      (blockIdx.y == 0) || (blockIdx.y == 31);
    __shared__ unsigned short mt8[20 * 21 * 8];
    __shared__ unsigned short ht8[324 * 48];      // reused as phs/zs in epilogue
    const int t = threadIdx.x;
    const float mu = red[b] * (1.f / CHW);
    const float rsv = rsqrtf(red[8 + b] * (1.f / CHW) - mu * mu + GEPS);
    float sc[3], sh[3];
    #pragma unroll
    for (int c = 0; c < 3; ++c) { sc[c] = rsv * ng[c]; sh[c] = nb[c] - mu * rsv * ng[c]; }
    if (edge) {
        for (int e = t; e < 20 * 21; e += 256) {
            int yy = e / 21, xx = e - yy * 21;
            int gy = ty0 - 2 + yy, gx = tx0 - 2 + xx;
            float v0 = 0, v1 = 0, v2 = 0;
            if (xx < 20 && (unsigned)gy < (unsigned)Hn && (unsigned)gx < (unsigned)Wn) {
                size_t p = (size_t)b * CHW + (size_t)gy * Wn + gx;
                v0 = x[p] * sc[0] + sh[0];
                v1 = x[p + HW] * sc[1] + sh[1];
                v2 = x[p + 2 * HW] * sc[2] + sh[2];
            }
            *(uint4*)(mt8 + e * 8) = make_uint4(t2(v0, v1), (unsigned)t1(v2), 0u, 0u);
        }
    } else {
        for (int e = t; e < 20 * 21; e += 256) {
            int yy = e / 21, xx = e - yy * 21;
            float v0 = 0, v1 = 0, v2 = 0;
            if (xx < 20) {
                size_t p = (size_t)b * CHW + (size_t)(ty0 - 2 + yy) * Wn + (tx0 - 2 + xx);
                v0 = x[p] * sc[0] + sh[0];
                v1 = x[p + HW] * sc[1] + sh[1];
                v2 = x[p + 2 * HW] * sc[2] + sh[2];
            }
            *(uint4*)(mt8 + e * 8) = make_uint4(t2(v0, v1), (unsigned)t1(v2), 0u, 0u);
        }
    }
    const int wv = t >> 6, lane = t & 63, ln = lane & 15, q = lane >> 4;
    bfx8 Bf[3][3];
    #pragma unroll
    for (int ks = 0; ks < 3; ++ks)
        #pragma unroll
        for (int nt = 0; nt < 3; ++nt)
            Bf[ks][nt] = *(const bfx8*)(wh1 + (nt * 16 + ln) * 96 + ks * 32 + q * 8);
    const float bb0 = phb1[ln], bb1 = zb1[ln], bb2 = zb1[16 + ln];
    __syncthreads();
    for (int mt = wv; mt < 21; mt += 4) {
        int p = mt * 16 + ln; if (p > 323) p = 323;
        const int hy = p / 18, hx = p - hy * 18;
        fx4 a0 = {0,0,0,0}, a1 = {0,0,0,0}, a2 = {0,0,0,0};
        #pragma unroll
        for (int ks = 0; ks < 3; ++ks) {
            bfx8 A = *(const bfx8*)(mt8 + ((hy + ks) * 21 + hx + q) * 8);
            a0 = __builtin_amdgcn_mfma_f32_16x16x32_bf16(A, Bf[ks][0], a0, 0, 0, 0);
            a1 = __builtin_amdgcn_mfma_f32_16x16x32_bf16(A, Bf[ks][1], a1, 0, 0, 0);
            a2 = __builtin_amdgcn_mfma_f32_16x16x32_bf16(A, Bf[ks][2], a2, 0, 0, 0);
        }
        const int prb = mt * 16 + q * 4;
        if (edge) {
            #pragma unroll
            for (int r = 0; r < 4; ++r) {
                const int pr = prb + r;
                if (pr < 324) {
                    const int py = pr / 18, px = pr - py * 18;
                    const int gy = ty0 - 1 + py, gx = tx0 - 1 + px;
                    const bool inimg = (unsigned)gy < (unsigned)Hn && (unsigned)gx < (unsigned)Wn;
                    unsigned short* hp = ht8 + pr * 48;
                    hp[ln]      = inimg ? t1(siluf(a0[r] + bb0)) : (unsigned short)0;
                    hp[16 + ln] = inimg ? t1(siluf(a1[r] + bb1)) : (unsigned short)0;
                    hp[32 + ln] = inimg ? t1(siluf(a2[r] + bb2)) : (unsigned short)0;
                }
            }
        } else {
            #pragma unroll
            for (int r = 0; r < 4; ++r) {
                const int pr = prb + r;
                if (pr < 324) {
                    unsigned short* hp = ht8 + pr * 48;
                    hp[ln]      = t1(siluf(a0[r] + bb0));
                    hp[16 + ln] = t1(siluf(a1[r] + bb1));
                    hp[32 + ln] = t1(siluf(a2[r] + bb2));
                }
            }
        }
    }
    __syncthreads();
    fx4 accp[4], accz[4];
    #pragma unroll
    for (int i = 0; i < 4; ++i) { accp[i] = fx4{0,0,0,0}; accz[i] = fx4{0,0,0,0}; }
    #pragma unroll
    for (int tap = 0; tap < 9; ++tap) {
        const int ky = tap / 3, kx = tap - ky * 3;
        bfx8 Bp = *(const bfx8*)(wp2 + tap * 512 + ln * 32 + q * 8);
        bfx8 Bz = *(const bfx8*)(wz2 + tap * 512 + ln * 32 + q * 8);
        #pragma unroll
        for (int i = 0; i < 4; ++i) {
            const int oy = wv * 4 + i;
            const unsigned short* ap = ht8 + ((oy + ky) * 18 + ln + kx) * 48;
            bfx8 Ap = *(const bfx8*)(ap + q * 8);
            bfx8 Az = *(const bfx8*)(ap + 16 + q * 8);
            accp[i] = __builtin_amdgcn_mfma_f32_16x16x32_bf16(Ap, Bp, accp[i], 0, 0, 0);
            accz[i] = __builtin_amdgcn_mfma_f32_16x16x32_bf16(Az, Bz, accz[i], 0, 0, 0);
        }
    }
    // epilogue via LDS: full-lane tanh/sigm, coalesced fp16 stores
    __syncthreads();                       // ht8 reads done; reuse as float staging
    float* phs = (float*)ht8;              // [256][4]
    float* zs  = phs + 1024;               // [256][4]
    if (ln < 3) {
        #pragma unroll
        for (int i = 0; i < 4; ++i)
            #pragma unroll
            for (int r = 0; r < 4; ++r) {
                int pl = (wv * 4 + i) * 16 + q * 4 + r;
                phs[pl * 4 + ln] = accp[i][r];
                zs [pl * 4 + ln] = accz[i][r];
            }
    }
    __syncthreads();
    float4 pv = ((const float4*)phs)[t];
    float4 zv = ((const float4*)zs)[t];
    const int gy = ty0 + (t >> 4), gx = tx0 + (t & 15);
    size_t pp = (size_t)b * CHW + (size_t)gy * Wn + gx;
    phi[pp]          = f2h(ftanh(pv.x + phb2[0]) * PIf);
    phi[pp + HW]     = f2h(ftanh(pv.y + phb2[1]) * PIf);
    phi[pp + 2 * HW] = f2h(ftanh(pv.z + phb2[2]) * PIf);
    float z0 = sigm(zv.x + zb2[0]) * 0.3f;
    float z1 = sigm(zv.y + zb2[1]) * 0.3f;
    float z2 = sigm(zv.z + zb2[2]) * 0.3f;
    float r0 = blockReduceSum(z0);
    float r1 = blockReduceSum(z1);
    float r2 = blockReduceSum(z2);
    if (t == 0) {
        part[PZ + (size_t)(b * 3 + 0) * 1024 + local] = r0;
        part[PZ + (size_t)(b * 3 + 1) * 1024 + local] = r1;
        part[PZ + (size_t)(b * 3 + 2) * 1024 + local] = r2;
    }
}

// ---------------- FFT: 512-pt Stockham radix-4 (x4) + radix-2, wave-per-line ----------------
template<bool INV>
DINL float2* fft512_wave4(float2* a, float2* b, const float2* tw, int l)
{
    float2* src = a; float2* dst = b;
    int s = 1;
    #pragma unroll
    for (int st = 0; st < 4; ++st) {
        #pragma unroll
        for (int h = 0; h < 2; ++h) {
            const int i = l + h * 64;          // butterfly index in [0,128)
            const int q = i & (s - 1);
            const int sm = i - q;              // s*m
            float2 A = src[i], B = src[i + 128], C = src[i + 256], D = src[i + 384];
            float t0x = A.x + C.x, t0y = A.y + C.y;
            float t1x = A.x - C.x, t1y = A.y - C.y;
            float t2x = B.x + D.x, t2y = B.y + D.y;
            float t3x = B.x - D.x, t3y = B.y - D.y;
            float i3x = INV ? -t3y : t3y;
            float i3y = INV ? t3x : -t3x;
            float u0x = t0x + t2x, u0y = t0y + t2y;
            float u2x = t0x - t2x, u2y = t0y - t2y;
            float u1x = t1x + i3x, u1y = t1y + i3y;
            float u3x = t1x - i3x, u3y = t1y - i3y;
            float2 w1 = tw[sm], w2 = tw[2 * sm], w3 = tw[3 * sm];
            float w1y = INV ? -w1.y : w1.y;
            float w2y = INV ? -w2.y : w2.y;
            float w3y = INV ? -w3.y : w3.y;
            const int base = q + 4 * sm;
            dst[base]         = make_float2(u0x, u0y);
            dst[base + s]     = make_float2(u1x * w1.x - u1y * w1y, u1x * w1y + u1y * w1.x);
            dst[base + 2 * s] = make_float2(u2x * w2.x - u2y * w2y, u2x * w2y + u2y * w2.x);
            dst[base + 3 * s] = make_float2(u3x * w3.x - u3y * w3y, u3x * w3y + u3y * w3.x);
        }
        float2* tmp = src; src = dst; dst = tmp;
        s <<= 2;
        asm volatile("" ::: "memory");   // wave-synchronous LDS: fence compiler only
    }
    // final radix-2, s=256 (m=0 -> no twiddle)
    #pragma unroll
    for (int h = 0; h < 4; ++h) {
        const int j = l + h * 64;
        float2 u = src[j], v = src[j + 256];
        dst[j]       = make_float2(u.x + v.x, u.y + v.y);
        dst[j + 256] = make_float2(u.x - v.x, u.y - v.y);
    }
    float2* tmp = src; src = dst; dst = tmp;
    asm volatile("" ::: "memory");
    return src;
}

__global__ __launch_bounds__(256) void k_fftA(
    const float* __restrict__ x, const unsigned short* __restrict__ phi,
    unsigned* __restrict__ U)
{
    __shared__ float2 buf[4][2][512];
    __shared__ float2 tw[512];
    const int t = threadIdx.x, wv = t >> 6, l = t & 63;
    #pragma unroll
    for (int i = t; i < 512; i += 256) {
        float s, c; __sincosf(-2.f * PIf * (float)i * (1.f / 512.f), &s, &c);
        tw[i] = make_float2(c, s);
    }
    __syncthreads();
    const size_t line = (size_t)blockIdx.x * 4 + wv;
    const float* xr = x + line * 512;
    const unsigned short* pr = phi + line * 512;
    float2* A = buf[wv][0];
    float2* B = buf[wv][1];
    #pragma unroll
    for (int i = l; i < 512; i += 64) {
        float s, c; __sincosf(h2f(pr[i]), &s, &c);
        float xv = xr[i];
        A[i] = make_float2(xv * c, xv * s);
    }
    asm volatile("" ::: "memory");
    float2* res = fft512_wave4<false>(A, B, tw, l);
    unsigned* Ur = U + line * 512;
    #pragma unroll
    for (int i = l; i < 512; i += 64) Ur[i] = pkh(res[i].x, res[i].y);
}

__global__ __launch_bounds__(256) void k_transpose(unsigned* __restrict__ U)
{
    const int img = blockIdx.y;
    int rem = blockIdx.x, ti = 0;
    while (rem >= 16 - ti) { rem -= 16 - ti; ++ti; }
    const int tj = ti + rem;
    unsigned* Ub = U + (size_t)img * HW;
    __shared__ unsigned ta[32][33];
    __shared__ unsigned tb[32][33];
    const int t = threadIdx.x;
    const int cc = t & 31, r0 = t >> 5;
    const int ar = ti * 32, ac = tj * 32;
    #pragma unroll
    for (int k = 0; k < 4; ++k) {
        int r = r0 + k * 8;
        ta[r][cc] = Ub[(size_t)(ar + r) * 512 + ac + cc];
    }
    if (ti != tj) {
        #pragma unroll
        for (int k = 0; k < 4; ++k) {
            int r = r0 + k * 8;
            tb[r][cc] = Ub[(size_t)(ac + r) * 512 + ar + cc];
        }
    }
    __syncthreads();
    #pragma unroll
    for (int k = 0; k < 4; ++k) {
        int r = r0 + k * 8;
        Ub[(size_t)(ac + r) * 512 + ar + cc] = ta[cc][r];
    }
    if (ti != tj) {
        #pragma unroll
        for (int k = 0; k < 4; ++k) {
            int r = r0 + k * 8;
            Ub[(size_t)(ar + r) * 512 + ac + cc] = tb[cc][r];
        }
    }
}

__global__ __launch_bounds__(256) void k_fftB(
    unsigned* __restrict__ U, const float* __restrict__ red, const float* __restrict__ fgain)
{
    __shared__ float2 buf[4][2][512];
    __shared__ float2 tw[512];
    const int t = threadIdx.x, wv = t >> 6, l = t & 63;
    #pragma unroll
    for (int i = t; i < 512; i += 256) {
        float s, c; __sincosf(-2.f * PIf * (float)i * (1.f / 512.f), &s, &c);
        tw[i] = make_float2(c, s);
    }
    __syncthreads();
    const int line = blockIdx.x * 4 + wv;          // (b*3+c)*512 + fw
    const int bc = line >> 9;
    const int fw = line & 511;
    const int c = bc % 3;
    unsigned* Ur = U + (size_t)line * 512;
    float2* A = buf[wv][0];
    float2* B = buf[wv][1];
    #pragma unroll
    for (int i = l; i < 512; i += 64) A[i] = uph(Ur[i]);
    asm volatile("" ::: "memory");
    float2* res = fft512_wave4<false>(A, B, tw, l);
    const float zm   = red[16 + bc] * (1.f / HW);
    const float gain = 1.f + fgain[c];
    const float lam  = (c == 0) ? 0.65f : (c == 1) ? 0.53f : 0.47f;
    const float il2  = 1.f / (lam * lam);
    const float fwv  = (float)(fw < 256 ? fw : fw - 512) * (1.f / 512.f);
    const float f2w  = fwv * fwv;
    #pragma unroll
    for (int i = l; i < 512; i += 64) {
        float fh = (float)(i < 256 ? i : i - 512) * (1.f / 512.f);
        float kz = 2.f * PIf * sqrtf(fmaxf(il2 - f2w - fh * fh, 0.f));
        float sn, cs; __sincosf(kz * zm, &sn, &cs);
        float2 v = res[i];
        res[i] = make_float2(gain * (v.x * cs - v.y * sn), gain * (v.x * sn + v.y * cs));
    }
    asm volatile("" ::: "memory");
    float2* other = (res == A) ? B : A;
    float2* res2 = fft512_wave4<true>(res, other, tw, l);
    #pragma unroll
    for (int i = l; i < 512; i += 64) {
        float2 v = res2[i];
        Ur[i] = pkh(v.x * (1.f / 512.f), v.y * (1.f / 512.f));
    }
}

__global__ __launch_bounds__(256) void k_fftC(
    const unsigned* __restrict__ U, unsigned short* __restrict__ J)
{
    __shared__ float2 buf[4][2][512];
    __shared__ float2 tw[512];
    const int t = threadIdx.x, wv = t >> 6, l = t & 63;
    #pragma unroll
    for (int i = t; i < 512; i += 256) {
        float s, c; __sincosf(-2.f * PIf * (float)i * (1.f / 512.f), &s, &c);
        tw[i] = make_float2(c, s);
    }
    __syncthreads();
    const size_t line = (size_t)blockIdx.x * 4 + wv;
    const unsigned* Ur = U + line * 512;
    float2* A = buf[wv][0];
    float2* B = buf[wv][1];
    #pragma unroll
    for (int i = l; i < 512; i += 64) A[i] = uph(Ur[i]);
    asm volatile("" ::: "memory");
    float2* res = fft512_wave4<true>(A, B, tw, l);
    unsigned short* Jr = J + line * 512;
    #pragma unroll
    for (int i = l; i < 512; i += 64) {
        float2 v = res[i];
        float re = v.x * (1.f / 512.f), im = v.y * (1.f / 512.f);
        Jr[i] = f2h(sqrtf(fmaxf(re * re + im * im, 1e-12f)));
    }
}

// ---------------- mix path (MFMA) ----------------
__global__ __launch_bounds__(256) void k_m1(
    const float* __restrict__ x, const unsigned short* __restrict__ Jb,
    const unsigned short* __restrict__ w1bf, const float* __restrict__ b1,
    float* __restrict__ part)
{
    const int tx0 = blockIdx.x * 16, ty0 = blockIdx.y * 16, b = blockIdx.z;
    const int local = blockIdx.y * 32 + blockIdx.x;
    const bool edge = (blockIdx.x == 0) || (blockIdx.x == 31) ||
                      (blockIdx.y == 0) || (blockIdx.y == 31);
    __shared__ unsigned short mt8[18 * 19 * 8];
    const int t = threadIdx.x;
    for (int e = t; e < 18 * 19; e += 256) {
        int yy = e / 19, xx = e - yy * 19;
        int gy = ty0 - 1 + yy, gx = tx0 - 1 + xx;
        float v0 = 0, v1 = 0, v2 = 0, jl = 0, d5 = 0;
        bool ok = edge ? (xx < 18 && (unsigned)gy < (unsigned)Hn && (unsigned)gx < (unsigned)Wn)
                       : (xx < 18);
        if (ok) {
            size_t p = (size_t)b * CHW + (size_t)gy * Wn + gx;
            v0 = x[p]; v1 = x[p + HW]; v2 = x[p + 2 * HW];
            float j0 = h2f(Jb[p]), j1 = h2f(Jb[p + HW]), j2 = h2f(Jb[p + 2 * HW]);
            float xl = 0.299f * v0 + 0.587f * v1 + 0.114f * v2;
            jl = 0.299f * j0 + 0.587f * j1 + 0.114f * j2;
            d5 = jl - xl;
        }
        *(uint4*)(mt8 + e * 8) = make_uint4(t2(v0, v1), t2(v2, jl), (unsigned)t1(d5), 0u);
    }
    __syncthreads();
    const int wv = t >> 6, lane = t & 63, ln = lane & 15, q = lane >> 4;
    bfx8 Bf[3][2];
    #pragma unroll
    for (int ks = 0; ks < 3; ++ks)
        #pragma unroll
        for (int nt = 0; nt < 2; ++nt)
            Bf[ks][nt] = *(const bfx8*)(w1bf + (nt * 16 + ln) * 96 + ks * 32 + q * 8);
    const float b1v0 = b1[ln], b1v1 = b1[16 + ln];
    float s = 0.f, ss = 0.f;
    #pragma unroll
    for (int i = 0; i < 4; ++i) {
        const int oy = wv * 4 + i;
        fx4 a0 = {0.f, 0.f, 0.f, 0.f}, a1 = {0.f, 0.f, 0.f, 0.f};
        #pragma unroll
        for (int ks = 0; ks < 3; ++ks) {
            bfx8 A = *(const bfx8*)(mt8 + ((oy + ks) * 19 + ln + q) * 8);
            a0 = __builtin_amdgcn_mfma_f32_16x16x32_bf16(A, Bf[ks][0], a0, 0, 0, 0);
            a1 = __builtin_amdgcn_mfma_f32_16x16x32_bf16(A, Bf[ks][1], a1, 0, 0, 0);
        }
        #pragma unroll
        for (int r = 0; r < 4; ++r) {
            float u0 = a0[r] + b1v0, u1 = a1[r] + b1v1;
            s += u0 + u1; ss += u0 * u0 + u1 * u1;
        }
    }
    float rs = blockReduceSum(s);
    float rss = blockReduceSum(ss);
    if (t == 0) {
        part[PG1 + (size_t)b * 1024 + local] = rs;
        part[PG1 + (size_t)(8 + b) * 1024 + local] = rss;
    }
}

// conv1 -> gn1 -> silu -> conv2 (MFMA); y2 channel-last + gn2 partials
__global__ __launch_bounds__(256) void k_m2(
    const float* __restrict__ x, const unsigned short* __restrict__ Jb,
    const unsigned short* __restrict__ w1bf, const float* __restrict__ b1,
    const float* __restrict__ g1g, const float* __restrict__ g1b,
    const unsigned short* __restrict__ w2bf, const float* __restrict__ b2,
    const float* __restrict__ red, float* __restrict__ part,
    unsigned short* __restrict__ y2)
{
    const int tx0 = blockIdx.x * 16, ty0 = blockIdx.y * 16, b = blockIdx.z;
    const int local = blockIdx.y * 32 + blockIdx.x;
    const bool edge = (blockIdx.x == 0) || (blockIdx.x == 31) ||
                      (blockIdx.y == 0) || (blockIdx.y == 31);
    __shared__ unsigned short mt8[20 * 21 * 8];
    __shared__ unsigned short dt2[324 * 40];
    const int t = threadIdx.x;
    const float mu1 = red[40 + b] * (1.f / (32.f * HW));
    const float rs1 = rsqrtf(red[48 + b] * (1.f / (32.f * HW)) - mu1 * mu1 + GEPS);
    for (int e = t; e < 20 * 21; e += 256) {
        int yy = e / 21, xx = e - yy * 21;
        int gy = ty0 - 2 + yy, gx = tx0 - 2 + xx;
        float v0 = 0, v1 = 0, v2 = 0, jl = 0, d5 = 0;
        bool ok = edge ? (xx < 20 && (unsigned)gy < (unsigned)Hn && (unsigned)gx < (unsigned)Wn)
                       : (xx < 20);
        if (ok) {
            size_t p = (size_t)b * CHW + (size_t)gy * Wn + gx;
            v0 = x[p]; v1 = x[p + HW]; v2 = x[p + 2 * HW];
            float j0 = h2f(Jb[p]), j1 = h2f(Jb[p + HW]), j2 = h2f(Jb[p + 2 * HW]);
            float xl = 0.299f * v0 + 0.587f * v1 + 0.114f * v2;
            jl = 0.299f * j0 + 0.587f * j1 + 0.114f * j2;
            d5 = jl - xl;
        }
        *(uint4*)(mt8 + e * 8) = make_uint4(t2(v0, v1), t2(v2, jl), (unsigned)t1(d5), 0u);
    }
    const int wv = t >> 6, lane = t & 63, ln = lane & 15, q = lane >> 4;
    const float sc0 = rs1 * g1g[ln],       sc1 = rs1 * g1g[16 + ln];
    const float of0 = (b1[ln] - mu1) * sc0 + g1b[ln];
    const float of1 = (b1[16 + ln] - mu1) * sc1 + g1b[16 + ln];
    bfx8 Bf[3][2];
    #pragma unroll
    for (int ks = 0; ks < 3; ++ks)
        #pragma unroll
        for (int nt = 0; nt < 2; ++nt)
            Bf[ks][nt] = *(const bfx8*)(w1bf + (nt * 16 + ln) * 96 + ks * 32 + q * 8);
    __syncthreads();
    for (int mt = wv; mt < 21; mt += 4) {
        int p = mt * 16 + ln; if (p > 323) p = 323;
        const int hy = p / 18, hx = p - hy * 18;
        fx4 a0 = {0.f, 0.f, 0.f, 0.f}, a1 = {0.f, 0.f, 0.f, 0.f};
        #pragma unroll
        for (int ks = 0; ks < 3; ++ks) {
            bfx8 A = *(const bfx8*)(mt8 + ((hy + ks) * 21 + hx + q) * 8);
            a0 = __builtin_amdgcn_mfma_f32_16x16x32_bf16(A, Bf[ks][0], a0, 0, 0, 0);
            a1 = __builtin_amdgcn_mfma_f32_16x16x32_bf16(A, Bf[ks][1], a1, 0, 0, 0);
        }
        const int prb = mt * 16 + q * 4;
        if (edge) {
            #pragma unroll
            for (int r = 0; r < 4; ++r) {
                const int pr = prb + r;
                if (pr < 324) {
                    const int py = pr / 18, px = pr - py * 18;
                    const int gy = ty0 - 1 + py, gx = tx0 - 1 + px;
                    const bool inimg = (unsigned)gy < (unsigned)Hn && (unsigned)gx < (unsigned)Wn;
                    dt2[pr * 40 + ln]      = inimg ? t1(siluf(a0[r] * sc0 + of0)) : (unsigned short)0;
                    dt2[pr * 40 + 16 + ln] = inimg ? t1(siluf(a1[r] * sc1 + of1)) : (unsigned short)0;
                }
            }
        } else {
            #pragma unroll
            for (int r = 0; r < 4; ++r) {
                const int pr = prb + r;
                if (pr < 324) {
                    dt2[pr * 40 + ln]      = t1(siluf(a0[r] * sc0 + of0));
                    dt2[pr * 40 + 16 + ln] = t1(siluf(a1[r] * sc1 + of1));
                }
            }
        }
    }
    __syncthreads();
    fx4 c2[4][2];
    #pragma unroll
    for (int i = 0; i < 4; ++i)
        #pragma unroll
        for (int nt = 0; nt < 2; ++nt)
            c2[i][nt] = fx4{0.f, 0.f, 0.f, 0.f};
    #pragma unroll
    for (int tap = 0; tap < 9; ++tap) {
        const int ky = tap / 3, kx = tap - ky * 3;
        bfx8 B0 = *(const bfx8*)(w2bf + tap * 1024 + ln * 32 + q * 8);
        bfx8 B1 = *(const bfx8*)(w2bf + tap * 1024 + (16 + ln) * 32 + q * 8);
        #pragma unroll
        for (int i = 0; i < 4; ++i) {
            const int oy = wv * 4 + i;
            bfx8 A = *(const bfx8*)(dt2 + ((oy + ky) * 18 + ln + kx) * 40 + q * 8);
            c2[i][0] = __builtin_amdgcn_mfma_f32_16x16x32_bf16(A, B0, c2[i][0], 0, 0, 0);
            c2[i][1] = __builtin_amdgcn_mfma_f32_16x16x32_bf16(A, B1, c2[i][1], 0, 0, 0);
        }
    }
    float s = 0.f, ss = 0.f;
    const float b2v0 = b2[ln], b2v1 = b2[16 + ln];
    #pragma unroll
    for (int i = 0; i < 4; ++i) {
        const int gy = ty0 + wv * 4 + i;
        #pragma unroll
        for (int r = 0; r < 4; ++r) {
            const int gx = tx0 + q * 4 + r;
            float a0 = c2[i][0][r] + b2v0;
            float a1 = c2[i][1][r] + b2v1;
            s += a0 + a1; ss += a0 * a0 + a1 * a1;
            unsigned pk = pk2(a0, a1);
            size_t off = ((size_t)b * HW + (size_t)gy * Wn + gx) * 32 + ln * 2;
            *(unsigned*)(y2 + off) = pk;
        }
    }
    float rsum = blockReduceSum(s);
    float rss = blockReduceSum(ss);
    if (t == 0) {
        part[PG2 + (size_t)b * 1024 + local] = rsum;
        part[PG2 + (size_t)(8 + b) * 1024 + local] = rss;
    }
}

// gn2 -> silu -> 1x1 conv; channel-last y2; dl fp16; dsum partials (no atomics)
__global__ __launch_bounds__(256) void k_m3(
    const unsigned short* __restrict__ y2, const float* __restrict__ red,
    const float* __restrict__ prm, const float* __restrict__ b3,
    unsigned short* __restrict__ dl, float* __restrict__ part)
{
    int idx = blockIdx.x * 256 + threadIdx.x;     // global pixel (b*HW+pix)
    int b = idx >> 18;
    int pix = idx & (HW - 1);
    const int local = blockIdx.x & 1023;
    float mu = red[56 + b] * (1.f / (32.f * HW));
    float rs = rsqrtf(red[64 + b] * (1.f / (32.f * HW)) - mu * mu + GEPS);
    const uint4* yp = (const uint4*)(y2 + (size_t)idx * 32);
    uint4 L[4];
    #pragma unroll
    for (int c = 0; c < 4; ++c) L[c] = yp[c];
    float a0 = b3[0], a1 = b3[1], a2 = b3[2];
    const unsigned* Lw = (const unsigned*)L;
    #pragma unroll
    for (int w = 0; w < 16; ++w) {     // 16 dwords = all 32 channels
        unsigned u = Lw[w];
        #pragma unroll
        for (int h = 0; h < 2; ++h) {
            int j = w * 2 + h;
            float v = bf2f((unsigned short)(h ? (u >> 16) : (u & 0xFFFFu)));
            float dn = (v - mu) * rs * prm[j] + prm[32 + j];
            float sv = siluf(dn);
            a0 += sv * prm[64 + j]; a1 += sv * prm[96 + j]; a2 += sv * prm[128 + j];
        }
    }
    size_t p = (size_t)b * CHW + pix;
    dl[p] = f2h(a0); dl[p + HW] = f2h(a1); dl[p + 2 * HW] = f2h(a2);
    float r0 = blockReduceSum(a0);
    float r1 = blockReduceSum(a1);
    float r2 = blockReduceSum(a2);
    if (threadIdx.x == 0) {
        part[PD + (size_t)(b * 3 + 0) * 1024 + local] = r0;
        part[PD + (size_t)(b * 3 + 1) * 1024 + local] = r1;
        part[PD + (size_t)(b * 3 + 2) * 1024 + local] = r2;
    }
}

__global__ void k_se(float* __restrict__ red,
    const float* __restrict__ w1, const float* __restrict__ b1,
    const float* __restrict__ w2, const float* __restrict__ b2,
    const float* __restrict__ alpha)
{
    int b = threadIdx.x;
    if (b < 8) {
        float p0 = red[72 + b * 3 + 0] * (1.f / HW);
        float p1 = red[72 + b * 3 + 1] * (1.f / HW);
        float p2 = red[72 + b * 3 + 2] * (1.f / HW);
        float h[4];
        #pragma unroll
        for (int j = 0; j < 4; ++j) {
            float a = b1[j] + p0 * w1[j * 3] + p1 * w1[j * 3 + 1] + p2 * w1[j * 3 + 2];
            h[j] = siluf(a);
        }
        float al = alpha[0];
        #pragma unroll
        for (int c = 0; c < 3; ++c) {
            float a = b2[c] + h[0] * w2[c * 4] + h[1] * w2[c * 4 + 1]
                            + h[2] * w2[c * 4 + 2] + h[3] * w2[c * 4 + 3];
            red[96 + b * 3 + c] = al * sigm(a);
        }
    }
}

__global__ __launch_bounds__(256) void k_out(
    const float* __restrict__ x, const unsigned short* __restrict__ dl,
    const float* __restrict__ red, float* __restrict__ out)
{
    int i = blockIdx.x * 256 + threadIdx.x;     // float4 index
    float aw = red[96 + (i >> 16)];
    float4 xv = ((const float4*)x)[i];
    uint2 dv2 = ((const uint2*)dl)[i];          // 4 fp16
    float2 d01 = uph(dv2.x);
    float2 d23 = uph(dv2.y);
    float4 o;
    o.x = xv.x + aw * d01.x; o.y = xv.y + aw * d01.y;
    o.z = xv.z + aw * d23.x; o.w = xv.w + aw * d23.y;
    ((float4*)out)[i] = o;
}

extern "C" void kernel_launch(void* const* d_in, const int* in_sizes, int n_in,
                              void* d_out, int out_size, void* d_ws, size_t ws_size,
                              hipStream_t stream)
{
    const float* x     = (const float*)d_in[0];
    const float* ng    = (const float*)d_in[1];
    const float* nb    = (const float*)d_in[2];
    const float* ph_w1 = (const float*)d_in[3];
    const float* ph_b1 = (const float*)d_in[4];
    const float* ph_w2 = (const float*)d_in[5];
    const float* ph_b2 = (const float*)d_in[6];
    const float* z_w1  = (const float*)d_in[7];
    const float* z_b1  = (const float*)d_in[8];
    const float* z_w2  = (const float*)d_in[9];
    const float* z_b2  = (const float*)d_in[10];
    const float* fgain = (const float*)d_in[11];
    const float* mw1   = (const float*)d_in[12];
    const float* mb1   = (const float*)d_in[13];
    const float* g1g   = (const float*)d_in[14];
    const float* g1b   = (const float*)d_in[15];
    const float* mw2   = (const float*)d_in[16];
    const float* mb2   = (const float*)d_in[17];
    const float* g2g   = (const float*)d_in[18];
    const float* g2b   = (const float*)d_in[19];
    const float* mw3   = (const float*)d_in[20];
    const float* mb3   = (const float*)d_in[21];
    const float* sw1   = (const float*)d_in[22];
    const float* sb1   = (const float*)d_in[23];
    const float* sw2   = (const float*)d_in[24];
    const float* sb2   = (const float*)d_in[25];
    const float* alpha = (const float*)d_in[26];

    char* ws = (char*)d_ws;
    float*  red = (float*)(ws + OFF_RED);
    unsigned short* phi = (unsigned short*)(ws + OFF_PHI);
    unsigned* U = (unsigned*)(ws + OFF_U);
    unsigned short* Jb = (unsigned short*)(ws + OFF_J);
    unsigned short* dl = (unsigned short*)(ws + OFF_D);
    unsigned short* y2   = (unsigned short*)(ws + OFF_Y2);
    unsigned short* w1bf = (unsigned short*)(ws + OFF_W1B);
    unsigned short* w2bf = (unsigned short*)(ws + OFF_W2B);
    unsigned short* wh1  = (unsigned short*)(ws + OFF_WH1);
    unsigned short* wp2  = (unsigned short*)(ws + OFF_WP2);
    unsigned short* wz2  = (unsigned short*)(ws + OFF_WZ2);
    float* prm  = (float*)(ws + OFF_PRM);
    float* part = (float*)(ws + OFF_PART);
    float* out = (float*)d_out;

    hipLaunchKernelGGL(k_zero, dim3(1), dim3(128), 0, stream, red);
    hipLaunchKernelGGL(k_prep, dim3(36), dim3(256), 0, stream,
                       mw1, mw2, ph_w1, z_w1, ph_w2, z_w2, g2g, g2b, mw3,
                       w1bf, w2bf, wh1, wp2, wz2, prm);
    hipLaunchKernelGGL(k_reduce_x, dim3(256), dim3(256), 0, stream, x, red);
    hipLaunchKernelGGL(k_heads, dim3(32, 32, 8), dim3(256), 0, stream,
                       x, red, ng, nb, wh1, ph_b1, z_b1, wp2, wz2, ph_b2, z_b2, phi, part);
    hipLaunchKernelGGL(k_red, dim3(24), dim3(256), 0, stream, part + PZ, red + 16);
    hipLaunchKernelGGL(k_fftA, dim3(3072), dim3(256), 0, stream, x, phi, U);
    hipLaunchKernelGGL(k_transpose, dim3(136, 24), dim3(256), 0, stream, U);
    hipLaunchKernelGGL(k_fftB, dim3(3072), dim3(256), 0, stream, U, red, fgain);
    hipLaunchKernelGGL(k_transpose, dim3(136, 24), dim3(256), 0, stream, U);
    hipLaunchKernelGGL(k_fftC, dim3(3072), dim3(256), 0, stream, U, Jb);
    hipLaunchKernelGGL(k_m1, dim3(32, 32, 8), dim3(256), 0, stream, x, Jb, w1bf, mb1, part);
    hipLaunchKernelGGL(k_red, dim3(16), dim3(256), 0, stream, part + PG1, red + 40);
    hipLaunchKernelGGL(k_m2, dim3(32, 32, 8), dim3(256), 0, stream,
                       x, Jb, w1bf, mb1, g1g, g1b, w2bf, mb2, red, part, y2);
    hipLaunchKernelGGL(k_red, dim3(16), dim3(256), 0, stream, part + PG2, red + 56);
    hipLaunchKernelGGL(k_m3, dim3(8192), dim3(256), 0, stream, y2, red, prm, mb3, dl, part);
    hipLaunchKernelGGL(k_red, dim3(24), dim3(256), 0, stream, part + PD, red + 72);
    hipLaunchKernelGGL(k_se, dim3(1), dim3(64), 0, stream, red, sw1, sb1, sw2, sb2, alpha);
    hipLaunchKernelGGL(k_out, dim3(6144), dim3(256), 0, stream, x, dl, red, out);
}

// Round 13
// 513.147 us; speedup vs baseline: 5.9001x; 1.0345x over previous
//
#include <hip/hip_runtime.h>
#include <hip/hip_bf16.h>
#include <math.h>

#define DINL __device__ __forceinline__

namespace {
constexpr int Bn = 8, Cn = 3, Hn = 512, Wn = 512;
constexpr int HW  = Hn * Wn;        // 262144
constexpr int CHW = Cn * HW;        // 786432
constexpr float GEPS = 1e-5f;
constexpr float PIf  = 3.14159265358979323846f;

// workspace layout (bytes) — U packed half2, J/phi/dl fp16, head conv2 weights fp8
constexpr size_t OFF_RED = 0;                                   // 128 floats
constexpr size_t OFF_PHI = 512;                                 // Bn*CHW ushort
constexpr size_t OFF_U   = OFF_PHI + (size_t)Bn * CHW * 2;      // Bn*CHW uint (half2)
constexpr size_t OFF_J   = OFF_U   + (size_t)Bn * CHW * 4;      // Bn*CHW ushort
constexpr size_t OFF_D   = OFF_J   + (size_t)Bn * CHW * 2;      // Bn*CHW ushort
constexpr size_t OFF_Y2  = OFF_D   + (size_t)Bn * CHW * 2;      // 8*32*HW bf16 (channel-last)
constexpr size_t OFF_W1B = OFF_Y2  + (size_t)Bn * 32 * HW * 2;  // 3072 bf16
constexpr size_t OFF_W2B = OFF_W1B + 3072 * 2;                  // 9216 bf16
constexpr size_t OFF_WH1 = OFF_W2B + 9216 * 2;                  // 4608 bf16
constexpr size_t OFF_WP2 = OFF_WH1 + 4608 * 2;                  // 4608 fp8 (9x16x32 ph conv2)
constexpr size_t OFF_WZ2 = OFF_WP2 + 4608;                      // 4608 fp8 (9x16x32 z conv2)
constexpr size_t OFF_PRM = OFF_WZ2 + 4608;                      // 160 f32
constexpr size_t OFF_PART= OFF_PRM + 160 * 4;                   // 81920 f32 partials
// part float sub-offsets (in floats)
constexpr int PZ = 0;          // 24 groups (b*3+c) x 1024
constexpr int PG1 = 24576;     // 16 groups (b:sum, 8+b:ss) x 1024
constexpr int PG2 = 40960;     // 16 groups x 1024
constexpr int PD  = 57344;     // 24 groups (b*3+c) x 1024
}

typedef __bf16 bfx8 __attribute__((ext_vector_type(8)));
typedef float  fx4  __attribute__((ext_vector_type(4)));

DINL float frcp(float a) { return __builtin_amdgcn_rcpf(a); }   // v_rcp_f32, 1 ULP
DINL float sigm(float a) { return frcp(1.f + __expf(-a)); }
DINL float siluf(float a) { return a * frcp(1.f + __expf(-a)); }
DINL float ftanh(float a) { return 1.f - 2.f * frcp(1.f + __expf(2.f * a)); }
DINL unsigned short f2bf(float f) {           // RNE float->bf16 bits
    unsigned u = __float_as_uint(f);
    return (unsigned short)((u + 0x7FFFu + ((u >> 16) & 1u)) >> 16);
}
DINL float bf2f(unsigned short h) {
    return __uint_as_float(((unsigned)h) << 16);
}
DINL unsigned pk2(float a, float b) {         // RNE pack (for global y2)
    return (unsigned)f2bf(a) | ((unsigned)f2bf(b) << 16);
}
// truncating bf16 (LDS-internal MFMA operands only; 1 inst each)
DINL unsigned short t1(float a) { return (unsigned short)(__float_as_uint(a) >> 16); }
DINL unsigned t2(float a, float b) {
    return (__float_as_uint(a) >> 16) | (__float_as_uint(b) & 0xFFFF0000u);
}
// fp8 e4m3 (OCP) encode — saturating HW convert
DINL unsigned char f2f8(float v) {
    return (unsigned char)(__builtin_amdgcn_cvt_pk_fp8_f32(v, v, 0, false) & 0xFF);
}
// fp16 helpers
DINL unsigned pkh(float a, float b) {
    auto h = __builtin_amdgcn_cvt_pkrtz(a, b);   // __fp16 ext_vector(2)
    unsigned u; __builtin_memcpy(&u, &h, 4); return u;
}
DINL float2 uph(unsigned u) {
    _Float16 h[2]; __builtin_memcpy(h, &u, 4);
    return make_float2((float)h[0], (float)h[1]);
}
DINL unsigned short f2h(float a) {
    _Float16 h = (_Float16)a; unsigned short s; __builtin_memcpy(&s, &h, 2); return s;
}
DINL float h2f(unsigned short s) {
    _Float16 h; __builtin_memcpy(&h, &s, 2); return (float)h;
}

DINL float blockReduceSum(float v) {   // blockDim.x == 256
    __shared__ float sm[4];
    int lane = threadIdx.x & 63, wid = threadIdx.x >> 6;
    #pragma unroll
    for (int o = 32; o > 0; o >>= 1) v += __shfl_down(v, o, 64);
    __syncthreads();
    if (lane == 0) sm[wid] = v;
    __syncthreads();
    if (wid == 0) {
        float r = (lane < 4) ? sm[lane] : 0.f;
        r += __shfl_down(r, 2, 64);
        r += __shfl_down(r, 1, 64);
        return r;                       // valid on thread 0
    }
    return 0.f;
}

__global__ void k_zero(float* __restrict__ red) { red[threadIdx.x] = 0.f; }

__global__ __launch_bounds__(256) void k_red(const float* __restrict__ src,
                                             float* __restrict__ dst)
{
    const float4* s4 = (const float4*)(src + (size_t)blockIdx.x * 1024);
    float4 q = s4[threadIdx.x];
    float r = blockReduceSum(q.x + q.y + q.z + q.w);
    if (threadIdx.x == 0) dst[blockIdx.x] = r;
}

// weight repack (bf16 fragment-order; head conv2 weights fp8)
__global__ __launch_bounds__(256) void k_prep(
    const float* __restrict__ w1, const float* __restrict__ w2,
    const float* __restrict__ phw1, const float* __restrict__ zw1,
    const float* __restrict__ phw2, const float* __restrict__ zw2,
    const float* __restrict__ g2g, const float* __restrict__ g2b,
    const float* __restrict__ w3,
    unsigned short* __restrict__ w1bf, unsigned short* __restrict__ w2bf,
    unsigned short* __restrict__ wh1, unsigned char* __restrict__ wp2,
    unsigned char* __restrict__ wz2, float* __restrict__ prm)
{
    int i = blockIdx.x * 256 + threadIdx.x;     // 0..9215
    if (i < 3072) {
        int o = i / 96, k = i - o * 96;
        int ky = k >> 5, r = k & 31, kx = r >> 3, c = r & 7;
        float v = (kx < 3 && c < 5) ? w1[o * 45 + c * 9 + ky * 3 + kx] : 0.f;
        w1bf[i] = f2bf(v);
    }
    if (i < 9216) {
        int tap = i >> 10, rr = i & 1023, o = rr >> 5, ci = rr & 31;
        w2bf[i] = f2bf(w2[o * 288 + ci * 9 + tap]);
    }
    if (i < 4608) {
        int o = i / 96, k = i - o * 96;
        int ky = k >> 5, r = k & 31, kx = r >> 3, c = r & 7;
        float v = 0.f;
        if (kx < 3 && c < 3)
            v = (o < 16) ? phw1[o * 27 + c * 9 + ky * 3 + kx]
                         : zw1[(o - 16) * 27 + c * 9 + ky * 3 + kx];
        wh1[i] = f2bf(v);
    }
    if (i < 4608) {
        int tap = i / 512, rr = i - tap * 512, n = rr >> 5, k = rr & 31;
        float vp = (n < 3 && k < 16) ? phw2[n * 144 + k * 9 + tap] : 0.f;
        float vz = (n < 3) ? zw2[n * 288 + k * 9 + tap] : 0.f;
        wp2[i] = f2f8(vp);
        wz2[i] = f2f8(vz);
    }
    if (i < 160) {
        if (i < 32) {
            int ch = (i & 1) * 16 + (i >> 1);
            prm[i] = g2g[ch];
        } else if (i < 64) {
            int j = i - 32, ch = (j & 1) * 16 + (j >> 1);
            prm[i] = g2b[ch];
        } else {
            int j = (i - 64) & 31, c = (i - 64) >> 5;
            int ch = (j & 1) * 16 + (j >> 1);
            prm[i] = w3[c * 32 + ch];
        }
    }
}

__global__ __launch_bounds__(256) void k_reduce_x(const float* __restrict__ x,
                                                  float* __restrict__ red) {
    int b = blockIdx.x >> 5, blk = blockIdx.x & 31;
    const float4* xv = (const float4*)(x + (size_t)b * CHW + (size_t)blk * (CHW / 32));
    float s = 0.f, ss = 0.f;
    for (int i = threadIdx.x; i < (CHW / 32) / 4; i += 256) {
        float4 v = xv[i];
        s  += v.x + v.y + v.z + v.w;
        ss += v.x * v.x + v.y * v.y + v.z * v.z + v.w * v.w;
    }
    float rs = blockReduceSum(s);
    float rss = blockReduceSum(ss);
    if (threadIdx.x == 0) { atomicAdd(&red[b], rs); atomicAdd(&red[8 + b], rss); }
}

// ---------------- fused heads (MFMA): xn -> [ph16 | z32] hidden(fp8) -> phi + z partials ----------------
__global__ __launch_bounds__(256) void k_heads(
    const float* __restrict__ x, const float* __restrict__ red,
    const float* __restrict__ ng, const float* __restrict__ nb,
    const unsigned short* __restrict__ wh1,
    const float* __restrict__ phb1, const float* __restrict__ zb1,
    const unsigned char* __restrict__ wp2, const unsigned char* __restrict__ wz2,
    const float* __restrict__ phb2, const float* __restrict__ zb2,
    unsigned short* __restrict__ phi, float* __restrict__ part)
{
    const int tx0 = blockIdx.x * 16, ty0 = blockIdx.y * 16, b = blockIdx.z;
    const int local = blockIdx.y * 32 + blockIdx.x;
    const bool edge = (blockIdx.x == 0) || (blockIdx.x == 31) ||
                      (blockIdx.y == 0) || (blockIdx.y == 31);
    __shared__ unsigned short mt8[20 * 21 * 8];
    __shared__ __attribute__((aligned(16))) unsigned char ht8[324 * 48];  // fp8 hidden; reused as phs/zs
    const int t = threadIdx.x;
    const float mu = red[b] * (1.f / CHW);
    const float rsv = rsqrtf(red[8 + b] * (1.f / CHW) - mu * mu + GEPS);
    float sc[3], sh[3];
    #pragma unroll
    for (int c = 0; c < 3; ++c) { sc[c] = rsv * ng[c]; sh[c] = nb[c] - mu * rsv * ng[c]; }
    if (edge) {
        for (int e = t; e < 20 * 21; e += 256) {
            int yy = e / 21, xx = e - yy * 21;
            int gy = ty0 - 2 + yy, gx = tx0 - 2 + xx;
            float v0 = 0, v1 = 0, v2 = 0;
            if (xx < 20 && (unsigned)gy < (unsigned)Hn && (unsigned)gx < (unsigned)Wn) {
                size_t p = (size_t)b * CHW + (size_t)gy * Wn + gx;
                v0 = x[p] * sc[0] + sh[0];
                v1 = x[p + HW] * sc[1] + sh[1];
                v2 = x[p + 2 * HW] * sc[2] + sh[2];
            }
            *(uint4*)(mt8 + e * 8) = make_uint4(t2(v0, v1), (unsigned)t1(v2), 0u, 0u);
        }
    } else {
        for (int e = t; e < 20 * 21; e += 256) {
            int yy = e / 21, xx = e - yy * 21;
            float v0 = 0, v1 = 0, v2 = 0;
            if (xx < 20) {
                size_t p = (size_t)b * CHW + (size_t)(ty0 - 2 + yy) * Wn + (tx0 - 2 + xx);
                v0 = x[p] * sc[0] + sh[0];
                v1 = x[p + HW] * sc[1] + sh[1];
                v2 = x[p + 2 * HW] * sc[2] + sh[2];
            }
            *(uint4*)(mt8 + e * 8) = make_uint4(t2(v0, v1), (unsigned)t1(v2), 0u, 0u);
        }
    }
    const int wv = t >> 6, lane = t & 63, ln = lane & 15, q = lane >> 4;
    bfx8 Bf[3][3];
    #pragma unroll
    for (int ks = 0; ks < 3; ++ks)
        #pragma unroll
        for (int nt = 0; nt < 3; ++nt)
            Bf[ks][nt] = *(const bfx8*)(wh1 + (nt * 16 + ln) * 96 + ks * 32 + q * 8);
    const float bb0 = phb1[ln], bb1 = zb1[ln], bb2 = zb1[16 + ln];
    __syncthreads();
    // conv1 (bf16 MFMA) -> silu -> ht8 (fp8, zero outside image)
    for (int mt = wv; mt < 21; mt += 4) {
        int p = mt * 16 + ln; if (p > 323) p = 323;
        const int hy = p / 18, hx = p - hy * 18;
        fx4 a0 = {0,0,0,0}, a1 = {0,0,0,0}, a2 = {0,0,0,0};
        #pragma unroll
        for (int ks = 0; ks < 3; ++ks) {
            bfx8 A = *(const bfx8*)(mt8 + ((hy + ks) * 21 + hx + q) * 8);
            a0 = __builtin_amdgcn_mfma_f32_16x16x32_bf16(A, Bf[ks][0], a0, 0, 0, 0);
            a1 = __builtin_amdgcn_mfma_f32_16x16x32_bf16(A, Bf[ks][1], a1, 0, 0, 0);
            a2 = __builtin_amdgcn_mfma_f32_16x16x32_bf16(A, Bf[ks][2], a2, 0, 0, 0);
        }
        const int prb = mt * 16 + q * 4;
        if (edge) {
            #pragma unroll
            for (int r = 0; r < 4; ++r) {
                const int pr = prb + r;
                if (pr < 324) {
                    const int py = pr / 18, px = pr - py * 18;
                    const int gy = ty0 - 1 + py, gx = tx0 - 1 + px;
                    const bool inimg = (unsigned)gy < (unsigned)Hn && (unsigned)gx < (unsigned)Wn;
                    unsigned char* hp = ht8 + pr * 48;
                    hp[ln]      = inimg ? f2f8(siluf(a0[r] + bb0)) : (unsigned char)0;
                    hp[16 + ln] = inimg ? f2f8(siluf(a1[r] + bb1)) : (unsigned char)0;
                    hp[32 + ln] = inimg ? f2f8(siluf(a2[r] + bb2)) : (unsigned char)0;
                }
            }
        } else {
            #pragma unroll
            for (int r = 0; r < 4; ++r) {
                const int pr = prb + r;
                if (pr < 324) {
                    unsigned char* hp = ht8 + pr * 48;
                    hp[ln]      = f2f8(siluf(a0[r] + bb0));
                    hp[16 + ln] = f2f8(siluf(a1[r] + bb1));
                    hp[32 + ln] = f2f8(siluf(a2[r] + bb2));
                }
            }
        }
    }
    __syncthreads();
    // conv2: 9 tap-GEMMs on fp8 MFMA (K=32). ph reads ch0..31 (k>=16 weights zero), z reads ch16..47.
    fx4 accp[4], accz[4];
    #pragma unroll
    for (int i = 0; i < 4; ++i) { accp[i] = fx4{0,0,0,0}; accz[i] = fx4{0,0,0,0}; }
    #pragma unroll
    for (int tap = 0; tap < 9; ++tap) {
        const int ky = tap / 3, kx = tap - ky * 3;
        long Bp = *(const long*)(wp2 + tap * 512 + ln * 32 + q * 8);
        long Bz = *(const long*)(wz2 + tap * 512 + ln * 32 + q * 8);
        #pragma unroll
        for (int i = 0; i < 4; ++i) {
            const int oy = wv * 4 + i;
            const unsigned char* ap = ht8 + ((oy + ky) * 18 + ln + kx) * 48;
            long Ap = *(const long*)(ap + q * 8);
            long Az = *(const long*)(ap + 16 + q * 8);
            accp[i] = __builtin_amdgcn_mfma_f32_16x16x32_fp8_fp8(Ap, Bp, accp[i], 0, 0, 0);
            accz[i] = __builtin_amdgcn_mfma_f32_16x16x32_fp8_fp8(Az, Bz, accz[i], 0, 0, 0);
        }
    }
    // epilogue via LDS (wave-local redistribution): full-lane tanh/sigm, coalesced fp16 stores
    __syncthreads();                       // all conv2 ht8 reads (cross-wave halo) done
    float* phs = (float*)ht8;              // [256][4]
    float* zs  = phs + 1024;               // [256][4]
    if (ln < 3) {
        #pragma unroll
        for (int i = 0; i < 4; ++i)
            #pragma unroll
            for (int r = 0; r < 4; ++r) {
                int pl = (wv * 4 + i) * 16 + q * 4 + r;
                phs[pl * 4 + ln] = accp[i][r];
                zs [pl * 4 + ln] = accz[i][r];
            }
    }
    asm volatile("" ::: "memory");         // writer px rows == reader px rows per wave
    float4 pv = ((const float4*)phs)[t];
    float4 zv = ((const float4*)zs)[t];
    const int gy = ty0 + (t >> 4), gx = tx0 + (t & 15);
    size_t pp = (size_t)b * CHW + (size_t)gy * Wn + gx;
    phi[pp]          = f2h(ftanh(pv.x + phb2[0]) * PIf);
    phi[pp + HW]     = f2h(ftanh(pv.y + phb2[1]) * PIf);
    phi[pp + 2 * HW] = f2h(ftanh(pv.z + phb2[2]) * PIf);
    float z0 = sigm(zv.x + zb2[0]) * 0.3f;
    float z1 = sigm(zv.y + zb2[1]) * 0.3f;
    float z2 = sigm(zv.z + zb2[2]) * 0.3f;
    float r0 = blockReduceSum(z0);
    float r1 = blockReduceSum(z1);
    float r2 = blockReduceSum(z2);
    if (t == 0) {
        part[PZ + (size_t)(b * 3 + 0) * 1024 + local] = r0;
        part[PZ + (size_t)(b * 3 + 1) * 1024 + local] = r1;
        part[PZ + (size_t)(b * 3 + 2) * 1024 + local] = r2;
    }
}

// ---------------- FFT: 512-pt Stockham radix-4 (x4) + radix-2, wave-per-line ----------------
template<bool INV>
DINL float2* fft512_wave4(float2* a, float2* b, const float2* tw, int l)
{
    float2* src = a; float2* dst = b;
    int s = 1;
    #pragma unroll
    for (int st = 0; st < 4; ++st) {
        #pragma unroll
        for (int h = 0; h < 2; ++h) {
            const int i = l + h * 64;          // butterfly index in [0,128)
            const int q = i & (s - 1);
            const int sm = i - q;              // s*m
            float2 A = src[i], B = src[i + 128], C = src[i + 256], D = src[i + 384];
            float t0x = A.x + C.x, t0y = A.y + C.y;
            float t1x = A.x - C.x, t1y = A.y - C.y;
            float t2x = B.x + D.x, t2y = B.y + D.y;
            float t3x = B.x - D.x, t3y = B.y - D.y;
            float i3x = INV ? -t3y : t3y;
            float i3y = INV ? t3x : -t3x;
            float u0x = t0x + t2x, u0y = t0y + t2y;
            float u2x = t0x - t2x, u2y = t0y - t2y;
            float u1x = t1x + i3x, u1y = t1y + i3y;
            float u3x = t1x - i3x, u3y = t1y - i3y;
            float2 w1 = tw[sm], w2 = tw[2 * sm], w3 = tw[3 * sm];
            float w1y = INV ? -w1.y : w1.y;
            float w2y = INV ? -w2.y : w2.y;
            float w3y = INV ? -w3.y : w3.y;
            const int base = q + 4 * sm;
            dst[base]         = make_float2(u0x, u0y);
            dst[base + s]     = make_float2(u1x * w1.x - u1y * w1y, u1x * w1y + u1y * w1.x);
            dst[base + 2 * s] = make_float2(u2x * w2.x - u2y * w2y, u2x * w2y + u2y * w2.x);
            dst[base + 3 * s] = make_float2(u3x * w3.x - u3y * w3y, u3x * w3y + u3y * w3.x);
        }
        float2* tmp = src; src = dst; dst = tmp;
        s <<= 2;
        asm volatile("" ::: "memory");   // wave-synchronous LDS: fence compiler only
    }
    // final radix-2, s=256 (m=0 -> no twiddle)
    #pragma unroll
    for (int h = 0; h < 4; ++h) {
        const int j = l + h * 64;
        float2 u = src[j], v = src[j + 256];
        dst[j]       = make_float2(u.x + v.x, u.y + v.y);
        dst[j + 256] = make_float2(u.x - v.x, u.y - v.y);
    }
    float2* tmp = src; src = dst; dst = tmp;
    asm volatile("" ::: "memory");
    return src;
}

__global__ __launch_bounds__(256) void k_fftA(
    const float* __restrict__ x, const unsigned short* __restrict__ phi,
    unsigned* __restrict__ U)
{
    __shared__ float2 buf[4][2][512];
    __shared__ float2 tw[512];
    const int t = threadIdx.x, wv = t >> 6, l = t & 63;
    #pragma unroll
    for (int i = t; i < 512; i += 256) {
        float s, c; __sincosf(-2.f * PIf * (float)i * (1.f / 512.f), &s, &c);
        tw[i] = make_float2(c, s);
    }
    __syncthreads();
    const size_t line = (size_t)blockIdx.x * 4 + wv;
    const float* xr = x + line * 512;
    const unsigned short* pr = phi + line * 512;
    float2* A = buf[wv][0];
    float2* B = buf[wv][1];
    #pragma unroll
    for (int i = l; i < 512; i += 64) {
        float s, c; __sincosf(h2f(pr[i]), &s, &c);
        float xv = xr[i];
        A[i] = make_float2(xv * c, xv * s);
    }
    asm volatile("" ::: "memory");
    float2* res = fft512_wave4<false>(A, B, tw, l);
    unsigned* Ur = U + line * 512;
    #pragma unroll
    for (int i = l; i < 512; i += 64) Ur[i] = pkh(res[i].x, res[i].y);
}

__global__ __launch_bounds__(256) void k_transpose(unsigned* __restrict__ U)
{
    const int img = blockIdx.y;
    int rem = blockIdx.x, ti = 0;
    while (rem >= 16 - ti) { rem -= 16 - ti; ++ti; }
    const int tj = ti + rem;
    unsigned* Ub = U + (size_t)img * HW;
    __shared__ unsigned ta[32][33];
    __shared__ unsigned tb[32][33];
    const int t = threadIdx.x;
    const int cc = t & 31, r0 = t >> 5;
    const int ar = ti * 32, ac = tj * 32;
    #pragma unroll
    for (int k = 0; k < 4; ++k) {
        int r = r0 + k * 8;
        ta[r][cc] = Ub[(size_t)(ar + r) * 512 + ac + cc];
    }
    if (ti != tj) {
        #pragma unroll
        for (int k = 0; k < 4; ++k) {
            int r = r0 + k * 8;
            tb[r][cc] = Ub[(size_t)(ac + r) * 512 + ar + cc];
        }
    }
    __syncthreads();
    #pragma unroll
    for (int k = 0; k < 4; ++k) {
        int r = r0 + k * 8;
        Ub[(size_t)(ac + r) * 512 + ar + cc] = ta[cc][r];
    }
    if (ti != tj) {
        #pragma unroll
        for (int k = 0; k < 4; ++k) {
            int r = r0 + k * 8;
            Ub[(size_t)(ar + r) * 512 + ac + cc] = tb[cc][r];
        }
    }
}

__global__ __launch_bounds__(256) void k_fftB(
    unsigned* __restrict__ U, const float* __restrict__ red, const float* __restrict__ fgain)
{
    __shared__ float2 buf[4][2][512];
    __shared__ float2 tw[512];
    const int t = threadIdx.x, wv = t >> 6, l = t & 63;
    #pragma unroll
    for (int i = t; i < 512; i += 256) {
        float s, c; __sincosf(-2.f * PIf * (float)i * (1.f / 512.f), &s, &c);
        tw[i] = make_float2(c, s);
    }
    __syncthreads();
    const int line = blockIdx.x * 4 + wv;          // (b*3+c)*512 + fw
    const int bc = line >> 9;
    const int fw = line & 511;
    const int c = bc % 3;
    unsigned* Ur = U + (size_t)line * 512;
    float2* A = buf[wv][0];
    float2* B = buf[wv][1];
    #pragma unroll
    for (int i = l; i < 512; i += 64) A[i] = uph(Ur[i]);
    asm volatile("" ::: "memory");
    float2* res = fft512_wave4<false>(A, B, tw, l);
    const float zm   = red[16 + bc] * (1.f / HW);
    const float gain = 1.f + fgain[c];
    const float lam  = (c == 0) ? 0.65f : (c == 1) ? 0.53f : 0.47f;
    const float il2  = 1.f / (lam * lam);
    const float fwv  = (float)(fw < 256 ? fw : fw - 512) * (1.f / 512.f);
    const float f2w  = fwv * fwv;
    #pragma unroll
    for (int i = l; i < 512; i += 64) {
        float fh = (float)(i < 256 ? i : i - 512) * (1.f / 512.f);
        float kz = 2.f * PIf * sqrtf(fmaxf(il2 - f2w - fh * fh, 0.f));
        float sn, cs; __sincosf(kz * zm, &sn, &cs);
        float2 v = res[i];
        res[i] = make_float2(gain * (v.x * cs - v.y * sn), gain * (v.x * sn + v.y * cs));
    }
    asm volatile("" ::: "memory");
    float2* other = (res == A) ? B : A;
    float2* res2 = fft512_wave4<true>(res, other, tw, l);
    #pragma unroll
    for (int i = l; i < 512; i += 64) {
        float2 v = res2[i];
        Ur[i] = pkh(v.x * (1.f / 512.f), v.y * (1.f / 512.f));
    }
}

__global__ __launch_bounds__(256) void k_fftC(
    const unsigned* __restrict__ U, unsigned short* __restrict__ J)
{
    __shared__ float2 buf[4][2][512];
    __shared__ float2 tw[512];
    const int t = threadIdx.x, wv = t >> 6, l = t & 63;
    #pragma unroll
    for (int i = t; i < 512; i += 256) {
        float s, c; __sincosf(-2.f * PIf * (float)i * (1.f / 512.f), &s, &c);
        tw[i] = make_float2(c, s);
    }
    __syncthreads();
    const size_t line = (size_t)blockIdx.x * 4 + wv;
    const unsigned* Ur = U + line * 512;
    float2* A = buf[wv][0];
    float2* B = buf[wv][1];
    #pragma unroll
    for (int i = l; i < 512; i += 64) A[i] = uph(Ur[i]);
    asm volatile("" ::: "memory");
    float2* res = fft512_wave4<true>(A, B, tw, l);
    unsigned short* Jr = J + line * 512;
    #pragma unroll
    for (int i = l; i < 512; i += 64) {
        float2 v = res[i];
        float re = v.x * (1.f / 512.f), im = v.y * (1.f / 512.f);
        Jr[i] = f2h(sqrtf(fmaxf(re * re + im * im, 1e-12f)));
    }
}

// ---------------- mix path (MFMA) ----------------
__global__ __launch_bounds__(256) void k_m1(
    const float* __restrict__ x, const unsigned short* __restrict__ Jb,
    const unsigned short* __restrict__ w1bf, const float* __restrict__ b1,
    float* __restrict__ part)
{
    const int tx0 = blockIdx.x * 16, ty0 = blockIdx.y * 16, b = blockIdx.z;
    const int local = blockIdx.y * 32 + blockIdx.x;
    const bool edge = (blockIdx.x == 0) || (blockIdx.x == 31) ||
                      (blockIdx.y == 0) || (blockIdx.y == 31);
    __shared__ unsigned short mt8[18 * 19 * 8];
    const int t = threadIdx.x;
    for (int e = t; e < 18 * 19; e += 256) {
        int yy = e / 19, xx = e - yy * 19;
        int gy = ty0 - 1 + yy, gx = tx0 - 1 + xx;
        float v0 = 0, v1 = 0, v2 = 0, jl = 0, d5 = 0;
        bool ok = edge ? (xx < 18 && (unsigned)gy < (unsigned)Hn && (unsigned)gx < (unsigned)Wn)
                       : (xx < 18);
        if (ok) {
            size_t p = (size_t)b * CHW + (size_t)gy * Wn + gx;
            v0 = x[p]; v1 = x[p + HW]; v2 = x[p + 2 * HW];
            float j0 = h2f(Jb[p]), j1 = h2f(Jb[p + HW]), j2 = h2f(Jb[p + 2 * HW]);
            float xl = 0.299f * v0 + 0.587f * v1 + 0.114f * v2;
            jl = 0.299f * j0 + 0.587f * j1 + 0.114f * j2;
            d5 = jl - xl;
        }
        *(uint4*)(mt8 + e * 8) = make_uint4(t2(v0, v1), t2(v2, jl), (unsigned)t1(d5), 0u);
    }
    __syncthreads();
    const int wv = t >> 6, lane = t & 63, ln = lane & 15, q = lane >> 4;
    bfx8 Bf[3][2];
    #pragma unroll
    for (int ks = 0; ks < 3; ++ks)
        #pragma unroll
        for (int nt = 0; nt < 2; ++nt)
            Bf[ks][nt] = *(const bfx8*)(w1bf + (nt * 16 + ln) * 96 + ks * 32 + q * 8);
    const float b1v0 = b1[ln], b1v1 = b1[16 + ln];
    float s = 0.f, ss = 0.f;
    #pragma unroll
    for (int i = 0; i < 4; ++i) {
        const int oy = wv * 4 + i;
        fx4 a0 = {0.f, 0.f, 0.f, 0.f}, a1 = {0.f, 0.f, 0.f, 0.f};
        #pragma unroll
        for (int ks = 0; ks < 3; ++ks) {
            bfx8 A = *(const bfx8*)(mt8 + ((oy + ks) * 19 + ln + q) * 8);
            a0 = __builtin_amdgcn_mfma_f32_16x16x32_bf16(A, Bf[ks][0], a0, 0, 0, 0);
            a1 = __builtin_amdgcn_mfma_f32_16x16x32_bf16(A, Bf[ks][1], a1, 0, 0, 0);
        }
        #pragma unroll
        for (int r = 0; r < 4; ++r) {
            float u0 = a0[r] + b1v0, u1 = a1[r] + b1v1;
            s += u0 + u1; ss += u0 * u0 + u1 * u1;
        }
    }
    float rs = blockReduceSum(s);
    float rss = blockReduceSum(ss);
    if (t == 0) {
        part[PG1 + (size_t)b * 1024 + local] = rs;
        part[PG1 + (size_t)(8 + b) * 1024 + local] = rss;
    }
}

// conv1 -> gn1 -> silu -> conv2 (bf16 MFMA); y2 channel-last + gn2 partials
__global__ __launch_bounds__(256) void k_m2(
    const float* __restrict__ x, const unsigned short* __restrict__ Jb,
    const unsigned short* __restrict__ w1bf, const float* __restrict__ b1,
    const float* __restrict__ g1g, const float* __restrict__ g1b,
    const unsigned short* __restrict__ w2bf, const float* __restrict__ b2,
    const float* __restrict__ red, float* __restrict__ part,
    unsigned short* __restrict__ y2)
{
    const int tx0 = blockIdx.x * 16, ty0 = blockIdx.y * 16, b = blockIdx.z;
    const int local = blockIdx.y * 32 + blockIdx.x;
    const bool edge = (blockIdx.x == 0) || (blockIdx.x == 31) ||
                      (blockIdx.y == 0) || (blockIdx.y == 31);
    __shared__ unsigned short mt8[20 * 21 * 8];
    __shared__ unsigned short dt2[324 * 40];
    const int t = threadIdx.x;
    const float mu1 = red[40 + b] * (1.f / (32.f * HW));
    const float rs1 = rsqrtf(red[48 + b] * (1.f / (32.f * HW)) - mu1 * mu1 + GEPS);
    for (int e = t; e < 20 * 21; e += 256) {
        int yy = e / 21, xx = e - yy * 21;
        int gy = ty0 - 2 + yy, gx = tx0 - 2 + xx;
        float v0 = 0, v1 = 0, v2 = 0, jl = 0, d5 = 0;
        bool ok = edge ? (xx < 20 && (unsigned)gy < (unsigned)Hn && (unsigned)gx < (unsigned)Wn)
                       : (xx < 20);
        if (ok) {
            size_t p = (size_t)b * CHW + (size_t)gy * Wn + gx;
            v0 = x[p]; v1 = x[p + HW]; v2 = x[p + 2 * HW];
            float j0 = h2f(Jb[p]), j1 = h2f(Jb[p + HW]), j2 = h2f(Jb[p + 2 * HW]);
            float xl = 0.299f * v0 + 0.587f * v1 + 0.114f * v2;
            jl = 0.299f * j0 + 0.587f * j1 + 0.114f * j2;
            d5 = jl - xl;
        }
        *(uint4*)(mt8 + e * 8) = make_uint4(t2(v0, v1), t2(v2, jl), (unsigned)t1(d5), 0u);
    }
    const int wv = t >> 6, lane = t & 63, ln = lane & 15, q = lane >> 4;
    const float sc0 = rs1 * g1g[ln],       sc1 = rs1 * g1g[16 + ln];
    const float of0 = (b1[ln] - mu1) * sc0 + g1b[ln];
    const float of1 = (b1[16 + ln] - mu1) * sc1 + g1b[16 + ln];
    bfx8 Bf[3][2];
    #pragma unroll
    for (int ks = 0; ks < 3; ++ks)
        #pragma unroll
        for (int nt = 0; nt < 2; ++nt)
            Bf[ks][nt] = *(const bfx8*)(w1bf + (nt * 16 + ln) * 96 + ks * 32 + q * 8);
    __syncthreads();
    for (int mt = wv; mt < 21; mt += 4) {
        int p = mt * 16 + ln; if (p > 323) p = 323;
        const int hy = p / 18, hx = p - hy * 18;
        fx4 a0 = {0.f, 0.f, 0.f, 0.f}, a1 = {0.f, 0.f, 0.f, 0.f};
        #pragma unroll
        for (int ks = 0; ks < 3; ++ks) {
            bfx8 A = *(const bfx8*)(mt8 + ((hy + ks) * 21 + hx + q) * 8);
            a0 = __builtin_amdgcn_mfma_f32_16x16x32_bf16(A, Bf[ks][0], a0, 0, 0, 0);
            a1 = __builtin_amdgcn_mfma_f32_16x16x32_bf16(A, Bf[ks][1], a1, 0, 0, 0);
        }
        const int prb = mt * 16 + q * 4;
        if (edge) {
            #pragma unroll
            for (int r = 0; r < 4; ++r) {
                const int pr = prb + r;
                if (pr < 324) {
                    const int py = pr / 18, px = pr - py * 18;
                    const int gy = ty0 - 1 + py, gx = tx0 - 1 + px;
                    const bool inimg = (unsigned)gy < (unsigned)Hn && (unsigned)gx < (unsigned)Wn;
                    dt2[pr * 40 + ln]      = inimg ? t1(siluf(a0[r] * sc0 + of0)) : (unsigned short)0;
                    dt2[pr * 40 + 16 + ln] = inimg ? t1(siluf(a1[r] * sc1 + of1)) : (unsigned short)0;
                }
            }
        } else {
            #pragma unroll
            for (int r = 0; r < 4; ++r) {
                const int pr = prb + r;
                if (pr < 324) {
                    dt2[pr * 40 + ln]      = t1(siluf(a0[r] * sc0 + of0));
                    dt2[pr * 40 + 16 + ln] = t1(siluf(a1[r] * sc1 + of1));
                }
            }
        }
    }
    __syncthreads();
    fx4 c2[4][2];
    #pragma unroll
    for (int i = 0; i < 4; ++i)
        #pragma unroll
        for (int nt = 0; nt < 2; ++nt)
            c2[i][nt] = fx4{0.f, 0.f, 0.f, 0.f};
    #pragma unroll
    for (int tap = 0; tap < 9; ++tap) {
        const int ky = tap / 3, kx = tap - ky * 3;
        bfx8 B0 = *(const bfx8*)(w2bf + tap * 1024 + ln * 32 + q * 8);
        bfx8 B1 = *(const bfx8*)(w2bf + tap * 1024 + (16 + ln) * 32 + q * 8);
        #pragma unroll
        for (int i = 0; i < 4; ++i) {
            const int oy = wv * 4 + i;
            bfx8 A = *(const bfx8*)(dt2 + ((oy + ky) * 18 + ln + kx) * 40 + q * 8);
            c2[i][0] = __builtin_amdgcn_mfma_f32_16x16x32_bf16(A, B0, c2[i][0], 0, 0, 0);
            c2[i][1] = __builtin_amdgcn_mfma_f32_16x16x32_bf16(A, B1, c2[i][1], 0, 0, 0);
        }
    }
    float s = 0.f, ss = 0.f;
    const float b2v0 = b2[ln], b2v1 = b2[16 + ln];
    #pragma unroll
    for (int i = 0; i < 4; ++i) {
        const int gy = ty0 + wv * 4 + i;
        #pragma unroll
        for (int r = 0; r < 4; ++r) {
            const int gx = tx0 + q * 4 + r;
            float a0 = c2[i][0][r] + b2v0;
            float a1 = c2[i][1][r] + b2v1;
            s += a0 + a1; ss += a0 * a0 + a1 * a1;
            unsigned pk = pk2(a0, a1);
            size_t off = ((size_t)b * HW + (size_t)gy * Wn + gx) * 32 + ln * 2;
            *(unsigned*)(y2 + off) = pk;
        }
    }
    float rsum = blockReduceSum(s);
    float rss = blockReduceSum(ss);
    if (t == 0) {
        part[PG2 + (size_t)b * 1024 + local] = rsum;
        part[PG2 + (size_t)(8 + b) * 1024 + local] = rss;
    }
}

// gn2 -> silu -> 1x1 conv; channel-last y2; dl fp16; dsum partials (no atomics)
__global__ __launch_bounds__(256) void k_m3(
    const unsigned short* __restrict__ y2, const float* __restrict__ red,
    const float* __restrict__ prm, const float* __restrict__ b3,
    unsigned short* __restrict__ dl, float* __restrict__ part)
{
    int idx = blockIdx.x * 256 + threadIdx.x;     // global pixel (b*HW+pix)
    int b = idx >> 18;
    int pix = idx & (HW - 1);
    const int local = blockIdx.x & 1023;
    float mu = red[56 + b] * (1.f / (32.f * HW));
    float rs = rsqrtf(red[64 + b] * (1.f / (32.f * HW)) - mu * mu + GEPS);
    const uint4* yp = (const uint4*)(y2 + (size_t)idx * 32);
    uint4 L[4];
    #pragma unroll
    for (int c = 0; c < 4; ++c) L[c] = yp[c];
    float a0 = b3[0], a1 = b3[1], a2 = b3[2];
    const unsigned* Lw = (const unsigned*)L;
    #pragma unroll
    for (int w = 0; w < 16; ++w) {     // 16 dwords = all 32 channels
        unsigned u = Lw[w];
        #pragma unroll
        for (int h = 0; h < 2; ++h) {
            int j = w * 2 + h;
            float v = bf2f((unsigned short)(h ? (u >> 16) : (u & 0xFFFFu)));
            float dn = (v - mu) * rs * prm[j] + prm[32 + j];
            float sv = siluf(dn);
            a0 += sv * prm[64 + j]; a1 += sv * prm[96 + j]; a2 += sv * prm[128 + j];
        }
    }
    size_t p = (size_t)b * CHW + pix;
    dl[p] = f2h(a0); dl[p + HW] = f2h(a1); dl[p + 2 * HW] = f2h(a2);
    float r0 = blockReduceSum(a0);
    float r1 = blockReduceSum(a1);
    float r2 = blockReduceSum(a2);
    if (threadIdx.x == 0) {
        part[PD + (size_t)(b * 3 + 0) * 1024 + local] = r0;
        part[PD + (size_t)(b * 3 + 1) * 1024 + local] = r1;
        part[PD + (size_t)(b * 3 + 2) * 1024 + local] = r2;
    }
}

__global__ void k_se(float* __restrict__ red,
    const float* __restrict__ w1, const float* __restrict__ b1,
    const float* __restrict__ w2, const float* __restrict__ b2,
    const float* __restrict__ alpha)
{
    int b = threadIdx.x;
    if (b < 8) {
        float p0 = red[72 + b * 3 + 0] * (1.f / HW);
        float p1 = red[72 + b * 3 + 1] * (1.f / HW);
        float p2 = red[72 + b * 3 + 2] * (1.f / HW);
        float h[4];
        #pragma unroll
        for (int j = 0; j < 4; ++j) {
            float a = b1[j] + p0 * w1[j * 3] + p1 * w1[j * 3 + 1] + p2 * w1[j * 3 + 2];
            h[j] = siluf(a);
        }
        float al = alpha[0];
        #pragma unroll
        for (int c = 0; c < 3; ++c) {
            float a = b2[c] + h[0] * w2[c * 4] + h[1] * w2[c * 4 + 1]
                            + h[2] * w2[c * 4 + 2] + h[3] * w2[c * 4 + 3];
            red[96 + b * 3 + c] = al * sigm(a);
        }
    }
}

__global__ __launch_bounds__(256) void k_out(
    const float* __restrict__ x, const unsigned short* __restrict__ dl,
    const float* __restrict__ red, float* __restrict__ out)
{
    int i = blockIdx.x * 256 + threadIdx.x;     // float4 index
    float aw = red[96 + (i >> 16)];
    float4 xv = ((const float4*)x)[i];
    uint2 dv2 = ((const uint2*)dl)[i];          // 4 fp16
    float2 d01 = uph(dv2.x);
    float2 d23 = uph(dv2.y);
    float4 o;
    o.x = xv.x + aw * d01.x; o.y = xv.y + aw * d01.y;
    o.z = xv.z + aw * d23.x; o.w = xv.w + aw * d23.y;
    ((float4*)out)[i] = o;
}

extern "C" void kernel_launch(void* const* d_in, const int* in_sizes, int n_in,
                              void* d_out, int out_size, void* d_ws, size_t ws_size,
                              hipStream_t stream)
{
    const float* x     = (const float*)d_in[0];
    const float* ng    = (const float*)d_in[1];
    const float* nb    = (const float*)d_in[2];
    const float* ph_w1 = (const float*)d_in[3];
    const float* ph_b1 = (const float*)d_in[4];
    const float* ph_w2 = (const float*)d_in[5];
    const float* ph_b2 = (const float*)d_in[6];
    const float* z_w1  = (const float*)d_in[7];
    const float* z_b1  = (const float*)d_in[8];
    const float* z_w2  = (const float*)d_in[9];
    const float* z_b2  = (const float*)d_in[10];
    const float* fgain = (const float*)d_in[11];
    const float* mw1   = (const float*)d_in[12];
    const float* mb1   = (const float*)d_in[13];
    const float* g1g   = (const float*)d_in[14];
    const float* g1b   = (const float*)d_in[15];
    const float* mw2   = (const float*)d_in[16];
    const float* mb2   = (const float*)d_in[17];
    const float* g2g   = (const float*)d_in[18];
    const float* g2b   = (const float*)d_in[19];
    const float* mw3   = (const float*)d_in[20];
    const float* mb3   = (const float*)d_in[21];
    const float* sw1   = (const float*)d_in[22];
    const float* sb1   = (const float*)d_in[23];
    const float* sw2   = (const float*)d_in[24];
    const float* sb2   = (const float*)d_in[25];
    const float* alpha = (const float*)d_in[26];

    char* ws = (char*)d_ws;
    float*  red = (float*)(ws + OFF_RED);
    unsigned short* phi = (unsigned short*)(ws + OFF_PHI);
    unsigned* U = (unsigned*)(ws + OFF_U);
    unsigned short* Jb = (unsigned short*)(ws + OFF_J);
    unsigned short* dl = (unsigned short*)(ws + OFF_D);
    unsigned short* y2   = (unsigned short*)(ws + OFF_Y2);
    unsigned short* w1bf = (unsigned short*)(ws + OFF_W1B);
    unsigned short* w2bf = (unsigned short*)(ws + OFF_W2B);
    unsigned short* wh1  = (unsigned short*)(ws + OFF_WH1);
    unsigned char*  wp2  = (unsigned char*)(ws + OFF_WP2);
    unsigned char*  wz2  = (unsigned char*)(ws + OFF_WZ2);
    float* prm  = (float*)(ws + OFF_PRM);
    float* part = (float*)(ws + OFF_PART);
    float* out = (float*)d_out;

    hipLaunchKernelGGL(k_zero, dim3(1), dim3(128), 0, stream, red);
    hipLaunchKernelGGL(k_prep, dim3(36), dim3(256), 0, stream,
                       mw1, mw2, ph_w1, z_w1, ph_w2, z_w2, g2g, g2b, mw3,
                       w1bf, w2bf, wh1, wp2, wz2, prm);
    hipLaunchKernelGGL(k_reduce_x, dim3(256), dim3(256), 0, stream, x, red);
    hipLaunchKernelGGL(k_heads, dim3(32, 32, 8), dim3(256), 0, stream,
                       x, red, ng, nb, wh1, ph_b1, z_b1, wp2, wz2, ph_b2, z_b2, phi, part);
    hipLaunchKernelGGL(k_red, dim3(24), dim3(256), 0, stream, part + PZ, red + 16);
    hipLaunchKernelGGL(k_fftA, dim3(3072), dim3(256), 0, stream, x, phi, U);
    hipLaunchKernelGGL(k_transpose, dim3(136, 24), dim3(256), 0, stream, U);
    hipLaunchKernelGGL(k_fftB, dim3(3072), dim3(256), 0, stream, U, red, fgain);
    hipLaunchKernelGGL(k_transpose, dim3(136, 24), dim3(256), 0, stream, U);
    hipLaunchKernelGGL(k_fftC, dim3(3072), dim3(256), 0, stream, U, Jb);
    hipLaunchKernelGGL(k_m1, dim3(32, 32, 8), dim3(256), 0, stream, x, Jb, w1bf, mb1, part);
    hipLaunchKernelGGL(k_red, dim3(16), dim3(256), 0, stream, part + PG1, red + 40);
    hipLaunchKernelGGL(k_m2, dim3(32, 32, 8), dim3(256), 0, stream,
                       x, Jb, w1bf, mb1, g1g, g1b, w2bf, mb2, red, part, y2);
    hipLaunchKernelGGL(k_red, dim3(16), dim3(256), 0, stream, part + PG2, red + 56);
    hipLaunchKernelGGL(k_m3, dim3(8192), dim3(256), 0, stream, y2, red, prm, mb3, dl, part);
    hipLaunchKernelGGL(k_red, dim3(24), dim3(256), 0, stream, part + PD, red + 72);
    hipLaunchKernelGGL(k_se, dim3(1), dim3(64), 0, stream, red, sw1, sb1, sw2, sb2, alpha);
    hipLaunchKernelGGL(k_out, dim3(6144), dim3(256), 0, stream, x, dl, red, out);
}

// Round 15
// 499.372 us; speedup vs baseline: 6.0629x; 1.0276x over previous
//
#include <hip/hip_runtime.h>
#include <hip/hip_bf16.h>
#include <math.h>

#define DINL __device__ __forceinline__

namespace {
constexpr int Bn = 8, Cn = 3, Hn = 512, Wn = 512;
constexpr int HW  = Hn * Wn;        // 262144
constexpr int CHW = Cn * HW;        // 786432
constexpr float GEPS = 1e-5f;
constexpr float PIf  = 3.14159265358979323846f;

// workspace layout (bytes) — U half2, J/phi/dl fp16, y2 fp8 channel-last
constexpr size_t OFF_RED = 0;                                   // 128 floats
constexpr size_t OFF_PHI = 512;                                 // Bn*CHW ushort
constexpr size_t OFF_U   = OFF_PHI + (size_t)Bn * CHW * 2;      // Bn*CHW uint (half2)
constexpr size_t OFF_J   = OFF_U   + (size_t)Bn * CHW * 4;      // Bn*CHW ushort
constexpr size_t OFF_D   = OFF_J   + (size_t)Bn * CHW * 2;      // Bn*CHW ushort
constexpr size_t OFF_Y2  = OFF_D   + (size_t)Bn * CHW * 2;      // 8*32*HW fp8 (channel-last)
constexpr size_t OFF_W1B = OFF_Y2  + (size_t)Bn * 32 * HW;      // 3072 bf16
constexpr size_t OFF_W2F = OFF_W1B + 3072 * 2;                  // 9216 fp8 (mix conv2)
constexpr size_t OFF_WH1 = OFF_W2F + 9216;                      // 4608 bf16
constexpr size_t OFF_WP2 = OFF_WH1 + 4608 * 2;                  // 4608 fp8
constexpr size_t OFF_WZ2 = OFF_WP2 + 4608;                      // 4608 fp8
constexpr size_t OFF_PRM = OFF_WZ2 + 4608;                      // 160 f32
constexpr size_t OFF_PART= OFF_PRM + 160 * 4;                   // 81920 f32 partials
// part float sub-offsets (in floats)
constexpr int PZ = 0;          // 24 groups (b*3+c) x 1024
constexpr int PG1 = 24576;     // 16 groups (b:sum, 8+b:ss) x 1024
constexpr int PG2 = 40960;     // 16 groups x 1024
constexpr int PD  = 57344;     // 24 groups (b*3+c) x 1024
}

typedef __bf16 bfx8 __attribute__((ext_vector_type(8)));
typedef float  fx4  __attribute__((ext_vector_type(4)));

DINL float frcp(float a) { return __builtin_amdgcn_rcpf(a); }   // v_rcp_f32, 1 ULP
DINL float sigm(float a) { return frcp(1.f + __expf(-a)); }
DINL float siluf(float a) { return a * frcp(1.f + __expf(-a)); }
DINL float ftanh(float a) { return 1.f - 2.f * frcp(1.f + __expf(2.f * a)); }
DINL unsigned short f2bf(float f) {           // RNE float->bf16 bits
    unsigned u = __float_as_uint(f);
    return (unsigned short)((u + 0x7FFFu + ((u >> 16) & 1u)) >> 16);
}
DINL float bf2f(unsigned short h) {
    return __uint_as_float(((unsigned)h) << 16);
}
// truncating bf16 (LDS-internal MFMA operands only; 1 inst each)
DINL unsigned short t1(float a) { return (unsigned short)(__float_as_uint(a) >> 16); }
DINL unsigned t2(float a, float b) {
    return (__float_as_uint(a) >> 16) | (__float_as_uint(b) & 0xFFFF0000u);
}
// fp8 e4m3 (OCP) — saturating HW convert
DINL unsigned char f2f8(float v) {
    return (unsigned char)(__builtin_amdgcn_cvt_pk_fp8_f32(v, v, 0, false) & 0xFF);
}
DINL unsigned short pk8(float a, float b) {   // 2 fp8 in low 16 bits
    return (unsigned short)(__builtin_amdgcn_cvt_pk_fp8_f32(a, b, 0, false) & 0xFFFF);
}
template<int SEL>
DINL float f8f(unsigned u) { return __builtin_amdgcn_cvt_f32_fp8(u, SEL); }
// fp16 helpers
DINL unsigned pkh(float a, float b) {
    auto h = __builtin_amdgcn_cvt_pkrtz(a, b);   // __fp16 ext_vector(2)
    unsigned u; __builtin_memcpy(&u, &h, 4); return u;
}
DINL float2 uph(unsigned u) {
    _Float16 h[2]; __builtin_memcpy(h, &u, 4);
    return make_float2((float)h[0], (float)h[1]);
}
DINL unsigned short f2h(float a) {
    _Float16 h = (_Float16)a; unsigned short s; __builtin_memcpy(&s, &h, 2); return s;
}
DINL float h2f(unsigned short s) {
    _Float16 h; __builtin_memcpy(&h, &s, 2); return (float)h;
}

DINL float blockReduceSum(float v) {   // blockDim.x == 256
    __shared__ float sm[4];
    int lane = threadIdx.x & 63, wid = threadIdx.x >> 6;
    #pragma unroll
    for (int o = 32; o > 0; o >>= 1) v += __shfl_down(v, o, 64);
    __syncthreads();
    if (lane == 0) sm[wid] = v;
    __syncthreads();
    if (wid == 0) {
        float r = (lane < 4) ? sm[lane] : 0.f;
        r += __shfl_down(r, 2, 64);
        r += __shfl_down(r, 1, 64);
        return r;                       // valid on thread 0
    }
    return 0.f;
}

__global__ void k_zero(float* __restrict__ red) { red[threadIdx.x] = 0.f; }

__global__ __launch_bounds__(256) void k_red(const float* __restrict__ src,
                                             float* __restrict__ dst)
{
    const float4* s4 = (const float4*)(src + (size_t)blockIdx.x * 1024);
    float4 q = s4[threadIdx.x];
    float r = blockReduceSum(q.x + q.y + q.z + q.w);
    if (threadIdx.x == 0) dst[blockIdx.x] = r;
}

// weight repack (bf16 fragment-order; conv2 weights fp8)
__global__ __launch_bounds__(256) void k_prep(
    const float* __restrict__ w1, const float* __restrict__ w2,
    const float* __restrict__ phw1, const float* __restrict__ zw1,
    const float* __restrict__ phw2, const float* __restrict__ zw2,
    const float* __restrict__ g2g, const float* __restrict__ g2b,
    const float* __restrict__ w3,
    unsigned short* __restrict__ w1bf, unsigned char* __restrict__ w2f8,
    unsigned short* __restrict__ wh1, unsigned char* __restrict__ wp2,
    unsigned char* __restrict__ wz2, float* __restrict__ prm)
{
    int i = blockIdx.x * 256 + threadIdx.x;     // 0..9215
    if (i < 3072) {
        int o = i / 96, k = i - o * 96;
        int ky = k >> 5, r = k & 31, kx = r >> 3, c = r & 7;
        float v = (kx < 3 && c < 5) ? w1[o * 45 + c * 9 + ky * 3 + kx] : 0.f;
        w1bf[i] = f2bf(v);
    }
    if (i < 9216) {
        int tap = i >> 10, rr = i & 1023, o = rr >> 5, ci = rr & 31;
        w2f8[i] = f2f8(w2[o * 288 + ci * 9 + tap]);
    }
    if (i < 4608) {
        int o = i / 96, k = i - o * 96;
        int ky = k >> 5, r = k & 31, kx = r >> 3, c = r & 7;
        float v = 0.f;
        if (kx < 3 && c < 3)
            v = (o < 16) ? phw1[o * 27 + c * 9 + ky * 3 + kx]
                         : zw1[(o - 16) * 27 + c * 9 + ky * 3 + kx];
        wh1[i] = f2bf(v);
    }
    if (i < 4608) {
        int tap = i / 512, rr = i - tap * 512, n = rr >> 5, k = rr & 31;
        float vp = (n < 3 && k < 16) ? phw2[n * 144 + k * 9 + tap] : 0.f;
        float vz = (n < 3) ? zw2[n * 288 + k * 9 + tap] : 0.f;
        wp2[i] = f2f8(vp);
        wz2[i] = f2f8(vz);
    }
    if (i < 160) {
        if (i < 32) {
            int ch = (i & 1) * 16 + (i >> 1);
            prm[i] = g2g[ch];
        } else if (i < 64) {
            int j = i - 32, ch = (j & 1) * 16 + (j >> 1);
            prm[i] = g2b[ch];
        } else {
            int j = (i - 64) & 31, c = (i - 64) >> 5;
            int ch = (j & 1) * 16 + (j >> 1);
            prm[i] = w3[c * 32 + ch];
        }
    }
}

__global__ __launch_bounds__(256) void k_reduce_x(const float* __restrict__ x,
                                                  float* __restrict__ red) {
    int b = blockIdx.x >> 5, blk = blockIdx.x & 31;
    const float4* xv = (const float4*)(x + (size_t)b * CHW + (size_t)blk * (CHW / 32));
    float s = 0.f, ss = 0.f;
    for (int i = threadIdx.x; i < (CHW / 32) / 4; i += 256) {
        float4 v = xv[i];
        s  += v.x + v.y + v.z + v.w;
        ss += v.x * v.x + v.y * v.y + v.z * v.z + v.w * v.w;
    }
    float rs = blockReduceSum(s);
    float rss = blockReduceSum(ss);
    if (threadIdx.x == 0) { atomicAdd(&red[b], rs); atomicAdd(&red[8 + b], rss); }
}

// ---------------- fused heads (MFMA): xn -> [ph16 | z32] hidden(fp8) -> phi + z partials ----------------
__global__ __launch_bounds__(256) void k_heads(
    const float* __restrict__ x, const float* __restrict__ red,
    const float* __restrict__ ng, const float* __restrict__ nb,
    const unsigned short* __restrict__ wh1,
    const float* __restrict__ phb1, const float* __restrict__ zb1,
    const unsigned char* __restrict__ wp2, const unsigned char* __restrict__ wz2,
    const float* __restrict__ phb2, const float* __restrict__ zb2,
    unsigned short* __restrict__ phi, float* __restrict__ part)
{
    const int tx0 = blockIdx.x * 16, ty0 = blockIdx.y * 16, b = blockIdx.z;
    const int local = blockIdx.y * 32 + blockIdx.x;
    const bool edge = (blockIdx.x == 0) || (blockIdx.x == 31) ||
                      (blockIdx.y == 0) || (blockIdx.y == 31);
    __shared__ unsigned short mt8[20 * 21 * 8];
    __shared__ __attribute__((aligned(16))) unsigned char ht8[324 * 48];  // fp8 hidden; reused as phs/zs
    const int t = threadIdx.x;
    const float mu = red[b] * (1.f / CHW);
    const float rsv = rsqrtf(red[8 + b] * (1.f / CHW) - mu * mu + GEPS);
    float sc[3], sh[3];
    #pragma unroll
    for (int c = 0; c < 3; ++c) { sc[c] = rsv * ng[c]; sh[c] = nb[c] - mu * rsv * ng[c]; }
    if (edge) {
        for (int e = t; e < 20 * 21; e += 256) {
            int yy = e / 21, xx = e - yy * 21;
            int gy = ty0 - 2 + yy, gx = tx0 - 2 + xx;
            float v0 = 0, v1 = 0, v2 = 0;
            if (xx < 20 && (unsigned)gy < (unsigned)Hn && (unsigned)gx < (unsigned)Wn) {
                size_t p = (size_t)b * CHW + (size_t)gy * Wn + gx;
                v0 = x[p] * sc[0] + sh[0];
                v1 = x[p + HW] * sc[1] + sh[1];
                v2 = x[p + 2 * HW] * sc[2] + sh[2];
            }
            *(uint4*)(mt8 + e * 8) = make_uint4(t2(v0, v1), (unsigned)t1(v2), 0u, 0u);
        }
    } else {
        for (int e = t; e < 20 * 21; e += 256) {
            int yy = e / 21, xx = e - yy * 21;
            float v0 = 0, v1 = 0, v2 = 0;
            if (xx < 20) {
                size_t p = (size_t)b * CHW + (size_t)(ty0 - 2 + yy) * Wn + (tx0 - 2 + xx);
                v0 = x[p] * sc[0] + sh[0];
                v1 = x[p + HW] * sc[1] + sh[1];
                v2 = x[p + 2 * HW] * sc[2] + sh[2];
            }
            *(uint4*)(mt8 + e * 8) = make_uint4(t2(v0, v1), (unsigned)t1(v2), 0u, 0u);
        }
    }
    const int wv = t >> 6, lane = t & 63, ln = lane & 15, q = lane >> 4;
    bfx8 Bf[3][3];
    #pragma unroll
    for (int ks = 0; ks < 3; ++ks)
        #pragma unroll
        for (int nt = 0; nt < 3; ++nt)
            Bf[ks][nt] = *(const bfx8*)(wh1 + (nt * 16 + ln) * 96 + ks * 32 + q * 8);
    const float bb0 = phb1[ln], bb1 = zb1[ln], bb2 = zb1[16 + ln];
    __syncthreads();
    // conv1 (bf16 MFMA) -> silu -> ht8 (fp8, zero outside image)
    for (int mt = wv; mt < 21; mt += 4) {
        int p = mt * 16 + ln; if (p > 323) p = 323;
        const int hy = p / 18, hx = p - hy * 18;
        fx4 a0 = {0,0,0,0}, a1 = {0,0,0,0}, a2 = {0,0,0,0};
        #pragma unroll
        for (int ks = 0; ks < 3; ++ks) {
            bfx8 A = *(const bfx8*)(mt8 + ((hy + ks) * 21 + hx + q) * 8);
            a0 = __builtin_amdgcn_mfma_f32_16x16x32_bf16(A, Bf[ks][0], a0, 0, 0, 0);
            a1 = __builtin_amdgcn_mfma_f32_16x16x32_bf16(A, Bf[ks][1], a1, 0, 0, 0);
            a2 = __builtin_amdgcn_mfma_f32_16x16x32_bf16(A, Bf[ks][2], a2, 0, 0, 0);
        }
        const int prb = mt * 16 + q * 4;
        if (edge) {
            #pragma unroll
            for (int r = 0; r < 4; ++r) {
                const int pr = prb + r;
                if (pr < 324) {
                    const int py = pr / 18, px = pr - py * 18;
                    const int gy = ty0 - 1 + py, gx = tx0 - 1 + px;
                    const bool inimg = (unsigned)gy < (unsigned)Hn && (unsigned)gx < (unsigned)Wn;
                    unsigned char* hp = ht8 + pr * 48;
                    hp[ln]      = inimg ? f2f8(siluf(a0[r] + bb0)) : (unsigned char)0;
                    hp[16 + ln] = inimg ? f2f8(siluf(a1[r] + bb1)) : (unsigned char)0;
                    hp[32 + ln] = inimg ? f2f8(siluf(a2[r] + bb2)) : (unsigned char)0;
                }
            }
        } else {
            #pragma unroll
            for (int r = 0; r < 4; ++r) {
                const int pr = prb + r;
                if (pr < 324) {
                    unsigned char* hp = ht8 + pr * 48;
                    hp[ln]      = f2f8(siluf(a0[r] + bb0));
                    hp[16 + ln] = f2f8(siluf(a1[r] + bb1));
                    hp[32 + ln] = f2f8(siluf(a2[r] + bb2));
                }
            }
        }
    }
    __syncthreads();
    // conv2: 9 tap-GEMMs on fp8 MFMA (K=32). ph reads ch0..31 (k>=16 weights zero), z reads ch16..47.
    fx4 accp[4], accz[4];
    #pragma unroll
    for (int i = 0; i < 4; ++i) { accp[i] = fx4{0,0,0,0}; accz[i] = fx4{0,0,0,0}; }
    #pragma unroll
    for (int tap = 0; tap < 9; ++tap) {
        const int ky = tap / 3, kx = tap - ky * 3;
        long Bp = *(const long*)(wp2 + tap * 512 + ln * 32 + q * 8);
        long Bz = *(const long*)(wz2 + tap * 512 + ln * 32 + q * 8);
        #pragma unroll
        for (int i = 0; i < 4; ++i) {
            const int oy = wv * 4 + i;
            const unsigned char* ap = ht8 + ((oy + ky) * 18 + ln + kx) * 48;
            long Ap = *(const long*)(ap + q * 8);
            long Az = *(const long*)(ap + 16 + q * 8);
            accp[i] = __builtin_amdgcn_mfma_f32_16x16x32_fp8_fp8(Ap, Bp, accp[i], 0, 0, 0);
            accz[i] = __builtin_amdgcn_mfma_f32_16x16x32_fp8_fp8(Az, Bz, accz[i], 0, 0, 0);
        }
    }
    // epilogue via LDS (wave-local redistribution): full-lane tanh/sigm, coalesced fp16 stores
    __syncthreads();                       // all conv2 ht8 reads (cross-wave halo) done
    float* phs = (float*)ht8;              // [256][4]
    float* zs  = phs + 1024;               // [256][4]
    if (ln < 3) {
        #pragma unroll
        for (int i = 0; i < 4; ++i)
            #pragma unroll
            for (int r = 0; r < 4; ++r) {
                int pl = (wv * 4 + i) * 16 + q * 4 + r;
                phs[pl * 4 + ln] = accp[i][r];
                zs [pl * 4 + ln] = accz[i][r];
            }
    }
    asm volatile("" ::: "memory");         // writer px rows == reader px rows per wave
    float4 pv = ((const float4*)phs)[t];
    float4 zv = ((const float4*)zs)[t];
    const int gy = ty0 + (t >> 4), gx = tx0 + (t & 15);
    size_t pp = (size_t)b * CHW + (size_t)gy * Wn + gx;
    phi[pp]          = f2h(ftanh(pv.x + phb2[0]) * PIf);
    phi[pp + HW]     = f2h(ftanh(pv.y + phb2[1]) * PIf);
    phi[pp + 2 * HW] = f2h(ftanh(pv.z + phb2[2]) * PIf);
    float z0 = sigm(zv.x + zb2[0]) * 0.3f;
    float z1 = sigm(zv.y + zb2[1]) * 0.3f;
    float z2 = sigm(zv.z + zb2[2]) * 0.3f;
    float r0 = blockReduceSum(z0);
    float r1 = blockReduceSum(z1);
    float r2 = blockReduceSum(z2);
    if (t == 0) {
        part[PZ + (size_t)(b * 3 + 0) * 1024 + local] = r0;
        part[PZ + (size_t)(b * 3 + 1) * 1024 + local] = r1;
        part[PZ + (size_t)(b * 3 + 2) * 1024 + local] = r2;
    }
}

// ---------------- FFT: 512-pt Stockham radix-4 (x4) + radix-2, wave-per-line ----------------
template<bool INV>
DINL float2* fft512_wave4(float2* a, float2* b, const float2* tw, int l)
{
    float2* src = a; float2* dst = b;
    int s = 1;
    #pragma unroll
    for (int st = 0; st < 4; ++st) {
        #pragma unroll
        for (int h = 0; h < 2; ++h) {
            const int i = l + h * 64;          // butterfly index in [0,128)
            const int q = i & (s - 1);
            const int sm = i - q;              // s*m
            float2 A = src[i], B = src[i + 128], C = src[i + 256], D = src[i + 384];
            float t0x = A.x + C.x, t0y = A.y + C.y;
            float t1x = A.x - C.x, t1y = A.y - C.y;
            float t2x = B.x + D.x, t2y = B.y + D.y;
            float t3x = B.x - D.x, t3y = B.y - D.y;
            float i3x = INV ? -t3y : t3y;
            float i3y = INV ? t3x : -t3x;
            float u0x = t0x + t2x, u0y = t0y + t2y;
            float u2x = t0x - t2x, u2y = t0y - t2y;
            float u1x = t1x + i3x, u1y = t1y + i3y;
            float u3x = t1x - i3x, u3y = t1y - i3y;
            float2 w1 = tw[sm], w2 = tw[2 * sm], w3 = tw[3 * sm];
            float w1y = INV ? -w1.y : w1.y;
            float w2y = INV ? -w2.y : w2.y;
            float w3y = INV ? -w3.y : w3.y;
            const int base = q + 4 * sm;
            dst[base]         = make_float2(u0x, u0y);
            dst[base + s]     = make_float2(u1x * w1.x - u1y * w1y, u1x * w1y + u1y * w1.x);
            dst[base + 2 * s] = make_float2(u2x * w2.x - u2y * w2y, u2x * w2y + u2y * w2.x);
            dst[base + 3 * s] = make_float2(u3x * w3.x - u3y * w3y, u3x * w3y + u3y * w3.x);
        }
        float2* tmp = src; src = dst; dst = tmp;
        s <<= 2;
        asm volatile("" ::: "memory");   // wave-synchronous LDS: fence compiler only
    }
    // final radix-2, s=256 (m=0 -> no twiddle)
    #pragma unroll
    for (int h = 0; h < 4; ++h) {
        const int j = l + h * 64;
        float2 u = src[j], v = src[j + 256];
        dst[j]       = make_float2(u.x + v.x, u.y + v.y);
        dst[j + 256] = make_float2(u.x - v.x, u.y - v.y);
    }
    float2* tmp = src; src = dst; dst = tmp;
    asm volatile("" ::: "memory");
    return src;
}

__global__ __launch_bounds__(256) void k_fftA(
    const float* __restrict__ x, const unsigned short* __restrict__ phi,
    unsigned* __restrict__ U)
{
    __shared__ float2 buf[4][2][512];
    __shared__ float2 tw[512];
    const int t = threadIdx.x, wv = t >> 6, l = t & 63;
    #pragma unroll
    for (int i = t; i < 512; i += 256) {
        float s, c; __sincosf(-2.f * PIf * (float)i * (1.f / 512.f), &s, &c);
        tw[i] = make_float2(c, s);
    }
    __syncthreads();
    const size_t line = (size_t)blockIdx.x * 4 + wv;
    const float* xr = x + line * 512;
    const unsigned short* pr = phi + line * 512;
    float2* A = buf[wv][0];
    float2* B = buf[wv][1];
    #pragma unroll
    for (int i = l; i < 512; i += 64) {
        float s, c; __sincosf(h2f(pr[i]), &s, &c);
        float xv = xr[i];
        A[i] = make_float2(xv * c, xv * s);
    }
    asm volatile("" ::: "memory");
    float2* res = fft512_wave4<false>(A, B, tw, l);
    unsigned* Ur = U + line * 512;
    #pragma unroll
    for (int i = l; i < 512; i += 64) Ur[i] = pkh(res[i].x, res[i].y);
}

__global__ __launch_bounds__(256) void k_transpose(unsigned* __restrict__ U)
{
    const int img = blockIdx.y;
    int rem = blockIdx.x, ti = 0;
    while (rem >= 16 - ti) { rem -= 16 - ti; ++ti; }
    const int tj = ti + rem;
    unsigned* Ub = U + (size_t)img * HW;
    __shared__ unsigned ta[32][33];
    __shared__ unsigned tb[32][33];
    const int t = threadIdx.x;
    const int cc = t & 31, r0 = t >> 5;
    const int ar = ti * 32, ac = tj * 32;
    #pragma unroll
    for (int k = 0; k < 4; ++k) {
        int r = r0 + k * 8;
        ta[r][cc] = Ub[(size_t)(ar + r) * 512 + ac + cc];
    }
    if (ti != tj) {
        #pragma unroll
        for (int k = 0; k < 4; ++k) {
            int r = r0 + k * 8;
            tb[r][cc] = Ub[(size_t)(ac + r) * 512 + ar + cc];
        }
    }
    __syncthreads();
    #pragma unroll
    for (int k = 0; k < 4; ++k) {
        int r = r0 + k * 8;
        Ub[(size_t)(ac + r) * 512 + ar + cc] = ta[cc][r];
    }
    if (ti != tj) {
        #pragma unroll
        for (int k = 0; k < 4; ++k) {
            int r = r0 + k * 8;
            Ub[(size_t)(ar + r) * 512 + ac + cc] = tb[cc][r];
        }
    }
}

__global__ __launch_bounds__(256) void k_fftB(
    unsigned* __restrict__ U, const float* __restrict__ red, const float* __restrict__ fgain)
{
    __shared__ float2 buf[4][2][512];
    __shared__ float2 tw[512];
    const int t = threadIdx.x, wv = t >> 6, l = t & 63;
    #pragma unroll
    for (int i = t; i < 512; i += 256) {
        float s, c; __sincosf(-2.f * PIf * (float)i * (1.f / 512.f), &s, &c);
        tw[i] = make_float2(c, s);
    }
    __syncthreads();
    const int line = blockIdx.x * 4 + wv;          // (b*3+c)*512 + fw
    const int bc = line >> 9;
    const int fw = line & 511;
    const int c = bc % 3;
    unsigned* Ur = U + (size_t)line * 512;
    float2* A = buf[wv][0];
    float2* B = buf[wv][1];
    #pragma unroll
    for (int i = l; i < 512; i += 64) A[i] = uph(Ur[i]);
    asm volatile("" ::: "memory");
    float2* res = fft512_wave4<false>(A, B, tw, l);
    const float zm   = red[16 + bc] * (1.f / HW);
    const float gain = 1.f + fgain[c];
    const float lam  = (c == 0) ? 0.65f : (c == 1) ? 0.53f : 0.47f;
    const float il2  = 1.f / (lam * lam);
    const float fwv  = (float)(fw < 256 ? fw : fw - 512) * (1.f / 512.f);
    const float f2w  = fwv * fwv;
    #pragma unroll
    for (int i = l; i < 512; i += 64) {
        float fh = (float)(i < 256 ? i : i - 512) * (1.f / 512.f);
        float kz = 2.f * PIf * sqrtf(fmaxf(il2 - f2w - fh * fh, 0.f));
        float sn, cs; __sincosf(kz * zm, &sn, &cs);
        float2 v = res[i];
        res[i] = make_float2(gain * (v.x * cs - v.y * sn), gain * (v.x * sn + v.y * cs));
    }
    asm volatile("" ::: "memory");
    float2* other = (res == A) ? B : A;
    float2* res2 = fft512_wave4<true>(res, other, tw, l);
    #pragma unroll
    for (int i = l; i < 512; i += 64) {
        float2 v = res2[i];
        Ur[i] = pkh(v.x * (1.f / 512.f), v.y * (1.f / 512.f));
    }
}

__global__ __launch_bounds__(256) void k_fftC(
    const unsigned* __restrict__ U, unsigned short* __restrict__ J)
{
    __shared__ float2 buf[4][2][512];
    __shared__ float2 tw[512];
    const int t = threadIdx.x, wv = t >> 6, l = t & 63;
    #pragma unroll
    for (int i = t; i < 512; i += 256) {
        float s, c; __sincosf(-2.f * PIf * (float)i * (1.f / 512.f), &s, &c);
        tw[i] = make_float2(c, s);
    }
    __syncthreads();
    const size_t line = (size_t)blockIdx.x * 4 + wv;
    const unsigned* Ur = U + line * 512;
    float2* A = buf[wv][0];
    float2* B = buf[wv][1];
    #pragma unroll
    for (int i = l; i < 512; i += 64) A[i] = uph(Ur[i]);
    asm volatile("" ::: "memory");
    float2* res = fft512_wave4<true>(A, B, tw, l);
    unsigned short* Jr = J + line * 512;
    #pragma unroll
    for (int i = l; i < 512; i += 64) {
        float2 v = res[i];
        float re = v.x * (1.f / 512.f), im = v.y * (1.f / 512.f);
        Jr[i] = f2h(sqrtf(fmaxf(re * re + im * im, 1e-12f)));
    }
}

// ---------------- mix path (MFMA) ----------------
__global__ __launch_bounds__(256) void k_m1(
    const float* __restrict__ x, const unsigned short* __restrict__ Jb,
    const unsigned short* __restrict__ w1bf, const float* __restrict__ b1,
    float* __restrict__ part)
{
    const int tx0 = blockIdx.x * 16, ty0 = blockIdx.y * 16, b = blockIdx.z;
    const int local = blockIdx.y * 32 + blockIdx.x;
    const bool edge = (blockIdx.x == 0) || (blockIdx.x == 31) ||
                      (blockIdx.y == 0) || (blockIdx.y == 31);
    __shared__ unsigned short mt8[18 * 19 * 8];
    const int t = threadIdx.x;
    for (int e = t; e < 18 * 19; e += 256) {
        int yy = e / 19, xx = e - yy * 19;
        int gy = ty0 - 1 + yy, gx = tx0 - 1 + xx;
        float v0 = 0, v1 = 0, v2 = 0, jl = 0, d5 = 0;
        bool ok = edge ? (xx < 18 && (unsigned)gy < (unsigned)Hn && (unsigned)gx < (unsigned)Wn)
                       : (xx < 18);
        if (ok) {
            size_t p = (size_t)b * CHW + (size_t)gy * Wn + gx;
            v0 = x[p]; v1 = x[p + HW]; v2 = x[p + 2 * HW];
            float j0 = h2f(Jb[p]), j1 = h2f(Jb[p + HW]), j2 = h2f(Jb[p + 2 * HW]);
            float xl = 0.299f * v0 + 0.587f * v1 + 0.114f * v2;
            jl = 0.299f * j0 + 0.587f * j1 + 0.114f * j2;
            d5 = jl - xl;
        }
        *(uint4*)(mt8 + e * 8) = make_uint4(t2(v0, v1), t2(v2, jl), (unsigned)t1(d5), 0u);
    }
    __syncthreads();
    const int wv = t >> 6, lane = t & 63, ln = lane & 15, q = lane >> 4;
    bfx8 Bf[3][2];
    #pragma unroll
    for (int ks = 0; ks < 3; ++ks)
        #pragma unroll
        for (int nt = 0; nt < 2; ++nt)
            Bf[ks][nt] = *(const bfx8*)(w1bf + (nt * 16 + ln) * 96 + ks * 32 + q * 8);
    const float b1v0 = b1[ln], b1v1 = b1[16 + ln];
    float s = 0.f, ss = 0.f;
    #pragma unroll
    for (int i = 0; i < 4; ++i) {
        const int oy = wv * 4 + i;
        fx4 a0 = {0.f, 0.f, 0.f, 0.f}, a1 = {0.f, 0.f, 0.f, 0.f};
        #pragma unroll
        for (int ks = 0; ks < 3; ++ks) {
            bfx8 A = *(const bfx8*)(mt8 + ((oy + ks) * 19 + ln + q) * 8);
            a0 = __builtin_amdgcn_mfma_f32_16x16x32_bf16(A, Bf[ks][0], a0, 0, 0, 0);
            a1 = __builtin_amdgcn_mfma_f32_16x16x32_bf16(A, Bf[ks][1], a1, 0, 0, 0);
        }
        #pragma unroll
        for (int r = 0; r < 4; ++r) {
            float u0 = a0[r] + b1v0, u1 = a1[r] + b1v1;
            s += u0 + u1; ss += u0 * u0 + u1 * u1;
        }
    }
    float rs = blockReduceSum(s);
    float rss = blockReduceSum(ss);
    if (t == 0) {
        part[PG1 + (size_t)b * 1024 + local] = rs;
        part[PG1 + (size_t)(8 + b) * 1024 + local] = rss;
    }
}

// conv1(bf16) -> gn1 -> silu -> conv2(fp8 MFMA); y2 fp8 channel-last + gn2 partials
__global__ __launch_bounds__(256) void k_m2(
    const float* __restrict__ x, const unsigned short* __restrict__ Jb,
    const unsigned short* __restrict__ w1bf, const float* __restrict__ b1,
    const float* __restrict__ g1g, const float* __restrict__ g1b,
    const unsigned char* __restrict__ w2f8, const float* __restrict__ b2,
    const float* __restrict__ red, float* __restrict__ part,
    unsigned char* __restrict__ y2)
{
    const int tx0 = blockIdx.x * 16, ty0 = blockIdx.y * 16, b = blockIdx.z;
    const int local = blockIdx.y * 32 + blockIdx.x;
    const bool edge = (blockIdx.x == 0) || (blockIdx.x == 31) ||
                      (blockIdx.y == 0) || (blockIdx.y == 31);
    __shared__ unsigned short mt8[20 * 21 * 8];
    __shared__ __attribute__((aligned(16))) unsigned char dt2[324 * 40];  // fp8 hidden (32ch + 8 pad)
    const int t = threadIdx.x;
    const float mu1 = red[40 + b] * (1.f / (32.f * HW));
    const float rs1 = rsqrtf(red[48 + b] * (1.f / (32.f * HW)) - mu1 * mu1 + GEPS);
    for (int e = t; e < 20 * 21; e += 256) {
        int yy = e / 21, xx = e - yy * 21;
        int gy = ty0 - 2 + yy, gx = tx0 - 2 + xx;
        float v0 = 0, v1 = 0, v2 = 0, jl = 0, d5 = 0;
        bool ok = edge ? (xx < 20 && (unsigned)gy < (unsigned)Hn && (unsigned)gx < (unsigned)Wn)
                       : (xx < 20);
        if (ok) {
            size_t p = (size_t)b * CHW + (size_t)gy * Wn + gx;
            v0 = x[p]; v1 = x[p + HW]; v2 = x[p + 2 * HW];
            float j0 = h2f(Jb[p]), j1 = h2f(Jb[p + HW]), j2 = h2f(Jb[p + 2 * HW]);
            float xl = 0.299f * v0 + 0.587f * v1 + 0.114f * v2;
            jl = 0.299f * j0 + 0.587f * j1 + 0.114f * j2;
            d5 = jl - xl;
        }
        *(uint4*)(mt8 + e * 8) = make_uint4(t2(v0, v1), t2(v2, jl), (unsigned)t1(d5), 0u);
    }
    const int wv = t >> 6, lane = t & 63, ln = lane & 15, q = lane >> 4;
    const float sc0 = rs1 * g1g[ln],       sc1 = rs1 * g1g[16 + ln];
    const float of0 = (b1[ln] - mu1) * sc0 + g1b[ln];
    const float of1 = (b1[16 + ln] - mu1) * sc1 + g1b[16 + ln];
    bfx8 Bf[3][2];
    #pragma unroll
    for (int ks = 0; ks < 3; ++ks)
        #pragma unroll
        for (int nt = 0; nt < 2; ++nt)
            Bf[ks][nt] = *(const bfx8*)(w1bf + (nt * 16 + ln) * 96 + ks * 32 + q * 8);
    __syncthreads();
    for (int mt = wv; mt < 21; mt += 4) {
        int p = mt * 16 + ln; if (p > 323) p = 323;
        const int hy = p / 18, hx = p - hy * 18;
        fx4 a0 = {0.f, 0.f, 0.f, 0.f}, a1 = {0.f, 0.f, 0.f, 0.f};
        #pragma unroll
        for (int ks = 0; ks < 3; ++ks) {
            bfx8 A = *(const bfx8*)(mt8 + ((hy + ks) * 21 + hx + q) * 8);
            a0 = __builtin_amdgcn_mfma_f32_16x16x32_bf16(A, Bf[ks][0], a0, 0, 0, 0);
            a1 = __builtin_amdgcn_mfma_f32_16x16x32_bf16(A, Bf[ks][1], a1, 0, 0, 0);
        }
        const int prb = mt * 16 + q * 4;
        if (edge) {
            #pragma unroll
            for (int r = 0; r < 4; ++r) {
                const int pr = prb + r;
                if (pr < 324) {
                    const int py = pr / 18, px = pr - py * 18;
                    const int gy = ty0 - 1 + py, gx = tx0 - 1 + px;
                    const bool inimg = (unsigned)gy < (unsigned)Hn && (unsigned)gx < (unsigned)Wn;
                    dt2[pr * 40 + ln]      = inimg ? f2f8(siluf(a0[r] * sc0 + of0)) : (unsigned char)0;
                    dt2[pr * 40 + 16 + ln] = inimg ? f2f8(siluf(a1[r] * sc1 + of1)) : (unsigned char)0;
                }
            }
        } else {
            #pragma unroll
            for (int r = 0; r < 4; ++r) {
                const int pr = prb + r;
                if (pr < 324) {
                    dt2[pr * 40 + ln]      = f2f8(siluf(a0[r] * sc0 + of0));
                    dt2[pr * 40 + 16 + ln] = f2f8(siluf(a1[r] * sc1 + of1));
                }
            }
        }
    }
    __syncthreads();
    fx4 c2[4][2];
    #pragma unroll
    for (int i = 0; i < 4; ++i)
        #pragma unroll
        for (int nt = 0; nt < 2; ++nt)
            c2[i][nt] = fx4{0.f, 0.f, 0.f, 0.f};
    #pragma unroll
    for (int tap = 0; tap < 9; ++tap) {
        const int ky = tap / 3, kx = tap - ky * 3;
        long B0 = *(const long*)(w2f8 + tap * 1024 + ln * 32 + q * 8);
        long B1 = *(const long*)(w2f8 + tap * 1024 + (16 + ln) * 32 + q * 8);
        #pragma unroll
        for (int i = 0; i < 4; ++i) {
            const int oy = wv * 4 + i;
            long A = *(const long*)(dt2 + ((oy + ky) * 18 + ln + kx) * 40 + q * 8);
            c2[i][0] = __builtin_amdgcn_mfma_f32_16x16x32_fp8_fp8(A, B0, c2[i][0], 0, 0, 0);
            c2[i][1] = __builtin_amdgcn_mfma_f32_16x16x32_fp8_fp8(A, B1, c2[i][1], 0, 0, 0);
        }
    }
    float s = 0.f, ss = 0.f;
    const float b2v0 = b2[ln], b2v1 = b2[16 + ln];
    #pragma unroll
    for (int i = 0; i < 4; ++i) {
        const int gy = ty0 + wv * 4 + i;
        #pragma unroll
        for (int r = 0; r < 4; ++r) {
            const int gx = tx0 + q * 4 + r;
            float a0 = c2[i][0][r] + b2v0;
            float a1 = c2[i][1][r] + b2v1;
            s += a0 + a1; ss += a0 * a0 + a1 * a1;
            size_t off = ((size_t)b * HW + (size_t)gy * Wn + gx) * 32 + ln * 2;
            *(unsigned short*)(y2 + off) = pk8(a0, a1);
        }
    }
    float rsum = blockReduceSum(s);
    float rss = blockReduceSum(ss);
    if (t == 0) {
        part[PG2 + (size_t)b * 1024 + local] = rsum;
        part[PG2 + (size_t)(8 + b) * 1024 + local] = rss;
    }
}

// gn2 -> silu -> 1x1 conv; fp8 channel-last y2; dl fp16; dsum partials (no atomics)
__global__ __launch_bounds__(256) void k_m3(
    const unsigned char* __restrict__ y2, const float* __restrict__ red,
    const float* __restrict__ prm, const float* __restrict__ b3,
    unsigned short* __restrict__ dl, float* __restrict__ part)
{
    int idx = blockIdx.x * 256 + threadIdx.x;     // global pixel (b*HW+pix)
    int b = idx >> 18;
    int pix = idx & (HW - 1);
    const int local = blockIdx.x & 1023;
    float mu = red[56 + b] * (1.f / (32.f * HW));
    float rs = rsqrtf(red[64 + b] * (1.f / (32.f * HW)) - mu * mu + GEPS);
    const uint4* yp = (const uint4*)(y2 + (size_t)idx * 32);
    uint4 L0 = yp[0], L1 = yp[1];
    unsigned Lw[8] = {L0.x, L0.y, L0.z, L0.w, L1.x, L1.y, L1.z, L1.w};
    float a0 = b3[0], a1 = b3[1], a2 = b3[2];
    #pragma unroll
    for (int w = 0; w < 8; ++w) {     // 8 dwords x 4 fp8 = 32 channels
        unsigned u = Lw[w];
        float vv[4] = { f8f<0>(u), f8f<1>(u), f8f<2>(u), f8f<3>(u) };
        #pragma unroll
        for (int h = 0; h < 4; ++h) {
            int j = w * 4 + h;
            float dn = (vv[h] - mu) * rs * prm[j] + prm[32 + j];
            float sv = siluf(dn);
            a0 += sv * prm[64 + j]; a1 += sv * prm[96 + j]; a2 += sv * prm[128 + j];
        }
    }
    size_t p = (size_t)b * CHW + pix;
    dl[p] = f2h(a0); dl[p + HW] = f2h(a1); dl[p + 2 * HW] = f2h(a2);
    float r0 = blockReduceSum(a0);
    float r1 = blockReduceSum(a1);
    float r2 = blockReduceSum(a2);
    if (threadIdx.x == 0) {
        part[PD + (size_t)(b * 3 + 0) * 1024 + local] = r0;
        part[PD + (size_t)(b * 3 + 1) * 1024 + local] = r1;
        part[PD + (size_t)(b * 3 + 2) * 1024 + local] = r2;
    }
}

__global__ void k_se(float* __restrict__ red,
    const float* __restrict__ w1, const float* __restrict__ b1,
    const float* __restrict__ w2, const float* __restrict__ b2,
    const float* __restrict__ alpha)
{
    int b = threadIdx.x;
    if (b < 8) {
        float p0 = red[72 + b * 3 + 0] * (1.f / HW);
        float p1 = red[72 + b * 3 + 1] * (1.f / HW);
        float p2 = red[72 + b * 3 + 2] * (1.f / HW);
        float h[4];
        #pragma unroll
        for (int j = 0; j < 4; ++j) {
            float a = b1[j] + p0 * w1[j * 3] + p1 * w1[j * 3 + 1] + p2 * w1[j * 3 + 2];
            h[j] = siluf(a);
        }
        float al = alpha[0];
        #pragma unroll
        for (int c = 0; c < 3; ++c) {
            float a = b2[c] + h[0] * w2[c * 4] + h[1] * w2[c * 4 + 1]
                            + h[2] * w2[c * 4 + 2] + h[3] * w2[c * 4 + 3];
            red[96 + b * 3 + c] = al * sigm(a);
        }
    }
}

__global__ __launch_bounds__(256) void k_out(
    const float* __restrict__ x, const unsigned short* __restrict__ dl,
    const float* __restrict__ red, float* __restrict__ out)
{
    int i = blockIdx.x * 256 + threadIdx.x;     // float4 index
    float aw = red[96 + (i >> 16)];
    float4 xv = ((const float4*)x)[i];
    uint2 dv2 = ((const uint2*)dl)[i];          // 4 fp16
    float2 d01 = uph(dv2.x);
    float2 d23 = uph(dv2.y);
    float4 o;
    o.x = xv.x + aw * d01.x; o.y = xv.y + aw * d01.y;
    o.z = xv.z + aw * d23.x; o.w = xv.w + aw * d23.y;
    ((float4*)out)[i] = o;
}

extern "C" void kernel_launch(void* const* d_in, const int* in_sizes, int n_in,
                              void* d_out, int out_size, void* d_ws, size_t ws_size,
                              hipStream_t stream)
{
    const float* x     = (const float*)d_in[0];
    const float* ng    = (const float*)d_in[1];
    const float* nb    = (const float*)d_in[2];
    const float* ph_w1 = (const float*)d_in[3];
    const float* ph_b1 = (const float*)d_in[4];
    const float* ph_w2 = (const float*)d_in[5];
    const float* ph_b2 = (const float*)d_in[6];
    const float* z_w1  = (const float*)d_in[7];
    const float* z_b1  = (const float*)d_in[8];
    const float* z_w2  = (const float*)d_in[9];
    const float* z_b2  = (const float*)d_in[10];
    const float* fgain = (const float*)d_in[11];
    const float* mw1   = (const float*)d_in[12];
    const float* mb1   = (const float*)d_in[13];
    const float* g1g   = (const float*)d_in[14];
    const float* g1b   = (const float*)d_in[15];
    const float* mw2   = (const float*)d_in[16];
    const float* mb2   = (const float*)d_in[17];
    const float* g2g   = (const float*)d_in[18];
    const float* g2b   = (const float*)d_in[19];
    const float* mw3   = (const float*)d_in[20];
    const float* mb3   = (const float*)d_in[21];
    const float* sw1   = (const float*)d_in[22];
    const float* sb1   = (const float*)d_in[23];
    const float* sw2   = (const float*)d_in[24];
    const float* sb2   = (const float*)d_in[25];
    const float* alpha = (const float*)d_in[26];

    char* ws = (char*)d_ws;
    float*  red = (float*)(ws + OFF_RED);
    unsigned short* phi = (unsigned short*)(ws + OFF_PHI);
    unsigned* U = (unsigned*)(ws + OFF_U);
    unsigned short* Jb = (unsigned short*)(ws + OFF_J);
    unsigned short* dl = (unsigned short*)(ws + OFF_D);
    unsigned char*  y2   = (unsigned char*)(ws + OFF_Y2);
    unsigned short* w1bf = (unsigned short*)(ws + OFF_W1B);
    unsigned char*  w2f8 = (unsigned char*)(ws + OFF_W2F);
    unsigned short* wh1  = (unsigned short*)(ws + OFF_WH1);
    unsigned char*  wp2  = (unsigned char*)(ws + OFF_WP2);
    unsigned char*  wz2  = (unsigned char*)(ws + OFF_WZ2);
    float* prm  = (float*)(ws + OFF_PRM);
    float* part = (float*)(ws + OFF_PART);
    float* out = (float*)d_out;

    hipLaunchKernelGGL(k_zero, dim3(1), dim3(128), 0, stream, red);
    hipLaunchKernelGGL(k_prep, dim3(36), dim3(256), 0, stream,
                       mw1, mw2, ph_w1, z_w1, ph_w2, z_w2, g2g, g2b, mw3,
                       w1bf, w2f8, wh1, wp2, wz2, prm);
    hipLaunchKernelGGL(k_reduce_x, dim3(256), dim3(256), 0, stream, x, red);
    hipLaunchKernelGGL(k_heads, dim3(32, 32, 8), dim3(256), 0, stream,
                       x, red, ng, nb, wh1, ph_b1, z_b1, wp2, wz2, ph_b2, z_b2, phi, part);
    hipLaunchKernelGGL(k_red, dim3(24), dim3(256), 0, stream, part + PZ, red + 16);
    hipLaunchKernelGGL(k_fftA, dim3(3072), dim3(256), 0, stream, x, phi, U);
    hipLaunchKernelGGL(k_transpose, dim3(136, 24), dim3(256), 0, stream, U);
    hipLaunchKernelGGL(k_fftB, dim3(3072), dim3(256), 0, stream, U, red, fgain);
    hipLaunchKernelGGL(k_transpose, dim3(136, 24), dim3(256), 0, stream, U);
    hipLaunchKernelGGL(k_fftC, dim3(3072), dim3(256), 0, stream, U, Jb);
    hipLaunchKernelGGL(k_m1, dim3(32, 32, 8), dim3(256), 0, stream, x, Jb, w1bf, mb1, part);
    hipLaunchKernelGGL(k_red, dim3(16), dim3(256), 0, stream, part + PG1, red + 40);
    hipLaunchKernelGGL(k_m2, dim3(32, 32, 8), dim3(256), 0, stream,
                       x, Jb, w1bf, mb1, g1g, g1b, w2f8, mb2, red, part, y2);
    hipLaunchKernelGGL(k_red, dim3(16), dim3(256), 0, stream, part + PG2, red + 56);
    hipLaunchKernelGGL(k_m3, dim3(8192), dim3(256), 0, stream, y2, red, prm, mb3, dl, part);
    hipLaunchKernelGGL(k_red, dim3(24), dim3(256), 0, stream, part + PD, red + 72);
    hipLaunchKernelGGL(k_se, dim3(1), dim3(64), 0, stream, red, sw1, sb1, sw2, sb2, alpha);
    hipLaunchKernelGGL(k_out, dim3(6144), dim3(256), 0, stream, x, dl, red, out);
}